// Round 1
// baseline (3354.940 us; speedup 1.0000x reference)
//
#include <hip/hip_runtime.h>
#include <hip/hip_bf16.h>
#include <math.h>
#include <stdint.h>

#define B 2
#define S 4095
#define LSEQ 4096
#define F_IN 32
#define D 512
#define H 8
#define E 64
#define DFF 2048
#define NL 2
#define U 45
#define EPSL 1e-5f
#define LU (LSEQ * U)
#define HALF_LU (LU / 2)

// ---------------- Threefry-2x32 (20 rounds), exactly JAX's algorithm ----------------
__device__ __forceinline__ uint32_t rotl32(uint32_t x, int r) {
    return (x << r) | (x >> (32 - r));
}

__device__ void threefry2x32(uint32_t k0, uint32_t k1, uint32_t c0, uint32_t c1,
                             uint32_t& o0, uint32_t& o1) {
    uint32_t ks2 = k0 ^ k1 ^ 0x1BD11BDAu;
    uint32_t x0 = c0 + k0, x1 = c1 + k1;
    // group 1: rotations {13,15,26,6}, inject (k1, ks2+1)
    x0 += x1; x1 = rotl32(x1, 13); x1 ^= x0;
    x0 += x1; x1 = rotl32(x1, 15); x1 ^= x0;
    x0 += x1; x1 = rotl32(x1, 26); x1 ^= x0;
    x0 += x1; x1 = rotl32(x1, 6);  x1 ^= x0;
    x0 += k1; x1 += ks2 + 1u;
    // group 2: {17,29,16,24}, inject (ks2, k0+2)
    x0 += x1; x1 = rotl32(x1, 17); x1 ^= x0;
    x0 += x1; x1 = rotl32(x1, 29); x1 ^= x0;
    x0 += x1; x1 = rotl32(x1, 16); x1 ^= x0;
    x0 += x1; x1 = rotl32(x1, 24); x1 ^= x0;
    x0 += ks2; x1 += k0 + 2u;
    // group 3: {13,15,26,6}, inject (k0, k1+3)
    x0 += x1; x1 = rotl32(x1, 13); x1 ^= x0;
    x0 += x1; x1 = rotl32(x1, 15); x1 ^= x0;
    x0 += x1; x1 = rotl32(x1, 26); x1 ^= x0;
    x0 += x1; x1 = rotl32(x1, 6);  x1 ^= x0;
    x0 += k0; x1 += k1 + 3u;
    // group 4: {17,29,16,24}, inject (k1, ks2+4)
    x0 += x1; x1 = rotl32(x1, 17); x1 ^= x0;
    x0 += x1; x1 = rotl32(x1, 29); x1 ^= x0;
    x0 += x1; x1 = rotl32(x1, 16); x1 ^= x0;
    x0 += x1; x1 = rotl32(x1, 24); x1 ^= x0;
    x0 += k1; x1 += ks2 + 4u;
    // group 5: {13,15,26,6}, inject (ks2, k0+5)
    x0 += x1; x1 = rotl32(x1, 13); x1 ^= x0;
    x0 += x1; x1 = rotl32(x1, 15); x1 ^= x0;
    x0 += x1; x1 = rotl32(x1, 26); x1 ^= x0;
    x0 += x1; x1 = rotl32(x1, 6);  x1 ^= x0;
    x0 += ks2; x1 += k0 + 5u;
    o0 = x0; o1 = x1;
}

// idx[l][t] = lower_bits % 4096, reproducing jax.random.randint of shape (L, U)
__global__ void idx_kernel(int* __restrict__ idx, int layer) {
    int j = blockIdx.x * blockDim.x + threadIdx.x;
    if (j >= HALF_LU) return;
    uint32_t f0, f1, a0, a1, b0, b1, o0, o1;
    // fold_in(key(42), layer): threefry(key=(0,42), count=(0,layer))
    threefry2x32(0u, 42u, 0u, (uint32_t)layer, f0, f1);
    // split: counts [0,1,2,3] -> pairs (0,2),(1,3); k2 = (o1_pair0, o1_pair1)
    threefry2x32(f0, f1, 0u, 2u, a0, a1);
    threefry2x32(f0, f1, 1u, 3u, b0, b1);
    // lower bits = random_bits(k2, 32, (L,U)); element i pairs (j, j+HALF)
    threefry2x32(a1, b1, (uint32_t)j, (uint32_t)(j + HALF_LU), o0, o1);
    idx[j] = (int)(o0 & 4095u);
    idx[j + HALF_LU] = (int)(o1 & 4095u);
}

// ---------------- embed + cls + positional encoding ----------------
__global__ void embed_kernel(const float* __restrict__ x, const float* __restrict__ We,
                             const float* __restrict__ be, const float* __restrict__ cls,
                             float* __restrict__ h) {
    int gid = blockIdx.x * blockDim.x + threadIdx.x;
    if (gid >= B * LSEQ * D) return;
    int d = gid % D;
    int l = (gid / D) % LSEQ;
    int b = gid / (D * LSEQ);
    float v;
    if (l == 0) {
        v = cls[d];
    } else {
        const float* xr = x + ((size_t)b * S + (l - 1)) * F_IN;
        const float* wr = We + (size_t)d * F_IN;
        float acc = 0.f;
#pragma unroll
        for (int i = 0; i < F_IN; ++i) acc += xr[i] * wr[i];
        v = acc + be[d];
    }
    int i = d >> 1;
    float divv = expf((float)(2 * i) * (float)(-9.210340371976184 / 512.0));
    float ang = (float)l * divv;
    v += (d & 1) ? cosf(ang) : sinf(ang);
    h[gid] = v;
}

// ---------------- generic f32 GEMM: C[M,N] = A[M,K] @ W[N,K]^T + bias[N] ----------------
// M % 64 == 0, N % 64 == 0, K % 16 == 0
template <int ACT>
__global__ __launch_bounds__(256) void gemm_bias(const float* __restrict__ A,
                                                 const float* __restrict__ W,
                                                 const float* __restrict__ bias,
                                                 float* __restrict__ C,
                                                 int M, int N, int K) {
    __shared__ float As[64][17];
    __shared__ float Ws[64][17];
    int tid = threadIdx.x;
    int m0 = blockIdx.y * 64, n0 = blockIdx.x * 64;
    int lr = tid >> 2, lc = (tid & 3) * 4;
    int ty = tid >> 4, tx = tid & 15;
    float acc[4][4] = {};
    for (int k0 = 0; k0 < K; k0 += 16) {
        float4 av = *(const float4*)(A + (size_t)(m0 + lr) * K + k0 + lc);
        float4 wv = *(const float4*)(W + (size_t)(n0 + lr) * K + k0 + lc);
        __syncthreads();
        As[lr][lc] = av.x; As[lr][lc + 1] = av.y; As[lr][lc + 2] = av.z; As[lr][lc + 3] = av.w;
        Ws[lr][lc] = wv.x; Ws[lr][lc + 1] = wv.y; Ws[lr][lc + 2] = wv.z; Ws[lr][lc + 3] = wv.w;
        __syncthreads();
#pragma unroll
        for (int kk = 0; kk < 16; ++kk) {
            float a[4], w[4];
#pragma unroll
            for (int i = 0; i < 4; ++i) a[i] = As[ty * 4 + i][kk];
#pragma unroll
            for (int j = 0; j < 4; ++j) w[j] = Ws[tx * 4 + j][kk];
#pragma unroll
            for (int i = 0; i < 4; ++i)
#pragma unroll
                for (int j = 0; j < 4; ++j) acc[i][j] += a[i] * w[j];
        }
    }
#pragma unroll
    for (int i = 0; i < 4; ++i) {
        int m = m0 + ty * 4 + i;
#pragma unroll
        for (int j = 0; j < 4; ++j) {
            int n = n0 + tx * 4 + j;
            float v = acc[i][j] + bias[n];
            if (ACT == 1) v = fmaxf(v, 0.f);
            C[(size_t)m * N + n] = v;
        }
    }
}

// ---------------- M-score: one wave per (b,h,l) ----------------
__global__ __launch_bounds__(256) void mscore_kernel(const float* __restrict__ q,
                                                     const float* __restrict__ k,
                                                     const int* __restrict__ idx,
                                                     float* __restrict__ Mv) {
    int wid = (blockIdx.x * blockDim.x + threadIdx.x) >> 6;
    int lane = threadIdx.x & 63;
    int l = wid % LSEQ;
    int hh = (wid / LSEQ) % H;
    int b = wid / (LSEQ * H);
    float s = -INFINITY, ssum = 0.f;
    const float* qr = q + ((size_t)b * LSEQ + l) * D + hh * E;
    if (lane < U) {
        int kr = idx[l * U + lane];
        const float* kp = k + ((size_t)b * LSEQ + kr) * D + hh * E;
        float acc = 0.f;
#pragma unroll
        for (int e = 0; e < E; e += 4) {
            float4 qa = *(const float4*)(qr + e);
            float4 kb = *(const float4*)(kp + e);
            acc += qa.x * kb.x + qa.y * kb.y + qa.z * kb.z + qa.w * kb.w;
        }
        s = acc; ssum = acc;
    }
    for (int off = 32; off; off >>= 1) {
        s = fmaxf(s, __shfl_xor(s, off));
        ssum += __shfl_xor(ssum, off);
    }
    if (lane == 0) Mv[wid] = s - ssum / (float)LSEQ;
}

// ---------------- top-k (u=45) per (b,h), JAX tie semantics ----------------
__global__ __launch_bounds__(256) void topk_kernel(const float* __restrict__ Mv,
                                                   int* __restrict__ top) {
    __shared__ float buf[LSEQ];
    __shared__ float rv[256];
    __shared__ int ri[256];
    int bh = blockIdx.x;
    const float* mrow = Mv + (size_t)bh * LSEQ;
    for (int i = threadIdx.x; i < LSEQ; i += 256) buf[i] = mrow[i];
    __syncthreads();
    for (int t = 0; t < U; ++t) {
        float bv = -INFINITY;
        int bi = LSEQ;
        for (int i = threadIdx.x; i < LSEQ; i += 256) {
            float v = buf[i];
            if (v > bv) { bv = v; bi = i; }
        }
        rv[threadIdx.x] = bv; ri[threadIdx.x] = bi;
        __syncthreads();
        for (int sft = 128; sft; sft >>= 1) {
            if (threadIdx.x < sft) {
                float v2 = rv[threadIdx.x + sft];
                int i2 = ri[threadIdx.x + sft];
                if (v2 > rv[threadIdx.x] || (v2 == rv[threadIdx.x] && i2 < ri[threadIdx.x])) {
                    rv[threadIdx.x] = v2; ri[threadIdx.x] = i2;
                }
            }
            __syncthreads();
        }
        if (threadIdx.x == 0) {
            top[bh * U + t] = ri[0];
            buf[ri[0]] = -INFINITY;
        }
        __syncthreads();
    }
}

// ---------------- v mean over L per (b,h,e) ----------------
__global__ void vmean_kernel(const float* __restrict__ v, float* __restrict__ vm) {
    int gid = blockIdx.x * blockDim.x + threadIdx.x;
    if (gid >= B * H * E) return;
    int e = gid % E;
    int hh = (gid / E) % H;
    int b = gid / (E * H);
    const float* vp = v + (size_t)b * LSEQ * D + hh * E + e;
    float acc = 0.f;
    for (int l = 0; l < LSEQ; ++l) acc += vp[(size_t)l * D];
    vm[gid] = acc / (float)LSEQ;
}

// ---------------- ctx = broadcast vmean ----------------
__global__ void fill_ctx(const float* __restrict__ vm, float* __restrict__ ctx) {
    int gid = blockIdx.x * blockDim.x + threadIdx.x;
    if (gid >= B * LSEQ * D) return;
    int d = gid % D;
    int b = gid / (D * LSEQ);
    int hh = d >> 6, e = d & 63;
    ctx[gid] = vm[(b * H + hh) * E + e];
}

// ---------------- full attention for selected rows; writes ctx directly ----------------
__global__ __launch_bounds__(256) void attn_kernel(const float* __restrict__ q,
                                                   const float* __restrict__ k,
                                                   const float* __restrict__ v,
                                                   const int* __restrict__ top,
                                                   float* __restrict__ ctx) {
    __shared__ float sc[LSEQ];
    __shared__ float qs[E];
    __shared__ float red[256];
    __shared__ float part[4][E];
    int bid = blockIdx.x;  // B*H*U
    int t = bid % U;
    int hh = (bid / U) % H;
    int b = bid / (U * H);
    int r = top[(b * H + hh) * U + t];
    int tid = threadIdx.x;
    if (tid < E) qs[tid] = q[((size_t)b * LSEQ + r) * D + hh * E + tid];
    __syncthreads();
    for (int kk = tid; kk < LSEQ; kk += 256) {
        const float* kp = k + ((size_t)b * LSEQ + kk) * D + hh * E;
        float acc = 0.f;
#pragma unroll
        for (int e = 0; e < E; e += 4) {
            float4 kb = *(const float4*)(kp + e);
            acc += qs[e] * kb.x + qs[e + 1] * kb.y + qs[e + 2] * kb.z + qs[e + 3] * kb.w;
        }
        sc[kk] = acc * 0.125f;  // / sqrt(64)
    }
    __syncthreads();
    float m = -INFINITY;
    for (int kk = tid; kk < LSEQ; kk += 256) m = fmaxf(m, sc[kk]);
    red[tid] = m;
    __syncthreads();
    for (int sft = 128; sft; sft >>= 1) {
        if (tid < sft) red[tid] = fmaxf(red[tid], red[tid + sft]);
        __syncthreads();
    }
    m = red[0];
    __syncthreads();
    float sum = 0.f;
    for (int kk = tid; kk < LSEQ; kk += 256) {
        float ev = expf(sc[kk] - m);
        sc[kk] = ev;
        sum += ev;
    }
    red[tid] = sum;
    __syncthreads();
    for (int sft = 128; sft; sft >>= 1) {
        if (tid < sft) red[tid] += red[tid + sft];
        __syncthreads();
    }
    float inv = 1.f / red[0];
    int e = tid & 63, seg = tid >> 6;
    float acc = 0.f;
    const float* vp = v + (size_t)b * LSEQ * D + hh * E + e;
    for (int kk = seg * 1024; kk < (seg + 1) * 1024; ++kk) acc += sc[kk] * vp[(size_t)kk * D];
    part[seg][e] = acc;
    __syncthreads();
    if (tid < E) {
        float uval = (part[0][tid] + part[1][tid] + part[2][tid] + part[3][tid]) * inv;
        ctx[((size_t)b * LSEQ + r) * D + hh * E + tid] = uval;
    }
}

// ---------------- h = LayerNorm(h + a) * g + b, one wave per row ----------------
__global__ __launch_bounds__(64) void add_ln_kernel(float* __restrict__ h,
                                                    const float* __restrict__ a,
                                                    const float* __restrict__ g,
                                                    const float* __restrict__ bb) {
    int row = blockIdx.x;
    int lane = threadIdx.x;
    float* hp = h + (size_t)row * D;
    const float* ap = a + (size_t)row * D;
    float x[8];
    float sum = 0.f;
#pragma unroll
    for (int j = 0; j < 8; ++j) {
        x[j] = hp[lane + 64 * j] + ap[lane + 64 * j];
        sum += x[j];
    }
    for (int off = 32; off; off >>= 1) sum += __shfl_xor(sum, off);
    float mu = sum / (float)D;
    float vs = 0.f;
#pragma unroll
    for (int j = 0; j < 8; ++j) {
        float dd = x[j] - mu;
        vs += dd * dd;
    }
    for (int off = 32; off; off >>= 1) vs += __shfl_xor(vs, off);
    float inv = 1.f / sqrtf(vs / (float)D + EPSL);
#pragma unroll
    for (int j = 0; j < 8; ++j)
        hp[lane + 64 * j] = (x[j] - mu) * inv * g[lane + 64 * j] + bb[lane + 64 * j];
}

// ---------------- final head: out[b] = h[b,0,:] . Wf + bf ----------------
__global__ void final_kernel(const float* __restrict__ h, const float* __restrict__ Wf,
                             const float* __restrict__ bf, float* __restrict__ out) {
    int b = blockIdx.x;
    int lane = threadIdx.x;
    const float* hp = h + (size_t)b * LSEQ * D;
    float acc = 0.f;
    for (int j = lane; j < D; j += 64) acc += hp[j] * Wf[j];
    for (int off = 32; off; off >>= 1) acc += __shfl_xor(acc, off);
    if (lane == 0) out[b] = acc + bf[0];
}

extern "C" void kernel_launch(void* const* d_in, const int* in_sizes, int n_in,
                              void* d_out, int out_size, void* d_ws, size_t ws_size,
                              hipStream_t stream) {
    (void)in_sizes; (void)n_in; (void)out_size; (void)ws_size;
    const float* x   = (const float*)d_in[0];
    const float* We  = (const float*)d_in[1];
    const float* be  = (const float*)d_in[2];
    const float* cls = (const float*)d_in[3];
    const float* Wq  = (const float*)d_in[4];
    const float* bq  = (const float*)d_in[5];
    const float* Wk  = (const float*)d_in[6];
    const float* bk  = (const float*)d_in[7];
    const float* Wv  = (const float*)d_in[8];
    const float* bv  = (const float*)d_in[9];
    const float* Wo  = (const float*)d_in[10];
    const float* bo  = (const float*)d_in[11];
    const float* g1  = (const float*)d_in[12];
    const float* b1  = (const float*)d_in[13];
    const float* g2  = (const float*)d_in[14];
    const float* b2  = (const float*)d_in[15];
    const float* W1  = (const float*)d_in[16];
    const float* bf1 = (const float*)d_in[17];
    const float* W2  = (const float*)d_in[18];
    const float* bf2 = (const float*)d_in[19];
    const float* Wf  = (const float*)d_in[20];
    const float* bff = (const float*)d_in[21];
    float* out = (float*)d_out;

    float* ws = (float*)d_ws;
    const size_t NT = (size_t)B * LSEQ * D;  // 4,194,304 floats
    float* h    = ws;
    float* aout = ws + NT;
    float* q    = ws + 2 * NT;
    float* kbuf = ws + 3 * NT;
    float* vbuf = ws + 4 * NT;
    float* ctx  = ws + 5 * NT;
    float* y1   = q;  // overlays q,k,v,ctx (4*NT) after attention is done
    float* Mbuf = ws + 6 * NT;
    int* idx    = (int*)(ws + 6 * NT + (size_t)B * H * LSEQ);
    int* top    = idx + LU;
    float* vm   = (float*)(top + B * H * U);

    const int ML = B * LSEQ;  // 8192 rows
    dim3 gD(D / 64, ML / 64);
    dim3 gF1(DFF / 64, ML / 64);

    embed_kernel<<<(B * LSEQ * D + 255) / 256, 256, 0, stream>>>(x, We, be, cls, h);

    for (int l = 0; l < NL; ++l) {
        const float* Wq_l = Wq + (size_t)l * D * D;
        const float* Wk_l = Wk + (size_t)l * D * D;
        const float* Wv_l = Wv + (size_t)l * D * D;
        const float* Wo_l = Wo + (size_t)l * D * D;
        const float* W1_l = W1 + (size_t)l * DFF * D;
        const float* W2_l = W2 + (size_t)l * D * DFF;

        gemm_bias<0><<<gD, 256, 0, stream>>>(h, Wq_l, bq + l * D, q, ML, D, D);
        gemm_bias<0><<<gD, 256, 0, stream>>>(h, Wk_l, bk + l * D, kbuf, ML, D, D);
        gemm_bias<0><<<gD, 256, 0, stream>>>(h, Wv_l, bv + l * D, vbuf, ML, D, D);

        idx_kernel<<<(HALF_LU + 255) / 256, 256, 0, stream>>>(idx, l);
        mscore_kernel<<<(B * H * LSEQ) / 4, 256, 0, stream>>>(q, kbuf, idx, Mbuf);
        topk_kernel<<<B * H, 256, 0, stream>>>(Mbuf, top);
        vmean_kernel<<<(B * H * E + 255) / 256, 256, 0, stream>>>(vbuf, vm);
        fill_ctx<<<(B * LSEQ * D + 255) / 256, 256, 0, stream>>>(vm, ctx);
        attn_kernel<<<B * H * U, 256, 0, stream>>>(q, kbuf, vbuf, top, ctx);

        gemm_bias<0><<<gD, 256, 0, stream>>>(ctx, Wo_l, bo + l * D, aout, ML, D, D);
        add_ln_kernel<<<ML, 64, 0, stream>>>(h, aout, g1 + l * D, b1 + l * D);

        gemm_bias<1><<<gF1, 256, 0, stream>>>(h, W1_l, bf1 + l * DFF, y1, ML, DFF, D);
        gemm_bias<0><<<gD, 256, 0, stream>>>(y1, W2_l, bf2 + l * D, aout, ML, D, DFF);
        add_ln_kernel<<<ML, 64, 0, stream>>>(h, aout, g2 + l * D, b2 + l * D);
    }

    final_kernel<<<B, 64, 0, stream>>>(h, Wf, bff, out);
}

// Round 2
// 1507.569 us; speedup vs baseline: 2.2254x; 2.2254x over previous
//
#include <hip/hip_runtime.h>
#include <hip/hip_bf16.h>
#include <math.h>
#include <stdint.h>

#define B 2
#define S 4095
#define LSEQ 4096
#define F_IN 32
#define D 512
#define H 8
#define E 64
#define DFF 2048
#define NL 2
#define U 45
#define EPSL 1e-5f
#define LU (LSEQ * U)
#define HALF_LU (LU / 2)

typedef __attribute__((ext_vector_type(8))) short short8;
typedef __attribute__((ext_vector_type(4))) float f32x4;

#define GLD(gp, lp)                                                            \
    __builtin_amdgcn_global_load_lds(                                          \
        (const __attribute__((address_space(1))) void*)(gp),                   \
        (__attribute__((address_space(3))) void*)(lp), 16, 0, 0)

__device__ __forceinline__ unsigned short bf16_bits(float f) {
    __hip_bfloat16 h = __float2bfloat16(f);
    return *(unsigned short*)&h;
}
__device__ __forceinline__ float bf16_val(const __hip_bfloat16* p) {
    return __bfloat162float(*p);
}

// ---------------- Threefry-2x32 (20 rounds), exactly JAX's algorithm ----------------
__device__ __forceinline__ uint32_t rotl32(uint32_t x, int r) {
    return (x << r) | (x >> (32 - r));
}

__device__ void threefry2x32(uint32_t k0, uint32_t k1, uint32_t c0, uint32_t c1,
                             uint32_t& o0, uint32_t& o1) {
    uint32_t ks2 = k0 ^ k1 ^ 0x1BD11BDAu;
    uint32_t x0 = c0 + k0, x1 = c1 + k1;
    x0 += x1; x1 = rotl32(x1, 13); x1 ^= x0;
    x0 += x1; x1 = rotl32(x1, 15); x1 ^= x0;
    x0 += x1; x1 = rotl32(x1, 26); x1 ^= x0;
    x0 += x1; x1 = rotl32(x1, 6);  x1 ^= x0;
    x0 += k1; x1 += ks2 + 1u;
    x0 += x1; x1 = rotl32(x1, 17); x1 ^= x0;
    x0 += x1; x1 = rotl32(x1, 29); x1 ^= x0;
    x0 += x1; x1 = rotl32(x1, 16); x1 ^= x0;
    x0 += x1; x1 = rotl32(x1, 24); x1 ^= x0;
    x0 += ks2; x1 += k0 + 2u;
    x0 += x1; x1 = rotl32(x1, 13); x1 ^= x0;
    x0 += x1; x1 = rotl32(x1, 15); x1 ^= x0;
    x0 += x1; x1 = rotl32(x1, 26); x1 ^= x0;
    x0 += x1; x1 = rotl32(x1, 6);  x1 ^= x0;
    x0 += k0; x1 += k1 + 3u;
    x0 += x1; x1 = rotl32(x1, 17); x1 ^= x0;
    x0 += x1; x1 = rotl32(x1, 29); x1 ^= x0;
    x0 += x1; x1 = rotl32(x1, 16); x1 ^= x0;
    x0 += x1; x1 = rotl32(x1, 24); x1 ^= x0;
    x0 += k1; x1 += ks2 + 4u;
    x0 += x1; x1 = rotl32(x1, 13); x1 ^= x0;
    x0 += x1; x1 = rotl32(x1, 15); x1 ^= x0;
    x0 += x1; x1 = rotl32(x1, 26); x1 ^= x0;
    x0 += x1; x1 = rotl32(x1, 6);  x1 ^= x0;
    x0 += ks2; x1 += k0 + 5u;
    o0 = x0; o1 = x1;
}

__global__ void idx_kernel(int* __restrict__ idx, int layer) {
    int j = blockIdx.x * blockDim.x + threadIdx.x;
    if (j >= HALF_LU) return;
    uint32_t f0, f1, a0, a1, b0, b1, o0, o1;
    threefry2x32(0u, 42u, 0u, (uint32_t)layer, f0, f1);
    threefry2x32(f0, f1, 0u, 2u, a0, a1);
    threefry2x32(f0, f1, 1u, 3u, b0, b1);
    threefry2x32(a1, b1, (uint32_t)j, (uint32_t)(j + HALF_LU), o0, o1);
    idx[j] = (int)(o0 & 4095u);
    idx[j + HALF_LU] = (int)(o1 & 4095u);
    (void)a0; (void)b0;
}

// ---------------- embed + cls + positional encoding (dual write f32 + bf16) --------
__global__ void embed_kernel(const float* __restrict__ x, const float* __restrict__ We,
                             const float* __restrict__ be, const float* __restrict__ cls,
                             float* __restrict__ h, __hip_bfloat16* __restrict__ hbf) {
    int gid = blockIdx.x * blockDim.x + threadIdx.x;
    if (gid >= B * LSEQ * D) return;
    int d = gid % D;
    int l = (gid / D) % LSEQ;
    int b = gid / (D * LSEQ);
    float v;
    if (l == 0) {
        v = cls[d];
    } else {
        const float* xr = x + ((size_t)b * S + (l - 1)) * F_IN;
        const float* wr = We + (size_t)d * F_IN;
        float acc = 0.f;
#pragma unroll
        for (int i = 0; i < F_IN; ++i) acc += xr[i] * wr[i];
        v = acc + be[d];
    }
    int i = d >> 1;
    float divv = expf((float)(2 * i) * (float)(-9.210340371976184 / 512.0));
    float ang = (float)l * divv;
    v += (d & 1) ? cosf(ang) : sinf(ang);
    h[gid] = v;
    hbf[gid] = __float2bfloat16(v);
}

// ---------------- f32 -> bf16 cast (4-wide) ----------------
__global__ void cast_bf16_kernel(const float* __restrict__ in,
                                 __hip_bfloat16* __restrict__ out, int n4) {
    int i = blockIdx.x * blockDim.x + threadIdx.x;
    if (i >= n4) return;
    float4 v = ((const float4*)in)[i];
    union { unsigned short u[4]; uint2 w; } o;
    o.u[0] = bf16_bits(v.x);
    o.u[1] = bf16_bits(v.y);
    o.u[2] = bf16_bits(v.z);
    o.u[3] = bf16_bits(v.w);
    ((uint2*)out)[i] = o.w;
}

// ---------------- bf16 MFMA GEMM: C[M,N] = A[M,K] @ W[N,K]^T + bias ----------------
// 128x128 tile, BK=32, 4 waves, 4x4 16x16x32 MFMA per wave. M%128==0, N%128==0, K%32==0.
template <int ACT, int OUTBF>
__global__ __launch_bounds__(256) void gemm_mfma(const unsigned short* __restrict__ A,
                                                 const unsigned short* __restrict__ W,
                                                 const float* __restrict__ bias,
                                                 void* __restrict__ Cout,
                                                 int M, int N, int K) {
    __shared__ unsigned short lds[2 * 128 * 32];
    unsigned short* As = lds;
    unsigned short* Bs = lds + 128 * 32;
    const int tid = threadIdx.x;
    const int m0 = blockIdx.y * 128, n0 = blockIdx.x * 128;
    const int wave = tid >> 6, lane = tid & 63;
    const int wm = (wave >> 1) * 64, wn = (wave & 1) * 64;
    const int quad = lane >> 4, m15 = lane & 15;
    const int srow = tid >> 2, scol = (tid & 3) * 8;
    f32x4 acc[4][4] = {};
    const unsigned short* Ag0 = A + (size_t)(m0 + srow) * K + scol;
    const unsigned short* Ag1 = A + (size_t)(m0 + srow + 64) * K + scol;
    const unsigned short* Wg0 = W + (size_t)(n0 + srow) * K + scol;
    const unsigned short* Wg1 = W + (size_t)(n0 + srow + 64) * K + scol;
    for (int k0 = 0; k0 < K; k0 += 32) {
        __syncthreads();
        GLD(Ag0 + k0, As + tid * 8);
        GLD(Ag1 + k0, As + 2048 + tid * 8);
        GLD(Wg0 + k0, Bs + tid * 8);
        GLD(Wg1 + k0, Bs + 2048 + tid * 8);
        __syncthreads();
        short8 af[4], bfr[4];
#pragma unroll
        for (int mi = 0; mi < 4; ++mi)
            af[mi] = *(const short8*)(As + (wm + mi * 16 + m15) * 32 + quad * 8);
#pragma unroll
        for (int ni = 0; ni < 4; ++ni)
            bfr[ni] = *(const short8*)(Bs + (wn + ni * 16 + m15) * 32 + quad * 8);
#pragma unroll
        for (int mi = 0; mi < 4; ++mi)
#pragma unroll
            for (int ni = 0; ni < 4; ++ni)
                acc[mi][ni] = __builtin_amdgcn_mfma_f32_16x16x32_bf16(
                    af[mi], bfr[ni], acc[mi][ni], 0, 0, 0);
    }
    float* Cf = (float*)Cout;
    __hip_bfloat16* Cb = (__hip_bfloat16*)Cout;
#pragma unroll
    for (int mi = 0; mi < 4; ++mi) {
        int mg = m0 + wm + mi * 16 + quad * 4;
#pragma unroll
        for (int ni = 0; ni < 4; ++ni) {
            int ng = n0 + wn + ni * 16 + m15;
            float bv = bias[ng];
#pragma unroll
            for (int r = 0; r < 4; ++r) {
                float v = acc[mi][ni][r] + bv;
                if (ACT == 1) v = fmaxf(v, 0.f);
                if (OUTBF == 1)
                    Cb[(size_t)(mg + r) * N + ng] = __float2bfloat16(v);
                else
                    Cf[(size_t)(mg + r) * N + ng] = v;
            }
        }
    }
}

// ---------------- M-score: one wave per (b,h,l) ----------------
__global__ __launch_bounds__(256) void mscore_kernel(const float* __restrict__ q,
                                                     const float* __restrict__ k,
                                                     const int* __restrict__ idx,
                                                     float* __restrict__ Mv) {
    int wid = (blockIdx.x * blockDim.x + threadIdx.x) >> 6;
    int lane = threadIdx.x & 63;
    int l = wid % LSEQ;
    int hh = (wid / LSEQ) % H;
    int b = wid / (LSEQ * H);
    float s = -INFINITY, ssum = 0.f;
    const float* qr = q + ((size_t)b * LSEQ + l) * D + hh * E;
    if (lane < U) {
        int kr = idx[l * U + lane];
        const float* kp = k + ((size_t)b * LSEQ + kr) * D + hh * E;
        float acc = 0.f;
#pragma unroll
        for (int e = 0; e < E; e += 4) {
            float4 qa = *(const float4*)(qr + e);
            float4 kb = *(const float4*)(kp + e);
            acc += qa.x * kb.x + qa.y * kb.y + qa.z * kb.z + qa.w * kb.w;
        }
        s = acc; ssum = acc;
    }
    for (int off = 32; off; off >>= 1) {
        s = fmaxf(s, __shfl_xor(s, off));
        ssum += __shfl_xor(ssum, off);
    }
    if (lane == 0) Mv[wid] = s - ssum / (float)LSEQ;
}

// ---------------- top-k (u=45) per (b,h), JAX tie semantics ----------------
__global__ __launch_bounds__(256) void topk_kernel(const float* __restrict__ Mv,
                                                   int* __restrict__ top) {
    __shared__ float buf[LSEQ];
    __shared__ float rv[256];
    __shared__ int ri[256];
    int bh = blockIdx.x;
    const float* mrow = Mv + (size_t)bh * LSEQ;
    for (int i = threadIdx.x; i < LSEQ; i += 256) buf[i] = mrow[i];
    __syncthreads();
    for (int t = 0; t < U; ++t) {
        float bv = -INFINITY;
        int bi = LSEQ;
        for (int i = threadIdx.x; i < LSEQ; i += 256) {
            float v = buf[i];
            if (v > bv) { bv = v; bi = i; }
        }
        rv[threadIdx.x] = bv; ri[threadIdx.x] = bi;
        __syncthreads();
        for (int sft = 128; sft; sft >>= 1) {
            if (threadIdx.x < sft) {
                float v2 = rv[threadIdx.x + sft];
                int i2 = ri[threadIdx.x + sft];
                if (v2 > rv[threadIdx.x] || (v2 == rv[threadIdx.x] && i2 < ri[threadIdx.x])) {
                    rv[threadIdx.x] = v2; ri[threadIdx.x] = i2;
                }
            }
            __syncthreads();
        }
        if (threadIdx.x == 0) {
            top[bh * U + t] = ri[0];
            buf[ri[0]] = -INFINITY;
        }
        __syncthreads();
    }
}

// ---------------- v mean over L per (b,h,e) — v is bf16 ----------------
__global__ void vmean_kernel(const __hip_bfloat16* __restrict__ v, float* __restrict__ vm) {
    int gid = blockIdx.x * blockDim.x + threadIdx.x;
    if (gid >= B * H * E) return;
    int e = gid % E;
    int hh = (gid / E) % H;
    int b = gid / (E * H);
    const __hip_bfloat16* vp = v + (size_t)b * LSEQ * D + hh * E + e;
    float acc = 0.f;
    for (int l = 0; l < LSEQ; ++l) acc += __bfloat162float(vp[(size_t)l * D]);
    vm[gid] = acc / (float)LSEQ;
}

// ---------------- ctx(bf16) = broadcast vmean ----------------
__global__ void fill_ctx(const float* __restrict__ vm, __hip_bfloat16* __restrict__ ctx) {
    int gid = blockIdx.x * blockDim.x + threadIdx.x;
    if (gid >= B * LSEQ * D) return;
    int d = gid % D;
    int b = gid / (D * LSEQ);
    int hh = d >> 6, e = d & 63;
    ctx[gid] = __float2bfloat16(vm[(b * H + hh) * E + e]);
}

// ---------------- full attention for selected rows; writes ctx(bf16) directly -------
__global__ __launch_bounds__(256) void attn_kernel(const float* __restrict__ q,
                                                   const float* __restrict__ k,
                                                   const __hip_bfloat16* __restrict__ v,
                                                   const int* __restrict__ top,
                                                   __hip_bfloat16* __restrict__ ctx) {
    __shared__ float sc[LSEQ];
    __shared__ float qs[E];
    __shared__ float red[256];
    __shared__ float part[4][E];
    int bid = blockIdx.x;  // B*H*U
    int t = bid % U;
    int hh = (bid / U) % H;
    int b = bid / (U * H);
    int r = top[(b * H + hh) * U + t];
    int tid = threadIdx.x;
    if (tid < E) qs[tid] = q[((size_t)b * LSEQ + r) * D + hh * E + tid];
    __syncthreads();
    for (int kk = tid; kk < LSEQ; kk += 256) {
        const float* kp = k + ((size_t)b * LSEQ + kk) * D + hh * E;
        float acc = 0.f;
#pragma unroll
        for (int e = 0; e < E; e += 4) {
            float4 kb = *(const float4*)(kp + e);
            acc += qs[e] * kb.x + qs[e + 1] * kb.y + qs[e + 2] * kb.z + qs[e + 3] * kb.w;
        }
        sc[kk] = acc * 0.125f;
    }
    __syncthreads();
    float m = -INFINITY;
    for (int kk = tid; kk < LSEQ; kk += 256) m = fmaxf(m, sc[kk]);
    red[tid] = m;
    __syncthreads();
    for (int sft = 128; sft; sft >>= 1) {
        if (tid < sft) red[tid] = fmaxf(red[tid], red[tid + sft]);
        __syncthreads();
    }
    m = red[0];
    __syncthreads();
    float sum = 0.f;
    for (int kk = tid; kk < LSEQ; kk += 256) {
        float ev = expf(sc[kk] - m);
        sc[kk] = ev;
        sum += ev;
    }
    red[tid] = sum;
    __syncthreads();
    for (int sft = 128; sft; sft >>= 1) {
        if (tid < sft) red[tid] += red[tid + sft];
        __syncthreads();
    }
    float inv = 1.f / red[0];
    int e = tid & 63, seg = tid >> 6;
    float acc = 0.f;
    const __hip_bfloat16* vp = v + (size_t)b * LSEQ * D + hh * E + e;
    for (int kk = seg * 1024; kk < (seg + 1) * 1024; ++kk)
        acc += sc[kk] * __bfloat162float(vp[(size_t)kk * D]);
    part[seg][e] = acc;
    __syncthreads();
    if (tid < E) {
        float uval = (part[0][tid] + part[1][tid] + part[2][tid] + part[3][tid]) * inv;
        ctx[((size_t)b * LSEQ + r) * D + hh * E + tid] = __float2bfloat16(uval);
    }
}

// -------- h = LayerNorm(h + a) * g + b, one wave per row, dual write f32+bf16 -------
__global__ __launch_bounds__(64) void add_ln_kernel(float* __restrict__ h,
                                                    const float* __restrict__ a,
                                                    const float* __restrict__ g,
                                                    const float* __restrict__ bb,
                                                    __hip_bfloat16* __restrict__ hbf) {
    int row = blockIdx.x;
    int lane = threadIdx.x;
    float* hp = h + (size_t)row * D;
    const float* ap = a + (size_t)row * D;
    float x[8];
    float sum = 0.f;
#pragma unroll
    for (int j = 0; j < 8; ++j) {
        x[j] = hp[lane + 64 * j] + ap[lane + 64 * j];
        sum += x[j];
    }
    for (int off = 32; off; off >>= 1) sum += __shfl_xor(sum, off);
    float mu = sum / (float)D;
    float vs = 0.f;
#pragma unroll
    for (int j = 0; j < 8; ++j) {
        float dd = x[j] - mu;
        vs += dd * dd;
    }
    for (int off = 32; off; off >>= 1) vs += __shfl_xor(vs, off);
    float inv = 1.f / sqrtf(vs / (float)D + EPSL);
#pragma unroll
    for (int j = 0; j < 8; ++j) {
        float o = (x[j] - mu) * inv * g[lane + 64 * j] + bb[lane + 64 * j];
        hp[lane + 64 * j] = o;
        hbf[(size_t)row * D + lane + 64 * j] = __float2bfloat16(o);
    }
}

// ---------------- final head ----------------
__global__ void final_kernel(const float* __restrict__ h, const float* __restrict__ Wf,
                             const float* __restrict__ bf, float* __restrict__ out) {
    int b = blockIdx.x;
    int lane = threadIdx.x;
    const float* hp = h + (size_t)b * LSEQ * D;
    float acc = 0.f;
    for (int j = lane; j < D; j += 64) acc += hp[j] * Wf[j];
    for (int off = 32; off; off >>= 1) acc += __shfl_xor(acc, off);
    if (lane == 0) out[b] = acc + bf[0];
}

extern "C" void kernel_launch(void* const* d_in, const int* in_sizes, int n_in,
                              void* d_out, int out_size, void* d_ws, size_t ws_size,
                              hipStream_t stream) {
    (void)in_sizes; (void)n_in; (void)out_size; (void)ws_size;
    const float* x   = (const float*)d_in[0];
    const float* We  = (const float*)d_in[1];
    const float* be  = (const float*)d_in[2];
    const float* cls = (const float*)d_in[3];
    const float* Wq  = (const float*)d_in[4];
    const float* bq  = (const float*)d_in[5];
    const float* Wk  = (const float*)d_in[6];
    const float* bk  = (const float*)d_in[7];
    const float* Wv  = (const float*)d_in[8];
    const float* bv  = (const float*)d_in[9];
    const float* Wo  = (const float*)d_in[10];
    const float* bo  = (const float*)d_in[11];
    const float* g1  = (const float*)d_in[12];
    const float* b1  = (const float*)d_in[13];
    const float* g2  = (const float*)d_in[14];
    const float* b2  = (const float*)d_in[15];
    const float* W1  = (const float*)d_in[16];
    const float* bf1 = (const float*)d_in[17];
    const float* W2  = (const float*)d_in[18];
    const float* bf2 = (const float*)d_in[19];
    const float* Wf  = (const float*)d_in[20];
    const float* bff = (const float*)d_in[21];
    float* out = (float*)d_out;

    float* ws = (float*)d_ws;
    const size_t NT = (size_t)B * LSEQ * D;  // 4,194,304
    float* h    = ws;                         // [0, NT)
    float* aout = ws + NT;                    // [NT, 2NT)
    float* q    = ws + 2 * NT;                // [2NT, 3NT)
    float* kbuf = ws + 3 * NT;                // [3NT, 4NT)
    __hip_bfloat16* y1_bf  = (__hip_bfloat16*)(ws + 2 * NT);  // overlays q,k (2NT fl)
    __hip_bfloat16* v_bf   = (__hip_bfloat16*)(ws + 4 * NT);  // NT bf16 = 0.5NT fl
    __hip_bfloat16* ctx_bf = (__hip_bfloat16*)(ws + 4 * NT + NT / 2);
    __hip_bfloat16* h_bf   = (__hip_bfloat16*)(ws + 5 * NT);
    float* wpool = ws + 5 * NT + NT / 2;
    // per-layer bf16 weights
    __hip_bfloat16* wqb = (__hip_bfloat16*)wpool;                     // D*D
    __hip_bfloat16* wkb = wqb + (size_t)D * D;
    __hip_bfloat16* wvb = wkb + (size_t)D * D;
    __hip_bfloat16* wob = wvb + (size_t)D * D;
    __hip_bfloat16* w1b = wob + (size_t)D * D;                        // DFF*D
    __hip_bfloat16* w2b = w1b + (size_t)DFF * D;                      // D*DFF
    float* after_w = wpool + ((size_t)4 * D * D + 2 * (size_t)DFF * D) / 2;
    float* Mbuf = after_w;                      // B*H*LSEQ
    int* idx    = (int*)(Mbuf + (size_t)B * H * LSEQ);
    int* top    = idx + LU;
    float* vm   = (float*)(top + B * H * U);

    const int ML = B * LSEQ;  // 8192
    dim3 gD(D / 128, ML / 128);
    dim3 gF1(DFF / 128, ML / 128);

    embed_kernel<<<(B * LSEQ * D + 255) / 256, 256, 0, stream>>>(x, We, be, cls, h, h_bf);

    for (int l = 0; l < NL; ++l) {
        const float* Wq_l = Wq + (size_t)l * D * D;
        const float* Wk_l = Wk + (size_t)l * D * D;
        const float* Wv_l = Wv + (size_t)l * D * D;
        const float* Wo_l = Wo + (size_t)l * D * D;
        const float* W1_l = W1 + (size_t)l * DFF * D;
        const float* W2_l = W2 + (size_t)l * D * DFF;

        int nDD4 = D * D / 4, nFD4 = DFF * D / 4;
        cast_bf16_kernel<<<(nDD4 + 255) / 256, 256, 0, stream>>>(Wq_l, wqb, nDD4);
        cast_bf16_kernel<<<(nDD4 + 255) / 256, 256, 0, stream>>>(Wk_l, wkb, nDD4);
        cast_bf16_kernel<<<(nDD4 + 255) / 256, 256, 0, stream>>>(Wv_l, wvb, nDD4);
        cast_bf16_kernel<<<(nDD4 + 255) / 256, 256, 0, stream>>>(Wo_l, wob, nDD4);
        cast_bf16_kernel<<<(nFD4 + 255) / 256, 256, 0, stream>>>(W1_l, w1b, nFD4);
        cast_bf16_kernel<<<(nFD4 + 255) / 256, 256, 0, stream>>>(W2_l, w2b, nFD4);

        gemm_mfma<0, 0><<<gD, 256, 0, stream>>>((const unsigned short*)h_bf,
                                                (const unsigned short*)wqb, bq + l * D, q,
                                                ML, D, D);
        gemm_mfma<0, 0><<<gD, 256, 0, stream>>>((const unsigned short*)h_bf,
                                                (const unsigned short*)wkb, bk + l * D, kbuf,
                                                ML, D, D);
        gemm_mfma<0, 1><<<gD, 256, 0, stream>>>((const unsigned short*)h_bf,
                                                (const unsigned short*)wvb, bv + l * D, v_bf,
                                                ML, D, D);

        idx_kernel<<<(HALF_LU + 255) / 256, 256, 0, stream>>>(idx, l);
        mscore_kernel<<<(B * H * LSEQ) / 4, 256, 0, stream>>>(q, kbuf, idx, Mbuf);
        topk_kernel<<<B * H, 256, 0, stream>>>(Mbuf, top);
        vmean_kernel<<<(B * H * E + 255) / 256, 256, 0, stream>>>(v_bf, vm);
        fill_ctx<<<(B * LSEQ * D + 255) / 256, 256, 0, stream>>>(vm, ctx_bf);
        attn_kernel<<<B * H * U, 256, 0, stream>>>(q, kbuf, v_bf, top, ctx_bf);

        gemm_mfma<0, 0><<<gD, 256, 0, stream>>>((const unsigned short*)ctx_bf,
                                                (const unsigned short*)wob, bo + l * D, aout,
                                                ML, D, D);
        add_ln_kernel<<<ML, 64, 0, stream>>>(h, aout, g1 + l * D, b1 + l * D, h_bf);

        gemm_mfma<1, 1><<<gF1, 256, 0, stream>>>((const unsigned short*)h_bf,
                                                 (const unsigned short*)w1b, bf1 + l * DFF,
                                                 y1_bf, ML, DFF, D);
        gemm_mfma<0, 0><<<gD, 256, 0, stream>>>((const unsigned short*)y1_bf,
                                                (const unsigned short*)w2b, bf2 + l * D, aout,
                                                ML, D, DFF);
        add_ln_kernel<<<ML, 64, 0, stream>>>(h, aout, g2 + l * D, b2 + l * D, h_bf);
    }

    final_kernel<<<B, 64, 0, stream>>>(h, Wf, bff, out);
}

// Round 3
// 1307.663 us; speedup vs baseline: 2.5656x; 1.1529x over previous
//
#include <hip/hip_runtime.h>
#include <hip/hip_bf16.h>
#include <math.h>
#include <stdint.h>

#define B 2
#define S 4095
#define LSEQ 4096
#define F_IN 32
#define D 512
#define H 8
#define E 64
#define DFF 2048
#define NL 2
#define U 45
#define EPSL 1e-5f
#define LU (LSEQ * U)
#define HALF_LU (LU / 2)

typedef __attribute__((ext_vector_type(8))) short short8;
typedef __attribute__((ext_vector_type(4))) float f32x4;

#define GLD(gp, lp)                                                            \
    __builtin_amdgcn_global_load_lds(                                          \
        (const __attribute__((address_space(1))) void*)(gp),                   \
        (__attribute__((address_space(3))) void*)(lp), 16, 0, 0)

__device__ __forceinline__ unsigned short bf16_bits(float f) {
    __hip_bfloat16 h = __float2bfloat16(f);
    return *(unsigned short*)&h;
}
__device__ __forceinline__ float bits_to_f32(unsigned short s) {
    union { uint32_t u; float f; } c;
    c.u = ((uint32_t)s) << 16;
    return c.f;
}

// ---------------- Threefry-2x32 (20 rounds), exactly JAX's algorithm ----------------
__device__ __forceinline__ uint32_t rotl32(uint32_t x, int r) {
    return (x << r) | (x >> (32 - r));
}

__device__ void threefry2x32(uint32_t k0, uint32_t k1, uint32_t c0, uint32_t c1,
                             uint32_t& o0, uint32_t& o1) {
    uint32_t ks2 = k0 ^ k1 ^ 0x1BD11BDAu;
    uint32_t x0 = c0 + k0, x1 = c1 + k1;
    x0 += x1; x1 = rotl32(x1, 13); x1 ^= x0;
    x0 += x1; x1 = rotl32(x1, 15); x1 ^= x0;
    x0 += x1; x1 = rotl32(x1, 26); x1 ^= x0;
    x0 += x1; x1 = rotl32(x1, 6);  x1 ^= x0;
    x0 += k1; x1 += ks2 + 1u;
    x0 += x1; x1 = rotl32(x1, 17); x1 ^= x0;
    x0 += x1; x1 = rotl32(x1, 29); x1 ^= x0;
    x0 += x1; x1 = rotl32(x1, 16); x1 ^= x0;
    x0 += x1; x1 = rotl32(x1, 24); x1 ^= x0;
    x0 += ks2; x1 += k0 + 2u;
    x0 += x1; x1 = rotl32(x1, 13); x1 ^= x0;
    x0 += x1; x1 = rotl32(x1, 15); x1 ^= x0;
    x0 += x1; x1 = rotl32(x1, 26); x1 ^= x0;
    x0 += x1; x1 = rotl32(x1, 6);  x1 ^= x0;
    x0 += k0; x1 += k1 + 3u;
    x0 += x1; x1 = rotl32(x1, 17); x1 ^= x0;
    x0 += x1; x1 = rotl32(x1, 29); x1 ^= x0;
    x0 += x1; x1 = rotl32(x1, 16); x1 ^= x0;
    x0 += x1; x1 = rotl32(x1, 24); x1 ^= x0;
    x0 += k1; x1 += ks2 + 4u;
    x0 += x1; x1 = rotl32(x1, 13); x1 ^= x0;
    x0 += x1; x1 = rotl32(x1, 15); x1 ^= x0;
    x0 += x1; x1 = rotl32(x1, 26); x1 ^= x0;
    x0 += x1; x1 = rotl32(x1, 6);  x1 ^= x0;
    x0 += ks2; x1 += k0 + 5u;
    o0 = x0; o1 = x1;
}

__global__ void idx_kernel(int* __restrict__ idx, int layer) {
    int j = blockIdx.x * blockDim.x + threadIdx.x;
    if (j >= HALF_LU) return;
    uint32_t f0, f1, a0, a1, b0, b1, o0, o1;
    threefry2x32(0u, 42u, 0u, (uint32_t)layer, f0, f1);
    threefry2x32(f0, f1, 0u, 2u, a0, a1);
    threefry2x32(f0, f1, 1u, 3u, b0, b1);
    threefry2x32(a1, b1, (uint32_t)j, (uint32_t)(j + HALF_LU), o0, o1);
    idx[j] = (int)(o0 & 4095u);
    idx[j + HALF_LU] = (int)(o1 & 4095u);
    (void)a0; (void)b0;
}

// ---------------- embed + cls + positional encoding (dual write f32 + bf16) --------
__global__ void embed_kernel(const float* __restrict__ x, const float* __restrict__ We,
                             const float* __restrict__ be, const float* __restrict__ cls,
                             float* __restrict__ h, __hip_bfloat16* __restrict__ hbf) {
    int gid = blockIdx.x * blockDim.x + threadIdx.x;
    if (gid >= B * LSEQ * D) return;
    int d = gid % D;
    int l = (gid / D) % LSEQ;
    int b = gid / (D * LSEQ);
    float v;
    if (l == 0) {
        v = cls[d];
    } else {
        const float* xr = x + ((size_t)b * S + (l - 1)) * F_IN;
        const float* wr = We + (size_t)d * F_IN;
        float acc = 0.f;
#pragma unroll
        for (int i = 0; i < F_IN; ++i) acc += xr[i] * wr[i];
        v = acc + be[d];
    }
    int i = d >> 1;
    float divv = expf((float)(2 * i) * (float)(-9.210340371976184 / 512.0));
    float ang = (float)l * divv;
    v += (d & 1) ? cosf(ang) : sinf(ang);
    h[gid] = v;
    hbf[gid] = __float2bfloat16(v);
}

// ---------------- f32 -> bf16 cast (4-wide) ----------------
__global__ void cast_bf16_kernel(const float* __restrict__ in,
                                 __hip_bfloat16* __restrict__ out, int n4) {
    int i = blockIdx.x * blockDim.x + threadIdx.x;
    if (i >= n4) return;
    float4 v = ((const float4*)in)[i];
    union { unsigned short u[4]; uint2 w; } o;
    o.u[0] = bf16_bits(v.x);
    o.u[1] = bf16_bits(v.y);
    o.u[2] = bf16_bits(v.z);
    o.u[3] = bf16_bits(v.w);
    ((uint2*)out)[i] = o.w;
}

// ---------------- bf16 MFMA GEMM: C[M,N] = A[M,K] @ W[N,K]^T + bias ----------------
template <int ACT, int OUTBF>
__global__ __launch_bounds__(256) void gemm_mfma(const unsigned short* __restrict__ A,
                                                 const unsigned short* __restrict__ W,
                                                 const float* __restrict__ bias,
                                                 void* __restrict__ Cout,
                                                 int M, int N, int K) {
    __shared__ unsigned short lds[2 * 128 * 32];
    unsigned short* As = lds;
    unsigned short* Bs = lds + 128 * 32;
    const int tid = threadIdx.x;
    const int m0 = blockIdx.y * 128, n0 = blockIdx.x * 128;
    const int wave = tid >> 6, lane = tid & 63;
    const int wm = (wave >> 1) * 64, wn = (wave & 1) * 64;
    const int quad = lane >> 4, m15 = lane & 15;
    const int srow = tid >> 2, scol = (tid & 3) * 8;
    f32x4 acc[4][4] = {};
    const unsigned short* Ag0 = A + (size_t)(m0 + srow) * K + scol;
    const unsigned short* Ag1 = A + (size_t)(m0 + srow + 64) * K + scol;
    const unsigned short* Wg0 = W + (size_t)(n0 + srow) * K + scol;
    const unsigned short* Wg1 = W + (size_t)(n0 + srow + 64) * K + scol;
    for (int k0 = 0; k0 < K; k0 += 32) {
        __syncthreads();
        GLD(Ag0 + k0, As + tid * 8);
        GLD(Ag1 + k0, As + 2048 + tid * 8);
        GLD(Wg0 + k0, Bs + tid * 8);
        GLD(Wg1 + k0, Bs + 2048 + tid * 8);
        __syncthreads();
        short8 af[4], bfr[4];
#pragma unroll
        for (int mi = 0; mi < 4; ++mi)
            af[mi] = *(const short8*)(As + (wm + mi * 16 + m15) * 32 + quad * 8);
#pragma unroll
        for (int ni = 0; ni < 4; ++ni)
            bfr[ni] = *(const short8*)(Bs + (wn + ni * 16 + m15) * 32 + quad * 8);
#pragma unroll
        for (int mi = 0; mi < 4; ++mi)
#pragma unroll
            for (int ni = 0; ni < 4; ++ni)
                acc[mi][ni] = __builtin_amdgcn_mfma_f32_16x16x32_bf16(
                    af[mi], bfr[ni], acc[mi][ni], 0, 0, 0);
    }
    float* Cf = (float*)Cout;
    __hip_bfloat16* Cb = (__hip_bfloat16*)Cout;
#pragma unroll
    for (int mi = 0; mi < 4; ++mi) {
        int mg = m0 + wm + mi * 16 + quad * 4;
#pragma unroll
        for (int ni = 0; ni < 4; ++ni) {
            int ng = n0 + wn + ni * 16 + m15;
            float bv = bias[ng];
#pragma unroll
            for (int r = 0; r < 4; ++r) {
                float v = acc[mi][ni][r] + bv;
                if (ACT == 1) v = fmaxf(v, 0.f);
                if (OUTBF == 1)
                    Cb[(size_t)(mg + r) * N + ng] = __float2bfloat16(v);
                else
                    Cf[(size_t)(mg + r) * N + ng] = v;
            }
        }
    }
}

// -------- M-score: one block per (b,l); 45 coalesced full-D K-row gathers serve 8 heads
__global__ __launch_bounds__(256) void mscore_kernel(const float* __restrict__ q,
                                                     const float* __restrict__ k,
                                                     const int* __restrict__ idx,
                                                     float* __restrict__ Mv) {
    __shared__ float Sbuf[U][8];
    __shared__ int sidx[U];
    int bid = blockIdx.x;
    int l = bid & (LSEQ - 1);
    int b = bid >> 12;
    int tid = threadIdx.x;
    const float* qr = q + ((size_t)(b * LSEQ) + l) * D;
    float2 qv = *(const float2*)(qr + 2 * tid);
    if (tid < U) sidx[tid] = idx[l * U + tid];
    __syncthreads();
    float q0 = qv.x, q1 = qv.y;
    const float* kbase = k + (size_t)(b * LSEQ) * D;
#pragma unroll 5
    for (int t = 0; t < U; ++t) {
        int kr = sidx[t];
        float2 kv = *(const float2*)(kbase + (size_t)kr * D + 2 * tid);
        float p = q0 * kv.x + q1 * kv.y;
        p += __shfl_xor(p, 1);
        p += __shfl_xor(p, 2);
        p += __shfl_xor(p, 4);
        p += __shfl_xor(p, 8);
        p += __shfl_xor(p, 16);
        if ((tid & 31) == 0) Sbuf[t][tid >> 5] = p;
    }
    __syncthreads();
    if (tid < 8) {
        float mx = -INFINITY, sm = 0.f;
        for (int t = 0; t < U; ++t) {
            float v = Sbuf[t][tid];
            mx = fmaxf(mx, v);
            sm += v;
        }
        Mv[((size_t)b * H + tid) * LSEQ + l] = mx - sm / (float)LSEQ;
    }
}

// ---------------- top-k (u=45) per (b,h), JAX tie semantics, shuffle argmax --------
__global__ __launch_bounds__(256) void topk_kernel(const float* __restrict__ Mv,
                                                   int* __restrict__ top) {
    __shared__ float buf[LSEQ];
    __shared__ float wv[4];
    __shared__ int wi[4];
    int bh = blockIdx.x;
    int tid = threadIdx.x;
    const float* mrow = Mv + (size_t)bh * LSEQ;
    for (int i = tid; i < LSEQ; i += 256) buf[i] = mrow[i];
    __syncthreads();
    for (int t = 0; t < U; ++t) {
        float bv = -INFINITY;
        int bi = LSEQ;
        for (int i = tid; i < LSEQ; i += 256) {
            float v = buf[i];
            if (v > bv) { bv = v; bi = i; }
        }
        for (int off = 32; off; off >>= 1) {
            float v2 = __shfl_xor(bv, off);
            int i2 = __shfl_xor(bi, off);
            if (v2 > bv || (v2 == bv && i2 < bi)) { bv = v2; bi = i2; }
        }
        if ((tid & 63) == 0) { wv[tid >> 6] = bv; wi[tid >> 6] = bi; }
        __syncthreads();
        if (tid == 0) {
            float fv = wv[0]; int fi = wi[0];
            for (int w = 1; w < 4; ++w)
                if (wv[w] > fv || (wv[w] == fv && wi[w] < fi)) { fv = wv[w]; fi = wi[w]; }
            top[bh * U + t] = fi;
            buf[fi] = -INFINITY;
        }
        __syncthreads();
    }
}

// ---------------- v mean: partial (128 blocks) + reduce ----------------
__global__ __launch_bounds__(256) void vmean_part(const __hip_bfloat16* __restrict__ v,
                                                  float* __restrict__ part) {
    int blk = blockIdx.x;  // B*H*8
    int seg = blk & 7, hh = (blk >> 3) & 7, b = blk >> 6;
    int e = threadIdx.x & 63, rg = threadIdx.x >> 6;
    const __hip_bfloat16* vp =
        v + ((size_t)(b * LSEQ) + seg * 512) * D + hh * 64 + e;
    float acc = 0.f;
    for (int r = rg; r < 512; r += 4) acc += __bfloat162float(vp[(size_t)r * D]);
    __shared__ float red[4][64];
    red[rg][e] = acc;
    __syncthreads();
    if (threadIdx.x < 64)
        part[(size_t)blk * 64 + threadIdx.x] =
            red[0][threadIdx.x] + red[1][threadIdx.x] + red[2][threadIdx.x] + red[3][threadIdx.x];
}

__global__ void vmean_reduce(const float* __restrict__ part, float* __restrict__ vm) {
    int gid = blockIdx.x * blockDim.x + threadIdx.x;
    if (gid >= B * H * E) return;
    int e = gid & 63, bh = gid >> 6;
    float acc = 0.f;
#pragma unroll
    for (int s = 0; s < 8; ++s) acc += part[((size_t)bh * 8 + s) * 64 + e];
    vm[gid] = acc / (float)LSEQ;
}

// ---------------- ctx(bf16) = broadcast vmean ----------------
__global__ void fill_ctx(const float* __restrict__ vm, __hip_bfloat16* __restrict__ ctx) {
    int gid = blockIdx.x * blockDim.x + threadIdx.x;
    if (gid >= B * LSEQ * D) return;
    int d = gid % D;
    int b = gid / (D * LSEQ);
    int hh = d >> 6, e = d & 63;
    ctx[gid] = __float2bfloat16(vm[(b * H + hh) * E + e]);
}

// ------- full attention for selected rows; bf16 K, coalesced 16-lane row dot -------
__global__ __launch_bounds__(256) void attn_kernel(const float* __restrict__ q,
                                                   const __hip_bfloat16* __restrict__ kbf,
                                                   const __hip_bfloat16* __restrict__ v,
                                                   const int* __restrict__ top,
                                                   __hip_bfloat16* __restrict__ ctx) {
    __shared__ float sc[LSEQ];
    __shared__ float qs[E];
    __shared__ float red[256];
    __shared__ float part[4][E];
    int bid = blockIdx.x;  // B*H*U
    int t = bid % U;
    int hh = (bid / U) % H;
    int b = bid / (U * H);
    int r = top[(b * H + hh) * U + t];
    int tid = threadIdx.x;
    if (tid < E) qs[tid] = q[((size_t)(b * LSEQ) + r) * D + hh * E + tid];
    __syncthreads();
    int lane = tid & 63, wave = tid >> 6;
    int l16 = lane & 15, rsub = lane >> 4;
    float ql[4];
#pragma unroll
    for (int j = 0; j < 4; ++j) ql[j] = qs[l16 * 4 + j];
    const __hip_bfloat16* kb = kbf + (size_t)(b * LSEQ) * D + hh * E;
    for (int k0 = wave * 4 + rsub; k0 < LSEQ; k0 += 16) {
        union { uint2 u; unsigned short s[4]; } kv;
        kv.u = *(const uint2*)(kb + (size_t)k0 * D + l16 * 4);
        float p = ql[0] * bits_to_f32(kv.s[0]) + ql[1] * bits_to_f32(kv.s[1]) +
                  ql[2] * bits_to_f32(kv.s[2]) + ql[3] * bits_to_f32(kv.s[3]);
        p += __shfl_xor(p, 1);
        p += __shfl_xor(p, 2);
        p += __shfl_xor(p, 4);
        p += __shfl_xor(p, 8);
        if (l16 == 0) sc[k0] = p * 0.125f;
    }
    __syncthreads();
    float m = -INFINITY;
    for (int kk = tid; kk < LSEQ; kk += 256) m = fmaxf(m, sc[kk]);
    red[tid] = m;
    __syncthreads();
    for (int sft = 128; sft; sft >>= 1) {
        if (tid < sft) red[tid] = fmaxf(red[tid], red[tid + sft]);
        __syncthreads();
    }
    m = red[0];
    __syncthreads();
    float sum = 0.f;
    for (int kk = tid; kk < LSEQ; kk += 256) {
        float ev = expf(sc[kk] - m);
        sc[kk] = ev;
        sum += ev;
    }
    red[tid] = sum;
    __syncthreads();
    for (int sft = 128; sft; sft >>= 1) {
        if (tid < sft) red[tid] += red[tid + sft];
        __syncthreads();
    }
    float inv = 1.f / red[0];
    int e = tid & 63, seg = tid >> 6;
    float acc = 0.f;
    const __hip_bfloat16* vp = v + (size_t)b * LSEQ * D + hh * E + e;
    for (int kk = seg * 1024; kk < (seg + 1) * 1024; ++kk)
        acc += sc[kk] * __bfloat162float(vp[(size_t)kk * D]);
    part[seg][e] = acc;
    __syncthreads();
    if (tid < E) {
        float uval = (part[0][tid] + part[1][tid] + part[2][tid] + part[3][tid]) * inv;
        ctx[((size_t)(b * LSEQ) + r) * D + hh * E + tid] = __float2bfloat16(uval);
    }
}

// -------- h = LayerNorm(h + a) * g + b, one wave per row, dual write f32+bf16 -------
__global__ __launch_bounds__(64) void add_ln_kernel(float* __restrict__ h,
                                                    const float* __restrict__ a,
                                                    const float* __restrict__ g,
                                                    const float* __restrict__ bb,
                                                    __hip_bfloat16* __restrict__ hbf) {
    int row = blockIdx.x;
    int lane = threadIdx.x;
    float* hp = h + (size_t)row * D;
    const float* ap = a + (size_t)row * D;
    float x[8];
    float sum = 0.f;
#pragma unroll
    for (int j = 0; j < 8; ++j) {
        x[j] = hp[lane + 64 * j] + ap[lane + 64 * j];
        sum += x[j];
    }
    for (int off = 32; off; off >>= 1) sum += __shfl_xor(sum, off);
    float mu = sum / (float)D;
    float vs = 0.f;
#pragma unroll
    for (int j = 0; j < 8; ++j) {
        float dd = x[j] - mu;
        vs += dd * dd;
    }
    for (int off = 32; off; off >>= 1) vs += __shfl_xor(vs, off);
    float inv = 1.f / sqrtf(vs / (float)D + EPSL);
#pragma unroll
    for (int j = 0; j < 8; ++j) {
        float o = (x[j] - mu) * inv * g[lane + 64 * j] + bb[lane + 64 * j];
        hp[lane + 64 * j] = o;
        hbf[(size_t)row * D + lane + 64 * j] = __float2bfloat16(o);
    }
}

// ---------------- final head ----------------
__global__ void final_kernel(const float* __restrict__ h, const float* __restrict__ Wf,
                             const float* __restrict__ bf, float* __restrict__ out) {
    int b = blockIdx.x;
    int lane = threadIdx.x;
    const float* hp = h + (size_t)b * LSEQ * D;
    float acc = 0.f;
    for (int j = lane; j < D; j += 64) acc += hp[j] * Wf[j];
    for (int off = 32; off; off >>= 1) acc += __shfl_xor(acc, off);
    if (lane == 0) out[b] = acc + bf[0];
}

extern "C" void kernel_launch(void* const* d_in, const int* in_sizes, int n_in,
                              void* d_out, int out_size, void* d_ws, size_t ws_size,
                              hipStream_t stream) {
    (void)in_sizes; (void)n_in; (void)out_size; (void)ws_size;
    const float* x   = (const float*)d_in[0];
    const float* We  = (const float*)d_in[1];
    const float* be  = (const float*)d_in[2];
    const float* cls = (const float*)d_in[3];
    const float* Wq  = (const float*)d_in[4];
    const float* bq  = (const float*)d_in[5];
    const float* Wk  = (const float*)d_in[6];
    const float* bk  = (const float*)d_in[7];
    const float* Wv  = (const float*)d_in[8];
    const float* bv  = (const float*)d_in[9];
    const float* Wo  = (const float*)d_in[10];
    const float* bo  = (const float*)d_in[11];
    const float* g1  = (const float*)d_in[12];
    const float* b1  = (const float*)d_in[13];
    const float* g2  = (const float*)d_in[14];
    const float* b2  = (const float*)d_in[15];
    const float* W1  = (const float*)d_in[16];
    const float* bf1 = (const float*)d_in[17];
    const float* W2  = (const float*)d_in[18];
    const float* bf2 = (const float*)d_in[19];
    const float* Wf  = (const float*)d_in[20];
    const float* bff = (const float*)d_in[21];
    float* out = (float*)d_out;

    float* ws = (float*)d_ws;
    const size_t NT = (size_t)B * LSEQ * D;  // 4,194,304
    float* h    = ws;                         // [0, NT)
    float* aout = ws + NT;                    // [NT, 2NT)
    float* q    = ws + 2 * NT;                // [2NT, 3NT)
    float* kbuf = ws + 3 * NT;                // [3NT, 4NT)
    // kbf overlays aout: written after K GEMM, consumed by attn; aout written after attn.
    __hip_bfloat16* kbf    = (__hip_bfloat16*)(ws + NT);
    __hip_bfloat16* y1_bf  = (__hip_bfloat16*)(ws + 2 * NT);  // overlays q,kbuf post-attn
    __hip_bfloat16* v_bf   = (__hip_bfloat16*)(ws + 4 * NT);
    __hip_bfloat16* ctx_bf = (__hip_bfloat16*)(ws + 4 * NT + NT / 2);
    __hip_bfloat16* h_bf   = (__hip_bfloat16*)(ws + 5 * NT);
    float* wpool = ws + 5 * NT + NT / 2;
    __hip_bfloat16* wqb = (__hip_bfloat16*)wpool;
    __hip_bfloat16* wkb = wqb + (size_t)D * D;
    __hip_bfloat16* wvb = wkb + (size_t)D * D;
    __hip_bfloat16* wob = wvb + (size_t)D * D;
    __hip_bfloat16* w1b = wob + (size_t)D * D;
    __hip_bfloat16* w2b = w1b + (size_t)DFF * D;
    float* after_w = wpool + ((size_t)4 * D * D + 2 * (size_t)DFF * D) / 2;
    float* Mbuf = after_w;
    int* idx    = (int*)(Mbuf + (size_t)B * H * LSEQ);
    int* top    = idx + LU;
    float* vm   = (float*)(top + B * H * U);
    float* vpart = vm + (size_t)B * H * E;   // 128*64 floats

    const int ML = B * LSEQ;  // 8192
    dim3 gD(D / 128, ML / 128);
    dim3 gF1(DFF / 128, ML / 128);

    embed_kernel<<<(B * LSEQ * D + 255) / 256, 256, 0, stream>>>(x, We, be, cls, h, h_bf);

    for (int l = 0; l < NL; ++l) {
        const float* Wq_l = Wq + (size_t)l * D * D;
        const float* Wk_l = Wk + (size_t)l * D * D;
        const float* Wv_l = Wv + (size_t)l * D * D;
        const float* Wo_l = Wo + (size_t)l * D * D;
        const float* W1_l = W1 + (size_t)l * DFF * D;
        const float* W2_l = W2 + (size_t)l * D * DFF;

        int nDD4 = D * D / 4, nFD4 = DFF * D / 4;
        cast_bf16_kernel<<<(nDD4 + 255) / 256, 256, 0, stream>>>(Wq_l, wqb, nDD4);
        cast_bf16_kernel<<<(nDD4 + 255) / 256, 256, 0, stream>>>(Wk_l, wkb, nDD4);
        cast_bf16_kernel<<<(nDD4 + 255) / 256, 256, 0, stream>>>(Wv_l, wvb, nDD4);
        cast_bf16_kernel<<<(nDD4 + 255) / 256, 256, 0, stream>>>(Wo_l, wob, nDD4);
        cast_bf16_kernel<<<(nFD4 + 255) / 256, 256, 0, stream>>>(W1_l, w1b, nFD4);
        cast_bf16_kernel<<<(nFD4 + 255) / 256, 256, 0, stream>>>(W2_l, w2b, nFD4);

        gemm_mfma<0, 0><<<gD, 256, 0, stream>>>((const unsigned short*)h_bf,
                                                (const unsigned short*)wqb, bq + l * D, q,
                                                ML, D, D);
        gemm_mfma<0, 0><<<gD, 256, 0, stream>>>((const unsigned short*)h_bf,
                                                (const unsigned short*)wkb, bk + l * D, kbuf,
                                                ML, D, D);
        gemm_mfma<0, 1><<<gD, 256, 0, stream>>>((const unsigned short*)h_bf,
                                                (const unsigned short*)wvb, bv + l * D, v_bf,
                                                ML, D, D);
        cast_bf16_kernel<<<((int)(NT / 4) + 255) / 256, 256, 0, stream>>>(kbuf, kbf,
                                                                          (int)(NT / 4));

        idx_kernel<<<(HALF_LU + 255) / 256, 256, 0, stream>>>(idx, l);
        mscore_kernel<<<B * LSEQ, 256, 0, stream>>>(q, kbuf, idx, Mbuf);
        topk_kernel<<<B * H, 256, 0, stream>>>(Mbuf, top);
        vmean_part<<<B * H * 8, 256, 0, stream>>>(v_bf, vpart);
        vmean_reduce<<<4, 256, 0, stream>>>(vpart, vm);
        fill_ctx<<<(B * LSEQ * D + 255) / 256, 256, 0, stream>>>(vm, ctx_bf);
        attn_kernel<<<B * H * U, 256, 0, stream>>>(q, kbf, v_bf, top, ctx_bf);

        gemm_mfma<0, 0><<<gD, 256, 0, stream>>>((const unsigned short*)ctx_bf,
                                                (const unsigned short*)wob, bo + l * D, aout,
                                                ML, D, D);
        add_ln_kernel<<<ML, 64, 0, stream>>>(h, aout, g1 + l * D, b1 + l * D, h_bf);

        gemm_mfma<1, 1><<<gF1, 256, 0, stream>>>((const unsigned short*)h_bf,
                                                 (const unsigned short*)w1b, bf1 + l * DFF,
                                                 y1_bf, ML, DFF, D);
        gemm_mfma<0, 0><<<gD, 256, 0, stream>>>((const unsigned short*)y1_bf,
                                                (const unsigned short*)w2b, bf2 + l * D, aout,
                                                ML, D, DFF);
        add_ln_kernel<<<ML, 64, 0, stream>>>(h, aout, g2 + l * D, b2 + l * D, h_bf);
    }

    final_kernel<<<B, 64, 0, stream>>>(h, Wf, bff, out);
}

// Round 4
// 1053.733 us; speedup vs baseline: 3.1839x; 1.2410x over previous
//
#include <hip/hip_runtime.h>
#include <hip/hip_bf16.h>
#include <math.h>
#include <stdint.h>

#define B 2
#define S 4095
#define LSEQ 4096
#define F_IN 32
#define D 512
#define H 8
#define E 64
#define DFF 2048
#define NL 2
#define U 45
#define EPSL 1e-5f
#define LU (LSEQ * U)
#define HALF_LU (LU / 2)
#define NS 32
#define SLICE 128

typedef __attribute__((ext_vector_type(8))) short short8;
typedef __attribute__((ext_vector_type(4))) float f32x4;

#define GLD(gp, lp)                                                            \
    __builtin_amdgcn_global_load_lds(                                          \
        (const __attribute__((address_space(1))) void*)(gp),                   \
        (__attribute__((address_space(3))) void*)(lp), 16, 0, 0)

__device__ __forceinline__ unsigned short bf16_bits(float f) {
    __hip_bfloat16 h = __float2bfloat16(f);
    return *(unsigned short*)&h;
}

// ---------------- Threefry-2x32 (20 rounds), exactly JAX's algorithm ----------------
__device__ __forceinline__ uint32_t rotl32(uint32_t x, int r) {
    return (x << r) | (x >> (32 - r));
}

__device__ void threefry2x32(uint32_t k0, uint32_t k1, uint32_t c0, uint32_t c1,
                             uint32_t& o0, uint32_t& o1) {
    uint32_t ks2 = k0 ^ k1 ^ 0x1BD11BDAu;
    uint32_t x0 = c0 + k0, x1 = c1 + k1;
    x0 += x1; x1 = rotl32(x1, 13); x1 ^= x0;
    x0 += x1; x1 = rotl32(x1, 15); x1 ^= x0;
    x0 += x1; x1 = rotl32(x1, 26); x1 ^= x0;
    x0 += x1; x1 = rotl32(x1, 6);  x1 ^= x0;
    x0 += k1; x1 += ks2 + 1u;
    x0 += x1; x1 = rotl32(x1, 17); x1 ^= x0;
    x0 += x1; x1 = rotl32(x1, 29); x1 ^= x0;
    x0 += x1; x1 = rotl32(x1, 16); x1 ^= x0;
    x0 += x1; x1 = rotl32(x1, 24); x1 ^= x0;
    x0 += ks2; x1 += k0 + 2u;
    x0 += x1; x1 = rotl32(x1, 13); x1 ^= x0;
    x0 += x1; x1 = rotl32(x1, 15); x1 ^= x0;
    x0 += x1; x1 = rotl32(x1, 26); x1 ^= x0;
    x0 += x1; x1 = rotl32(x1, 6);  x1 ^= x0;
    x0 += k0; x1 += k1 + 3u;
    x0 += x1; x1 = rotl32(x1, 17); x1 ^= x0;
    x0 += x1; x1 = rotl32(x1, 29); x1 ^= x0;
    x0 += x1; x1 = rotl32(x1, 16); x1 ^= x0;
    x0 += x1; x1 = rotl32(x1, 24); x1 ^= x0;
    x0 += k1; x1 += ks2 + 4u;
    x0 += x1; x1 = rotl32(x1, 13); x1 ^= x0;
    x0 += x1; x1 = rotl32(x1, 15); x1 ^= x0;
    x0 += x1; x1 = rotl32(x1, 26); x1 ^= x0;
    x0 += x1; x1 = rotl32(x1, 6);  x1 ^= x0;
    x0 += ks2; x1 += k0 + 5u;
    o0 = x0; o1 = x1;
}

__global__ void idx_kernel(int* __restrict__ idx, int layer) {
    int j = blockIdx.x * blockDim.x + threadIdx.x;
    if (j >= HALF_LU) return;
    uint32_t f0, f1, a0, a1, b0, b1, o0, o1;
    threefry2x32(0u, 42u, 0u, (uint32_t)layer, f0, f1);
    threefry2x32(f0, f1, 0u, 2u, a0, a1);
    threefry2x32(f0, f1, 1u, 3u, b0, b1);
    threefry2x32(a1, b1, (uint32_t)j, (uint32_t)(j + HALF_LU), o0, o1);
    idx[j] = (int)(o0 & 4095u);
    idx[j + HALF_LU] = (int)(o1 & 4095u);
    (void)a0; (void)b0;
}

// ---------------- embed + cls + positional encoding (dual write f32 + bf16) --------
__global__ void embed_kernel(const float* __restrict__ x, const float* __restrict__ We,
                             const float* __restrict__ be, const float* __restrict__ cls,
                             float* __restrict__ h, __hip_bfloat16* __restrict__ hbf) {
    int gid = blockIdx.x * blockDim.x + threadIdx.x;
    if (gid >= B * LSEQ * D) return;
    int d = gid % D;
    int l = (gid / D) % LSEQ;
    int b = gid / (D * LSEQ);
    float v;
    if (l == 0) {
        v = cls[d];
    } else {
        const float* xr = x + ((size_t)b * S + (l - 1)) * F_IN;
        const float* wr = We + (size_t)d * F_IN;
        float acc = 0.f;
#pragma unroll
        for (int i = 0; i < F_IN; ++i) acc += xr[i] * wr[i];
        v = acc + be[d];
    }
    int i = d >> 1;
    float divv = expf((float)(2 * i) * (float)(-9.210340371976184 / 512.0));
    float ang = (float)l * divv;
    v += (d & 1) ? cosf(ang) : sinf(ang);
    h[gid] = v;
    hbf[gid] = __float2bfloat16(v);
}

// ---------------- f32 -> bf16 cast (4-wide) ----------------
__global__ void cast_bf16_kernel(const float* __restrict__ in,
                                 __hip_bfloat16* __restrict__ out, int n4) {
    int i = blockIdx.x * blockDim.x + threadIdx.x;
    if (i >= n4) return;
    float4 v = ((const float4*)in)[i];
    union { unsigned short u[4]; uint2 w; } o;
    o.u[0] = bf16_bits(v.x);
    o.u[1] = bf16_bits(v.y);
    o.u[2] = bf16_bits(v.z);
    o.u[3] = bf16_bits(v.w);
    ((uint2*)out)[i] = o.w;
}

// ---------------- bf16 MFMA GEMM: C[M,N] = A[M,K] @ W[N,K]^T + bias ----------------
template <int ACT, int OUTBF>
__global__ __launch_bounds__(256) void gemm_mfma(const unsigned short* __restrict__ A,
                                                 const unsigned short* __restrict__ W,
                                                 const float* __restrict__ bias,
                                                 void* __restrict__ Cout,
                                                 int M, int N, int K) {
    __shared__ unsigned short lds[2 * 128 * 32];
    unsigned short* As = lds;
    unsigned short* Bs = lds + 128 * 32;
    const int tid = threadIdx.x;
    const int m0 = blockIdx.y * 128, n0 = blockIdx.x * 128;
    const int wave = tid >> 6, lane = tid & 63;
    const int wm = (wave >> 1) * 64, wn = (wave & 1) * 64;
    const int quad = lane >> 4, m15 = lane & 15;
    const int srow = tid >> 2, scol = (tid & 3) * 8;
    f32x4 acc[4][4] = {};
    const unsigned short* Ag0 = A + (size_t)(m0 + srow) * K + scol;
    const unsigned short* Ag1 = A + (size_t)(m0 + srow + 64) * K + scol;
    const unsigned short* Wg0 = W + (size_t)(n0 + srow) * K + scol;
    const unsigned short* Wg1 = W + (size_t)(n0 + srow + 64) * K + scol;
    for (int k0 = 0; k0 < K; k0 += 32) {
        __syncthreads();
        GLD(Ag0 + k0, As + tid * 8);
        GLD(Ag1 + k0, As + 2048 + tid * 8);
        GLD(Wg0 + k0, Bs + tid * 8);
        GLD(Wg1 + k0, Bs + 2048 + tid * 8);
        __syncthreads();
        short8 af[4], bfr[4];
#pragma unroll
        for (int mi = 0; mi < 4; ++mi)
            af[mi] = *(const short8*)(As + (wm + mi * 16 + m15) * 32 + quad * 8);
#pragma unroll
        for (int ni = 0; ni < 4; ++ni)
            bfr[ni] = *(const short8*)(Bs + (wn + ni * 16 + m15) * 32 + quad * 8);
#pragma unroll
        for (int mi = 0; mi < 4; ++mi)
#pragma unroll
            for (int ni = 0; ni < 4; ++ni)
                acc[mi][ni] = __builtin_amdgcn_mfma_f32_16x16x32_bf16(
                    af[mi], bfr[ni], acc[mi][ni], 0, 0, 0);
    }
    float* Cf = (float*)Cout;
    __hip_bfloat16* Cb = (__hip_bfloat16*)Cout;
#pragma unroll
    for (int mi = 0; mi < 4; ++mi) {
        int mg = m0 + wm + mi * 16 + quad * 4;
#pragma unroll
        for (int ni = 0; ni < 4; ++ni) {
            int ng = n0 + wn + ni * 16 + m15;
            float bv = bias[ng];
#pragma unroll
            for (int r = 0; r < 4; ++r) {
                float v = acc[mi][ni][r] + bv;
                if (ACT == 1) v = fmaxf(v, 0.f);
                if (OUTBF == 1)
                    Cb[(size_t)(mg + r) * N + ng] = __float2bfloat16(v);
                else
                    Cf[(size_t)(mg + r) * N + ng] = v;
            }
        }
    }
}

// -------- M-score: one block per (b,l); 45 coalesced full-D K-row gathers serve 8 heads
__global__ __launch_bounds__(256) void mscore_kernel(const float* __restrict__ q,
                                                     const float* __restrict__ k,
                                                     const int* __restrict__ idx,
                                                     float* __restrict__ Mv) {
    __shared__ float Sbuf[U][8];
    __shared__ int sidx[U];
    int bid = blockIdx.x;
    int l = bid & (LSEQ - 1);
    int b = bid >> 12;
    int tid = threadIdx.x;
    const float* qr = q + ((size_t)(b * LSEQ) + l) * D;
    float2 qv = *(const float2*)(qr + 2 * tid);
    if (tid < U) sidx[tid] = idx[l * U + tid];
    __syncthreads();
    float q0 = qv.x, q1 = qv.y;
    const float* kbase = k + (size_t)(b * LSEQ) * D;
#pragma unroll 5
    for (int t = 0; t < U; ++t) {
        int kr = sidx[t];
        float2 kv = *(const float2*)(kbase + (size_t)kr * D + 2 * tid);
        float p = q0 * kv.x + q1 * kv.y;
        p += __shfl_xor(p, 1);
        p += __shfl_xor(p, 2);
        p += __shfl_xor(p, 4);
        p += __shfl_xor(p, 8);
        p += __shfl_xor(p, 16);
        if ((tid & 31) == 0) Sbuf[t][tid >> 5] = p;
    }
    __syncthreads();
    if (tid < 8) {
        float mx = -INFINITY, sm = 0.f;
        for (int t = 0; t < U; ++t) {
            float v = Sbuf[t][tid];
            mx = fmaxf(mx, v);
            sm += v;
        }
        Mv[((size_t)b * H + tid) * LSEQ + l] = mx - sm / (float)LSEQ;
    }
}

// ---------------- top-k (u=45) per (b,h), JAX tie semantics, shuffle argmax --------
__global__ __launch_bounds__(256) void topk_kernel(const float* __restrict__ Mv,
                                                   int* __restrict__ top) {
    __shared__ float buf[LSEQ];
    __shared__ float wv[4];
    __shared__ int wi[4];
    int bh = blockIdx.x;
    int tid = threadIdx.x;
    const float* mrow = Mv + (size_t)bh * LSEQ;
    for (int i = tid; i < LSEQ; i += 256) buf[i] = mrow[i];
    __syncthreads();
    for (int t = 0; t < U; ++t) {
        float bv = -INFINITY;
        int bi = LSEQ;
        for (int i = tid; i < LSEQ; i += 256) {
            float v = buf[i];
            if (v > bv) { bv = v; bi = i; }
        }
        for (int off = 32; off; off >>= 1) {
            float v2 = __shfl_xor(bv, off);
            int i2 = __shfl_xor(bi, off);
            if (v2 > bv || (v2 == bv && i2 < bi)) { bv = v2; bi = i2; }
        }
        if ((tid & 63) == 0) { wv[tid >> 6] = bv; wi[tid >> 6] = bi; }
        __syncthreads();
        if (tid == 0) {
            float fv = wv[0]; int fi = wi[0];
            for (int w = 1; w < 4; ++w)
                if (wv[w] > fv || (wv[w] == fv && wi[w] < fi)) { fv = wv[w]; fi = wi[w]; }
            top[bh * U + t] = fi;
            buf[fi] = -INFINITY;
        }
        __syncthreads();
    }
}

// ---------------- v mean: partial (128 blocks) + reduce ----------------
__global__ __launch_bounds__(256) void vmean_part(const __hip_bfloat16* __restrict__ v,
                                                  float* __restrict__ part) {
    int blk = blockIdx.x;  // B*H*8
    int seg = blk & 7, hh = (blk >> 3) & 7, b = blk >> 6;
    int e = threadIdx.x & 63, rg = threadIdx.x >> 6;
    const __hip_bfloat16* vp =
        v + ((size_t)(b * LSEQ) + seg * 512) * D + hh * 64 + e;
    float acc = 0.f;
    for (int r = rg; r < 512; r += 4) acc += __bfloat162float(vp[(size_t)r * D]);
    __shared__ float red[4][64];
    red[rg][e] = acc;
    __syncthreads();
    if (threadIdx.x < 64)
        part[(size_t)blk * 64 + threadIdx.x] =
            red[0][threadIdx.x] + red[1][threadIdx.x] + red[2][threadIdx.x] + red[3][threadIdx.x];
}

__global__ void vmean_reduce(const float* __restrict__ part, float* __restrict__ vm) {
    int gid = blockIdx.x * blockDim.x + threadIdx.x;
    if (gid >= B * H * E) return;
    int e = gid & 63, bh = gid >> 6;
    float acc = 0.f;
#pragma unroll
    for (int s = 0; s < 8; ++s) acc += part[((size_t)bh * 8 + s) * 64 + e];
    vm[gid] = acc / (float)LSEQ;
}

// ---------------- ctx(bf16) = broadcast vmean ----------------
__global__ void fill_ctx(const float* __restrict__ vm, __hip_bfloat16* __restrict__ ctx) {
    int gid = blockIdx.x * blockDim.x + threadIdx.x;
    if (gid >= B * LSEQ * D) return;
    int d = gid % D;
    int b = gid / (D * LSEQ);
    int hh = d >> 6, e = d & 63;
    ctx[gid] = __float2bfloat16(vm[(b * H + hh) * E + e]);
}

// -------- flash-style MFMA attention partial: block = (slice, h, b) ----------------
// scores = Qr[48x64] . K_slice^T[64x128] via 16x16x32 bf16 MFMA; per-slice softmax
// partials (m_s, sumexp_s) + O_s = exp(sc-m_s).V written to workspace.
__global__ __launch_bounds__(256) void attn_part(const float* __restrict__ q,
                                                 const __hip_bfloat16* __restrict__ kbf,
                                                 const __hip_bfloat16* __restrict__ vbf,
                                                 const int* __restrict__ top,
                                                 float* __restrict__ Opart,
                                                 float* __restrict__ msum) {
    __shared__ unsigned short Qs[48 * 72];    // pad 72: conflict-free b128 A-frag reads
    __shared__ unsigned short Ks[SLICE * 72];
    __shared__ unsigned short Vs[SLICE * 68]; // pad 68: 2-way (free) strided u16 reads
    __shared__ unsigned short Ps[48 * 136];   // pad 136: conflict-free b128 A-frag reads
    __shared__ float mred[48][4];
    __shared__ float sred[48][4];
    const int slice = blockIdx.x, hh = blockIdx.y, b = blockIdx.z;
    const int bh = b * H + hh;
    const int tid = threadIdx.x;
    const int s0 = slice * SLICE;
    // stage Qs: gather top rows (f32 -> bf16), rows 45..47 zero-padded
    for (int i = tid; i < 48 * 64; i += 256) {
        int t = i >> 6, e = i & 63;
        float v = 0.f;
        if (t < U) {
            int r = top[bh * U + t];
            v = q[((size_t)(b * LSEQ) + r) * D + hh * E + e];
        }
        Qs[t * 72 + e] = bf16_bits(v);
    }
    // stage Ks (uint4 = 8 bf16)
    {
        const uint4* src = (const uint4*)(kbf + ((size_t)(b * LSEQ) + s0) * D + hh * E);
        for (int i = tid; i < SLICE * 8; i += 256) {
            int r = i >> 3, c = i & 7;
            uint4 d = src[(size_t)r * 64 + c];
            *(uint4*)(Ks + r * 72 + c * 8) = d;
        }
    }
    // stage Vs (uint2 = 4 bf16)
    {
        const uint2* src = (const uint2*)(vbf + ((size_t)(b * LSEQ) + s0) * D + hh * E);
        for (int i = tid; i < SLICE * 16; i += 256) {
            int r = i >> 4, c = i & 15;
            uint2 d = src[(size_t)r * 128 + c];
            *(uint2*)(Vs + r * 68 + c * 4) = d;
        }
    }
    __syncthreads();
    const int wave = tid >> 6, lane = tid & 63;
    const int quad = lane >> 4, m15 = lane & 15;
    const int wc = wave * 32;  // this wave's col offset within the 128-col slice
    // ---- scores: 3 M-tiles x 2 N-tiles x 2 K-steps ----
    f32x4 acc[3][2] = {};
#pragma unroll
    for (int ks = 0; ks < 2; ++ks) {
        short8 af[3], bfr[2];
#pragma unroll
        for (int mt = 0; mt < 3; ++mt)
            af[mt] = *(const short8*)(Qs + (mt * 16 + m15) * 72 + ks * 32 + quad * 8);
#pragma unroll
        for (int nt = 0; nt < 2; ++nt)
            bfr[nt] = *(const short8*)(Ks + (wc + nt * 16 + m15) * 72 + ks * 32 + quad * 8);
#pragma unroll
        for (int mt = 0; mt < 3; ++mt)
#pragma unroll
            for (int nt = 0; nt < 2; ++nt)
                acc[mt][nt] = __builtin_amdgcn_mfma_f32_16x16x32_bf16(
                    af[mt], bfr[nt], acc[mt][nt], 0, 0, 0);
    }
    float sc[3][2][4];
#pragma unroll
    for (int mt = 0; mt < 3; ++mt)
#pragma unroll
        for (int nt = 0; nt < 2; ++nt)
#pragma unroll
            for (int r = 0; r < 4; ++r) sc[mt][nt][r] = acc[mt][nt][r] * 0.125f;
    // per-wave row max over its 32 cols
#pragma unroll
    for (int mt = 0; mt < 3; ++mt)
#pragma unroll
        for (int r = 0; r < 4; ++r) {
            float mv = fmaxf(sc[mt][0][r], sc[mt][1][r]);
            mv = fmaxf(mv, __shfl_xor(mv, 1));
            mv = fmaxf(mv, __shfl_xor(mv, 2));
            mv = fmaxf(mv, __shfl_xor(mv, 4));
            mv = fmaxf(mv, __shfl_xor(mv, 8));
            if (m15 == 0) mred[mt * 16 + quad * 4 + r][wave] = mv;
        }
    __syncthreads();
    // combined slice max, exp, per-wave sums, write P (bf16)
#pragma unroll
    for (int mt = 0; mt < 3; ++mt)
#pragma unroll
        for (int r = 0; r < 4; ++r) {
            int row = mt * 16 + quad * 4 + r;
            float ms = fmaxf(fmaxf(mred[row][0], mred[row][1]),
                             fmaxf(mred[row][2], mred[row][3]));
            float p0 = __expf(sc[mt][0][r] - ms);
            float p1 = __expf(sc[mt][1][r] - ms);
            float sv = p0 + p1;
            sv += __shfl_xor(sv, 1);
            sv += __shfl_xor(sv, 2);
            sv += __shfl_xor(sv, 4);
            sv += __shfl_xor(sv, 8);
            if (m15 == 0) sred[row][wave] = sv;
            Ps[row * 136 + wc + m15] = bf16_bits(p0);
            Ps[row * 136 + wc + 16 + m15] = bf16_bits(p1);
        }
    __syncthreads();
    if (tid < U) {
        float mm = fmaxf(fmaxf(mred[tid][0], mred[tid][1]),
                         fmaxf(mred[tid][2], mred[tid][3]));
        float ss = sred[tid][0] + sred[tid][1] + sred[tid][2] + sred[tid][3];
        size_t base = (((size_t)bh * NS + slice) * U + tid) * 2;
        msum[base] = mm;
        msum[base + 1] = ss;
    }
    // ---- PV: O_s[48x64] = P[48x128] . V[128x64]; wave handles 16 output cols ----
    f32x4 apv[3] = {};
#pragma unroll
    for (int ks = 0; ks < 4; ++ks) {
        short8 bv;
#pragma unroll
        for (int j = 0; j < 8; ++j)
            bv[j] = (short)Vs[(ks * 32 + quad * 8 + j) * 68 + wave * 16 + m15];
        short8 af2[3];
#pragma unroll
        for (int mt = 0; mt < 3; ++mt)
            af2[mt] = *(const short8*)(Ps + (mt * 16 + m15) * 136 + ks * 32 + quad * 8);
#pragma unroll
        for (int mt = 0; mt < 3; ++mt)
            apv[mt] = __builtin_amdgcn_mfma_f32_16x16x32_bf16(af2[mt], bv, apv[mt], 0, 0, 0);
    }
    size_t obase = ((size_t)bh * NS + slice) * U;
#pragma unroll
    for (int mt = 0; mt < 3; ++mt)
#pragma unroll
        for (int r = 0; r < 4; ++r) {
            int row = mt * 16 + quad * 4 + r;
            if (row < U)
                Opart[(obase + row) * 64 + wave * 16 + m15] = apv[mt][r];
        }
}

// -------- combine slice partials, scatter into ctx at the selected rows ------------
__global__ __launch_bounds__(64) void attn_reduce(const float* __restrict__ Opart,
                                                  const float* __restrict__ msum,
                                                  const int* __restrict__ top,
                                                  __hip_bfloat16* __restrict__ ctx) {
    int t = blockIdx.x % U;
    int bh = blockIdx.x / U;
    int b = bh >> 3, hh = bh & 7;
    int lane = threadIdx.x;
    float m_s = -INFINITY, ss = 0.f;
    if (lane < NS) {
        size_t base = (((size_t)bh * NS + lane) * U + t) * 2;
        m_s = msum[base];
        ss = msum[base + 1];
    }
    float M = m_s;
    for (int off = 32; off; off >>= 1) M = fmaxf(M, __shfl_xor(M, off));
    float e_s = (lane < NS) ? __expf(m_s - M) : 0.f;
    float d = ss * e_s;
    for (int off = 32; off; off >>= 1) d += __shfl_xor(d, off);
    float acc = 0.f;
    for (int s = 0; s < NS; ++s) {
        float w = __shfl(e_s, s);
        acc += w * Opart[(((size_t)bh * NS + s) * U + t) * 64 + lane];
    }
    int r = top[bh * U + t];
    ctx[((size_t)(b * LSEQ) + r) * D + hh * E + lane] = __float2bfloat16(acc / d);
}

// -------- h = LayerNorm(h + a) * g + b, one wave per row, dual write f32+bf16 -------
__global__ __launch_bounds__(64) void add_ln_kernel(float* __restrict__ h,
                                                    const float* __restrict__ a,
                                                    const float* __restrict__ g,
                                                    const float* __restrict__ bb,
                                                    __hip_bfloat16* __restrict__ hbf) {
    int row = blockIdx.x;
    int lane = threadIdx.x;
    float* hp = h + (size_t)row * D;
    const float* ap = a + (size_t)row * D;
    float x[8];
    float sum = 0.f;
#pragma unroll
    for (int j = 0; j < 8; ++j) {
        x[j] = hp[lane + 64 * j] + ap[lane + 64 * j];
        sum += x[j];
    }
    for (int off = 32; off; off >>= 1) sum += __shfl_xor(sum, off);
    float mu = sum / (float)D;
    float vs = 0.f;
#pragma unroll
    for (int j = 0; j < 8; ++j) {
        float dd = x[j] - mu;
        vs += dd * dd;
    }
    for (int off = 32; off; off >>= 1) vs += __shfl_xor(vs, off);
    float inv = 1.f / sqrtf(vs / (float)D + EPSL);
#pragma unroll
    for (int j = 0; j < 8; ++j) {
        float o = (x[j] - mu) * inv * g[lane + 64 * j] + bb[lane + 64 * j];
        hp[lane + 64 * j] = o;
        hbf[(size_t)row * D + lane + 64 * j] = __float2bfloat16(o);
    }
}

// ---------------- final head ----------------
__global__ void final_kernel(const float* __restrict__ h, const float* __restrict__ Wf,
                             const float* __restrict__ bf, float* __restrict__ out) {
    int b = blockIdx.x;
    int lane = threadIdx.x;
    const float* hp = h + (size_t)b * LSEQ * D;
    float acc = 0.f;
    for (int j = lane; j < D; j += 64) acc += hp[j] * Wf[j];
    for (int off = 32; off; off >>= 1) acc += __shfl_xor(acc, off);
    if (lane == 0) out[b] = acc + bf[0];
}

extern "C" void kernel_launch(void* const* d_in, const int* in_sizes, int n_in,
                              void* d_out, int out_size, void* d_ws, size_t ws_size,
                              hipStream_t stream) {
    (void)in_sizes; (void)n_in; (void)out_size; (void)ws_size;
    const float* x   = (const float*)d_in[0];
    const float* We  = (const float*)d_in[1];
    const float* be  = (const float*)d_in[2];
    const float* cls = (const float*)d_in[3];
    const float* Wq  = (const float*)d_in[4];
    const float* bq  = (const float*)d_in[5];
    const float* Wk  = (const float*)d_in[6];
    const float* bk  = (const float*)d_in[7];
    const float* Wv  = (const float*)d_in[8];
    const float* bv  = (const float*)d_in[9];
    const float* Wo  = (const float*)d_in[10];
    const float* bo  = (const float*)d_in[11];
    const float* g1  = (const float*)d_in[12];
    const float* b1  = (const float*)d_in[13];
    const float* g2  = (const float*)d_in[14];
    const float* b2  = (const float*)d_in[15];
    const float* W1  = (const float*)d_in[16];
    const float* bf1 = (const float*)d_in[17];
    const float* W2  = (const float*)d_in[18];
    const float* bf2 = (const float*)d_in[19];
    const float* Wf  = (const float*)d_in[20];
    const float* bff = (const float*)d_in[21];
    float* out = (float*)d_out;

    float* ws = (float*)d_ws;
    const size_t NT = (size_t)B * LSEQ * D;  // 4,194,304
    float* h    = ws;                         // [0, NT)
    float* aout = ws + NT;                    // [NT, 2NT)
    float* q    = ws + 2 * NT;                // [2NT, 3NT)
    float* kbuf = ws + 3 * NT;                // [3NT, 4NT)
    // kbf overlays aout: written after K GEMM, consumed by attn; aout written after attn.
    __hip_bfloat16* kbf    = (__hip_bfloat16*)(ws + NT);
    __hip_bfloat16* y1_bf  = (__hip_bfloat16*)(ws + 2 * NT);  // overlays q,kbuf post-attn
    __hip_bfloat16* v_bf   = (__hip_bfloat16*)(ws + 4 * NT);
    __hip_bfloat16* ctx_bf = (__hip_bfloat16*)(ws + 4 * NT + NT / 2);
    __hip_bfloat16* h_bf   = (__hip_bfloat16*)(ws + 5 * NT);
    // attention partials overlay kbuf (dead after mscore)
    float* Opart = ws + 3 * NT;                       // B*H*NS*U*64 = 1,474,560 floats
    float* msumb = Opart + (size_t)B * H * NS * U * 64;  // B*H*NS*U*2 floats
    float* wpool = ws + 5 * NT + NT / 2;
    __hip_bfloat16* wqb = (__hip_bfloat16*)wpool;
    __hip_bfloat16* wkb = wqb + (size_t)D * D;
    __hip_bfloat16* wvb = wkb + (size_t)D * D;
    __hip_bfloat16* wob = wvb + (size_t)D * D;
    __hip_bfloat16* w1b = wob + (size_t)D * D;
    __hip_bfloat16* w2b = w1b + (size_t)DFF * D;
    float* after_w = wpool + ((size_t)4 * D * D + 2 * (size_t)DFF * D) / 2;
    float* Mbuf = after_w;
    int* idx    = (int*)(Mbuf + (size_t)B * H * LSEQ);
    int* top    = idx + LU;
    float* vm   = (float*)(top + B * H * U);
    float* vpart = vm + (size_t)B * H * E;   // 128*64 floats

    const int ML = B * LSEQ;  // 8192
    dim3 gD(D / 128, ML / 128);
    dim3 gF1(DFF / 128, ML / 128);

    embed_kernel<<<(B * LSEQ * D + 255) / 256, 256, 0, stream>>>(x, We, be, cls, h, h_bf);

    for (int l = 0; l < NL; ++l) {
        const float* Wq_l = Wq + (size_t)l * D * D;
        const float* Wk_l = Wk + (size_t)l * D * D;
        const float* Wv_l = Wv + (size_t)l * D * D;
        const float* Wo_l = Wo + (size_t)l * D * D;
        const float* W1_l = W1 + (size_t)l * DFF * D;
        const float* W2_l = W2 + (size_t)l * D * DFF;

        int nDD4 = D * D / 4, nFD4 = DFF * D / 4;
        cast_bf16_kernel<<<(nDD4 + 255) / 256, 256, 0, stream>>>(Wq_l, wqb, nDD4);
        cast_bf16_kernel<<<(nDD4 + 255) / 256, 256, 0, stream>>>(Wk_l, wkb, nDD4);
        cast_bf16_kernel<<<(nDD4 + 255) / 256, 256, 0, stream>>>(Wv_l, wvb, nDD4);
        cast_bf16_kernel<<<(nDD4 + 255) / 256, 256, 0, stream>>>(Wo_l, wob, nDD4);
        cast_bf16_kernel<<<(nFD4 + 255) / 256, 256, 0, stream>>>(W1_l, w1b, nFD4);
        cast_bf16_kernel<<<(nFD4 + 255) / 256, 256, 0, stream>>>(W2_l, w2b, nFD4);

        gemm_mfma<0, 0><<<gD, 256, 0, stream>>>((const unsigned short*)h_bf,
                                                (const unsigned short*)wqb, bq + l * D, q,
                                                ML, D, D);
        gemm_mfma<0, 0><<<gD, 256, 0, stream>>>((const unsigned short*)h_bf,
                                                (const unsigned short*)wkb, bk + l * D, kbuf,
                                                ML, D, D);
        gemm_mfma<0, 1><<<gD, 256, 0, stream>>>((const unsigned short*)h_bf,
                                                (const unsigned short*)wvb, bv + l * D, v_bf,
                                                ML, D, D);
        cast_bf16_kernel<<<((int)(NT / 4) + 255) / 256, 256, 0, stream>>>(kbuf, kbf,
                                                                          (int)(NT / 4));

        idx_kernel<<<(HALF_LU + 255) / 256, 256, 0, stream>>>(idx, l);
        mscore_kernel<<<B * LSEQ, 256, 0, stream>>>(q, kbuf, idx, Mbuf);
        topk_kernel<<<B * H, 256, 0, stream>>>(Mbuf, top);
        vmean_part<<<B * H * 8, 256, 0, stream>>>(v_bf, vpart);
        vmean_reduce<<<4, 256, 0, stream>>>(vpart, vm);
        fill_ctx<<<(B * LSEQ * D + 255) / 256, 256, 0, stream>>>(vm, ctx_bf);
        attn_part<<<dim3(NS, H, B), 256, 0, stream>>>(q, kbf, v_bf, top, Opart, msumb);
        attn_reduce<<<B * H * U, 64, 0, stream>>>(Opart, msumb, top, ctx_bf);

        gemm_mfma<0, 0><<<gD, 256, 0, stream>>>((const unsigned short*)ctx_bf,
                                                (const unsigned short*)wob, bo + l * D, aout,
                                                ML, D, D);
        add_ln_kernel<<<ML, 64, 0, stream>>>(h, aout, g1 + l * D, b1 + l * D, h_bf);

        gemm_mfma<1, 1><<<gF1, 256, 0, stream>>>((const unsigned short*)h_bf,
                                                 (const unsigned short*)w1b, bf1 + l * DFF,
                                                 y1_bf, ML, DFF, D);
        gemm_mfma<0, 0><<<gD, 256, 0, stream>>>((const unsigned short*)y1_bf,
                                                (const unsigned short*)w2b, bf2 + l * D, aout,
                                                ML, D, DFF);
        add_ln_kernel<<<ML, 64, 0, stream>>>(h, aout, g2 + l * D, b2 + l * D, h_bf);
    }

    final_kernel<<<B, 64, 0, stream>>>(h, Wf, bff, out);
}

// Round 5
// 1023.089 us; speedup vs baseline: 3.2792x; 1.0300x over previous
//
#include <hip/hip_runtime.h>
#include <hip/hip_bf16.h>
#include <math.h>
#include <stdint.h>

#define B 2
#define S 4095
#define LSEQ 4096
#define F_IN 32
#define D 512
#define H 8
#define E 64
#define DFF 2048
#define NL 2
#define U 45
#define EPSL 1e-5f
#define LU (LSEQ * U)
#define HALF_LU (LU / 2)
#define NS 32
#define SLICE 128

typedef __attribute__((ext_vector_type(8))) short short8;
typedef __attribute__((ext_vector_type(4))) float f32x4;

#define GLD(gp, lp)                                                            \
    __builtin_amdgcn_global_load_lds(                                          \
        (const __attribute__((address_space(1))) void*)(gp),                   \
        (__attribute__((address_space(3))) void*)(lp), 16, 0, 0)

__device__ __forceinline__ unsigned short bf16_bits(float f) {
    __hip_bfloat16 h = __float2bfloat16(f);
    return *(unsigned short*)&h;
}
__device__ __forceinline__ float bits_to_f32(unsigned short s) {
    union { uint32_t u; float f; } c;
    c.u = ((uint32_t)s) << 16;
    return c.f;
}

// ---------------- Threefry-2x32 (20 rounds), exactly JAX's algorithm ----------------
__device__ __forceinline__ uint32_t rotl32(uint32_t x, int r) {
    return (x << r) | (x >> (32 - r));
}

__device__ void threefry2x32(uint32_t k0, uint32_t k1, uint32_t c0, uint32_t c1,
                             uint32_t& o0, uint32_t& o1) {
    uint32_t ks2 = k0 ^ k1 ^ 0x1BD11BDAu;
    uint32_t x0 = c0 + k0, x1 = c1 + k1;
    x0 += x1; x1 = rotl32(x1, 13); x1 ^= x0;
    x0 += x1; x1 = rotl32(x1, 15); x1 ^= x0;
    x0 += x1; x1 = rotl32(x1, 26); x1 ^= x0;
    x0 += x1; x1 = rotl32(x1, 6);  x1 ^= x0;
    x0 += k1; x1 += ks2 + 1u;
    x0 += x1; x1 = rotl32(x1, 17); x1 ^= x0;
    x0 += x1; x1 = rotl32(x1, 29); x1 ^= x0;
    x0 += x1; x1 = rotl32(x1, 16); x1 ^= x0;
    x0 += x1; x1 = rotl32(x1, 24); x1 ^= x0;
    x0 += ks2; x1 += k0 + 2u;
    x0 += x1; x1 = rotl32(x1, 13); x1 ^= x0;
    x0 += x1; x1 = rotl32(x1, 15); x1 ^= x0;
    x0 += x1; x1 = rotl32(x1, 26); x1 ^= x0;
    x0 += x1; x1 = rotl32(x1, 6);  x1 ^= x0;
    x0 += k0; x1 += k1 + 3u;
    x0 += x1; x1 = rotl32(x1, 17); x1 ^= x0;
    x0 += x1; x1 = rotl32(x1, 29); x1 ^= x0;
    x0 += x1; x1 = rotl32(x1, 16); x1 ^= x0;
    x0 += x1; x1 = rotl32(x1, 24); x1 ^= x0;
    x0 += k1; x1 += ks2 + 4u;
    x0 += x1; x1 = rotl32(x1, 13); x1 ^= x0;
    x0 += x1; x1 = rotl32(x1, 15); x1 ^= x0;
    x0 += x1; x1 = rotl32(x1, 26); x1 ^= x0;
    x0 += x1; x1 = rotl32(x1, 6);  x1 ^= x0;
    x0 += ks2; x1 += k0 + 5u;
    o0 = x0; o1 = x1;
}

__global__ void idx_kernel(int* __restrict__ idx, int layer) {
    int j = blockIdx.x * blockDim.x + threadIdx.x;
    if (j >= HALF_LU) return;
    uint32_t f0, f1, a0, a1, b0, b1, o0, o1;
    threefry2x32(0u, 42u, 0u, (uint32_t)layer, f0, f1);
    threefry2x32(f0, f1, 0u, 2u, a0, a1);
    threefry2x32(f0, f1, 1u, 3u, b0, b1);
    threefry2x32(a1, b1, (uint32_t)j, (uint32_t)(j + HALF_LU), o0, o1);
    idx[j] = (int)(o0 & 4095u);
    idx[j + HALF_LU] = (int)(o1 & 4095u);
    (void)a0; (void)b0;
}

// ---------------- embed + cls + positional encoding (dual write f32 + bf16) --------
__global__ void embed_kernel(const float* __restrict__ x, const float* __restrict__ We,
                             const float* __restrict__ be, const float* __restrict__ cls,
                             float* __restrict__ h, __hip_bfloat16* __restrict__ hbf) {
    int gid = blockIdx.x * blockDim.x + threadIdx.x;
    if (gid >= B * LSEQ * D) return;
    int d = gid % D;
    int l = (gid / D) % LSEQ;
    int b = gid / (D * LSEQ);
    float v;
    if (l == 0) {
        v = cls[d];
    } else {
        const float* xr = x + ((size_t)b * S + (l - 1)) * F_IN;
        const float* wr = We + (size_t)d * F_IN;
        float acc = 0.f;
#pragma unroll
        for (int i = 0; i < F_IN; ++i) acc += xr[i] * wr[i];
        v = acc + be[d];
    }
    int i = d >> 1;
    float divv = expf((float)(2 * i) * (float)(-9.210340371976184 / 512.0));
    float ang = (float)l * divv;
    v += (d & 1) ? cosf(ang) : sinf(ang);
    h[gid] = v;
    hbf[gid] = __float2bfloat16(v);
}

// ---------------- f32 -> bf16 cast (4-wide) ----------------
__global__ void cast_bf16_kernel(const float* __restrict__ in,
                                 __hip_bfloat16* __restrict__ out, int n4) {
    int i = blockIdx.x * blockDim.x + threadIdx.x;
    if (i >= n4) return;
    float4 v = ((const float4*)in)[i];
    union { unsigned short u[4]; uint2 w; } o;
    o.u[0] = bf16_bits(v.x);
    o.u[1] = bf16_bits(v.y);
    o.u[2] = bf16_bits(v.z);
    o.u[3] = bf16_bits(v.w);
    ((uint2*)out)[i] = o.w;
}

// ---------------- bf16 MFMA GEMM: C[M,N] = A[M,K] @ W[N,K]^T + bias ----------------
template <int ACT, int OUTBF>
__global__ __launch_bounds__(256) void gemm_mfma(const unsigned short* __restrict__ A,
                                                 const unsigned short* __restrict__ W,
                                                 const float* __restrict__ bias,
                                                 void* __restrict__ Cout,
                                                 int M, int N, int K) {
    __shared__ unsigned short lds[2 * 128 * 32];
    unsigned short* As = lds;
    unsigned short* Bs = lds + 128 * 32;
    const int tid = threadIdx.x;
    const int m0 = blockIdx.y * 128, n0 = blockIdx.x * 128;
    const int wave = tid >> 6, lane = tid & 63;
    const int wm = (wave >> 1) * 64, wn = (wave & 1) * 64;
    const int quad = lane >> 4, m15 = lane & 15;
    const int srow = tid >> 2, scol = (tid & 3) * 8;
    f32x4 acc[4][4] = {};
    const unsigned short* Ag0 = A + (size_t)(m0 + srow) * K + scol;
    const unsigned short* Ag1 = A + (size_t)(m0 + srow + 64) * K + scol;
    const unsigned short* Wg0 = W + (size_t)(n0 + srow) * K + scol;
    const unsigned short* Wg1 = W + (size_t)(n0 + srow + 64) * K + scol;
    for (int k0 = 0; k0 < K; k0 += 32) {
        __syncthreads();
        GLD(Ag0 + k0, As + tid * 8);
        GLD(Ag1 + k0, As + 2048 + tid * 8);
        GLD(Wg0 + k0, Bs + tid * 8);
        GLD(Wg1 + k0, Bs + 2048 + tid * 8);
        __syncthreads();
        short8 af[4], bfr[4];
#pragma unroll
        for (int mi = 0; mi < 4; ++mi)
            af[mi] = *(const short8*)(As + (wm + mi * 16 + m15) * 32 + quad * 8);
#pragma unroll
        for (int ni = 0; ni < 4; ++ni)
            bfr[ni] = *(const short8*)(Bs + (wn + ni * 16 + m15) * 32 + quad * 8);
#pragma unroll
        for (int mi = 0; mi < 4; ++mi)
#pragma unroll
            for (int ni = 0; ni < 4; ++ni)
                acc[mi][ni] = __builtin_amdgcn_mfma_f32_16x16x32_bf16(
                    af[mi], bfr[ni], acc[mi][ni], 0, 0, 0);
    }
    float* Cf = (float*)Cout;
    __hip_bfloat16* Cb = (__hip_bfloat16*)Cout;
#pragma unroll
    for (int mi = 0; mi < 4; ++mi) {
        int mg = m0 + wm + mi * 16 + quad * 4;
#pragma unroll
        for (int ni = 0; ni < 4; ++ni) {
            int ng = n0 + wn + ni * 16 + m15;
            float bv = bias[ng];
#pragma unroll
            for (int r = 0; r < 4; ++r) {
                float v = acc[mi][ni][r] + bv;
                if (ACT == 1) v = fmaxf(v, 0.f);
                if (OUTBF == 1)
                    Cb[(size_t)(mg + r) * N + ng] = __float2bfloat16(v);
                else
                    Cf[(size_t)(mg + r) * N + ng] = v;
            }
        }
    }
}

// -------- M-score: one block per (b,l); bf16 K gathers; b = bid&1 so each XCD
// (round-robin dispatch) touches only one batch's 4 MB K -> L2-resident.
__global__ __launch_bounds__(256) void mscore_kernel(const float* __restrict__ q,
                                                     const __hip_bfloat16* __restrict__ kbf,
                                                     const int* __restrict__ idx,
                                                     float* __restrict__ Mv) {
    __shared__ float Sbuf[U][8];
    __shared__ int sidx[U];
    int bid = blockIdx.x;
    int b = bid & 1;
    int l = bid >> 1;
    int tid = threadIdx.x;
    const float* qr = q + ((size_t)(b * LSEQ) + l) * D;
    float2 qv = *(const float2*)(qr + 2 * tid);
    if (tid < U) sidx[tid] = idx[l * U + tid];
    __syncthreads();
    float q0 = qv.x, q1 = qv.y;
    const uint32_t* kbase = (const uint32_t*)(kbf + (size_t)(b * LSEQ) * D);
#pragma unroll 5
    for (int t = 0; t < U; ++t) {
        int kr = sidx[t];
        uint32_t kv = kbase[(size_t)kr * 256 + tid];
        float k0 = bits_to_f32((unsigned short)(kv & 0xffffu));
        float k1 = bits_to_f32((unsigned short)(kv >> 16));
        float p = q0 * k0 + q1 * k1;
        p += __shfl_xor(p, 1);
        p += __shfl_xor(p, 2);
        p += __shfl_xor(p, 4);
        p += __shfl_xor(p, 8);
        p += __shfl_xor(p, 16);
        if ((tid & 31) == 0) Sbuf[t][tid >> 5] = p;
    }
    __syncthreads();
    if (tid < 8) {
        float mx = -INFINITY, sm = 0.f;
        for (int t = 0; t < U; ++t) {
            float v = Sbuf[t][tid];
            mx = fmaxf(mx, v);
            sm += v;
        }
        Mv[((size_t)b * H + tid) * LSEQ + l] = mx - sm / (float)LSEQ;
    }
}

// ------- top-k (u=45) per (b,h), JAX tie semantics; incremental per-thread argmax ---
__global__ __launch_bounds__(256) void topk_kernel(const float* __restrict__ Mv,
                                                   int* __restrict__ top) {
    __shared__ float buf[LSEQ];
    __shared__ float wv[4];
    __shared__ int wi[4];
    int bh = blockIdx.x;
    int tid = threadIdx.x;
    const float* mrow = Mv + (size_t)bh * LSEQ;
    for (int i = tid; i < LSEQ; i += 256) buf[i] = mrow[i];
    __syncthreads();
    float bv = -INFINITY;
    int bi = LSEQ;
    for (int i = tid; i < LSEQ; i += 256) {
        float v = buf[i];
        if (v > bv) { bv = v; bi = i; }
    }
    for (int t = 0; t < U; ++t) {
        float cv = bv;
        int ci = bi;
        for (int off = 32; off; off >>= 1) {
            float v2 = __shfl_xor(cv, off);
            int i2 = __shfl_xor(ci, off);
            if (v2 > cv || (v2 == cv && i2 < ci)) { cv = v2; ci = i2; }
        }
        if ((tid & 63) == 0) { wv[tid >> 6] = cv; wi[tid >> 6] = ci; }
        __syncthreads();
        float fv = wv[0];
        int fi = wi[0];
        for (int w = 1; w < 4; ++w)
            if (wv[w] > fv || (wv[w] == fv && wi[w] < fi)) { fv = wv[w]; fi = wi[w]; }
        if (tid == 0) top[bh * U + t] = fi;
        if ((fi & 255) == tid) {
            buf[fi] = -INFINITY;
            bv = -INFINITY; bi = LSEQ;
            for (int i = tid; i < LSEQ; i += 256) {
                float v = buf[i];
                if (v > bv) { bv = v; bi = i; }
            }
        }
        __syncthreads();
    }
}

// ---------------- v mean: partial (128 blocks) + reduce ----------------
__global__ __launch_bounds__(256) void vmean_part(const __hip_bfloat16* __restrict__ v,
                                                  float* __restrict__ part) {
    int blk = blockIdx.x;  // B*H*8
    int seg = blk & 7, hh = (blk >> 3) & 7, b = blk >> 6;
    int e = threadIdx.x & 63, rg = threadIdx.x >> 6;
    const __hip_bfloat16* vp =
        v + ((size_t)(b * LSEQ) + seg * 512) * D + hh * 64 + e;
    float acc = 0.f;
    for (int r = rg; r < 512; r += 4) acc += __bfloat162float(vp[(size_t)r * D]);
    __shared__ float red[4][64];
    red[rg][e] = acc;
    __syncthreads();
    if (threadIdx.x < 64)
        part[(size_t)blk * 64 + threadIdx.x] =
            red[0][threadIdx.x] + red[1][threadIdx.x] + red[2][threadIdx.x] + red[3][threadIdx.x];
}

__global__ void vmean_reduce(const float* __restrict__ part, float* __restrict__ vm) {
    int gid = blockIdx.x * blockDim.x + threadIdx.x;
    if (gid >= B * H * E) return;
    int e = gid & 63, bh = gid >> 6;
    float acc = 0.f;
#pragma unroll
    for (int s = 0; s < 8; ++s) acc += part[((size_t)bh * 8 + s) * 64 + e];
    vm[gid] = acc / (float)LSEQ;
}

// ---------------- ctx(bf16) = broadcast vmean ----------------
__global__ void fill_ctx(const float* __restrict__ vm, __hip_bfloat16* __restrict__ ctx) {
    int gid = blockIdx.x * blockDim.x + threadIdx.x;
    if (gid >= B * LSEQ * D) return;
    int d = gid % D;
    int b = gid / (D * LSEQ);
    int hh = d >> 6, e = d & 63;
    ctx[gid] = __float2bfloat16(vm[(b * H + hh) * E + e]);
}

// -------- flash-style MFMA attention partial: block = (slice, h, b) ----------------
__global__ __launch_bounds__(256) void attn_part(const float* __restrict__ q,
                                                 const __hip_bfloat16* __restrict__ kbf,
                                                 const __hip_bfloat16* __restrict__ vbf,
                                                 const int* __restrict__ top,
                                                 float* __restrict__ Opart,
                                                 float* __restrict__ msum) {
    __shared__ unsigned short Qs[48 * 72];
    __shared__ unsigned short Ks[SLICE * 72];
    __shared__ unsigned short Vs[SLICE * 68];
    __shared__ unsigned short Ps[48 * 136];
    __shared__ float mred[48][4];
    __shared__ float sred[48][4];
    const int slice = blockIdx.x, hh = blockIdx.y, b = blockIdx.z;
    const int bh = b * H + hh;
    const int tid = threadIdx.x;
    const int s0 = slice * SLICE;
    for (int i = tid; i < 48 * 64; i += 256) {
        int t = i >> 6, e = i & 63;
        float v = 0.f;
        if (t < U) {
            int r = top[bh * U + t];
            v = q[((size_t)(b * LSEQ) + r) * D + hh * E + e];
        }
        Qs[t * 72 + e] = bf16_bits(v);
    }
    {
        const uint4* src = (const uint4*)(kbf + ((size_t)(b * LSEQ) + s0) * D + hh * E);
        for (int i = tid; i < SLICE * 8; i += 256) {
            int r = i >> 3, c = i & 7;
            uint4 d = src[(size_t)r * 64 + c];
            *(uint4*)(Ks + r * 72 + c * 8) = d;
        }
    }
    {
        const uint2* src = (const uint2*)(vbf + ((size_t)(b * LSEQ) + s0) * D + hh * E);
        for (int i = tid; i < SLICE * 16; i += 256) {
            int r = i >> 4, c = i & 15;
            uint2 d = src[(size_t)r * 128 + c];
            *(uint2*)(Vs + r * 68 + c * 4) = d;
        }
    }
    __syncthreads();
    const int wave = tid >> 6, lane = tid & 63;
    const int quad = lane >> 4, m15 = lane & 15;
    const int wc = wave * 32;
    f32x4 acc[3][2] = {};
#pragma unroll
    for (int ks = 0; ks < 2; ++ks) {
        short8 af[3], bfr[2];
#pragma unroll
        for (int mt = 0; mt < 3; ++mt)
            af[mt] = *(const short8*)(Qs + (mt * 16 + m15) * 72 + ks * 32 + quad * 8);
#pragma unroll
        for (int nt = 0; nt < 2; ++nt)
            bfr[nt] = *(const short8*)(Ks + (wc + nt * 16 + m15) * 72 + ks * 32 + quad * 8);
#pragma unroll
        for (int mt = 0; mt < 3; ++mt)
#pragma unroll
            for (int nt = 0; nt < 2; ++nt)
                acc[mt][nt] = __builtin_amdgcn_mfma_f32_16x16x32_bf16(
                    af[mt], bfr[nt], acc[mt][nt], 0, 0, 0);
    }
    float sc[3][2][4];
#pragma unroll
    for (int mt = 0; mt < 3; ++mt)
#pragma unroll
        for (int nt = 0; nt < 2; ++nt)
#pragma unroll
            for (int r = 0; r < 4; ++r) sc[mt][nt][r] = acc[mt][nt][r] * 0.125f;
#pragma unroll
    for (int mt = 0; mt < 3; ++mt)
#pragma unroll
        for (int r = 0; r < 4; ++r) {
            float mv = fmaxf(sc[mt][0][r], sc[mt][1][r]);
            mv = fmaxf(mv, __shfl_xor(mv, 1));
            mv = fmaxf(mv, __shfl_xor(mv, 2));
            mv = fmaxf(mv, __shfl_xor(mv, 4));
            mv = fmaxf(mv, __shfl_xor(mv, 8));
            if (m15 == 0) mred[mt * 16 + quad * 4 + r][wave] = mv;
        }
    __syncthreads();
#pragma unroll
    for (int mt = 0; mt < 3; ++mt)
#pragma unroll
        for (int r = 0; r < 4; ++r) {
            int row = mt * 16 + quad * 4 + r;
            float ms = fmaxf(fmaxf(mred[row][0], mred[row][1]),
                             fmaxf(mred[row][2], mred[row][3]));
            float p0 = __expf(sc[mt][0][r] - ms);
            float p1 = __expf(sc[mt][1][r] - ms);
            float sv = p0 + p1;
            sv += __shfl_xor(sv, 1);
            sv += __shfl_xor(sv, 2);
            sv += __shfl_xor(sv, 4);
            sv += __shfl_xor(sv, 8);
            if (m15 == 0) sred[row][wave] = sv;
            Ps[row * 136 + wc + m15] = bf16_bits(p0);
            Ps[row * 136 + wc + 16 + m15] = bf16_bits(p1);
        }
    __syncthreads();
    if (tid < U) {
        float mm = fmaxf(fmaxf(mred[tid][0], mred[tid][1]),
                         fmaxf(mred[tid][2], mred[tid][3]));
        float ss = sred[tid][0] + sred[tid][1] + sred[tid][2] + sred[tid][3];
        size_t base = (((size_t)bh * NS + slice) * U + tid) * 2;
        msum[base] = mm;
        msum[base + 1] = ss;
    }
    f32x4 apv[3] = {};
#pragma unroll
    for (int ks = 0; ks < 4; ++ks) {
        short8 bv;
#pragma unroll
        for (int j = 0; j < 8; ++j)
            bv[j] = (short)Vs[(ks * 32 + quad * 8 + j) * 68 + wave * 16 + m15];
        short8 af2[3];
#pragma unroll
        for (int mt = 0; mt < 3; ++mt)
            af2[mt] = *(const short8*)(Ps + (mt * 16 + m15) * 136 + ks * 32 + quad * 8);
#pragma unroll
        for (int mt = 0; mt < 3; ++mt)
            apv[mt] = __builtin_amdgcn_mfma_f32_16x16x32_bf16(af2[mt], bv, apv[mt], 0, 0, 0);
    }
    size_t obase = ((size_t)bh * NS + slice) * U;
#pragma unroll
    for (int mt = 0; mt < 3; ++mt)
#pragma unroll
        for (int r = 0; r < 4; ++r) {
            int row = mt * 16 + quad * 4 + r;
            if (row < U)
                Opart[(obase + row) * 64 + wave * 16 + m15] = apv[mt][r];
        }
}

// -------- combine slice partials, scatter into ctx at the selected rows ------------
__global__ __launch_bounds__(64) void attn_reduce(const float* __restrict__ Opart,
                                                  const float* __restrict__ msum,
                                                  const int* __restrict__ top,
                                                  __hip_bfloat16* __restrict__ ctx) {
    int t = blockIdx.x % U;
    int bh = blockIdx.x / U;
    int b = bh >> 3, hh = bh & 7;
    int lane = threadIdx.x;
    float m_s = -INFINITY, ss = 0.f;
    if (lane < NS) {
        size_t base = (((size_t)bh * NS + lane) * U + t) * 2;
        m_s = msum[base];
        ss = msum[base + 1];
    }
    float M = m_s;
    for (int off = 32; off; off >>= 1) M = fmaxf(M, __shfl_xor(M, off));
    float e_s = (lane < NS) ? __expf(m_s - M) : 0.f;
    float d = ss * e_s;
    for (int off = 32; off; off >>= 1) d += __shfl_xor(d, off);
    float acc = 0.f;
    for (int s = 0; s < NS; ++s) {
        float w = __shfl(e_s, s);
        acc += w * Opart[(((size_t)bh * NS + s) * U + t) * 64 + lane];
    }
    int r = top[bh * U + t];
    ctx[((size_t)(b * LSEQ) + r) * D + hh * E + lane] = __float2bfloat16(acc / d);
}

// -------- h = LayerNorm(h + a) * g + b, one wave per row, dual write f32+bf16 -------
__global__ __launch_bounds__(64) void add_ln_kernel(float* __restrict__ h,
                                                    const float* __restrict__ a,
                                                    const float* __restrict__ g,
                                                    const float* __restrict__ bb,
                                                    __hip_bfloat16* __restrict__ hbf) {
    int row = blockIdx.x;
    int lane = threadIdx.x;
    float* hp = h + (size_t)row * D;
    const float* ap = a + (size_t)row * D;
    float x[8];
    float sum = 0.f;
#pragma unroll
    for (int j = 0; j < 8; ++j) {
        x[j] = hp[lane + 64 * j] + ap[lane + 64 * j];
        sum += x[j];
    }
    for (int off = 32; off; off >>= 1) sum += __shfl_xor(sum, off);
    float mu = sum / (float)D;
    float vs = 0.f;
#pragma unroll
    for (int j = 0; j < 8; ++j) {
        float dd = x[j] - mu;
        vs += dd * dd;
    }
    for (int off = 32; off; off >>= 1) vs += __shfl_xor(vs, off);
    float inv = 1.f / sqrtf(vs / (float)D + EPSL);
#pragma unroll
    for (int j = 0; j < 8; ++j) {
        float o = (x[j] - mu) * inv * g[lane + 64 * j] + bb[lane + 64 * j];
        hp[lane + 64 * j] = o;
        hbf[(size_t)row * D + lane + 64 * j] = __float2bfloat16(o);
    }
}

// ---------------- final head ----------------
__global__ void final_kernel(const float* __restrict__ h, const float* __restrict__ Wf,
                             const float* __restrict__ bf, float* __restrict__ out) {
    int b = blockIdx.x;
    int lane = threadIdx.x;
    const float* hp = h + (size_t)b * LSEQ * D;
    float acc = 0.f;
    for (int j = lane; j < D; j += 64) acc += hp[j] * Wf[j];
    for (int off = 32; off; off >>= 1) acc += __shfl_xor(acc, off);
    if (lane == 0) out[b] = acc + bf[0];
}

extern "C" void kernel_launch(void* const* d_in, const int* in_sizes, int n_in,
                              void* d_out, int out_size, void* d_ws, size_t ws_size,
                              hipStream_t stream) {
    (void)in_sizes; (void)n_in; (void)out_size; (void)ws_size;
    const float* x   = (const float*)d_in[0];
    const float* We  = (const float*)d_in[1];
    const float* be  = (const float*)d_in[2];
    const float* cls = (const float*)d_in[3];
    const float* Wq  = (const float*)d_in[4];
    const float* bq  = (const float*)d_in[5];
    const float* Wk  = (const float*)d_in[6];
    const float* bk  = (const float*)d_in[7];
    const float* Wv  = (const float*)d_in[8];
    const float* bv  = (const float*)d_in[9];
    const float* Wo  = (const float*)d_in[10];
    const float* bo  = (const float*)d_in[11];
    const float* g1  = (const float*)d_in[12];
    const float* b1  = (const float*)d_in[13];
    const float* g2  = (const float*)d_in[14];
    const float* b2  = (const float*)d_in[15];
    const float* W1  = (const float*)d_in[16];
    const float* bf1 = (const float*)d_in[17];
    const float* W2  = (const float*)d_in[18];
    const float* bf2 = (const float*)d_in[19];
    const float* Wf  = (const float*)d_in[20];
    const float* bff = (const float*)d_in[21];
    float* out = (float*)d_out;

    float* ws = (float*)d_ws;
    const size_t NT = (size_t)B * LSEQ * D;  // 4,194,304
    float* h    = ws;                         // [0, NT)
    float* aout = ws + NT;                    // [NT, 2NT)
    float* q    = ws + 2 * NT;                // [2NT, 3NT)
    // kbf overlays aout: written by K GEMM, consumed by mscore/attn; aout written after.
    __hip_bfloat16* kbf    = (__hip_bfloat16*)(ws + NT);
    __hip_bfloat16* y1_bf  = (__hip_bfloat16*)(ws + 2 * NT);  // overlays q post-attn
    __hip_bfloat16* v_bf   = (__hip_bfloat16*)(ws + 4 * NT);
    __hip_bfloat16* ctx_bf = (__hip_bfloat16*)(ws + 4 * NT + NT / 2);
    __hip_bfloat16* h_bf   = (__hip_bfloat16*)(ws + 5 * NT);
    // attention partials live in the former kbuf region (3NT..4NT)
    float* Opart = ws + 3 * NT;                           // B*H*NS*U*64 floats
    float* msumb = Opart + (size_t)B * H * NS * U * 64;   // B*H*NS*U*2 floats
    float* wpool = ws + 5 * NT + NT / 2;
    __hip_bfloat16* wqb = (__hip_bfloat16*)wpool;
    __hip_bfloat16* wkb = wqb + (size_t)D * D;
    __hip_bfloat16* wvb = wkb + (size_t)D * D;
    __hip_bfloat16* wob = wvb + (size_t)D * D;
    __hip_bfloat16* w1b = wob + (size_t)D * D;
    __hip_bfloat16* w2b = w1b + (size_t)DFF * D;
    float* after_w = wpool + ((size_t)4 * D * D + 2 * (size_t)DFF * D) / 2;
    float* Mbuf = after_w;
    int* idx    = (int*)(Mbuf + (size_t)B * H * LSEQ);
    int* top    = idx + LU;
    float* vm   = (float*)(top + B * H * U);
    float* vpart = vm + (size_t)B * H * E;

    const int ML = B * LSEQ;  // 8192
    dim3 gD(D / 128, ML / 128);
    dim3 gF1(DFF / 128, ML / 128);

    embed_kernel<<<(B * LSEQ * D + 255) / 256, 256, 0, stream>>>(x, We, be, cls, h, h_bf);

    for (int l = 0; l < NL; ++l) {
        const float* Wq_l = Wq + (size_t)l * D * D;
        const float* Wk_l = Wk + (size_t)l * D * D;
        const float* Wv_l = Wv + (size_t)l * D * D;
        const float* Wo_l = Wo + (size_t)l * D * D;
        const float* W1_l = W1 + (size_t)l * DFF * D;
        const float* W2_l = W2 + (size_t)l * D * DFF;

        int nDD4 = D * D / 4, nFD4 = DFF * D / 4;
        cast_bf16_kernel<<<(nDD4 + 255) / 256, 256, 0, stream>>>(Wq_l, wqb, nDD4);
        cast_bf16_kernel<<<(nDD4 + 255) / 256, 256, 0, stream>>>(Wk_l, wkb, nDD4);
        cast_bf16_kernel<<<(nDD4 + 255) / 256, 256, 0, stream>>>(Wv_l, wvb, nDD4);
        cast_bf16_kernel<<<(nDD4 + 255) / 256, 256, 0, stream>>>(Wo_l, wob, nDD4);
        cast_bf16_kernel<<<(nFD4 + 255) / 256, 256, 0, stream>>>(W1_l, w1b, nFD4);
        cast_bf16_kernel<<<(nFD4 + 255) / 256, 256, 0, stream>>>(W2_l, w2b, nFD4);

        gemm_mfma<0, 0><<<gD, 256, 0, stream>>>((const unsigned short*)h_bf,
                                                (const unsigned short*)wqb, bq + l * D, q,
                                                ML, D, D);
        gemm_mfma<0, 1><<<gD, 256, 0, stream>>>((const unsigned short*)h_bf,
                                                (const unsigned short*)wkb, bk + l * D, kbf,
                                                ML, D, D);
        gemm_mfma<0, 1><<<gD, 256, 0, stream>>>((const unsigned short*)h_bf,
                                                (const unsigned short*)wvb, bv + l * D, v_bf,
                                                ML, D, D);

        idx_kernel<<<(HALF_LU + 255) / 256, 256, 0, stream>>>(idx, l);
        mscore_kernel<<<B * LSEQ, 256, 0, stream>>>(q, kbf, idx, Mbuf);
        topk_kernel<<<B * H, 256, 0, stream>>>(Mbuf, top);
        vmean_part<<<B * H * 8, 256, 0, stream>>>(v_bf, vpart);
        vmean_reduce<<<4, 256, 0, stream>>>(vpart, vm);
        fill_ctx<<<(B * LSEQ * D + 255) / 256, 256, 0, stream>>>(vm, ctx_bf);
        attn_part<<<dim3(NS, H, B), 256, 0, stream>>>(q, kbf, v_bf, top, Opart, msumb);
        attn_reduce<<<B * H * U, 64, 0, stream>>>(Opart, msumb, top, ctx_bf);

        gemm_mfma<0, 0><<<gD, 256, 0, stream>>>((const unsigned short*)ctx_bf,
                                                (const unsigned short*)wob, bo + l * D, aout,
                                                ML, D, D);
        add_ln_kernel<<<ML, 64, 0, stream>>>(h, aout, g1 + l * D, b1 + l * D, h_bf);

        gemm_mfma<1, 1><<<gF1, 256, 0, stream>>>((const unsigned short*)h_bf,
                                                 (const unsigned short*)w1b, bf1 + l * DFF,
                                                 y1_bf, ML, DFF, D);
        gemm_mfma<0, 0><<<gD, 256, 0, stream>>>((const unsigned short*)y1_bf,
                                                (const unsigned short*)w2b, bf2 + l * D, aout,
                                                ML, D, DFF);
        add_ln_kernel<<<ML, 64, 0, stream>>>(h, aout, g2 + l * D, b2 + l * D, h_bf);
    }

    final_kernel<<<B, 64, 0, stream>>>(h, Wf, bff, out);
}

// Round 6
// 880.221 us; speedup vs baseline: 3.8115x; 1.1623x over previous
//
#include <hip/hip_runtime.h>
#include <hip/hip_bf16.h>
#include <math.h>
#include <stdint.h>

#define B 2
#define S 4095
#define LSEQ 4096
#define F_IN 32
#define D 512
#define H 8
#define E 64
#define DFF 2048
#define NL 2
#define U 45
#define EPSL 1e-5f
#define LU (LSEQ * U)
#define HALF_LU (LU / 2)
#define NS 32
#define SLICE 128

typedef __attribute__((ext_vector_type(8))) short short8;
typedef __attribute__((ext_vector_type(4))) float f32x4;

#define GLD(gp, lp)                                                            \
    __builtin_amdgcn_global_load_lds(                                          \
        (const __attribute__((address_space(1))) void*)(gp),                   \
        (__attribute__((address_space(3))) void*)(lp), 16, 0, 0)

__device__ __forceinline__ unsigned short bf16_bits(float f) {
    __hip_bfloat16 h = __float2bfloat16(f);
    return *(unsigned short*)&h;
}
__device__ __forceinline__ float bits_to_f32(unsigned short s) {
    union { uint32_t u; float f; } c;
    c.u = ((uint32_t)s) << 16;
    return c.f;
}

// ---------------- Threefry-2x32 (20 rounds), exactly JAX's algorithm ----------------
__device__ __forceinline__ uint32_t rotl32(uint32_t x, int r) {
    return (x << r) | (x >> (32 - r));
}

__device__ void threefry2x32(uint32_t k0, uint32_t k1, uint32_t c0, uint32_t c1,
                             uint32_t& o0, uint32_t& o1) {
    uint32_t ks2 = k0 ^ k1 ^ 0x1BD11BDAu;
    uint32_t x0 = c0 + k0, x1 = c1 + k1;
    x0 += x1; x1 = rotl32(x1, 13); x1 ^= x0;
    x0 += x1; x1 = rotl32(x1, 15); x1 ^= x0;
    x0 += x1; x1 = rotl32(x1, 26); x1 ^= x0;
    x0 += x1; x1 = rotl32(x1, 6);  x1 ^= x0;
    x0 += k1; x1 += ks2 + 1u;
    x0 += x1; x1 = rotl32(x1, 17); x1 ^= x0;
    x0 += x1; x1 = rotl32(x1, 29); x1 ^= x0;
    x0 += x1; x1 = rotl32(x1, 16); x1 ^= x0;
    x0 += x1; x1 = rotl32(x1, 24); x1 ^= x0;
    x0 += ks2; x1 += k0 + 2u;
    x0 += x1; x1 = rotl32(x1, 13); x1 ^= x0;
    x0 += x1; x1 = rotl32(x1, 15); x1 ^= x0;
    x0 += x1; x1 = rotl32(x1, 26); x1 ^= x0;
    x0 += x1; x1 = rotl32(x1, 6);  x1 ^= x0;
    x0 += k0; x1 += k1 + 3u;
    x0 += x1; x1 = rotl32(x1, 17); x1 ^= x0;
    x0 += x1; x1 = rotl32(x1, 29); x1 ^= x0;
    x0 += x1; x1 = rotl32(x1, 16); x1 ^= x0;
    x0 += x1; x1 = rotl32(x1, 24); x1 ^= x0;
    x0 += k1; x1 += ks2 + 4u;
    x0 += x1; x1 = rotl32(x1, 13); x1 ^= x0;
    x0 += x1; x1 = rotl32(x1, 15); x1 ^= x0;
    x0 += x1; x1 = rotl32(x1, 26); x1 ^= x0;
    x0 += x1; x1 = rotl32(x1, 6);  x1 ^= x0;
    x0 += ks2; x1 += k0 + 5u;
    o0 = x0; o1 = x1;
}

__global__ void idx_kernel(int* __restrict__ idx, int layer) {
    int j = blockIdx.x * blockDim.x + threadIdx.x;
    if (j >= HALF_LU) return;
    uint32_t f0, f1, a0, a1, b0, b1, o0, o1;
    threefry2x32(0u, 42u, 0u, (uint32_t)layer, f0, f1);
    threefry2x32(f0, f1, 0u, 2u, a0, a1);
    threefry2x32(f0, f1, 1u, 3u, b0, b1);
    threefry2x32(a1, b1, (uint32_t)j, (uint32_t)(j + HALF_LU), o0, o1);
    idx[j] = (int)(o0 & 4095u);
    idx[j + HALF_LU] = (int)(o1 & 4095u);
    (void)a0; (void)b0;
}

// ---------------- embed + cls + positional encoding (dual write f32 + bf16) --------
__global__ void embed_kernel(const float* __restrict__ x, const float* __restrict__ We,
                             const float* __restrict__ be, const float* __restrict__ cls,
                             float* __restrict__ h, __hip_bfloat16* __restrict__ hbf) {
    int gid = blockIdx.x * blockDim.x + threadIdx.x;
    if (gid >= B * LSEQ * D) return;
    int d = gid % D;
    int l = (gid / D) % LSEQ;
    int b = gid / (D * LSEQ);
    float v;
    if (l == 0) {
        v = cls[d];
    } else {
        const float* xr = x + ((size_t)b * S + (l - 1)) * F_IN;
        const float* wr = We + (size_t)d * F_IN;
        float acc = 0.f;
#pragma unroll
        for (int i = 0; i < F_IN; ++i) acc += xr[i] * wr[i];
        v = acc + be[d];
    }
    int i = d >> 1;
    float divv = expf((float)(2 * i) * (float)(-9.210340371976184 / 512.0));
    float ang = (float)l * divv;
    v += (d & 1) ? cosf(ang) : sinf(ang);
    h[gid] = v;
    hbf[gid] = __float2bfloat16(v);
}

// ---------------- f32 -> bf16 cast (4-wide) ----------------
__global__ void cast_bf16_kernel(const float* __restrict__ in,
                                 __hip_bfloat16* __restrict__ out, int n4) {
    int i = blockIdx.x * blockDim.x + threadIdx.x;
    if (i >= n4) return;
    float4 v = ((const float4*)in)[i];
    union { unsigned short u[4]; uint2 w; } o;
    o.u[0] = bf16_bits(v.x);
    o.u[1] = bf16_bits(v.y);
    o.u[2] = bf16_bits(v.z);
    o.u[3] = bf16_bits(v.w);
    ((uint2*)out)[i] = o.w;
}

// ---------------- bf16 MFMA GEMM: C[M,N] = A[M,K] @ W[N,K]^T + bias ----------------
template <int ACT, int OUTBF>
__global__ __launch_bounds__(256) void gemm_mfma(const unsigned short* __restrict__ A,
                                                 const unsigned short* __restrict__ W,
                                                 const float* __restrict__ bias,
                                                 void* __restrict__ Cout,
                                                 int M, int N, int K) {
    __shared__ unsigned short lds[2 * 128 * 32];
    unsigned short* As = lds;
    unsigned short* Bs = lds + 128 * 32;
    const int tid = threadIdx.x;
    const int m0 = blockIdx.y * 128, n0 = blockIdx.x * 128;
    const int wave = tid >> 6, lane = tid & 63;
    const int wm = (wave >> 1) * 64, wn = (wave & 1) * 64;
    const int quad = lane >> 4, m15 = lane & 15;
    const int srow = tid >> 2, scol = (tid & 3) * 8;
    f32x4 acc[4][4] = {};
    const unsigned short* Ag0 = A + (size_t)(m0 + srow) * K + scol;
    const unsigned short* Ag1 = A + (size_t)(m0 + srow + 64) * K + scol;
    const unsigned short* Wg0 = W + (size_t)(n0 + srow) * K + scol;
    const unsigned short* Wg1 = W + (size_t)(n0 + srow + 64) * K + scol;
    for (int k0 = 0; k0 < K; k0 += 32) {
        __syncthreads();
        GLD(Ag0 + k0, As + tid * 8);
        GLD(Ag1 + k0, As + 2048 + tid * 8);
        GLD(Wg0 + k0, Bs + tid * 8);
        GLD(Wg1 + k0, Bs + 2048 + tid * 8);
        __syncthreads();
        short8 af[4], bfr[4];
#pragma unroll
        for (int mi = 0; mi < 4; ++mi)
            af[mi] = *(const short8*)(As + (wm + mi * 16 + m15) * 32 + quad * 8);
#pragma unroll
        for (int ni = 0; ni < 4; ++ni)
            bfr[ni] = *(const short8*)(Bs + (wn + ni * 16 + m15) * 32 + quad * 8);
#pragma unroll
        for (int mi = 0; mi < 4; ++mi)
#pragma unroll
            for (int ni = 0; ni < 4; ++ni)
                acc[mi][ni] = __builtin_amdgcn_mfma_f32_16x16x32_bf16(
                    af[mi], bfr[ni], acc[mi][ni], 0, 0, 0);
    }
    float* Cf = (float*)Cout;
    __hip_bfloat16* Cb = (__hip_bfloat16*)Cout;
#pragma unroll
    for (int mi = 0; mi < 4; ++mi) {
        int mg = m0 + wm + mi * 16 + quad * 4;
#pragma unroll
        for (int ni = 0; ni < 4; ++ni) {
            int ng = n0 + wn + ni * 16 + m15;
            float bv = bias[ng];
#pragma unroll
            for (int r = 0; r < 4; ++r) {
                float v = acc[mi][ni][r] + bv;
                if (ACT == 1) v = fmaxf(v, 0.f);
                if (OUTBF == 1)
                    Cb[(size_t)(mg + r) * N + ng] = __float2bfloat16(v);
                else
                    Cf[(size_t)(mg + r) * N + ng] = v;
            }
        }
    }
}

// -------- M-score: block per (b,l); one WAVE per sampled row (full 1KB coalesced),
// lane j holds dims [8j,8j+8): only 3 shuffles per row (xor 1/2/4 in 8-lane head grp).
__global__ __launch_bounds__(256) void mscore_kernel(const float* __restrict__ q,
                                                     const __hip_bfloat16* __restrict__ kbf,
                                                     const int* __restrict__ idx,
                                                     float* __restrict__ Mv) {
    __shared__ float Sbuf[U][8];
    __shared__ int sidx[U];
    int bid = blockIdx.x;
    int b = bid & 1;
    int l = bid >> 1;
    int tid = threadIdx.x;
    int wave = tid >> 6, lane = tid & 63;
    if (tid < U) sidx[tid] = idx[l * U + tid];
    const float* qr = q + ((size_t)(b * LSEQ) + l) * D + lane * 8;
    float4 qa = *(const float4*)qr;
    float4 qb = *(const float4*)(qr + 4);
    __syncthreads();
    const unsigned short* kbase = (const unsigned short*)(kbf + (size_t)(b * LSEQ) * D);
    for (int t = wave; t < U; t += 4) {
        int kr = sidx[t];
        union { uint4 u; unsigned short s[8]; } kv;
        kv.u = *(const uint4*)(kbase + (size_t)kr * D + lane * 8);
        float p = qa.x * bits_to_f32(kv.s[0]) + qa.y * bits_to_f32(kv.s[1]) +
                  qa.z * bits_to_f32(kv.s[2]) + qa.w * bits_to_f32(kv.s[3]) +
                  qb.x * bits_to_f32(kv.s[4]) + qb.y * bits_to_f32(kv.s[5]) +
                  qb.z * bits_to_f32(kv.s[6]) + qb.w * bits_to_f32(kv.s[7]);
        p += __shfl_xor(p, 1);
        p += __shfl_xor(p, 2);
        p += __shfl_xor(p, 4);
        if ((lane & 7) == 0) Sbuf[t][lane >> 3] = p;
    }
    __syncthreads();
    if (tid < 8) {
        float mx = -INFINITY, sm = 0.f;
        for (int t = 0; t < U; ++t) {
            float v = Sbuf[t][tid];
            mx = fmaxf(mx, v);
            sm += v;
        }
        Mv[((size_t)b * H + tid) * LSEQ + l] = mx - sm / (float)LSEQ;
    }
}

// ------- top-k (u=45) per (b,h), JAX tie semantics; incremental per-thread argmax ---
__global__ __launch_bounds__(256) void topk_kernel(const float* __restrict__ Mv,
                                                   int* __restrict__ top) {
    __shared__ float buf[LSEQ];
    __shared__ float wv[4];
    __shared__ int wi[4];
    int bh = blockIdx.x;
    int tid = threadIdx.x;
    const float* mrow = Mv + (size_t)bh * LSEQ;
    for (int i = tid; i < LSEQ; i += 256) buf[i] = mrow[i];
    __syncthreads();
    float bv = -INFINITY;
    int bi = LSEQ;
    for (int i = tid; i < LSEQ; i += 256) {
        float v = buf[i];
        if (v > bv) { bv = v; bi = i; }
    }
    for (int t = 0; t < U; ++t) {
        float cv = bv;
        int ci = bi;
        for (int off = 32; off; off >>= 1) {
            float v2 = __shfl_xor(cv, off);
            int i2 = __shfl_xor(ci, off);
            if (v2 > cv || (v2 == cv && i2 < ci)) { cv = v2; ci = i2; }
        }
        if ((tid & 63) == 0) { wv[tid >> 6] = cv; wi[tid >> 6] = ci; }
        __syncthreads();
        float fv = wv[0];
        int fi = wi[0];
        for (int w = 1; w < 4; ++w)
            if (wv[w] > fv || (wv[w] == fv && wi[w] < fi)) { fv = wv[w]; fi = wi[w]; }
        if (tid == 0) top[bh * U + t] = fi;
        if ((fi & 255) == tid) {
            buf[fi] = -INFINITY;
            bv = -INFINITY; bi = LSEQ;
            for (int i = tid; i < LSEQ; i += 256) {
                float v = buf[i];
                if (v > bv) { bv = v; bi = i; }
            }
        }
        __syncthreads();
    }
}

// ---------------- v mean: partial (128 blocks) + reduce ----------------
__global__ __launch_bounds__(256) void vmean_part(const __hip_bfloat16* __restrict__ v,
                                                  float* __restrict__ part) {
    int blk = blockIdx.x;  // B*H*8
    int seg = blk & 7, hh = (blk >> 3) & 7, b = blk >> 6;
    int e = threadIdx.x & 63, rg = threadIdx.x >> 6;
    const __hip_bfloat16* vp =
        v + ((size_t)(b * LSEQ) + seg * 512) * D + hh * 64 + e;
    float acc = 0.f;
    for (int r = rg; r < 512; r += 4) acc += __bfloat162float(vp[(size_t)r * D]);
    __shared__ float red[4][64];
    red[rg][e] = acc;
    __syncthreads();
    if (threadIdx.x < 64)
        part[(size_t)blk * 64 + threadIdx.x] =
            red[0][threadIdx.x] + red[1][threadIdx.x] + red[2][threadIdx.x] + red[3][threadIdx.x];
}

__global__ void vmean_reduce(const float* __restrict__ part, float* __restrict__ vm) {
    int gid = blockIdx.x * blockDim.x + threadIdx.x;
    if (gid >= B * H * E) return;
    int e = gid & 63, bh = gid >> 6;
    float acc = 0.f;
#pragma unroll
    for (int s = 0; s < 8; ++s) acc += part[((size_t)bh * 8 + s) * 64 + e];
    vm[gid] = acc / (float)LSEQ;
}

// ------- base[b] = vmeanAll[b] . Wo^T + bo (one wave per output n) -----------------
__global__ __launch_bounds__(256) void wo_base_kernel(const float* __restrict__ vm,
                                                      const unsigned short* __restrict__ wob,
                                                      const float* __restrict__ bo,
                                                      float* __restrict__ base) {
    int b = blockIdx.x >> 7;            // grid B*128
    int n = (blockIdx.x & 127) * 4 + (threadIdx.x >> 6);
    int lane = threadIdx.x & 63;
    const float* vmr = vm + (size_t)b * D + lane * 8;
    float4 va = *(const float4*)vmr;
    float4 vb = *(const float4*)(vmr + 4);
    union { uint4 u; unsigned short s[8]; } w;
    w.u = *(const uint4*)(wob + (size_t)n * D + lane * 8);
    float p = va.x * bits_to_f32(w.s[0]) + va.y * bits_to_f32(w.s[1]) +
              va.z * bits_to_f32(w.s[2]) + va.w * bits_to_f32(w.s[3]) +
              vb.x * bits_to_f32(w.s[4]) + vb.y * bits_to_f32(w.s[5]) +
              vb.z * bits_to_f32(w.s[6]) + vb.w * bits_to_f32(w.s[7]);
    for (int off = 32; off; off >>= 1) p += __shfl_xor(p, off);
    if (lane == 0) base[(size_t)b * D + n] = p + bo[n];
}

// ------- aout[r] = base[b] broadcast (float4) --------------------------------------
__global__ void bcast_base(const float* __restrict__ base, float* __restrict__ aout) {
    int i = blockIdx.x * blockDim.x + threadIdx.x;  // over ML*D/4
    if (i >= B * LSEQ * D / 4) return;
    int b = i >> 19;          // LSEQ*D/4 = 2^19
    int c4 = i & 127;         // D/4 = 128
    ((float4*)aout)[i] = *(const float4*)(base + (size_t)b * D + c4 * 4);
}

// ------- scatter correction: aout[top[bh,t]] += (upd - vmean_h) . Wo_h^T -----------
__global__ __launch_bounds__(256) void wo_corr_kernel(const float* __restrict__ updbuf,
                                                      const float* __restrict__ vm,
                                                      const unsigned short* __restrict__ wob,
                                                      const int* __restrict__ top,
                                                      float* __restrict__ aout) {
    __shared__ float dlt[E];
    int bid = blockIdx.x;  // B*H*U
    int t = bid % U;
    int bh = bid / U;
    int b = bh >> 3, hh = bh & 7;
    int tid = threadIdx.x;
    if (tid < E) dlt[tid] = updbuf[((size_t)bh * U + t) * E + tid] - vm[(size_t)bh * E + tid];
    __syncthreads();
    int r = top[bh * U + t];
    float* arow = aout + (size_t)(b * LSEQ + r) * D;
    for (int n = tid; n < D; n += 256) {
        const unsigned short* wr = wob + (size_t)n * D + hh * E;
        float acc = 0.f;
#pragma unroll
        for (int k2 = 0; k2 < E; ++k2) acc += dlt[k2] * bits_to_f32(wr[k2]);
        atomicAdd(arow + n, acc);
    }
}

// -------- flash-style MFMA attention partial: block = (slice, h, b) ----------------
__global__ __launch_bounds__(256) void attn_part(const float* __restrict__ q,
                                                 const __hip_bfloat16* __restrict__ kbf,
                                                 const __hip_bfloat16* __restrict__ vbf,
                                                 const int* __restrict__ top,
                                                 float* __restrict__ Opart,
                                                 float* __restrict__ msum) {
    __shared__ unsigned short Qs[48 * 72];
    __shared__ unsigned short Ks[SLICE * 72];
    __shared__ unsigned short Vs[SLICE * 68];
    __shared__ unsigned short Ps[48 * 136];
    __shared__ float mred[48][4];
    __shared__ float sred[48][4];
    const int slice = blockIdx.x, hh = blockIdx.y, b = blockIdx.z;
    const int bh = b * H + hh;
    const int tid = threadIdx.x;
    const int s0 = slice * SLICE;
    for (int i = tid; i < 48 * 64; i += 256) {
        int t = i >> 6, e = i & 63;
        float v = 0.f;
        if (t < U) {
            int r = top[bh * U + t];
            v = q[((size_t)(b * LSEQ) + r) * D + hh * E + e];
        }
        Qs[t * 72 + e] = bf16_bits(v);
    }
    {
        const uint4* src = (const uint4*)(kbf + ((size_t)(b * LSEQ) + s0) * D + hh * E);
        for (int i = tid; i < SLICE * 8; i += 256) {
            int r = i >> 3, c = i & 7;
            uint4 d = src[(size_t)r * 64 + c];
            *(uint4*)(Ks + r * 72 + c * 8) = d;
        }
    }
    {
        const uint2* src = (const uint2*)(vbf + ((size_t)(b * LSEQ) + s0) * D + hh * E);
        for (int i = tid; i < SLICE * 16; i += 256) {
            int r = i >> 4, c = i & 15;
            uint2 d = src[(size_t)r * 128 + c];
            *(uint2*)(Vs + r * 68 + c * 4) = d;
        }
    }
    __syncthreads();
    const int wave = tid >> 6, lane = tid & 63;
    const int quad = lane >> 4, m15 = lane & 15;
    const int wc = wave * 32;
    f32x4 acc[3][2] = {};
#pragma unroll
    for (int ks = 0; ks < 2; ++ks) {
        short8 af[3], bfr[2];
#pragma unroll
        for (int mt = 0; mt < 3; ++mt)
            af[mt] = *(const short8*)(Qs + (mt * 16 + m15) * 72 + ks * 32 + quad * 8);
#pragma unroll
        for (int nt = 0; nt < 2; ++nt)
            bfr[nt] = *(const short8*)(Ks + (wc + nt * 16 + m15) * 72 + ks * 32 + quad * 8);
#pragma unroll
        for (int mt = 0; mt < 3; ++mt)
#pragma unroll
            for (int nt = 0; nt < 2; ++nt)
                acc[mt][nt] = __builtin_amdgcn_mfma_f32_16x16x32_bf16(
                    af[mt], bfr[nt], acc[mt][nt], 0, 0, 0);
    }
    float sc[3][2][4];
#pragma unroll
    for (int mt = 0; mt < 3; ++mt)
#pragma unroll
        for (int nt = 0; nt < 2; ++nt)
#pragma unroll
            for (int r = 0; r < 4; ++r) sc[mt][nt][r] = acc[mt][nt][r] * 0.125f;
#pragma unroll
    for (int mt = 0; mt < 3; ++mt)
#pragma unroll
        for (int r = 0; r < 4; ++r) {
            float mv = fmaxf(sc[mt][0][r], sc[mt][1][r]);
            mv = fmaxf(mv, __shfl_xor(mv, 1));
            mv = fmaxf(mv, __shfl_xor(mv, 2));
            mv = fmaxf(mv, __shfl_xor(mv, 4));
            mv = fmaxf(mv, __shfl_xor(mv, 8));
            if (m15 == 0) mred[mt * 16 + quad * 4 + r][wave] = mv;
        }
    __syncthreads();
#pragma unroll
    for (int mt = 0; mt < 3; ++mt)
#pragma unroll
        for (int r = 0; r < 4; ++r) {
            int row = mt * 16 + quad * 4 + r;
            float ms = fmaxf(fmaxf(mred[row][0], mred[row][1]),
                             fmaxf(mred[row][2], mred[row][3]));
            float p0 = __expf(sc[mt][0][r] - ms);
            float p1 = __expf(sc[mt][1][r] - ms);
            float sv = p0 + p1;
            sv += __shfl_xor(sv, 1);
            sv += __shfl_xor(sv, 2);
            sv += __shfl_xor(sv, 4);
            sv += __shfl_xor(sv, 8);
            if (m15 == 0) sred[row][wave] = sv;
            Ps[row * 136 + wc + m15] = bf16_bits(p0);
            Ps[row * 136 + wc + 16 + m15] = bf16_bits(p1);
        }
    __syncthreads();
    if (tid < U) {
        float mm = fmaxf(fmaxf(mred[tid][0], mred[tid][1]),
                         fmaxf(mred[tid][2], mred[tid][3]));
        float ss = sred[tid][0] + sred[tid][1] + sred[tid][2] + sred[tid][3];
        size_t base = (((size_t)bh * NS + slice) * U + tid) * 2;
        msum[base] = mm;
        msum[base + 1] = ss;
    }
    f32x4 apv[3] = {};
#pragma unroll
    for (int ks = 0; ks < 4; ++ks) {
        short8 bv;
#pragma unroll
        for (int j = 0; j < 8; ++j)
            bv[j] = (short)Vs[(ks * 32 + quad * 8 + j) * 68 + wave * 16 + m15];
        short8 af2[3];
#pragma unroll
        for (int mt = 0; mt < 3; ++mt)
            af2[mt] = *(const short8*)(Ps + (mt * 16 + m15) * 136 + ks * 32 + quad * 8);
#pragma unroll
        for (int mt = 0; mt < 3; ++mt)
            apv[mt] = __builtin_amdgcn_mfma_f32_16x16x32_bf16(af2[mt], bv, apv[mt], 0, 0, 0);
    }
    size_t obase = ((size_t)bh * NS + slice) * U;
#pragma unroll
    for (int mt = 0; mt < 3; ++mt)
#pragma unroll
        for (int r = 0; r < 4; ++r) {
            int row = mt * 16 + quad * 4 + r;
            if (row < U)
                Opart[(obase + row) * 64 + wave * 16 + m15] = apv[mt][r];
        }
}

// -------- combine slice partials -> dense upd buffer (f32) -------------------------
__global__ __launch_bounds__(64) void attn_reduce(const float* __restrict__ Opart,
                                                  const float* __restrict__ msum,
                                                  float* __restrict__ updbuf) {
    int t = blockIdx.x % U;
    int bh = blockIdx.x / U;
    int lane = threadIdx.x;
    float m_s = -INFINITY, ss = 0.f;
    if (lane < NS) {
        size_t base = (((size_t)bh * NS + lane) * U + t) * 2;
        m_s = msum[base];
        ss = msum[base + 1];
    }
    float M = m_s;
    for (int off = 32; off; off >>= 1) M = fmaxf(M, __shfl_xor(M, off));
    float e_s = (lane < NS) ? __expf(m_s - M) : 0.f;
    float d = ss * e_s;
    for (int off = 32; off; off >>= 1) d += __shfl_xor(d, off);
    float acc = 0.f;
    for (int s = 0; s < NS; ++s) {
        float w = __shfl(e_s, s);
        acc += w * Opart[(((size_t)bh * NS + s) * U + t) * 64 + lane];
    }
    updbuf[((size_t)bh * U + t) * E + lane] = acc / d;
}

// -------- h = LayerNorm(h + a) * g + b, one wave per row, dual write f32+bf16 -------
__global__ __launch_bounds__(64) void add_ln_kernel(float* __restrict__ h,
                                                    const float* __restrict__ a,
                                                    const float* __restrict__ g,
                                                    const float* __restrict__ bb,
                                                    __hip_bfloat16* __restrict__ hbf) {
    int row = blockIdx.x;
    int lane = threadIdx.x;
    float* hp = h + (size_t)row * D;
    const float* ap = a + (size_t)row * D;
    float x[8];
    float sum = 0.f;
#pragma unroll
    for (int j = 0; j < 8; ++j) {
        x[j] = hp[lane + 64 * j] + ap[lane + 64 * j];
        sum += x[j];
    }
    for (int off = 32; off; off >>= 1) sum += __shfl_xor(sum, off);
    float mu = sum / (float)D;
    float vs = 0.f;
#pragma unroll
    for (int j = 0; j < 8; ++j) {
        float dd = x[j] - mu;
        vs += dd * dd;
    }
    for (int off = 32; off; off >>= 1) vs += __shfl_xor(vs, off);
    float inv = 1.f / sqrtf(vs / (float)D + EPSL);
#pragma unroll
    for (int j = 0; j < 8; ++j) {
        float o = (x[j] - mu) * inv * g[lane + 64 * j] + bb[lane + 64 * j];
        hp[lane + 64 * j] = o;
        hbf[(size_t)row * D + lane + 64 * j] = __float2bfloat16(o);
    }
}

// ---------------- final head ----------------
__global__ void final_kernel(const float* __restrict__ h, const float* __restrict__ Wf,
                             const float* __restrict__ bf, float* __restrict__ out) {
    int b = blockIdx.x;
    int lane = threadIdx.x;
    const float* hp = h + (size_t)b * LSEQ * D;
    float acc = 0.f;
    for (int j = lane; j < D; j += 64) acc += hp[j] * Wf[j];
    for (int off = 32; off; off >>= 1) acc += __shfl_xor(acc, off);
    if (lane == 0) out[b] = acc + bf[0];
}

extern "C" void kernel_launch(void* const* d_in, const int* in_sizes, int n_in,
                              void* d_out, int out_size, void* d_ws, size_t ws_size,
                              hipStream_t stream) {
    (void)in_sizes; (void)n_in; (void)out_size; (void)ws_size;
    const float* x   = (const float*)d_in[0];
    const float* We  = (const float*)d_in[1];
    const float* be  = (const float*)d_in[2];
    const float* cls = (const float*)d_in[3];
    const float* Wq  = (const float*)d_in[4];
    const float* bq  = (const float*)d_in[5];
    const float* Wk  = (const float*)d_in[6];
    const float* bk  = (const float*)d_in[7];
    const float* Wv  = (const float*)d_in[8];
    const float* bv  = (const float*)d_in[9];
    const float* Wo  = (const float*)d_in[10];
    const float* bo  = (const float*)d_in[11];
    const float* g1  = (const float*)d_in[12];
    const float* b1  = (const float*)d_in[13];
    const float* g2  = (const float*)d_in[14];
    const float* b2  = (const float*)d_in[15];
    const float* W1  = (const float*)d_in[16];
    const float* bf1 = (const float*)d_in[17];
    const float* W2  = (const float*)d_in[18];
    const float* bf2 = (const float*)d_in[19];
    const float* Wf  = (const float*)d_in[20];
    const float* bff = (const float*)d_in[21];
    float* out = (float*)d_out;

    float* ws = (float*)d_ws;
    const size_t NT = (size_t)B * LSEQ * D;  // 4,194,304
    float* h    = ws;                         // [0, NT)
    float* aout = ws + NT;                    // [NT, 2NT)
    float* q    = ws + 2 * NT;                // [2NT, 3NT)
    // kbf overlays aout: written by K GEMM, consumed by mscore/attn_part;
    // aout (bcast_base) is only written AFTER attn_part in stream order.
    __hip_bfloat16* kbf    = (__hip_bfloat16*)(ws + NT);
    __hip_bfloat16* y1_bf  = (__hip_bfloat16*)(ws + 2 * NT);  // overlays q/Opart post-attn
    __hip_bfloat16* v_bf   = (__hip_bfloat16*)(ws + 4 * NT);
    __hip_bfloat16* h_bf   = (__hip_bfloat16*)(ws + 5 * NT);
    float* Opart = ws + 3 * NT;                           // B*H*NS*U*64 floats
    float* msumb = Opart + (size_t)B * H * NS * U * 64;   // B*H*NS*U*2 floats
    float* wpool = ws + 5 * NT + NT / 2;
    __hip_bfloat16* wqb = (__hip_bfloat16*)wpool;
    __hip_bfloat16* wkb = wqb + (size_t)D * D;
    __hip_bfloat16* wvb = wkb + (size_t)D * D;
    __hip_bfloat16* wob = wvb + (size_t)D * D;
    __hip_bfloat16* w1b = wob + (size_t)D * D;
    __hip_bfloat16* w2b = w1b + (size_t)DFF * D;
    float* after_w = wpool + ((size_t)4 * D * D + 2 * (size_t)DFF * D) / 2;
    float* Mbuf = after_w;
    int* idx    = (int*)(Mbuf + (size_t)B * H * LSEQ);
    int* top    = idx + LU;
    float* vm   = (float*)(top + B * H * U);
    float* vpart  = vm + (size_t)B * H * E;
    float* updbuf = vpart + (size_t)128 * 64;         // B*H*U*64 floats
    float* baseb  = updbuf + (size_t)B * H * U * 64;  // B*D floats

    const int ML = B * LSEQ;  // 8192
    dim3 gD(D / 128, ML / 128);
    dim3 gF1(DFF / 128, ML / 128);

    embed_kernel<<<(B * LSEQ * D + 255) / 256, 256, 0, stream>>>(x, We, be, cls, h, h_bf);

    for (int l = 0; l < NL; ++l) {
        const float* Wq_l = Wq + (size_t)l * D * D;
        const float* Wk_l = Wk + (size_t)l * D * D;
        const float* Wv_l = Wv + (size_t)l * D * D;
        const float* Wo_l = Wo + (size_t)l * D * D;
        const float* W1_l = W1 + (size_t)l * DFF * D;
        const float* W2_l = W2 + (size_t)l * D * DFF;

        int nDD4 = D * D / 4, nFD4 = DFF * D / 4;
        cast_bf16_kernel<<<(nDD4 + 255) / 256, 256, 0, stream>>>(Wq_l, wqb, nDD4);
        cast_bf16_kernel<<<(nDD4 + 255) / 256, 256, 0, stream>>>(Wk_l, wkb, nDD4);
        cast_bf16_kernel<<<(nDD4 + 255) / 256, 256, 0, stream>>>(Wv_l, wvb, nDD4);
        cast_bf16_kernel<<<(nDD4 + 255) / 256, 256, 0, stream>>>(Wo_l, wob, nDD4);
        cast_bf16_kernel<<<(nFD4 + 255) / 256, 256, 0, stream>>>(W1_l, w1b, nFD4);
        cast_bf16_kernel<<<(nFD4 + 255) / 256, 256, 0, stream>>>(W2_l, w2b, nFD4);

        gemm_mfma<0, 0><<<gD, 256, 0, stream>>>((const unsigned short*)h_bf,
                                                (const unsigned short*)wqb, bq + l * D, q,
                                                ML, D, D);
        gemm_mfma<0, 1><<<gD, 256, 0, stream>>>((const unsigned short*)h_bf,
                                                (const unsigned short*)wkb, bk + l * D, kbf,
                                                ML, D, D);
        gemm_mfma<0, 1><<<gD, 256, 0, stream>>>((const unsigned short*)h_bf,
                                                (const unsigned short*)wvb, bv + l * D, v_bf,
                                                ML, D, D);

        idx_kernel<<<(HALF_LU + 255) / 256, 256, 0, stream>>>(idx, l);
        mscore_kernel<<<B * LSEQ, 256, 0, stream>>>(q, kbf, idx, Mbuf);
        topk_kernel<<<B * H, 256, 0, stream>>>(Mbuf, top);
        vmean_part<<<B * H * 8, 256, 0, stream>>>(v_bf, vpart);
        vmean_reduce<<<4, 256, 0, stream>>>(vpart, vm);
        wo_base_kernel<<<B * 128, 256, 0, stream>>>(vm, (const unsigned short*)wob,
                                                    bo + l * D, baseb);
        attn_part<<<dim3(NS, H, B), 256, 0, stream>>>(q, kbf, v_bf, top, Opart, msumb);
        attn_reduce<<<B * H * U, 64, 0, stream>>>(Opart, msumb, updbuf);
        bcast_base<<<(B * LSEQ * D / 4 + 255) / 256, 256, 0, stream>>>(baseb, aout);
        wo_corr_kernel<<<B * H * U, 256, 0, stream>>>(updbuf, vm,
                                                      (const unsigned short*)wob, top, aout);
        add_ln_kernel<<<ML, 64, 0, stream>>>(h, aout, g1 + l * D, b1 + l * D, h_bf);

        gemm_mfma<1, 1><<<gF1, 256, 0, stream>>>((const unsigned short*)h_bf,
                                                 (const unsigned short*)w1b, bf1 + l * DFF,
                                                 y1_bf, ML, DFF, D);
        gemm_mfma<0, 0><<<gD, 256, 0, stream>>>((const unsigned short*)y1_bf,
                                                (const unsigned short*)w2b, bf2 + l * D, aout,
                                                ML, D, DFF);
        add_ln_kernel<<<ML, 64, 0, stream>>>(h, aout, g2 + l * D, b2 + l * D, h_bf);
    }

    final_kernel<<<B, 64, 0, stream>>>(h, Wf, bff, out);
}

// Round 8
// 799.694 us; speedup vs baseline: 4.1953x; 1.1007x over previous
//
#include <hip/hip_runtime.h>
#include <hip/hip_bf16.h>
#include <math.h>
#include <stdint.h>

#define B 2
#define S 4095
#define LSEQ 4096
#define F_IN 32
#define D 512
#define H 8
#define E 64
#define DFF 2048
#define NL 2
#define U 45
#define EPSL 1e-5f
#define LU (LSEQ * U)
#define HALF_LU (LU / 2)
#define NS 32
#define SLICE 128

typedef __attribute__((ext_vector_type(8))) short short8;
typedef __attribute__((ext_vector_type(4))) float f32x4;

#define GLD(gp, lp)                                                            \
    __builtin_amdgcn_global_load_lds(                                          \
        (const __attribute__((address_space(1))) void*)(gp),                   \
        (__attribute__((address_space(3))) void*)(lp), 16, 0, 0)

__device__ __forceinline__ unsigned short bf16_bits(float f) {
    __hip_bfloat16 h = __float2bfloat16(f);
    return *(unsigned short*)&h;
}
__device__ __forceinline__ float bits_to_f32(unsigned short s) {
    union { uint32_t u; float f; } c;
    c.u = ((uint32_t)s) << 16;
    return c.f;
}

// ---------------- Threefry-2x32 (20 rounds), exactly JAX's algorithm ----------------
__device__ __forceinline__ uint32_t rotl32(uint32_t x, int r) {
    return (x << r) | (x >> (32 - r));
}

__device__ void threefry2x32(uint32_t k0, uint32_t k1, uint32_t c0, uint32_t c1,
                             uint32_t& o0, uint32_t& o1) {
    uint32_t ks2 = k0 ^ k1 ^ 0x1BD11BDAu;
    uint32_t x0 = c0 + k0, x1 = c1 + k1;
    x0 += x1; x1 = rotl32(x1, 13); x1 ^= x0;
    x0 += x1; x1 = rotl32(x1, 15); x1 ^= x0;
    x0 += x1; x1 = rotl32(x1, 26); x1 ^= x0;
    x0 += x1; x1 = rotl32(x1, 6);  x1 ^= x0;
    x0 += k1; x1 += ks2 + 1u;
    x0 += x1; x1 = rotl32(x1, 17); x1 ^= x0;
    x0 += x1; x1 = rotl32(x1, 29); x1 ^= x0;
    x0 += x1; x1 = rotl32(x1, 16); x1 ^= x0;
    x0 += x1; x1 = rotl32(x1, 24); x1 ^= x0;
    x0 += ks2; x1 += k0 + 2u;
    x0 += x1; x1 = rotl32(x1, 13); x1 ^= x0;
    x0 += x1; x1 = rotl32(x1, 15); x1 ^= x0;
    x0 += x1; x1 = rotl32(x1, 26); x1 ^= x0;
    x0 += x1; x1 = rotl32(x1, 6);  x1 ^= x0;
    x0 += k0; x1 += k1 + 3u;
    x0 += x1; x1 = rotl32(x1, 17); x1 ^= x0;
    x0 += x1; x1 = rotl32(x1, 29); x1 ^= x0;
    x0 += x1; x1 = rotl32(x1, 16); x1 ^= x0;
    x0 += x1; x1 = rotl32(x1, 24); x1 ^= x0;
    x0 += k1; x1 += ks2 + 4u;
    x0 += x1; x1 = rotl32(x1, 13); x1 ^= x0;
    x0 += x1; x1 = rotl32(x1, 15); x1 ^= x0;
    x0 += x1; x1 = rotl32(x1, 26); x1 ^= x0;
    x0 += x1; x1 = rotl32(x1, 6);  x1 ^= x0;
    x0 += ks2; x1 += k0 + 5u;
    o0 = x0; o1 = x1;
}

__global__ void idx_kernel(int* __restrict__ idx, int layer) {
    int j = blockIdx.x * blockDim.x + threadIdx.x;
    if (j >= HALF_LU) return;
    uint32_t f0, f1, a0, a1, b0, b1, o0, o1;
    threefry2x32(0u, 42u, 0u, (uint32_t)layer, f0, f1);
    threefry2x32(f0, f1, 0u, 2u, a0, a1);
    threefry2x32(f0, f1, 1u, 3u, b0, b1);
    threefry2x32(a1, b1, (uint32_t)j, (uint32_t)(j + HALF_LU), o0, o1);
    idx[j] = (int)(o0 & 4095u);
    idx[j + HALF_LU] = (int)(o1 & 4095u);
    (void)a0; (void)b0;
}

// ------- prep: xbf[8192x32] (row l=0 zero, else x[b,l-1,:]) + We_bf cast -----------
__global__ void prep_embed_kernel(const float* __restrict__ x, const float* __restrict__ We,
                                  __hip_bfloat16* __restrict__ xbf,
                                  __hip_bfloat16* __restrict__ webf) {
    int u = blockIdx.x * blockDim.x + threadIdx.x;  // 4-element units
    const int NX = B * LSEQ * F_IN / 4;             // 65536
    const int NW = D * F_IN / 4;                    // 4096
    if (u < NX) {
        int e0 = u * 4;
        int i = e0 & 31;
        int l = (e0 >> 5) & (LSEQ - 1);
        int b = e0 >> 17;
        union { unsigned short s[4]; uint2 w; } o;
        if (l == 0) {
            o.s[0] = o.s[1] = o.s[2] = o.s[3] = 0;
        } else {
            float4 v = *(const float4*)(x + ((size_t)b * S + (l - 1)) * F_IN + i);
            o.s[0] = bf16_bits(v.x); o.s[1] = bf16_bits(v.y);
            o.s[2] = bf16_bits(v.z); o.s[3] = bf16_bits(v.w);
        }
        ((uint2*)xbf)[u] = o.w;
    } else if (u < NX + NW) {
        int w = u - NX;
        float4 v = ((const float4*)We)[w];
        union { unsigned short s[4]; uint2 w2; } o;
        o.s[0] = bf16_bits(v.x); o.s[1] = bf16_bits(v.y);
        o.s[2] = bf16_bits(v.z); o.s[3] = bf16_bits(v.w);
        ((uint2*)webf)[w] = o.w2;
    }
}

// ------- posenc: h = (l==0 ? cls : emb) + PE; dual write f32 + bf16 ----------------
__global__ void posenc_kernel(const float* __restrict__ emb, const float* __restrict__ cls,
                              float* __restrict__ h, __hip_bfloat16* __restrict__ hbf) {
    int gid = blockIdx.x * blockDim.x + threadIdx.x;
    if (gid >= B * LSEQ * D) return;
    int d = gid % D;
    int l = (gid / D) % LSEQ;
    float v = (l == 0) ? cls[d] : emb[gid];
    int i = d >> 1;
    float divv = expf((float)(2 * i) * (float)(-9.210340371976184 / 512.0));
    float ang = (float)l * divv;
    v += (d & 1) ? cosf(ang) : sinf(ang);
    h[gid] = v;
    hbf[gid] = __float2bfloat16(v);
}

// ------- fused per-layer weight cast: all 6 weights in one launch ------------------
__global__ void cast_weights_kernel(const float* __restrict__ Wq_l,
                                    const float* __restrict__ Wk_l,
                                    const float* __restrict__ Wv_l,
                                    const float* __restrict__ Wo_l,
                                    const float* __restrict__ W1_l,
                                    const float* __restrict__ W2_l,
                                    __hip_bfloat16* __restrict__ wqb,
                                    __hip_bfloat16* __restrict__ wkb,
                                    __hip_bfloat16* __restrict__ wvb,
                                    __hip_bfloat16* __restrict__ wob,
                                    __hip_bfloat16* __restrict__ w1b,
                                    __hip_bfloat16* __restrict__ w2b) {
    const int SDD = D * D / 4;       // 65536
    const int SFD = DFF * D / 4;     // 262144
    int u = blockIdx.x * blockDim.x + threadIdx.x;  // < 4*SDD + 2*SFD
    const float* src;
    __hip_bfloat16* dst;
    int off;
    if (u < SDD) { src = Wq_l; dst = wqb; off = u; }
    else if (u < 2 * SDD) { src = Wk_l; dst = wkb; off = u - SDD; }
    else if (u < 3 * SDD) { src = Wv_l; dst = wvb; off = u - 2 * SDD; }
    else if (u < 4 * SDD) { src = Wo_l; dst = wob; off = u - 3 * SDD; }
    else if (u < 4 * SDD + SFD) { src = W1_l; dst = w1b; off = u - 4 * SDD; }
    else { src = W2_l; dst = w2b; off = u - 4 * SDD - SFD; }
    float4 v = ((const float4*)src)[off];
    union { unsigned short s[4]; uint2 w; } o;
    o.s[0] = bf16_bits(v.x); o.s[1] = bf16_bits(v.y);
    o.s[2] = bf16_bits(v.z); o.s[3] = bf16_bits(v.w);
    ((uint2*)dst)[off] = o.w;
}

// ---------------- bf16 MFMA GEMM: C[M,N] = A[M,K] @ W[N,K]^T + bias ----------------
template <int ACT, int OUTBF>
__global__ __launch_bounds__(256) void gemm_mfma(const unsigned short* __restrict__ A,
                                                 const unsigned short* __restrict__ W,
                                                 const float* __restrict__ bias,
                                                 void* __restrict__ Cout,
                                                 int M, int N, int K) {
    __shared__ unsigned short lds[2 * 128 * 32];
    unsigned short* As = lds;
    unsigned short* Bs = lds + 128 * 32;
    const int tid = threadIdx.x;
    const int m0 = blockIdx.y * 128, n0 = blockIdx.x * 128;
    const int wave = tid >> 6, lane = tid & 63;
    const int wm = (wave >> 1) * 64, wn = (wave & 1) * 64;
    const int quad = lane >> 4, m15 = lane & 15;
    const int srow = tid >> 2, scol = (tid & 3) * 8;
    f32x4 acc[4][4] = {};
    const unsigned short* Ag0 = A + (size_t)(m0 + srow) * K + scol;
    const unsigned short* Ag1 = A + (size_t)(m0 + srow + 64) * K + scol;
    const unsigned short* Wg0 = W + (size_t)(n0 + srow) * K + scol;
    const unsigned short* Wg1 = W + (size_t)(n0 + srow + 64) * K + scol;
    for (int k0 = 0; k0 < K; k0 += 32) {
        __syncthreads();
        GLD(Ag0 + k0, As + tid * 8);
        GLD(Ag1 + k0, As + 2048 + tid * 8);
        GLD(Wg0 + k0, Bs + tid * 8);
        GLD(Wg1 + k0, Bs + 2048 + tid * 8);
        __syncthreads();
        short8 af[4], bfr[4];
#pragma unroll
        for (int mi = 0; mi < 4; ++mi)
            af[mi] = *(const short8*)(As + (wm + mi * 16 + m15) * 32 + quad * 8);
#pragma unroll
        for (int ni = 0; ni < 4; ++ni)
            bfr[ni] = *(const short8*)(Bs + (wn + ni * 16 + m15) * 32 + quad * 8);
#pragma unroll
        for (int mi = 0; mi < 4; ++mi)
#pragma unroll
            for (int ni = 0; ni < 4; ++ni)
                acc[mi][ni] = __builtin_amdgcn_mfma_f32_16x16x32_bf16(
                    af[mi], bfr[ni], acc[mi][ni], 0, 0, 0);
    }
    float* Cf = (float*)Cout;
    __hip_bfloat16* Cb = (__hip_bfloat16*)Cout;
#pragma unroll
    for (int mi = 0; mi < 4; ++mi) {
        int mg = m0 + wm + mi * 16 + quad * 4;
#pragma unroll
        for (int ni = 0; ni < 4; ++ni) {
            int ng = n0 + wn + ni * 16 + m15;
            float bv = bias[ng];
#pragma unroll
            for (int r = 0; r < 4; ++r) {
                float v = acc[mi][ni][r] + bv;
                if (ACT == 1) v = fmaxf(v, 0.f);
                if (OUTBF == 1)
                    Cb[(size_t)(mg + r) * N + ng] = __float2bfloat16(v);
                else
                    Cf[(size_t)(mg + r) * N + ng] = v;
            }
        }
    }
}

// -------- M-score: block per (b,l); one WAVE per sampled row -----------------------
__global__ __launch_bounds__(256) void mscore_kernel(const float* __restrict__ q,
                                                     const __hip_bfloat16* __restrict__ kbf,
                                                     const int* __restrict__ idx,
                                                     float* __restrict__ Mv) {
    __shared__ float Sbuf[U][8];
    __shared__ int sidx[U];
    int bid = blockIdx.x;
    int b = bid & 1;
    int l = bid >> 1;
    int tid = threadIdx.x;
    int wave = tid >> 6, lane = tid & 63;
    if (tid < U) sidx[tid] = idx[l * U + tid];
    const float* qr = q + ((size_t)(b * LSEQ) + l) * D + lane * 8;
    float4 qa = *(const float4*)qr;
    float4 qb = *(const float4*)(qr + 4);
    __syncthreads();
    const unsigned short* kbase = (const unsigned short*)(kbf + (size_t)(b * LSEQ) * D);
    for (int t = wave; t < U; t += 4) {
        int kr = sidx[t];
        union { uint4 u; unsigned short s[8]; } kv;
        kv.u = *(const uint4*)(kbase + (size_t)kr * D + lane * 8);
        float p = qa.x * bits_to_f32(kv.s[0]) + qa.y * bits_to_f32(kv.s[1]) +
                  qa.z * bits_to_f32(kv.s[2]) + qa.w * bits_to_f32(kv.s[3]) +
                  qb.x * bits_to_f32(kv.s[4]) + qb.y * bits_to_f32(kv.s[5]) +
                  qb.z * bits_to_f32(kv.s[6]) + qb.w * bits_to_f32(kv.s[7]);
        p += __shfl_xor(p, 1);
        p += __shfl_xor(p, 2);
        p += __shfl_xor(p, 4);
        if ((lane & 7) == 0) Sbuf[t][lane >> 3] = p;
    }
    __syncthreads();
    if (tid < 8) {
        float mx = -INFINITY, sm = 0.f;
        for (int t = 0; t < U; ++t) {
            float v = Sbuf[t][tid];
            mx = fmaxf(mx, v);
            sm += v;
        }
        Mv[((size_t)b * H + tid) * LSEQ + l] = mx - sm / (float)LSEQ;
    }
}

// ------- top-k (u=45) per (b,h), JAX tie semantics; incremental per-thread argmax ---
__global__ __launch_bounds__(256) void topk_kernel(const float* __restrict__ Mv,
                                                   int* __restrict__ top) {
    __shared__ float buf[LSEQ];
    __shared__ float wv[4];
    __shared__ int wi[4];
    int bh = blockIdx.x;
    int tid = threadIdx.x;
    const float* mrow = Mv + (size_t)bh * LSEQ;
    for (int i = tid; i < LSEQ; i += 256) buf[i] = mrow[i];
    __syncthreads();
    float bv = -INFINITY;
    int bi = LSEQ;
    for (int i = tid; i < LSEQ; i += 256) {
        float v = buf[i];
        if (v > bv) { bv = v; bi = i; }
    }
    for (int t = 0; t < U; ++t) {
        float cv = bv;
        int ci = bi;
        for (int off = 32; off; off >>= 1) {
            float v2 = __shfl_xor(cv, off);
            int i2 = __shfl_xor(ci, off);
            if (v2 > cv || (v2 == cv && i2 < ci)) { cv = v2; ci = i2; }
        }
        if ((tid & 63) == 0) { wv[tid >> 6] = cv; wi[tid >> 6] = ci; }
        __syncthreads();
        float fv = wv[0];
        int fi = wi[0];
        for (int w = 1; w < 4; ++w)
            if (wv[w] > fv || (wv[w] == fv && wi[w] < fi)) { fv = wv[w]; fi = wi[w]; }
        if (tid == 0) top[bh * U + t] = fi;
        if ((fi & 255) == tid) {
            buf[fi] = -INFINITY;
            bv = -INFINITY; bi = LSEQ;
            for (int i = tid; i < LSEQ; i += 256) {
                float v = buf[i];
                if (v > bv) { bv = v; bi = i; }
            }
        }
        __syncthreads();
    }
}

// ---------------- v mean: partial (128 blocks) + reduce ----------------
__global__ __launch_bounds__(256) void vmean_part(const __hip_bfloat16* __restrict__ v,
                                                  float* __restrict__ part) {
    int blk = blockIdx.x;  // B*H*8
    int seg = blk & 7, hh = (blk >> 3) & 7, b = blk >> 6;
    int e = threadIdx.x & 63, rg = threadIdx.x >> 6;
    const __hip_bfloat16* vp =
        v + ((size_t)(b * LSEQ) + seg * 512) * D + hh * 64 + e;
    float acc = 0.f;
    for (int r = rg; r < 512; r += 4) acc += __bfloat162float(vp[(size_t)r * D]);
    __shared__ float red[4][64];
    red[rg][e] = acc;
    __syncthreads();
    if (threadIdx.x < 64)
        part[(size_t)blk * 64 + threadIdx.x] =
            red[0][threadIdx.x] + red[1][threadIdx.x] + red[2][threadIdx.x] + red[3][threadIdx.x];
}

__global__ void vmean_reduce(const float* __restrict__ part, float* __restrict__ vm) {
    int gid = blockIdx.x * blockDim.x + threadIdx.x;
    if (gid >= B * H * E) return;
    int e = gid & 63, bh = gid >> 6;
    float acc = 0.f;
#pragma unroll
    for (int s = 0; s < 8; ++s) acc += part[((size_t)bh * 8 + s) * 64 + e];
    vm[gid] = acc / (float)LSEQ;
}

// ------- base[b] = vmeanAll[b] . Wo^T + bo (one wave per output n) -----------------
__global__ __launch_bounds__(256) void wo_base_kernel(const float* __restrict__ vm,
                                                      const unsigned short* __restrict__ wob,
                                                      const float* __restrict__ bo,
                                                      float* __restrict__ base) {
    int b = blockIdx.x >> 7;            // grid B*128
    int n = (blockIdx.x & 127) * 4 + (threadIdx.x >> 6);
    int lane = threadIdx.x & 63;
    const float* vmr = vm + (size_t)b * D + lane * 8;
    float4 va = *(const float4*)vmr;
    float4 vb = *(const float4*)(vmr + 4);
    union { uint4 u; unsigned short s[8]; } w;
    w.u = *(const uint4*)(wob + (size_t)n * D + lane * 8);
    float p = va.x * bits_to_f32(w.s[0]) + va.y * bits_to_f32(w.s[1]) +
              va.z * bits_to_f32(w.s[2]) + va.w * bits_to_f32(w.s[3]) +
              vb.x * bits_to_f32(w.s[4]) + vb.y * bits_to_f32(w.s[5]) +
              vb.z * bits_to_f32(w.s[6]) + vb.w * bits_to_f32(w.s[7]);
    for (int off = 32; off; off >>= 1) p += __shfl_xor(p, off);
    if (lane == 0) base[(size_t)b * D + n] = p + bo[n];
}

// ------- aout[r] = base[b] broadcast (float4) --------------------------------------
__global__ void bcast_base(const float* __restrict__ base, float* __restrict__ aout) {
    int i = blockIdx.x * blockDim.x + threadIdx.x;  // over ML*D/4
    if (i >= B * LSEQ * D / 4) return;
    int b = i >> 19;          // LSEQ*D/4 = 2^19
    int c4 = i & 127;         // D/4 = 128
    ((float4*)aout)[i] = *(const float4*)(base + (size_t)b * D + c4 * 4);
}

// ------- scatter correction: aout[top[bh,t]] += (upd - vmean_h) . Wo_h^T -----------
__global__ __launch_bounds__(256) void wo_corr_kernel(const float* __restrict__ updbuf,
                                                      const float* __restrict__ vm,
                                                      const unsigned short* __restrict__ wob,
                                                      const int* __restrict__ top,
                                                      float* __restrict__ aout) {
    __shared__ float dlt[E];
    int bid = blockIdx.x;  // B*H*U
    int t = bid % U;
    int bh = bid / U;
    int b = bh >> 3, hh = bh & 7;
    int tid = threadIdx.x;
    if (tid < E) dlt[tid] = updbuf[((size_t)bh * U + t) * E + tid] - vm[(size_t)bh * E + tid];
    __syncthreads();
    int r = top[bh * U + t];
    float* arow = aout + (size_t)(b * LSEQ + r) * D;
    for (int n = tid; n < D; n += 256) {
        const unsigned short* wr = wob + (size_t)n * D + hh * E;
        float acc = 0.f;
#pragma unroll
        for (int k2 = 0; k2 < E; ++k2) acc += dlt[k2] * bits_to_f32(wr[k2]);
        atomicAdd(arow + n, acc);
    }
}

// -------- flash-style MFMA attention partial: block = (slice, h, b) ----------------
__global__ __launch_bounds__(256) void attn_part(const float* __restrict__ q,
                                                 const __hip_bfloat16* __restrict__ kbf,
                                                 const __hip_bfloat16* __restrict__ vbf,
                                                 const int* __restrict__ top,
                                                 float* __restrict__ Opart,
                                                 float* __restrict__ msum) {
    __shared__ unsigned short Qs[48 * 72];
    __shared__ unsigned short Ks[SLICE * 72];
    __shared__ unsigned short Vs[SLICE * 68];
    __shared__ unsigned short Ps[48 * 136];
    __shared__ float mred[48][4];
    __shared__ float sred[48][4];
    const int slice = blockIdx.x, hh = blockIdx.y, b = blockIdx.z;
    const int bh = b * H + hh;
    const int tid = threadIdx.x;
    const int s0 = slice * SLICE;
    for (int i = tid; i < 48 * 64; i += 256) {
        int t = i >> 6, e = i & 63;
        float v = 0.f;
        if (t < U) {
            int r = top[bh * U + t];
            v = q[((size_t)(b * LSEQ) + r) * D + hh * E + e];
        }
        Qs[t * 72 + e] = bf16_bits(v);
    }
    {
        const uint4* src = (const uint4*)(kbf + ((size_t)(b * LSEQ) + s0) * D + hh * E);
        for (int i = tid; i < SLICE * 8; i += 256) {
            int r = i >> 3, c = i & 7;
            uint4 d = src[(size_t)r * 64 + c];
            *(uint4*)(Ks + r * 72 + c * 8) = d;
        }
    }
    {
        const uint2* src = (const uint2*)(vbf + ((size_t)(b * LSEQ) + s0) * D + hh * E);
        for (int i = tid; i < SLICE * 16; i += 256) {
            int r = i >> 4, c = i & 15;
            uint2 d = src[(size_t)r * 128 + c];
            *(uint2*)(Vs + r * 68 + c * 4) = d;
        }
    }
    __syncthreads();
    const int wave = tid >> 6, lane = tid & 63;
    const int quad = lane >> 4, m15 = lane & 15;
    const int wc = wave * 32;
    f32x4 acc[3][2] = {};
#pragma unroll
    for (int ks = 0; ks < 2; ++ks) {
        short8 af[3], bfr[2];
#pragma unroll
        for (int mt = 0; mt < 3; ++mt)
            af[mt] = *(const short8*)(Qs + (mt * 16 + m15) * 72 + ks * 32 + quad * 8);
#pragma unroll
        for (int nt = 0; nt < 2; ++nt)
            bfr[nt] = *(const short8*)(Ks + (wc + nt * 16 + m15) * 72 + ks * 32 + quad * 8);
#pragma unroll
        for (int mt = 0; mt < 3; ++mt)
#pragma unroll
            for (int nt = 0; nt < 2; ++nt)
                acc[mt][nt] = __builtin_amdgcn_mfma_f32_16x16x32_bf16(
                    af[mt], bfr[nt], acc[mt][nt], 0, 0, 0);
    }
    float sc[3][2][4];
#pragma unroll
    for (int mt = 0; mt < 3; ++mt)
#pragma unroll
        for (int nt = 0; nt < 2; ++nt)
#pragma unroll
            for (int r = 0; r < 4; ++r) sc[mt][nt][r] = acc[mt][nt][r] * 0.125f;
#pragma unroll
    for (int mt = 0; mt < 3; ++mt)
#pragma unroll
        for (int r = 0; r < 4; ++r) {
            float mv = fmaxf(sc[mt][0][r], sc[mt][1][r]);
            mv = fmaxf(mv, __shfl_xor(mv, 1));
            mv = fmaxf(mv, __shfl_xor(mv, 2));
            mv = fmaxf(mv, __shfl_xor(mv, 4));
            mv = fmaxf(mv, __shfl_xor(mv, 8));
            if (m15 == 0) mred[mt * 16 + quad * 4 + r][wave] = mv;
        }
    __syncthreads();
#pragma unroll
    for (int mt = 0; mt < 3; ++mt)
#pragma unroll
        for (int r = 0; r < 4; ++r) {
            int row = mt * 16 + quad * 4 + r;
            float ms = fmaxf(fmaxf(mred[row][0], mred[row][1]),
                             fmaxf(mred[row][2], mred[row][3]));
            float p0 = __expf(sc[mt][0][r] - ms);
            float p1 = __expf(sc[mt][1][r] - ms);
            float sv = p0 + p1;
            sv += __shfl_xor(sv, 1);
            sv += __shfl_xor(sv, 2);
            sv += __shfl_xor(sv, 4);
            sv += __shfl_xor(sv, 8);
            if (m15 == 0) sred[row][wave] = sv;
            Ps[row * 136 + wc + m15] = bf16_bits(p0);
            Ps[row * 136 + wc + 16 + m15] = bf16_bits(p1);
        }
    __syncthreads();
    if (tid < U) {
        float mm = fmaxf(fmaxf(mred[tid][0], mred[tid][1]),
                         fmaxf(mred[tid][2], mred[tid][3]));
        float ss = sred[tid][0] + sred[tid][1] + sred[tid][2] + sred[tid][3];
        size_t base = (((size_t)bh * NS + slice) * U + tid) * 2;
        msum[base] = mm;
        msum[base + 1] = ss;
    }
    f32x4 apv[3] = {};
#pragma unroll
    for (int ks = 0; ks < 4; ++ks) {
        short8 bv;
#pragma unroll
        for (int j = 0; j < 8; ++j)
            bv[j] = (short)Vs[(ks * 32 + quad * 8 + j) * 68 + wave * 16 + m15];
        short8 af2[3];
#pragma unroll
        for (int mt = 0; mt < 3; ++mt)
            af2[mt] = *(const short8*)(Ps + (mt * 16 + m15) * 136 + ks * 32 + quad * 8);
#pragma unroll
        for (int mt = 0; mt < 3; ++mt)
            apv[mt] = __builtin_amdgcn_mfma_f32_16x16x32_bf16(af2[mt], bv, apv[mt], 0, 0, 0);
    }
    size_t obase = ((size_t)bh * NS + slice) * U;
#pragma unroll
    for (int mt = 0; mt < 3; ++mt)
#pragma unroll
        for (int r = 0; r < 4; ++r) {
            int row = mt * 16 + quad * 4 + r;
            if (row < U)
                Opart[(obase + row) * 64 + wave * 16 + m15] = apv[mt][r];
        }
}

// -------- combine slice partials -> dense upd buffer (f32) -------------------------
__global__ __launch_bounds__(64) void attn_reduce(const float* __restrict__ Opart,
                                                  const float* __restrict__ msum,
                                                  float* __restrict__ updbuf) {
    int t = blockIdx.x % U;
    int bh = blockIdx.x / U;
    int lane = threadIdx.x;
    float m_s = -INFINITY, ss = 0.f;
    if (lane < NS) {
        size_t base = (((size_t)bh * NS + lane) * U + t) * 2;
        m_s = msum[base];
        ss = msum[base + 1];
    }
    float M = m_s;
    for (int off = 32; off; off >>= 1) M = fmaxf(M, __shfl_xor(M, off));
    float e_s = (lane < NS) ? __expf(m_s - M) : 0.f;
    float d = ss * e_s;
    for (int off = 32; off; off >>= 1) d += __shfl_xor(d, off);
    float acc = 0.f;
    for (int s = 0; s < NS; ++s) {
        float w = __shfl(e_s, s);
        acc += w * Opart[(((size_t)bh * NS + s) * U + t) * 64 + lane];
    }
    updbuf[((size_t)bh * U + t) * E + lane] = acc / d;
}

// -------- h = LayerNorm(h + a) * g + b, one wave per row, dual write f32+bf16 -------
__global__ __launch_bounds__(64) void add_ln_kernel(float* __restrict__ h,
                                                    const float* __restrict__ a,
                                                    const float* __restrict__ g,
                                                    const float* __restrict__ bb,
                                                    __hip_bfloat16* __restrict__ hbf) {
    int row = blockIdx.x;
    int lane = threadIdx.x;
    float* hp = h + (size_t)row * D;
    const float* ap = a + (size_t)row * D;
    float x[8];
    float sum = 0.f;
#pragma unroll
    for (int j = 0; j < 8; ++j) {
        x[j] = hp[lane + 64 * j] + ap[lane + 64 * j];
        sum += x[j];
    }
    for (int off = 32; off; off >>= 1) sum += __shfl_xor(sum, off);
    float mu = sum / (float)D;
    float vs = 0.f;
#pragma unroll
    for (int j = 0; j < 8; ++j) {
        float dd = x[j] - mu;
        vs += dd * dd;
    }
    for (int off = 32; off; off >>= 1) vs += __shfl_xor(vs, off);
    float inv = 1.f / sqrtf(vs / (float)D + EPSL);
#pragma unroll
    for (int j = 0; j < 8; ++j) {
        float o = (x[j] - mu) * inv * g[lane + 64 * j] + bb[lane + 64 * j];
        hp[lane + 64 * j] = o;
        hbf[(size_t)row * D + lane + 64 * j] = __float2bfloat16(o);
    }
}

// ---------------- final head ----------------
__global__ void final_kernel(const float* __restrict__ h, const float* __restrict__ Wf,
                             const float* __restrict__ bf, float* __restrict__ out) {
    int b = blockIdx.x;
    int lane = threadIdx.x;
    const float* hp = h + (size_t)b * LSEQ * D;
    float acc = 0.f;
    for (int j = lane; j < D; j += 64) acc += hp[j] * Wf[j];
    for (int off = 32; off; off >>= 1) acc += __shfl_xor(acc, off);
    if (lane == 0) out[b] = acc + bf[0];
}

extern "C" void kernel_launch(void* const* d_in, const int* in_sizes, int n_in,
                              void* d_out, int out_size, void* d_ws, size_t ws_size,
                              hipStream_t stream) {
    (void)in_sizes; (void)n_in; (void)out_size; (void)ws_size;
    const float* x   = (const float*)d_in[0];
    const float* We  = (const float*)d_in[1];
    const float* be  = (const float*)d_in[2];
    const float* cls = (const float*)d_in[3];
    const float* Wq  = (const float*)d_in[4];
    const float* bq  = (const float*)d_in[5];
    const float* Wk  = (const float*)d_in[6];
    const float* bk  = (const float*)d_in[7];
    const float* Wv  = (const float*)d_in[8];
    const float* bv  = (const float*)d_in[9];
    const float* Wo  = (const float*)d_in[10];
    const float* bo  = (const float*)d_in[11];
    const float* g1  = (const float*)d_in[12];
    const float* b1  = (const float*)d_in[13];
    const float* g2  = (const float*)d_in[14];
    const float* b2  = (const float*)d_in[15];
    const float* W1  = (const float*)d_in[16];
    const float* bf1 = (const float*)d_in[17];
    const float* W2  = (const float*)d_in[18];
    const float* bf2 = (const float*)d_in[19];
    const float* Wf  = (const float*)d_in[20];
    const float* bff = (const float*)d_in[21];
    float* out = (float*)d_out;

    float* ws = (float*)d_ws;
    const size_t NT = (size_t)B * LSEQ * D;  // 4,194,304
    float* h    = ws;                         // [0, NT)
    float* aout = ws + NT;                    // [NT, 2NT)
    float* q    = ws + 2 * NT;                // [2NT, 3NT)
    __hip_bfloat16* kbf    = (__hip_bfloat16*)(ws + NT);      // overlays aout
    __hip_bfloat16* y1_bf  = (__hip_bfloat16*)(ws + 2 * NT);  // overlays q post-attn
    __hip_bfloat16* v_bf   = (__hip_bfloat16*)(ws + 4 * NT);
    __hip_bfloat16* h_bf   = (__hip_bfloat16*)(ws + 5 * NT);
    float* Opart = ws + 3 * NT;
    float* msumb = Opart + (size_t)B * H * NS * U * 64;
    float* wpool = ws + 5 * NT + NT / 2;
    __hip_bfloat16* wqb = (__hip_bfloat16*)wpool;
    __hip_bfloat16* wkb = wqb + (size_t)D * D;
    __hip_bfloat16* wvb = wkb + (size_t)D * D;
    __hip_bfloat16* wob = wvb + (size_t)D * D;
    __hip_bfloat16* w1b = wob + (size_t)D * D;
    __hip_bfloat16* w2b = w1b + (size_t)DFF * D;
    float* after_w = wpool + ((size_t)4 * D * D + 2 * (size_t)DFF * D) / 2;
    float* Mbuf = after_w;
    int* idx    = (int*)(Mbuf + (size_t)B * H * LSEQ);
    int* top    = idx + LU;
    float* vm   = (float*)(top + B * H * U);
    float* vpart  = vm + (size_t)B * H * E;
    float* updbuf = vpart + (size_t)128 * 64;
    float* baseb  = updbuf + (size_t)B * H * U * 64;
    __hip_bfloat16* xbf  = (__hip_bfloat16*)(baseb + (size_t)B * D);   // B*LSEQ*F_IN
    __hip_bfloat16* webf = xbf + (size_t)B * LSEQ * F_IN;              // D*F_IN

    const int ML = B * LSEQ;  // 8192
    dim3 gD(D / 128, ML / 128);
    dim3 gF1(DFF / 128, ML / 128);
    const int CAST_N = 4 * (D * D / 4) + 2 * (DFF * D / 4);  // 786432

    // ---- embed as MFMA GEMM + posenc ----
    prep_embed_kernel<<<(B * LSEQ * F_IN / 4 + D * F_IN / 4 + 255) / 256, 256, 0, stream>>>(
        x, We, xbf, webf);
    gemm_mfma<0, 0><<<gD, 256, 0, stream>>>((const unsigned short*)xbf,
                                            (const unsigned short*)webf, be, aout,
                                            ML, D, F_IN);
    posenc_kernel<<<(B * LSEQ * D + 255) / 256, 256, 0, stream>>>(aout, cls, h, h_bf);

    for (int l = 0; l < NL; ++l) {
        cast_weights_kernel<<<(CAST_N + 255) / 256, 256, 0, stream>>>(
            Wq + (size_t)l * D * D, Wk + (size_t)l * D * D, Wv + (size_t)l * D * D,
            Wo + (size_t)l * D * D, W1 + (size_t)l * DFF * D, W2 + (size_t)l * D * DFF,
            wqb, wkb, wvb, wob, w1b, w2b);

        gemm_mfma<0, 0><<<gD, 256, 0, stream>>>((const unsigned short*)h_bf,
                                                (const unsigned short*)wqb, bq + l * D, q,
                                                ML, D, D);
        gemm_mfma<0, 1><<<gD, 256, 0, stream>>>((const unsigned short*)h_bf,
                                                (const unsigned short*)wkb, bk + l * D, kbf,
                                                ML, D, D);
        gemm_mfma<0, 1><<<gD, 256, 0, stream>>>((const unsigned short*)h_bf,
                                                (const unsigned short*)wvb, bv + l * D, v_bf,
                                                ML, D, D);

        idx_kernel<<<(HALF_LU + 255) / 256, 256, 0, stream>>>(idx, l);
        mscore_kernel<<<B * LSEQ, 256, 0, stream>>>(q, kbf, idx, Mbuf);
        topk_kernel<<<B * H, 256, 0, stream>>>(Mbuf, top);
        vmean_part<<<B * H * 8, 256, 0, stream>>>(v_bf, vpart);
        vmean_reduce<<<4, 256, 0, stream>>>(vpart, vm);
        wo_base_kernel<<<B * 128, 256, 0, stream>>>(vm, (const unsigned short*)wob,
                                                    bo + l * D, baseb);
        attn_part<<<dim3(NS, H, B), 256, 0, stream>>>(q, kbf, v_bf, top, Opart, msumb);
        attn_reduce<<<B * H * U, 64, 0, stream>>>(Opart, msumb, updbuf);
        bcast_base<<<(B * LSEQ * D / 4 + 255) / 256, 256, 0, stream>>>(baseb, aout);
        wo_corr_kernel<<<B * H * U, 256, 0, stream>>>(updbuf, vm,
                                                      (const unsigned short*)wob, top, aout);
        add_ln_kernel<<<ML, 64, 0, stream>>>(h, aout, g1 + l * D, b1 + l * D, h_bf);

        gemm_mfma<1, 1><<<gF1, 256, 0, stream>>>((const unsigned short*)h_bf,
                                                 (const unsigned short*)w1b, bf1 + l * DFF,
                                                 y1_bf, ML, DFF, D);
        gemm_mfma<0, 0><<<gD, 256, 0, stream>>>((const unsigned short*)y1_bf,
                                                (const unsigned short*)w2b, bf2 + l * D, aout,
                                                ML, D, DFF);
        add_ln_kernel<<<ML, 64, 0, stream>>>(h, aout, g2 + l * D, b2 + l * D, h_bf);
    }

    final_kernel<<<B, 64, 0, stream>>>(h, Wf, bff, out);
}

// Round 9
// 740.003 us; speedup vs baseline: 4.5337x; 1.0807x over previous
//
#include <hip/hip_runtime.h>
#include <hip/hip_bf16.h>
#include <math.h>
#include <stdint.h>

#define B 2
#define S 4095
#define LSEQ 4096
#define F_IN 32
#define D 512
#define H 8
#define E 64
#define DFF 2048
#define NL 2
#define U 45
#define EPSL 1e-5f
#define LU (LSEQ * U)
#define HALF_LU (LU / 2)
#define NS 32
#define SLICE 128

typedef __attribute__((ext_vector_type(8))) short short8;
typedef __attribute__((ext_vector_type(4))) float f32x4;

#define GLD(gp, lp)                                                            \
    __builtin_amdgcn_global_load_lds(                                          \
        (const __attribute__((address_space(1))) void*)(gp),                   \
        (__attribute__((address_space(3))) void*)(lp), 16, 0, 0)

__device__ __forceinline__ unsigned short bf16_bits(float f) {
    __hip_bfloat16 h = __float2bfloat16(f);
    return *(unsigned short*)&h;
}
__device__ __forceinline__ float bits_to_f32(unsigned short s) {
    union { uint32_t u; float f; } c;
    c.u = ((uint32_t)s) << 16;
    return c.f;
}
// monotone sortable key: desc key order == (value desc, index asc) — JAX top_k ties
__device__ __forceinline__ unsigned long long mkey(float v, int index) {
    uint32_t u = __float_as_uint(v);
    uint32_t mono = (u & 0x80000000u) ? ~u : (u | 0x80000000u);
    return ((unsigned long long)mono << 32) | (uint32_t)(0xFFFFFFFFu - (uint32_t)index);
}

// ---------------- Threefry-2x32 (20 rounds), exactly JAX's algorithm ----------------
__device__ __forceinline__ uint32_t rotl32(uint32_t x, int r) {
    return (x << r) | (x >> (32 - r));
}

__device__ void threefry2x32(uint32_t k0, uint32_t k1, uint32_t c0, uint32_t c1,
                             uint32_t& o0, uint32_t& o1) {
    uint32_t ks2 = k0 ^ k1 ^ 0x1BD11BDAu;
    uint32_t x0 = c0 + k0, x1 = c1 + k1;
    x0 += x1; x1 = rotl32(x1, 13); x1 ^= x0;
    x0 += x1; x1 = rotl32(x1, 15); x1 ^= x0;
    x0 += x1; x1 = rotl32(x1, 26); x1 ^= x0;
    x0 += x1; x1 = rotl32(x1, 6);  x1 ^= x0;
    x0 += k1; x1 += ks2 + 1u;
    x0 += x1; x1 = rotl32(x1, 17); x1 ^= x0;
    x0 += x1; x1 = rotl32(x1, 29); x1 ^= x0;
    x0 += x1; x1 = rotl32(x1, 16); x1 ^= x0;
    x0 += x1; x1 = rotl32(x1, 24); x1 ^= x0;
    x0 += ks2; x1 += k0 + 2u;
    x0 += x1; x1 = rotl32(x1, 13); x1 ^= x0;
    x0 += x1; x1 = rotl32(x1, 15); x1 ^= x0;
    x0 += x1; x1 = rotl32(x1, 26); x1 ^= x0;
    x0 += x1; x1 = rotl32(x1, 6);  x1 ^= x0;
    x0 += k0; x1 += k1 + 3u;
    x0 += x1; x1 = rotl32(x1, 17); x1 ^= x0;
    x0 += x1; x1 = rotl32(x1, 29); x1 ^= x0;
    x0 += x1; x1 = rotl32(x1, 16); x1 ^= x0;
    x0 += x1; x1 = rotl32(x1, 24); x1 ^= x0;
    x0 += k1; x1 += ks2 + 4u;
    x0 += x1; x1 = rotl32(x1, 13); x1 ^= x0;
    x0 += x1; x1 = rotl32(x1, 15); x1 ^= x0;
    x0 += x1; x1 = rotl32(x1, 26); x1 ^= x0;
    x0 += x1; x1 = rotl32(x1, 6);  x1 ^= x0;
    x0 += ks2; x1 += k0 + 5u;
    o0 = x0; o1 = x1;
}

__global__ void idx_kernel(int* __restrict__ idx, int layer) {
    int j = blockIdx.x * blockDim.x + threadIdx.x;
    if (j >= HALF_LU) return;
    uint32_t f0, f1, a0, a1, b0, b1, o0, o1;
    threefry2x32(0u, 42u, 0u, (uint32_t)layer, f0, f1);
    threefry2x32(f0, f1, 0u, 2u, a0, a1);
    threefry2x32(f0, f1, 1u, 3u, b0, b1);
    threefry2x32(a1, b1, (uint32_t)j, (uint32_t)(j + HALF_LU), o0, o1);
    idx[j] = (int)(o0 & 4095u);
    idx[j + HALF_LU] = (int)(o1 & 4095u);
    (void)a0; (void)b0;
}

// ------- prep: xbf[8192x32] (row l=0 zero, else x[b,l-1,:]) + We_bf cast -----------
__global__ void prep_embed_kernel(const float* __restrict__ x, const float* __restrict__ We,
                                  __hip_bfloat16* __restrict__ xbf,
                                  __hip_bfloat16* __restrict__ webf) {
    int u = blockIdx.x * blockDim.x + threadIdx.x;  // 4-element units
    const int NX = B * LSEQ * F_IN / 4;             // 65536
    const int NW = D * F_IN / 4;                    // 4096
    if (u < NX) {
        int e0 = u * 4;
        int i = e0 & 31;
        int l = (e0 >> 5) & (LSEQ - 1);
        int b = e0 >> 17;
        union { unsigned short s[4]; uint2 w; } o;
        if (l == 0) {
            o.s[0] = o.s[1] = o.s[2] = o.s[3] = 0;
        } else {
            float4 v = *(const float4*)(x + ((size_t)b * S + (l - 1)) * F_IN + i);
            o.s[0] = bf16_bits(v.x); o.s[1] = bf16_bits(v.y);
            o.s[2] = bf16_bits(v.z); o.s[3] = bf16_bits(v.w);
        }
        ((uint2*)xbf)[u] = o.w;
    } else if (u < NX + NW) {
        int w = u - NX;
        float4 v = ((const float4*)We)[w];
        union { unsigned short s[4]; uint2 w2; } o;
        o.s[0] = bf16_bits(v.x); o.s[1] = bf16_bits(v.y);
        o.s[2] = bf16_bits(v.z); o.s[3] = bf16_bits(v.w);
        ((uint2*)webf)[w] = o.w2;
    }
}

// ------- posenc: h = (l==0 ? cls : emb) + PE; dual write f32 + bf16 ----------------
__global__ void posenc_kernel(const float* __restrict__ emb, const float* __restrict__ cls,
                              float* __restrict__ h, __hip_bfloat16* __restrict__ hbf) {
    int gid = blockIdx.x * blockDim.x + threadIdx.x;
    if (gid >= B * LSEQ * D) return;
    int d = gid % D;
    int l = (gid / D) % LSEQ;
    float v = (l == 0) ? cls[d] : emb[gid];
    int i = d >> 1;
    float divv = expf((float)(2 * i) * (float)(-9.210340371976184 / 512.0));
    float ang = (float)l * divv;
    v += (d & 1) ? cosf(ang) : sinf(ang);
    h[gid] = v;
    hbf[gid] = __float2bfloat16(v);
}

// ------- fused per-layer weight cast: all 6 weights in one launch ------------------
__global__ void cast_weights_kernel(const float* __restrict__ Wq_l,
                                    const float* __restrict__ Wk_l,
                                    const float* __restrict__ Wv_l,
                                    const float* __restrict__ Wo_l,
                                    const float* __restrict__ W1_l,
                                    const float* __restrict__ W2_l,
                                    __hip_bfloat16* __restrict__ wqb,
                                    __hip_bfloat16* __restrict__ wkb,
                                    __hip_bfloat16* __restrict__ wvb,
                                    __hip_bfloat16* __restrict__ wob,
                                    __hip_bfloat16* __restrict__ w1b,
                                    __hip_bfloat16* __restrict__ w2b) {
    const int SDD = D * D / 4;       // 65536
    const int SFD = DFF * D / 4;     // 262144
    int u = blockIdx.x * blockDim.x + threadIdx.x;
    const float* src;
    __hip_bfloat16* dst;
    int off;
    if (u < SDD) { src = Wq_l; dst = wqb; off = u; }
    else if (u < 2 * SDD) { src = Wk_l; dst = wkb; off = u - SDD; }
    else if (u < 3 * SDD) { src = Wv_l; dst = wvb; off = u - 2 * SDD; }
    else if (u < 4 * SDD) { src = Wo_l; dst = wob; off = u - 3 * SDD; }
    else if (u < 4 * SDD + SFD) { src = W1_l; dst = w1b; off = u - 4 * SDD; }
    else { src = W2_l; dst = w2b; off = u - 4 * SDD - SFD; }
    float4 v = ((const float4*)src)[off];
    union { unsigned short s[4]; uint2 w; } o;
    o.s[0] = bf16_bits(v.x); o.s[1] = bf16_bits(v.y);
    o.s[2] = bf16_bits(v.z); o.s[3] = bf16_bits(v.w);
    ((uint2*)dst)[off] = o.w;
}

// ---------------- bf16 MFMA GEMM: C[M,N] = A[M,K] @ W[N,K]^T + bias ----------------
template <int ACT, int OUTBF>
__global__ __launch_bounds__(256) void gemm_mfma(const unsigned short* __restrict__ A,
                                                 const unsigned short* __restrict__ W,
                                                 const float* __restrict__ bias,
                                                 void* __restrict__ Cout,
                                                 int M, int N, int K) {
    __shared__ unsigned short lds[2 * 128 * 32];
    unsigned short* As = lds;
    unsigned short* Bs = lds + 128 * 32;
    const int tid = threadIdx.x;
    const int m0 = blockIdx.y * 128, n0 = blockIdx.x * 128;
    const int wave = tid >> 6, lane = tid & 63;
    const int wm = (wave >> 1) * 64, wn = (wave & 1) * 64;
    const int quad = lane >> 4, m15 = lane & 15;
    const int srow = tid >> 2, scol = (tid & 3) * 8;
    f32x4 acc[4][4] = {};
    const unsigned short* Ag0 = A + (size_t)(m0 + srow) * K + scol;
    const unsigned short* Ag1 = A + (size_t)(m0 + srow + 64) * K + scol;
    const unsigned short* Wg0 = W + (size_t)(n0 + srow) * K + scol;
    const unsigned short* Wg1 = W + (size_t)(n0 + srow + 64) * K + scol;
    for (int k0 = 0; k0 < K; k0 += 32) {
        __syncthreads();
        GLD(Ag0 + k0, As + tid * 8);
        GLD(Ag1 + k0, As + 2048 + tid * 8);
        GLD(Wg0 + k0, Bs + tid * 8);
        GLD(Wg1 + k0, Bs + 2048 + tid * 8);
        __syncthreads();
        short8 af[4], bfr[4];
#pragma unroll
        for (int mi = 0; mi < 4; ++mi)
            af[mi] = *(const short8*)(As + (wm + mi * 16 + m15) * 32 + quad * 8);
#pragma unroll
        for (int ni = 0; ni < 4; ++ni)
            bfr[ni] = *(const short8*)(Bs + (wn + ni * 16 + m15) * 32 + quad * 8);
#pragma unroll
        for (int mi = 0; mi < 4; ++mi)
#pragma unroll
            for (int ni = 0; ni < 4; ++ni)
                acc[mi][ni] = __builtin_amdgcn_mfma_f32_16x16x32_bf16(
                    af[mi], bfr[ni], acc[mi][ni], 0, 0, 0);
    }
    float* Cf = (float*)Cout;
    __hip_bfloat16* Cb = (__hip_bfloat16*)Cout;
#pragma unroll
    for (int mi = 0; mi < 4; ++mi) {
        int mg = m0 + wm + mi * 16 + quad * 4;
#pragma unroll
        for (int ni = 0; ni < 4; ++ni) {
            int ng = n0 + wn + ni * 16 + m15;
            float bv = bias[ng];
#pragma unroll
            for (int r = 0; r < 4; ++r) {
                float v = acc[mi][ni][r] + bv;
                if (ACT == 1) v = fmaxf(v, 0.f);
                if (OUTBF == 1)
                    Cb[(size_t)(mg + r) * N + ng] = __float2bfloat16(v);
                else
                    Cf[(size_t)(mg + r) * N + ng] = v;
            }
        }
    }
}

// -------- M-score: block per (b,l); one WAVE per sampled row -----------------------
__global__ __launch_bounds__(256) void mscore_kernel(const float* __restrict__ q,
                                                     const __hip_bfloat16* __restrict__ kbf,
                                                     const int* __restrict__ idx,
                                                     float* __restrict__ Mv) {
    __shared__ float Sbuf[U][8];
    __shared__ int sidx[U];
    int bid = blockIdx.x;
    int b = bid & 1;
    int l = bid >> 1;
    int tid = threadIdx.x;
    int wave = tid >> 6, lane = tid & 63;
    if (tid < U) sidx[tid] = idx[l * U + tid];
    const float* qr = q + ((size_t)(b * LSEQ) + l) * D + lane * 8;
    float4 qa = *(const float4*)qr;
    float4 qb = *(const float4*)(qr + 4);
    __syncthreads();
    const unsigned short* kbase = (const unsigned short*)(kbf + (size_t)(b * LSEQ) * D);
    for (int t = wave; t < U; t += 4) {
        int kr = sidx[t];
        union { uint4 u; unsigned short s[8]; } kv;
        kv.u = *(const uint4*)(kbase + (size_t)kr * D + lane * 8);
        float p = qa.x * bits_to_f32(kv.s[0]) + qa.y * bits_to_f32(kv.s[1]) +
                  qa.z * bits_to_f32(kv.s[2]) + qa.w * bits_to_f32(kv.s[3]) +
                  qb.x * bits_to_f32(kv.s[4]) + qb.y * bits_to_f32(kv.s[5]) +
                  qb.z * bits_to_f32(kv.s[6]) + qb.w * bits_to_f32(kv.s[7]);
        p += __shfl_xor(p, 1);
        p += __shfl_xor(p, 2);
        p += __shfl_xor(p, 4);
        if ((lane & 7) == 0) Sbuf[t][lane >> 3] = p;
    }
    __syncthreads();
    if (tid < 8) {
        float mx = -INFINITY, sm = 0.f;
        for (int t = 0; t < U; ++t) {
            float v = Sbuf[t][tid];
            mx = fmaxf(mx, v);
            sm += v;
        }
        Mv[((size_t)b * H + tid) * LSEQ + l] = mx - sm / (float)LSEQ;
    }
}

// ------- top-k phase A: bitonic sort each 256-chunk desc, emit top-45 keys ---------
__global__ __launch_bounds__(256) void topk_chunk_kernel(const float* __restrict__ Mv,
                                                         unsigned long long* __restrict__ cand) {
    __shared__ unsigned long long sk[256];
    int blk = blockIdx.x;  // B*H*16
    int chunk = blk & 15, bh = blk >> 4;
    int tid = threadIdx.x;
    int gi = chunk * 256 + tid;
    sk[tid] = mkey(Mv[(size_t)bh * LSEQ + gi], gi);
    __syncthreads();
    for (int k = 2; k <= 256; k <<= 1) {
        for (int j = k >> 1; j > 0; j >>= 1) {
            int ixj = tid ^ j;
            if (ixj > tid) {
                unsigned long long a = sk[tid], b = sk[ixj];
                bool desc = ((tid & k) == 0);
                if (desc ? (a < b) : (a > b)) { sk[tid] = b; sk[ixj] = a; }
            }
            __syncthreads();
        }
    }
    if (tid < U) cand[((size_t)bh * 16 + chunk) * U + tid] = sk[tid];
}

// ------- top-k phase B: merge 16x45 candidates via 1024-wide bitonic sort ----------
__global__ __launch_bounds__(256) void topk_merge_kernel(const unsigned long long* __restrict__ cand,
                                                         int* __restrict__ top) {
    __shared__ unsigned long long sk[1024];
    int bh = blockIdx.x;
    int tid = threadIdx.x;
    for (int e = tid; e < 1024; e += 256)
        sk[e] = (e < 16 * U) ? cand[(size_t)bh * 16 * U + e] : 0ull;
    __syncthreads();
    for (int k = 2; k <= 1024; k <<= 1) {
        for (int j = k >> 1; j > 0; j >>= 1) {
            for (int e = tid; e < 1024; e += 256) {
                int ixj = e ^ j;
                if (ixj > e) {
                    unsigned long long a = sk[e], b = sk[ixj];
                    bool desc = ((e & k) == 0);
                    if (desc ? (a < b) : (a > b)) { sk[e] = b; sk[ixj] = a; }
                }
            }
            __syncthreads();
        }
    }
    if (tid < U)
        top[bh * U + tid] = (int)(0xFFFFFFFFu - (uint32_t)(sk[tid] & 0xFFFFFFFFu));
}

// ---------------- v mean: partial (128 blocks) + reduce ----------------
__global__ __launch_bounds__(256) void vmean_part(const __hip_bfloat16* __restrict__ v,
                                                  float* __restrict__ part) {
    int blk = blockIdx.x;  // B*H*8
    int seg = blk & 7, hh = (blk >> 3) & 7, b = blk >> 6;
    int e = threadIdx.x & 63, rg = threadIdx.x >> 6;
    const __hip_bfloat16* vp =
        v + ((size_t)(b * LSEQ) + seg * 512) * D + hh * 64 + e;
    float acc = 0.f;
    for (int r = rg; r < 512; r += 4) acc += __bfloat162float(vp[(size_t)r * D]);
    __shared__ float red[4][64];
    red[rg][e] = acc;
    __syncthreads();
    if (threadIdx.x < 64)
        part[(size_t)blk * 64 + threadIdx.x] =
            red[0][threadIdx.x] + red[1][threadIdx.x] + red[2][threadIdx.x] + red[3][threadIdx.x];
}

__global__ void vmean_reduce(const float* __restrict__ part, float* __restrict__ vm) {
    int gid = blockIdx.x * blockDim.x + threadIdx.x;
    if (gid >= B * H * E) return;
    int e = gid & 63, bh = gid >> 6;
    float acc = 0.f;
#pragma unroll
    for (int s = 0; s < 8; ++s) acc += part[((size_t)bh * 8 + s) * 64 + e];
    vm[gid] = acc / (float)LSEQ;
}

// ------- base[b] = vmeanAll[b] . Wo^T + bo (one wave per output n) -----------------
__global__ __launch_bounds__(256) void wo_base_kernel(const float* __restrict__ vm,
                                                      const unsigned short* __restrict__ wob,
                                                      const float* __restrict__ bo,
                                                      float* __restrict__ base) {
    int b = blockIdx.x >> 7;            // grid B*128
    int n = (blockIdx.x & 127) * 4 + (threadIdx.x >> 6);
    int lane = threadIdx.x & 63;
    const float* vmr = vm + (size_t)b * D + lane * 8;
    float4 va = *(const float4*)vmr;
    float4 vb = *(const float4*)(vmr + 4);
    union { uint4 u; unsigned short s[8]; } w;
    w.u = *(const uint4*)(wob + (size_t)n * D + lane * 8);
    float p = va.x * bits_to_f32(w.s[0]) + va.y * bits_to_f32(w.s[1]) +
              va.z * bits_to_f32(w.s[2]) + va.w * bits_to_f32(w.s[3]) +
              vb.x * bits_to_f32(w.s[4]) + vb.y * bits_to_f32(w.s[5]) +
              vb.z * bits_to_f32(w.s[6]) + vb.w * bits_to_f32(w.s[7]);
    for (int off = 32; off; off >>= 1) p += __shfl_xor(p, off);
    if (lane == 0) base[(size_t)b * D + n] = p + bo[n];
}

// ------- aout[r] = base[b] broadcast (float4) --------------------------------------
__global__ void bcast_base(const float* __restrict__ base, float* __restrict__ aout) {
    int i = blockIdx.x * blockDim.x + threadIdx.x;  // over ML*D/4
    if (i >= B * LSEQ * D / 4) return;
    int b = i >> 19;          // LSEQ*D/4 = 2^19
    int c4 = i & 127;         // D/4 = 128
    ((float4*)aout)[i] = *(const float4*)(base + (size_t)b * D + c4 * 4);
}

// ------- scatter correction: aout[top[bh,t]] += (upd - vmean_h) . Wo_h^T -----------
__global__ __launch_bounds__(256) void wo_corr_kernel(const float* __restrict__ updbuf,
                                                      const float* __restrict__ vm,
                                                      const unsigned short* __restrict__ wob,
                                                      const int* __restrict__ top,
                                                      float* __restrict__ aout) {
    __shared__ float dlt[E];
    int bid = blockIdx.x;  // B*H*U
    int t = bid % U;
    int bh = bid / U;
    int b = bh >> 3, hh = bh & 7;
    int tid = threadIdx.x;
    if (tid < E) dlt[tid] = updbuf[((size_t)bh * U + t) * E + tid] - vm[(size_t)bh * E + tid];
    __syncthreads();
    int r = top[bh * U + t];
    float* arow = aout + (size_t)(b * LSEQ + r) * D;
    for (int n = tid; n < D; n += 256) {
        const unsigned short* wr = wob + (size_t)n * D + hh * E;
        float acc = 0.f;
#pragma unroll
        for (int k2 = 0; k2 < E; ++k2) acc += dlt[k2] * bits_to_f32(wr[k2]);
        atomicAdd(arow + n, acc);
    }
}

// -------- flash-style MFMA attention partial: block = (slice, h, b) ----------------
__global__ __launch_bounds__(256) void attn_part(const float* __restrict__ q,
                                                 const __hip_bfloat16* __restrict__ kbf,
                                                 const __hip_bfloat16* __restrict__ vbf,
                                                 const int* __restrict__ top,
                                                 float* __restrict__ Opart,
                                                 float* __restrict__ msum) {
    __shared__ unsigned short Qs[48 * 72];
    __shared__ unsigned short Ks[SLICE * 72];
    __shared__ unsigned short Vs[SLICE * 68];
    __shared__ unsigned short Ps[48 * 136];
    __shared__ float mred[48][4];
    __shared__ float sred[48][4];
    const int slice = blockIdx.x, hh = blockIdx.y, b = blockIdx.z;
    const int bh = b * H + hh;
    const int tid = threadIdx.x;
    const int s0 = slice * SLICE;
    for (int i = tid; i < 48 * 64; i += 256) {
        int t = i >> 6, e = i & 63;
        float v = 0.f;
        if (t < U) {
            int r = top[bh * U + t];
            v = q[((size_t)(b * LSEQ) + r) * D + hh * E + e];
        }
        Qs[t * 72 + e] = bf16_bits(v);
    }
    {
        const uint4* src = (const uint4*)(kbf + ((size_t)(b * LSEQ) + s0) * D + hh * E);
        for (int i = tid; i < SLICE * 8; i += 256) {
            int r = i >> 3, c = i & 7;
            uint4 d = src[(size_t)r * 64 + c];
            *(uint4*)(Ks + r * 72 + c * 8) = d;
        }
    }
    {
        const uint2* src = (const uint2*)(vbf + ((size_t)(b * LSEQ) + s0) * D + hh * E);
        for (int i = tid; i < SLICE * 16; i += 256) {
            int r = i >> 4, c = i & 15;
            uint2 d = src[(size_t)r * 128 + c];
            *(uint2*)(Vs + r * 68 + c * 4) = d;
        }
    }
    __syncthreads();
    const int wave = tid >> 6, lane = tid & 63;
    const int quad = lane >> 4, m15 = lane & 15;
    const int wc = wave * 32;
    f32x4 acc[3][2] = {};
#pragma unroll
    for (int ks = 0; ks < 2; ++ks) {
        short8 af[3], bfr[2];
#pragma unroll
        for (int mt = 0; mt < 3; ++mt)
            af[mt] = *(const short8*)(Qs + (mt * 16 + m15) * 72 + ks * 32 + quad * 8);
#pragma unroll
        for (int nt = 0; nt < 2; ++nt)
            bfr[nt] = *(const short8*)(Ks + (wc + nt * 16 + m15) * 72 + ks * 32 + quad * 8);
#pragma unroll
        for (int mt = 0; mt < 3; ++mt)
#pragma unroll
            for (int nt = 0; nt < 2; ++nt)
                acc[mt][nt] = __builtin_amdgcn_mfma_f32_16x16x32_bf16(
                    af[mt], bfr[nt], acc[mt][nt], 0, 0, 0);
    }
    float sc[3][2][4];
#pragma unroll
    for (int mt = 0; mt < 3; ++mt)
#pragma unroll
        for (int nt = 0; nt < 2; ++nt)
#pragma unroll
            for (int r = 0; r < 4; ++r) sc[mt][nt][r] = acc[mt][nt][r] * 0.125f;
#pragma unroll
    for (int mt = 0; mt < 3; ++mt)
#pragma unroll
        for (int r = 0; r < 4; ++r) {
            float mv = fmaxf(sc[mt][0][r], sc[mt][1][r]);
            mv = fmaxf(mv, __shfl_xor(mv, 1));
            mv = fmaxf(mv, __shfl_xor(mv, 2));
            mv = fmaxf(mv, __shfl_xor(mv, 4));
            mv = fmaxf(mv, __shfl_xor(mv, 8));
            if (m15 == 0) mred[mt * 16 + quad * 4 + r][wave] = mv;
        }
    __syncthreads();
#pragma unroll
    for (int mt = 0; mt < 3; ++mt)
#pragma unroll
        for (int r = 0; r < 4; ++r) {
            int row = mt * 16 + quad * 4 + r;
            float ms = fmaxf(fmaxf(mred[row][0], mred[row][1]),
                             fmaxf(mred[row][2], mred[row][3]));
            float p0 = __expf(sc[mt][0][r] - ms);
            float p1 = __expf(sc[mt][1][r] - ms);
            float sv = p0 + p1;
            sv += __shfl_xor(sv, 1);
            sv += __shfl_xor(sv, 2);
            sv += __shfl_xor(sv, 4);
            sv += __shfl_xor(sv, 8);
            if (m15 == 0) sred[row][wave] = sv;
            Ps[row * 136 + wc + m15] = bf16_bits(p0);
            Ps[row * 136 + wc + 16 + m15] = bf16_bits(p1);
        }
    __syncthreads();
    if (tid < U) {
        float mm = fmaxf(fmaxf(mred[tid][0], mred[tid][1]),
                         fmaxf(mred[tid][2], mred[tid][3]));
        float ss = sred[tid][0] + sred[tid][1] + sred[tid][2] + sred[tid][3];
        size_t base = (((size_t)bh * NS + slice) * U + tid) * 2;
        msum[base] = mm;
        msum[base + 1] = ss;
    }
    f32x4 apv[3] = {};
#pragma unroll
    for (int ks = 0; ks < 4; ++ks) {
        short8 bv;
#pragma unroll
        for (int j = 0; j < 8; ++j)
            bv[j] = (short)Vs[(ks * 32 + quad * 8 + j) * 68 + wave * 16 + m15];
        short8 af2[3];
#pragma unroll
        for (int mt = 0; mt < 3; ++mt)
            af2[mt] = *(const short8*)(Ps + (mt * 16 + m15) * 136 + ks * 32 + quad * 8);
#pragma unroll
        for (int mt = 0; mt < 3; ++mt)
            apv[mt] = __builtin_amdgcn_mfma_f32_16x16x32_bf16(af2[mt], bv, apv[mt], 0, 0, 0);
    }
    size_t obase = ((size_t)bh * NS + slice) * U;
#pragma unroll
    for (int mt = 0; mt < 3; ++mt)
#pragma unroll
        for (int r = 0; r < 4; ++r) {
            int row = mt * 16 + quad * 4 + r;
            if (row < U)
                Opart[(obase + row) * 64 + wave * 16 + m15] = apv[mt][r];
        }
}

// -------- combine slice partials -> dense upd buffer (f32) -------------------------
__global__ __launch_bounds__(64) void attn_reduce(const float* __restrict__ Opart,
                                                  const float* __restrict__ msum,
                                                  float* __restrict__ updbuf) {
    int t = blockIdx.x % U;
    int bh = blockIdx.x / U;
    int lane = threadIdx.x;
    float m_s = -INFINITY, ss = 0.f;
    if (lane < NS) {
        size_t base = (((size_t)bh * NS + lane) * U + t) * 2;
        m_s = msum[base];
        ss = msum[base + 1];
    }
    float M = m_s;
    for (int off = 32; off; off >>= 1) M = fmaxf(M, __shfl_xor(M, off));
    float e_s = (lane < NS) ? __expf(m_s - M) : 0.f;
    float d = ss * e_s;
    for (int off = 32; off; off >>= 1) d += __shfl_xor(d, off);
    float acc = 0.f;
    for (int s = 0; s < NS; ++s) {
        float w = __shfl(e_s, s);
        acc += w * Opart[(((size_t)bh * NS + s) * U + t) * 64 + lane];
    }
    updbuf[((size_t)bh * U + t) * E + lane] = acc / d;
}

// -------- h = LayerNorm(h + a) * g + b, one wave per row, dual write f32+bf16 -------
__global__ __launch_bounds__(64) void add_ln_kernel(float* __restrict__ h,
                                                    const float* __restrict__ a,
                                                    const float* __restrict__ g,
                                                    const float* __restrict__ bb,
                                                    __hip_bfloat16* __restrict__ hbf) {
    int row = blockIdx.x;
    int lane = threadIdx.x;
    float* hp = h + (size_t)row * D;
    const float* ap = a + (size_t)row * D;
    float x[8];
    float sum = 0.f;
#pragma unroll
    for (int j = 0; j < 8; ++j) {
        x[j] = hp[lane + 64 * j] + ap[lane + 64 * j];
        sum += x[j];
    }
    for (int off = 32; off; off >>= 1) sum += __shfl_xor(sum, off);
    float mu = sum / (float)D;
    float vs = 0.f;
#pragma unroll
    for (int j = 0; j < 8; ++j) {
        float dd = x[j] - mu;
        vs += dd * dd;
    }
    for (int off = 32; off; off >>= 1) vs += __shfl_xor(vs, off);
    float inv = 1.f / sqrtf(vs / (float)D + EPSL);
#pragma unroll
    for (int j = 0; j < 8; ++j) {
        float o = (x[j] - mu) * inv * g[lane + 64 * j] + bb[lane + 64 * j];
        hp[lane + 64 * j] = o;
        hbf[(size_t)row * D + lane + 64 * j] = __float2bfloat16(o);
    }
}

// ---------------- final head ----------------
__global__ void final_kernel(const float* __restrict__ h, const float* __restrict__ Wf,
                             const float* __restrict__ bf, float* __restrict__ out) {
    int b = blockIdx.x;
    int lane = threadIdx.x;
    const float* hp = h + (size_t)b * LSEQ * D;
    float acc = 0.f;
    for (int j = lane; j < D; j += 64) acc += hp[j] * Wf[j];
    for (int off = 32; off; off >>= 1) acc += __shfl_xor(acc, off);
    if (lane == 0) out[b] = acc + bf[0];
}

extern "C" void kernel_launch(void* const* d_in, const int* in_sizes, int n_in,
                              void* d_out, int out_size, void* d_ws, size_t ws_size,
                              hipStream_t stream) {
    (void)in_sizes; (void)n_in; (void)out_size; (void)ws_size;
    const float* x   = (const float*)d_in[0];
    const float* We  = (const float*)d_in[1];
    const float* be  = (const float*)d_in[2];
    const float* cls = (const float*)d_in[3];
    const float* Wq  = (const float*)d_in[4];
    const float* bq  = (const float*)d_in[5];
    const float* Wk  = (const float*)d_in[6];
    const float* bk  = (const float*)d_in[7];
    const float* Wv  = (const float*)d_in[8];
    const float* bv  = (const float*)d_in[9];
    const float* Wo  = (const float*)d_in[10];
    const float* bo  = (const float*)d_in[11];
    const float* g1  = (const float*)d_in[12];
    const float* b1  = (const float*)d_in[13];
    const float* g2  = (const float*)d_in[14];
    const float* b2  = (const float*)d_in[15];
    const float* W1  = (const float*)d_in[16];
    const float* bf1 = (const float*)d_in[17];
    const float* W2  = (const float*)d_in[18];
    const float* bf2 = (const float*)d_in[19];
    const float* Wf  = (const float*)d_in[20];
    const float* bff = (const float*)d_in[21];
    float* out = (float*)d_out;

    float* ws = (float*)d_ws;
    const size_t NT = (size_t)B * LSEQ * D;  // 4,194,304
    float* h    = ws;                         // [0, NT)
    float* aout = ws + NT;                    // [NT, 2NT)
    float* q    = ws + 2 * NT;                // [2NT, 3NT)
    __hip_bfloat16* kbf    = (__hip_bfloat16*)(ws + NT);      // overlays aout
    __hip_bfloat16* y1_bf  = (__hip_bfloat16*)(ws + 2 * NT);  // overlays q post-attn
    __hip_bfloat16* v_bf   = (__hip_bfloat16*)(ws + 4 * NT);
    __hip_bfloat16* h_bf   = (__hip_bfloat16*)(ws + 5 * NT);
    float* Opart = ws + 3 * NT;
    float* msumb = Opart + (size_t)B * H * NS * U * 64;
    float* wpool = ws + 5 * NT + NT / 2;
    __hip_bfloat16* wqb = (__hip_bfloat16*)wpool;
    __hip_bfloat16* wkb = wqb + (size_t)D * D;
    __hip_bfloat16* wvb = wkb + (size_t)D * D;
    __hip_bfloat16* wob = wvb + (size_t)D * D;
    __hip_bfloat16* w1b = wob + (size_t)D * D;
    __hip_bfloat16* w2b = w1b + (size_t)DFF * D;
    float* after_w = wpool + ((size_t)4 * D * D + 2 * (size_t)DFF * D) / 2;
    float* Mbuf = after_w;
    int* idx    = (int*)(Mbuf + (size_t)B * H * LSEQ);
    int* top    = idx + LU;
    float* vm   = (float*)(top + B * H * U);
    float* vpart  = vm + (size_t)B * H * E;
    float* updbuf = vpart + (size_t)128 * 64;
    float* baseb  = updbuf + (size_t)B * H * U * 64;
    __hip_bfloat16* xbf  = (__hip_bfloat16*)(baseb + (size_t)B * D);   // B*LSEQ*F_IN
    __hip_bfloat16* webf = xbf + (size_t)B * LSEQ * F_IN;              // D*F_IN
    unsigned long long* cand =
        (unsigned long long*)(((uintptr_t)(webf + (size_t)D * F_IN) + 7) & ~(uintptr_t)7);

    const int ML = B * LSEQ;  // 8192
    dim3 gD(D / 128, ML / 128);
    dim3 gF1(DFF / 128, ML / 128);
    const int CAST_N = 4 * (D * D / 4) + 2 * (DFF * D / 4);  // 786432

    // ---- embed as MFMA GEMM + posenc ----
    prep_embed_kernel<<<(B * LSEQ * F_IN / 4 + D * F_IN / 4 + 255) / 256, 256, 0, stream>>>(
        x, We, xbf, webf);
    gemm_mfma<0, 0><<<gD, 256, 0, stream>>>((const unsigned short*)xbf,
                                            (const unsigned short*)webf, be, aout,
                                            ML, D, F_IN);
    posenc_kernel<<<(B * LSEQ * D + 255) / 256, 256, 0, stream>>>(aout, cls, h, h_bf);

    for (int l = 0; l < NL; ++l) {
        cast_weights_kernel<<<(CAST_N + 255) / 256, 256, 0, stream>>>(
            Wq + (size_t)l * D * D, Wk + (size_t)l * D * D, Wv + (size_t)l * D * D,
            Wo + (size_t)l * D * D, W1 + (size_t)l * DFF * D, W2 + (size_t)l * D * DFF,
            wqb, wkb, wvb, wob, w1b, w2b);

        gemm_mfma<0, 0><<<gD, 256, 0, stream>>>((const unsigned short*)h_bf,
                                                (const unsigned short*)wqb, bq + l * D, q,
                                                ML, D, D);
        gemm_mfma<0, 1><<<gD, 256, 0, stream>>>((const unsigned short*)h_bf,
                                                (const unsigned short*)wkb, bk + l * D, kbf,
                                                ML, D, D);
        gemm_mfma<0, 1><<<gD, 256, 0, stream>>>((const unsigned short*)h_bf,
                                                (const unsigned short*)wvb, bv + l * D, v_bf,
                                                ML, D, D);

        idx_kernel<<<(HALF_LU + 255) / 256, 256, 0, stream>>>(idx, l);
        mscore_kernel<<<B * LSEQ, 256, 0, stream>>>(q, kbf, idx, Mbuf);
        topk_chunk_kernel<<<B * H * 16, 256, 0, stream>>>(Mbuf, cand);
        topk_merge_kernel<<<B * H, 256, 0, stream>>>(cand, top);
        vmean_part<<<B * H * 8, 256, 0, stream>>>(v_bf, vpart);
        vmean_reduce<<<4, 256, 0, stream>>>(vpart, vm);
        wo_base_kernel<<<B * 128, 256, 0, stream>>>(vm, (const unsigned short*)wob,
                                                    bo + l * D, baseb);
        attn_part<<<dim3(NS, H, B), 256, 0, stream>>>(q, kbf, v_bf, top, Opart, msumb);
        attn_reduce<<<B * H * U, 64, 0, stream>>>(Opart, msumb, updbuf);
        bcast_base<<<(B * LSEQ * D / 4 + 255) / 256, 256, 0, stream>>>(baseb, aout);
        wo_corr_kernel<<<B * H * U, 256, 0, stream>>>(updbuf, vm,
                                                      (const unsigned short*)wob, top, aout);
        add_ln_kernel<<<ML, 64, 0, stream>>>(h, aout, g1 + l * D, b1 + l * D, h_bf);

        gemm_mfma<1, 1><<<gF1, 256, 0, stream>>>((const unsigned short*)h_bf,
                                                 (const unsigned short*)w1b, bf1 + l * DFF,
                                                 y1_bf, ML, DFF, D);
        gemm_mfma<0, 0><<<gD, 256, 0, stream>>>((const unsigned short*)y1_bf,
                                                (const unsigned short*)w2b, bf2 + l * D, aout,
                                                ML, D, DFF);
        add_ln_kernel<<<ML, 64, 0, stream>>>(h, aout, g2 + l * D, b2 + l * D, h_bf);
    }

    final_kernel<<<B, 64, 0, stream>>>(h, Wf, bff, out);
}

// Round 10
// 702.130 us; speedup vs baseline: 4.7782x; 1.0539x over previous
//
#include <hip/hip_runtime.h>
#include <hip/hip_bf16.h>
#include <math.h>
#include <stdint.h>

#define B 2
#define S 4095
#define LSEQ 4096
#define F_IN 32
#define D 512
#define H 8
#define E 64
#define DFF 2048
#define NL 2
#define U 45
#define EPSL 1e-5f
#define LU (LSEQ * U)
#define HALF_LU (LU / 2)
#define NS 32
#define SLICE 128

typedef __attribute__((ext_vector_type(8))) short short8;
typedef __attribute__((ext_vector_type(4))) float f32x4;

#define GLD(gp, lp)                                                            \
    __builtin_amdgcn_global_load_lds(                                          \
        (const __attribute__((address_space(1))) void*)(gp),                   \
        (__attribute__((address_space(3))) void*)(lp), 16, 0, 0)

__device__ __forceinline__ unsigned short bf16_bits(float f) {
    __hip_bfloat16 h = __float2bfloat16(f);
    return *(unsigned short*)&h;
}
__device__ __forceinline__ float bits_to_f32(unsigned short s) {
    union { uint32_t u; float f; } c;
    c.u = ((uint32_t)s) << 16;
    return c.f;
}
// monotone sortable key: desc key order == (value desc, index asc) — JAX top_k ties
__device__ __forceinline__ unsigned long long mkey(float v, int index) {
    uint32_t u = __float_as_uint(v);
    uint32_t mono = (u & 0x80000000u) ? ~u : (u | 0x80000000u);
    return ((unsigned long long)mono << 32) | (uint32_t)(0xFFFFFFFFu - (uint32_t)index);
}

// ---------------- Threefry-2x32 (20 rounds), exactly JAX's algorithm ----------------
__device__ __forceinline__ uint32_t rotl32(uint32_t x, int r) {
    return (x << r) | (x >> (32 - r));
}

__device__ void threefry2x32(uint32_t k0, uint32_t k1, uint32_t c0, uint32_t c1,
                             uint32_t& o0, uint32_t& o1) {
    uint32_t ks2 = k0 ^ k1 ^ 0x1BD11BDAu;
    uint32_t x0 = c0 + k0, x1 = c1 + k1;
    x0 += x1; x1 = rotl32(x1, 13); x1 ^= x0;
    x0 += x1; x1 = rotl32(x1, 15); x1 ^= x0;
    x0 += x1; x1 = rotl32(x1, 26); x1 ^= x0;
    x0 += x1; x1 = rotl32(x1, 6);  x1 ^= x0;
    x0 += k1; x1 += ks2 + 1u;
    x0 += x1; x1 = rotl32(x1, 17); x1 ^= x0;
    x0 += x1; x1 = rotl32(x1, 29); x1 ^= x0;
    x0 += x1; x1 = rotl32(x1, 16); x1 ^= x0;
    x0 += x1; x1 = rotl32(x1, 24); x1 ^= x0;
    x0 += ks2; x1 += k0 + 2u;
    x0 += x1; x1 = rotl32(x1, 13); x1 ^= x0;
    x0 += x1; x1 = rotl32(x1, 15); x1 ^= x0;
    x0 += x1; x1 = rotl32(x1, 26); x1 ^= x0;
    x0 += x1; x1 = rotl32(x1, 6);  x1 ^= x0;
    x0 += k0; x1 += k1 + 3u;
    x0 += x1; x1 = rotl32(x1, 17); x1 ^= x0;
    x0 += x1; x1 = rotl32(x1, 29); x1 ^= x0;
    x0 += x1; x1 = rotl32(x1, 16); x1 ^= x0;
    x0 += x1; x1 = rotl32(x1, 24); x1 ^= x0;
    x0 += k1; x1 += ks2 + 4u;
    x0 += x1; x1 = rotl32(x1, 13); x1 ^= x0;
    x0 += x1; x1 = rotl32(x1, 15); x1 ^= x0;
    x0 += x1; x1 = rotl32(x1, 26); x1 ^= x0;
    x0 += x1; x1 = rotl32(x1, 6);  x1 ^= x0;
    x0 += ks2; x1 += k0 + 5u;
    o0 = x0; o1 = x1;
}

__global__ void idx_kernel(int* __restrict__ idx, int layer) {
    int j = blockIdx.x * blockDim.x + threadIdx.x;
    if (j >= HALF_LU) return;
    uint32_t f0, f1, a0, a1, b0, b1, o0, o1;
    threefry2x32(0u, 42u, 0u, (uint32_t)layer, f0, f1);
    threefry2x32(f0, f1, 0u, 2u, a0, a1);
    threefry2x32(f0, f1, 1u, 3u, b0, b1);
    threefry2x32(a1, b1, (uint32_t)j, (uint32_t)(j + HALF_LU), o0, o1);
    idx[j] = (int)(o0 & 4095u);
    idx[j + HALF_LU] = (int)(o1 & 4095u);
    (void)a0; (void)b0;
}

// ------- prep: xbf[8192x32] (row l=0 zero, else x[b,l-1,:]) + We_bf cast -----------
__global__ void prep_embed_kernel(const float* __restrict__ x, const float* __restrict__ We,
                                  __hip_bfloat16* __restrict__ xbf,
                                  __hip_bfloat16* __restrict__ webf) {
    int u = blockIdx.x * blockDim.x + threadIdx.x;  // 4-element units
    const int NX = B * LSEQ * F_IN / 4;             // 65536
    const int NW = D * F_IN / 4;                    // 4096
    if (u < NX) {
        int e0 = u * 4;
        int i = e0 & 31;
        int l = (e0 >> 5) & (LSEQ - 1);
        int b = e0 >> 17;
        union { unsigned short s[4]; uint2 w; } o;
        if (l == 0) {
            o.s[0] = o.s[1] = o.s[2] = o.s[3] = 0;
        } else {
            float4 v = *(const float4*)(x + ((size_t)b * S + (l - 1)) * F_IN + i);
            o.s[0] = bf16_bits(v.x); o.s[1] = bf16_bits(v.y);
            o.s[2] = bf16_bits(v.z); o.s[3] = bf16_bits(v.w);
        }
        ((uint2*)xbf)[u] = o.w;
    } else if (u < NX + NW) {
        int w = u - NX;
        float4 v = ((const float4*)We)[w];
        union { unsigned short s[4]; uint2 w2; } o;
        o.s[0] = bf16_bits(v.x); o.s[1] = bf16_bits(v.y);
        o.s[2] = bf16_bits(v.z); o.s[3] = bf16_bits(v.w);
        ((uint2*)webf)[w] = o.w2;
    }
}

// ------- posenc: h = (l==0 ? cls : emb) + PE; dual write f32 + bf16 ----------------
__global__ void posenc_kernel(const float* __restrict__ emb, const float* __restrict__ cls,
                              float* __restrict__ h, __hip_bfloat16* __restrict__ hbf) {
    int gid = blockIdx.x * blockDim.x + threadIdx.x;
    if (gid >= B * LSEQ * D) return;
    int d = gid % D;
    int l = (gid / D) % LSEQ;
    float v = (l == 0) ? cls[d] : emb[gid];
    int i = d >> 1;
    float divv = expf((float)(2 * i) * (float)(-9.210340371976184 / 512.0));
    float ang = (float)l * divv;
    v += (d & 1) ? cosf(ang) : sinf(ang);
    h[gid] = v;
    hbf[gid] = __float2bfloat16(v);
}

// ------- fused per-layer weight cast + packed qkv bias -----------------------------
__global__ void cast_weights_kernel(const float* __restrict__ Wq_l,
                                    const float* __restrict__ Wk_l,
                                    const float* __restrict__ Wv_l,
                                    const float* __restrict__ Wo_l,
                                    const float* __restrict__ W1_l,
                                    const float* __restrict__ W2_l,
                                    const float* __restrict__ bq_l,
                                    const float* __restrict__ bk_l,
                                    const float* __restrict__ bv_l,
                                    __hip_bfloat16* __restrict__ wqb,
                                    __hip_bfloat16* __restrict__ wkb,
                                    __hip_bfloat16* __restrict__ wvb,
                                    __hip_bfloat16* __restrict__ wob,
                                    __hip_bfloat16* __restrict__ w1b,
                                    __hip_bfloat16* __restrict__ w2b,
                                    float* __restrict__ qkvbias) {
    const int SDD = D * D / 4;       // 65536
    const int SFD = DFF * D / 4;     // 262144
    const int CAST_N = 4 * SDD + 2 * SFD;
    int u = blockIdx.x * blockDim.x + threadIdx.x;
    if (u >= CAST_N) {
        int j = u - CAST_N;          // 0..383, 4-float units over 1536 bias
        if (j < 384) {
            int seg = (j * 4) >> 9;  // 0:q 1:k 2:v
            int off = (j * 4) & 511;
            const float* src = (seg == 0) ? bq_l : (seg == 1) ? bk_l : bv_l;
            *(float4*)(qkvbias + j * 4) = *(const float4*)(src + off);
        }
        return;
    }
    const float* src;
    __hip_bfloat16* dst;
    int off;
    if (u < SDD) { src = Wq_l; dst = wqb; off = u; }
    else if (u < 2 * SDD) { src = Wk_l; dst = wkb; off = u - SDD; }
    else if (u < 3 * SDD) { src = Wv_l; dst = wvb; off = u - 2 * SDD; }
    else if (u < 4 * SDD) { src = Wo_l; dst = wob; off = u - 3 * SDD; }
    else if (u < 4 * SDD + SFD) { src = W1_l; dst = w1b; off = u - 4 * SDD; }
    else { src = W2_l; dst = w2b; off = u - 4 * SDD - SFD; }
    float4 v = ((const float4*)src)[off];
    union { unsigned short s[4]; uint2 w; } o;
    o.s[0] = bf16_bits(v.x); o.s[1] = bf16_bits(v.y);
    o.s[2] = bf16_bits(v.z); o.s[3] = bf16_bits(v.w);
    ((uint2*)dst)[off] = o.w;
}

// ------- bf16 MFMA GEMM, BK=32 (for K=32 embed) ------------------------------------
__global__ __launch_bounds__(256) void gemm32(const unsigned short* __restrict__ A,
                                              const unsigned short* __restrict__ W,
                                              const float* __restrict__ bias,
                                              float* __restrict__ Cf,
                                              int M, int N, int K) {
    __shared__ unsigned short lds[2 * 128 * 32];
    unsigned short* As = lds;
    unsigned short* Bs = lds + 128 * 32;
    const int tid = threadIdx.x;
    const int m0 = blockIdx.y * 128, n0 = blockIdx.x * 128;
    const int wave = tid >> 6, lane = tid & 63;
    const int wm = (wave >> 1) * 64, wn = (wave & 1) * 64;
    const int quad = lane >> 4, m15 = lane & 15;
    const int srow = tid >> 2, scol = (tid & 3) * 8;
    f32x4 acc[4][4] = {};
    const unsigned short* Ag0 = A + (size_t)(m0 + srow) * K + scol;
    const unsigned short* Ag1 = A + (size_t)(m0 + srow + 64) * K + scol;
    const unsigned short* Wg0 = W + (size_t)(n0 + srow) * K + scol;
    const unsigned short* Wg1 = W + (size_t)(n0 + srow + 64) * K + scol;
    for (int k0 = 0; k0 < K; k0 += 32) {
        __syncthreads();
        GLD(Ag0 + k0, As + tid * 8);
        GLD(Ag1 + k0, As + 2048 + tid * 8);
        GLD(Wg0 + k0, Bs + tid * 8);
        GLD(Wg1 + k0, Bs + 2048 + tid * 8);
        __syncthreads();
        short8 af[4], bfr[4];
#pragma unroll
        for (int mi = 0; mi < 4; ++mi)
            af[mi] = *(const short8*)(As + (wm + mi * 16 + m15) * 32 + quad * 8);
#pragma unroll
        for (int ni = 0; ni < 4; ++ni)
            bfr[ni] = *(const short8*)(Bs + (wn + ni * 16 + m15) * 32 + quad * 8);
#pragma unroll
        for (int mi = 0; mi < 4; ++mi)
#pragma unroll
            for (int ni = 0; ni < 4; ++ni)
                acc[mi][ni] = __builtin_amdgcn_mfma_f32_16x16x32_bf16(
                    af[mi], bfr[ni], acc[mi][ni], 0, 0, 0);
    }
#pragma unroll
    for (int mi = 0; mi < 4; ++mi) {
        int mg = m0 + wm + mi * 16 + quad * 4;
#pragma unroll
        for (int ni = 0; ni < 4; ++ni) {
            int ng = n0 + wn + ni * 16 + m15;
            float bv = bias[ng];
#pragma unroll
            for (int r = 0; r < 4; ++r)
                Cf[(size_t)(mg + r) * N + ng] = acc[mi][ni][r] + bv;
        }
    }
}

// ------- bf16 MFMA GEMM, BK=64 (two 128x32 sub-buffers per operand) ----------------
// MODE 0: f32 out; 1: bf16 out; 2: relu->bf16; 3: QKV-mixed (seg0 f32 q, seg1/2 bf16)
template <int MODE>
__global__ __launch_bounds__(256) void gemm64(const unsigned short* __restrict__ A,
                                              const unsigned short* __restrict__ W,
                                              const float* __restrict__ bias,
                                              void* __restrict__ C0,
                                              void* __restrict__ C1,
                                              void* __restrict__ C2,
                                              int M, int N, int K) {
    __shared__ unsigned short As[2][128 * 32];
    __shared__ unsigned short Bs[2][128 * 32];
    const int tid = threadIdx.x;
    const int m0 = blockIdx.y * 128, n0 = blockIdx.x * 128;
    const int wave = tid >> 6, lane = tid & 63;
    const int wm = (wave >> 1) * 64, wn = (wave & 1) * 64;
    const int quad = lane >> 4, m15 = lane & 15;
    const int srow = tid >> 2, scol = (tid & 3) * 8;
    f32x4 acc[4][4] = {};
    const unsigned short* Ag0 = A + (size_t)(m0 + srow) * K + scol;
    const unsigned short* Ag1 = A + (size_t)(m0 + srow + 64) * K + scol;
    const unsigned short* Wg0 = W + (size_t)(n0 + srow) * K + scol;
    const unsigned short* Wg1 = W + (size_t)(n0 + srow + 64) * K + scol;
    for (int k0 = 0; k0 < K; k0 += 64) {
        __syncthreads();
        GLD(Ag0 + k0, As[0] + tid * 8);
        GLD(Ag1 + k0, As[0] + 2048 + tid * 8);
        GLD(Ag0 + k0 + 32, As[1] + tid * 8);
        GLD(Ag1 + k0 + 32, As[1] + 2048 + tid * 8);
        GLD(Wg0 + k0, Bs[0] + tid * 8);
        GLD(Wg1 + k0, Bs[0] + 2048 + tid * 8);
        GLD(Wg0 + k0 + 32, Bs[1] + tid * 8);
        GLD(Wg1 + k0 + 32, Bs[1] + 2048 + tid * 8);
        __syncthreads();
#pragma unroll
        for (int ks = 0; ks < 2; ++ks) {
            short8 af[4], bfr[4];
#pragma unroll
            for (int mi = 0; mi < 4; ++mi)
                af[mi] = *(const short8*)(As[ks] + (wm + mi * 16 + m15) * 32 + quad * 8);
#pragma unroll
            for (int ni = 0; ni < 4; ++ni)
                bfr[ni] = *(const short8*)(Bs[ks] + (wn + ni * 16 + m15) * 32 + quad * 8);
#pragma unroll
            for (int mi = 0; mi < 4; ++mi)
#pragma unroll
                for (int ni = 0; ni < 4; ++ni)
                    acc[mi][ni] = __builtin_amdgcn_mfma_f32_16x16x32_bf16(
                        af[mi], bfr[ni], acc[mi][ni], 0, 0, 0);
        }
    }
#pragma unroll
    for (int mi = 0; mi < 4; ++mi) {
        int mg = m0 + wm + mi * 16 + quad * 4;
#pragma unroll
        for (int ni = 0; ni < 4; ++ni) {
            int ng = n0 + wn + ni * 16 + m15;
            float bv = bias[ng];
#pragma unroll
            for (int r = 0; r < 4; ++r) {
                float v = acc[mi][ni][r] + bv;
                if (MODE == 0) {
                    ((float*)C0)[(size_t)(mg + r) * N + ng] = v;
                } else if (MODE == 1) {
                    ((__hip_bfloat16*)C0)[(size_t)(mg + r) * N + ng] = __float2bfloat16(v);
                } else if (MODE == 2) {
                    ((__hip_bfloat16*)C0)[(size_t)(mg + r) * N + ng] =
                        __float2bfloat16(fmaxf(v, 0.f));
                } else {  // QKV mixed: N=1536, segments of 512
                    int seg = ng >> 9;
                    int col = ng & 511;
                    if (seg == 0)
                        ((float*)C0)[(size_t)(mg + r) * D + col] = v;
                    else if (seg == 1)
                        ((__hip_bfloat16*)C1)[(size_t)(mg + r) * D + col] = __float2bfloat16(v);
                    else
                        ((__hip_bfloat16*)C2)[(size_t)(mg + r) * D + col] = __float2bfloat16(v);
                }
            }
        }
    }
}

// -------- M-score: block per (b,l); one WAVE per sampled row -----------------------
__global__ __launch_bounds__(256) void mscore_kernel(const float* __restrict__ q,
                                                     const __hip_bfloat16* __restrict__ kbf,
                                                     const int* __restrict__ idx,
                                                     float* __restrict__ Mv) {
    __shared__ float Sbuf[U][8];
    __shared__ int sidx[U];
    int bid = blockIdx.x;
    int b = bid & 1;
    int l = bid >> 1;
    int tid = threadIdx.x;
    int wave = tid >> 6, lane = tid & 63;
    if (tid < U) sidx[tid] = idx[l * U + tid];
    const float* qr = q + ((size_t)(b * LSEQ) + l) * D + lane * 8;
    float4 qa = *(const float4*)qr;
    float4 qb = *(const float4*)(qr + 4);
    __syncthreads();
    const unsigned short* kbase = (const unsigned short*)(kbf + (size_t)(b * LSEQ) * D);
    for (int t = wave; t < U; t += 4) {
        int kr = sidx[t];
        union { uint4 u; unsigned short s[8]; } kv;
        kv.u = *(const uint4*)(kbase + (size_t)kr * D + lane * 8);
        float p = qa.x * bits_to_f32(kv.s[0]) + qa.y * bits_to_f32(kv.s[1]) +
                  qa.z * bits_to_f32(kv.s[2]) + qa.w * bits_to_f32(kv.s[3]) +
                  qb.x * bits_to_f32(kv.s[4]) + qb.y * bits_to_f32(kv.s[5]) +
                  qb.z * bits_to_f32(kv.s[6]) + qb.w * bits_to_f32(kv.s[7]);
        p += __shfl_xor(p, 1);
        p += __shfl_xor(p, 2);
        p += __shfl_xor(p, 4);
        if ((lane & 7) == 0) Sbuf[t][lane >> 3] = p;
    }
    __syncthreads();
    if (tid < 8) {
        float mx = -INFINITY, sm = 0.f;
        for (int t = 0; t < U; ++t) {
            float v = Sbuf[t][tid];
            mx = fmaxf(mx, v);
            sm += v;
        }
        Mv[((size_t)b * H + tid) * LSEQ + l] = mx - sm / (float)LSEQ;
    }
}

// ------- top-k phase A: bitonic sort each 256-chunk desc, emit top-45 keys ---------
__global__ __launch_bounds__(256) void topk_chunk_kernel(const float* __restrict__ Mv,
                                                         unsigned long long* __restrict__ cand) {
    __shared__ unsigned long long sk[256];
    int blk = blockIdx.x;  // B*H*16
    int chunk = blk & 15, bh = blk >> 4;
    int tid = threadIdx.x;
    int gi = chunk * 256 + tid;
    sk[tid] = mkey(Mv[(size_t)bh * LSEQ + gi], gi);
    __syncthreads();
    for (int k = 2; k <= 256; k <<= 1) {
        for (int j = k >> 1; j > 0; j >>= 1) {
            int ixj = tid ^ j;
            if (ixj > tid) {
                unsigned long long a = sk[tid], b = sk[ixj];
                bool desc = ((tid & k) == 0);
                if (desc ? (a < b) : (a > b)) { sk[tid] = b; sk[ixj] = a; }
            }
            __syncthreads();
        }
    }
    if (tid < U) cand[((size_t)bh * 16 + chunk) * U + tid] = sk[tid];
}

// ------- top-k phase B: merge 16x45 candidates via 1024-wide bitonic sort ----------
__global__ __launch_bounds__(256) void topk_merge_kernel(const unsigned long long* __restrict__ cand,
                                                         int* __restrict__ top) {
    __shared__ unsigned long long sk[1024];
    int bh = blockIdx.x;
    int tid = threadIdx.x;
    for (int e = tid; e < 1024; e += 256)
        sk[e] = (e < 16 * U) ? cand[(size_t)bh * 16 * U + e] : 0ull;
    __syncthreads();
    for (int k = 2; k <= 1024; k <<= 1) {
        for (int j = k >> 1; j > 0; j >>= 1) {
            for (int e = tid; e < 1024; e += 256) {
                int ixj = e ^ j;
                if (ixj > e) {
                    unsigned long long a = sk[e], b = sk[ixj];
                    bool desc = ((e & k) == 0);
                    if (desc ? (a < b) : (a > b)) { sk[e] = b; sk[ixj] = a; }
                }
            }
            __syncthreads();
        }
    }
    if (tid < U)
        top[bh * U + tid] = (int)(0xFFFFFFFFu - (uint32_t)(sk[tid] & 0xFFFFFFFFu));
}

// ---------------- v mean: partial (128 blocks) + reduce ----------------
__global__ __launch_bounds__(256) void vmean_part(const __hip_bfloat16* __restrict__ v,
                                                  float* __restrict__ part) {
    int blk = blockIdx.x;  // B*H*8
    int seg = blk & 7, hh = (blk >> 3) & 7, b = blk >> 6;
    int e = threadIdx.x & 63, rg = threadIdx.x >> 6;
    const __hip_bfloat16* vp =
        v + ((size_t)(b * LSEQ) + seg * 512) * D + hh * 64 + e;
    float acc = 0.f;
    for (int r = rg; r < 512; r += 4) acc += __bfloat162float(vp[(size_t)r * D]);
    __shared__ float red[4][64];
    red[rg][e] = acc;
    __syncthreads();
    if (threadIdx.x < 64)
        part[(size_t)blk * 64 + threadIdx.x] =
            red[0][threadIdx.x] + red[1][threadIdx.x] + red[2][threadIdx.x] + red[3][threadIdx.x];
}

__global__ void vmean_reduce(const float* __restrict__ part, float* __restrict__ vm) {
    int gid = blockIdx.x * blockDim.x + threadIdx.x;
    if (gid >= B * H * E) return;
    int e = gid & 63, bh = gid >> 6;
    float acc = 0.f;
#pragma unroll
    for (int s = 0; s < 8; ++s) acc += part[((size_t)bh * 8 + s) * 64 + e];
    vm[gid] = acc / (float)LSEQ;
}

// ------- base[b] = vmeanAll[b] . Wo^T + bo (one wave per output n) -----------------
__global__ __launch_bounds__(256) void wo_base_kernel(const float* __restrict__ vm,
                                                      const unsigned short* __restrict__ wob,
                                                      const float* __restrict__ bo,
                                                      float* __restrict__ base) {
    int b = blockIdx.x >> 7;            // grid B*128
    int n = (blockIdx.x & 127) * 4 + (threadIdx.x >> 6);
    int lane = threadIdx.x & 63;
    const float* vmr = vm + (size_t)b * D + lane * 8;
    float4 va = *(const float4*)vmr;
    float4 vb = *(const float4*)(vmr + 4);
    union { uint4 u; unsigned short s[8]; } w;
    w.u = *(const uint4*)(wob + (size_t)n * D + lane * 8);
    float p = va.x * bits_to_f32(w.s[0]) + va.y * bits_to_f32(w.s[1]) +
              va.z * bits_to_f32(w.s[2]) + va.w * bits_to_f32(w.s[3]) +
              vb.x * bits_to_f32(w.s[4]) + vb.y * bits_to_f32(w.s[5]) +
              vb.z * bits_to_f32(w.s[6]) + vb.w * bits_to_f32(w.s[7]);
    for (int off = 32; off; off >>= 1) p += __shfl_xor(p, off);
    if (lane == 0) base[(size_t)b * D + n] = p + bo[n];
}

// ------- aout[r] = base[b] broadcast (float4) --------------------------------------
__global__ void bcast_base(const float* __restrict__ base, float* __restrict__ aout) {
    int i = blockIdx.x * blockDim.x + threadIdx.x;  // over ML*D/4
    if (i >= B * LSEQ * D / 4) return;
    int b = i >> 19;          // LSEQ*D/4 = 2^19
    int c4 = i & 127;         // D/4 = 128
    ((float4*)aout)[i] = *(const float4*)(base + (size_t)b * D + c4 * 4);
}

// ------- scatter correction: aout[top[bh,t]] += (upd - vmean_h) . Wo_h^T -----------
__global__ __launch_bounds__(256) void wo_corr_kernel(const float* __restrict__ updbuf,
                                                      const float* __restrict__ vm,
                                                      const unsigned short* __restrict__ wob,
                                                      const int* __restrict__ top,
                                                      float* __restrict__ aout) {
    __shared__ float dlt[E];
    int bid = blockIdx.x;  // B*H*U
    int t = bid % U;
    int bh = bid / U;
    int b = bh >> 3, hh = bh & 7;
    int tid = threadIdx.x;
    if (tid < E) dlt[tid] = updbuf[((size_t)bh * U + t) * E + tid] - vm[(size_t)bh * E + tid];
    __syncthreads();
    int r = top[bh * U + t];
    float* arow = aout + (size_t)(b * LSEQ + r) * D;
    for (int n = tid; n < D; n += 256) {
        const unsigned short* wr = wob + (size_t)n * D + hh * E;
        float acc = 0.f;
#pragma unroll
        for (int k2 = 0; k2 < E; ++k2) acc += dlt[k2] * bits_to_f32(wr[k2]);
        atomicAdd(arow + n, acc);
    }
}

// -------- flash-style MFMA attention partial: block = (slice, h, b) ----------------
__global__ __launch_bounds__(256) void attn_part(const float* __restrict__ q,
                                                 const __hip_bfloat16* __restrict__ kbf,
                                                 const __hip_bfloat16* __restrict__ vbf,
                                                 const int* __restrict__ top,
                                                 float* __restrict__ Opart,
                                                 float* __restrict__ msum) {
    __shared__ unsigned short Qs[48 * 72];
    __shared__ unsigned short Ks[SLICE * 72];
    __shared__ unsigned short Vs[SLICE * 68];
    __shared__ unsigned short Ps[48 * 136];
    __shared__ float mred[48][4];
    __shared__ float sred[48][4];
    const int slice = blockIdx.x, hh = blockIdx.y, b = blockIdx.z;
    const int bh = b * H + hh;
    const int tid = threadIdx.x;
    const int s0 = slice * SLICE;
    for (int i = tid; i < 48 * 64; i += 256) {
        int t = i >> 6, e = i & 63;
        float v = 0.f;
        if (t < U) {
            int r = top[bh * U + t];
            v = q[((size_t)(b * LSEQ) + r) * D + hh * E + e];
        }
        Qs[t * 72 + e] = bf16_bits(v);
    }
    {
        const uint4* src = (const uint4*)(kbf + ((size_t)(b * LSEQ) + s0) * D + hh * E);
        for (int i = tid; i < SLICE * 8; i += 256) {
            int r = i >> 3, c = i & 7;
            uint4 d = src[(size_t)r * 64 + c];
            *(uint4*)(Ks + r * 72 + c * 8) = d;
        }
    }
    {
        const uint2* src = (const uint2*)(vbf + ((size_t)(b * LSEQ) + s0) * D + hh * E);
        for (int i = tid; i < SLICE * 16; i += 256) {
            int r = i >> 4, c = i & 15;
            uint2 d = src[(size_t)r * 128 + c];
            *(uint2*)(Vs + r * 68 + c * 4) = d;
        }
    }
    __syncthreads();
    const int wave = tid >> 6, lane = tid & 63;
    const int quad = lane >> 4, m15 = lane & 15;
    const int wc = wave * 32;
    f32x4 acc[3][2] = {};
#pragma unroll
    for (int ks = 0; ks < 2; ++ks) {
        short8 af[3], bfr[2];
#pragma unroll
        for (int mt = 0; mt < 3; ++mt)
            af[mt] = *(const short8*)(Qs + (mt * 16 + m15) * 72 + ks * 32 + quad * 8);
#pragma unroll
        for (int nt = 0; nt < 2; ++nt)
            bfr[nt] = *(const short8*)(Ks + (wc + nt * 16 + m15) * 72 + ks * 32 + quad * 8);
#pragma unroll
        for (int mt = 0; mt < 3; ++mt)
#pragma unroll
            for (int nt = 0; nt < 2; ++nt)
                acc[mt][nt] = __builtin_amdgcn_mfma_f32_16x16x32_bf16(
                    af[mt], bfr[nt], acc[mt][nt], 0, 0, 0);
    }
    float sc[3][2][4];
#pragma unroll
    for (int mt = 0; mt < 3; ++mt)
#pragma unroll
        for (int nt = 0; nt < 2; ++nt)
#pragma unroll
            for (int r = 0; r < 4; ++r) sc[mt][nt][r] = acc[mt][nt][r] * 0.125f;
#pragma unroll
    for (int mt = 0; mt < 3; ++mt)
#pragma unroll
        for (int r = 0; r < 4; ++r) {
            float mv = fmaxf(sc[mt][0][r], sc[mt][1][r]);
            mv = fmaxf(mv, __shfl_xor(mv, 1));
            mv = fmaxf(mv, __shfl_xor(mv, 2));
            mv = fmaxf(mv, __shfl_xor(mv, 4));
            mv = fmaxf(mv, __shfl_xor(mv, 8));
            if (m15 == 0) mred[mt * 16 + quad * 4 + r][wave] = mv;
        }
    __syncthreads();
#pragma unroll
    for (int mt = 0; mt < 3; ++mt)
#pragma unroll
        for (int r = 0; r < 4; ++r) {
            int row = mt * 16 + quad * 4 + r;
            float ms = fmaxf(fmaxf(mred[row][0], mred[row][1]),
                             fmaxf(mred[row][2], mred[row][3]));
            float p0 = __expf(sc[mt][0][r] - ms);
            float p1 = __expf(sc[mt][1][r] - ms);
            float sv = p0 + p1;
            sv += __shfl_xor(sv, 1);
            sv += __shfl_xor(sv, 2);
            sv += __shfl_xor(sv, 4);
            sv += __shfl_xor(sv, 8);
            if (m15 == 0) sred[row][wave] = sv;
            Ps[row * 136 + wc + m15] = bf16_bits(p0);
            Ps[row * 136 + wc + 16 + m15] = bf16_bits(p1);
        }
    __syncthreads();
    if (tid < U) {
        float mm = fmaxf(fmaxf(mred[tid][0], mred[tid][1]),
                         fmaxf(mred[tid][2], mred[tid][3]));
        float ss = sred[tid][0] + sred[tid][1] + sred[tid][2] + sred[tid][3];
        size_t base = (((size_t)bh * NS + slice) * U + tid) * 2;
        msum[base] = mm;
        msum[base + 1] = ss;
    }
    f32x4 apv[3] = {};
#pragma unroll
    for (int ks = 0; ks < 4; ++ks) {
        short8 bv;
#pragma unroll
        for (int j = 0; j < 8; ++j)
            bv[j] = (short)Vs[(ks * 32 + quad * 8 + j) * 68 + wave * 16 + m15];
        short8 af2[3];
#pragma unroll
        for (int mt = 0; mt < 3; ++mt)
            af2[mt] = *(const short8*)(Ps + (mt * 16 + m15) * 136 + ks * 32 + quad * 8);
#pragma unroll
        for (int mt = 0; mt < 3; ++mt)
            apv[mt] = __builtin_amdgcn_mfma_f32_16x16x32_bf16(af2[mt], bv, apv[mt], 0, 0, 0);
    }
    size_t obase = ((size_t)bh * NS + slice) * U;
#pragma unroll
    for (int mt = 0; mt < 3; ++mt)
#pragma unroll
        for (int r = 0; r < 4; ++r) {
            int row = mt * 16 + quad * 4 + r;
            if (row < U)
                Opart[(obase + row) * 64 + wave * 16 + m15] = apv[mt][r];
        }
}

// -------- combine slice partials -> dense upd buffer (f32) -------------------------
__global__ __launch_bounds__(64) void attn_reduce(const float* __restrict__ Opart,
                                                  const float* __restrict__ msum,
                                                  float* __restrict__ updbuf) {
    int t = blockIdx.x % U;
    int bh = blockIdx.x / U;
    int lane = threadIdx.x;
    float m_s = -INFINITY, ss = 0.f;
    if (lane < NS) {
        size_t base = (((size_t)bh * NS + lane) * U + t) * 2;
        m_s = msum[base];
        ss = msum[base + 1];
    }
    float M = m_s;
    for (int off = 32; off; off >>= 1) M = fmaxf(M, __shfl_xor(M, off));
    float e_s = (lane < NS) ? __expf(m_s - M) : 0.f;
    float d = ss * e_s;
    for (int off = 32; off; off >>= 1) d += __shfl_xor(d, off);
    float acc = 0.f;
    for (int s = 0; s < NS; ++s) {
        float w = __shfl(e_s, s);
        acc += w * Opart[(((size_t)bh * NS + s) * U + t) * 64 + lane];
    }
    updbuf[((size_t)bh * U + t) * E + lane] = acc / d;
}

// -------- h = LayerNorm(h + a) * g + b, one wave per row, dual write f32+bf16 -------
__global__ __launch_bounds__(64) void add_ln_kernel(float* __restrict__ h,
                                                    const float* __restrict__ a,
                                                    const float* __restrict__ g,
                                                    const float* __restrict__ bb,
                                                    __hip_bfloat16* __restrict__ hbf) {
    int row = blockIdx.x;
    int lane = threadIdx.x;
    float* hp = h + (size_t)row * D;
    const float* ap = a + (size_t)row * D;
    float x[8];
    float sum = 0.f;
#pragma unroll
    for (int j = 0; j < 8; ++j) {
        x[j] = hp[lane + 64 * j] + ap[lane + 64 * j];
        sum += x[j];
    }
    for (int off = 32; off; off >>= 1) sum += __shfl_xor(sum, off);
    float mu = sum / (float)D;
    float vs = 0.f;
#pragma unroll
    for (int j = 0; j < 8; ++j) {
        float dd = x[j] - mu;
        vs += dd * dd;
    }
    for (int off = 32; off; off >>= 1) vs += __shfl_xor(vs, off);
    float inv = 1.f / sqrtf(vs / (float)D + EPSL);
#pragma unroll
    for (int j = 0; j < 8; ++j) {
        float o = (x[j] - mu) * inv * g[lane + 64 * j] + bb[lane + 64 * j];
        hp[lane + 64 * j] = o;
        hbf[(size_t)row * D + lane + 64 * j] = __float2bfloat16(o);
    }
}

// ---------------- final head ----------------
__global__ void final_kernel(const float* __restrict__ h, const float* __restrict__ Wf,
                             const float* __restrict__ bf, float* __restrict__ out) {
    int b = blockIdx.x;
    int lane = threadIdx.x;
    const float* hp = h + (size_t)b * LSEQ * D;
    float acc = 0.f;
    for (int j = lane; j < D; j += 64) acc += hp[j] * Wf[j];
    for (int off = 32; off; off >>= 1) acc += __shfl_xor(acc, off);
    if (lane == 0) out[b] = acc + bf[0];
}

extern "C" void kernel_launch(void* const* d_in, const int* in_sizes, int n_in,
                              void* d_out, int out_size, void* d_ws, size_t ws_size,
                              hipStream_t stream) {
    (void)in_sizes; (void)n_in; (void)out_size; (void)ws_size;
    const float* x   = (const float*)d_in[0];
    const float* We  = (const float*)d_in[1];
    const float* be  = (const float*)d_in[2];
    const float* cls = (const float*)d_in[3];
    const float* Wq  = (const float*)d_in[4];
    const float* bq  = (const float*)d_in[5];
    const float* Wk  = (const float*)d_in[6];
    const float* bk  = (const float*)d_in[7];
    const float* Wv  = (const float*)d_in[8];
    const float* bv  = (const float*)d_in[9];
    const float* Wo  = (const float*)d_in[10];
    const float* bo  = (const float*)d_in[11];
    const float* g1  = (const float*)d_in[12];
    const float* b1  = (const float*)d_in[13];
    const float* g2  = (const float*)d_in[14];
    const float* b2  = (const float*)d_in[15];
    const float* W1  = (const float*)d_in[16];
    const float* bf1 = (const float*)d_in[17];
    const float* W2  = (const float*)d_in[18];
    const float* bf2 = (const float*)d_in[19];
    const float* Wf  = (const float*)d_in[20];
    const float* bff = (const float*)d_in[21];
    float* out = (float*)d_out;

    float* ws = (float*)d_ws;
    const size_t NT = (size_t)B * LSEQ * D;  // 4,194,304
    float* h    = ws;                         // [0, NT)
    float* aout = ws + NT;                    // [NT, 2NT)
    float* q    = ws + 2 * NT;                // [2NT, 3NT)
    __hip_bfloat16* kbf    = (__hip_bfloat16*)(ws + NT);      // overlays aout
    __hip_bfloat16* y1_bf  = (__hip_bfloat16*)(ws + 2 * NT);  // overlays q post-attn
    __hip_bfloat16* v_bf   = (__hip_bfloat16*)(ws + 4 * NT);
    __hip_bfloat16* h_bf   = (__hip_bfloat16*)(ws + 5 * NT);
    float* Opart = ws + 3 * NT;
    float* msumb = Opart + (size_t)B * H * NS * U * 64;
    float* wpool = ws + 5 * NT + NT / 2;
    __hip_bfloat16* wqb = (__hip_bfloat16*)wpool;   // wq|wk|wv contiguous = packed QKV
    __hip_bfloat16* wkb = wqb + (size_t)D * D;
    __hip_bfloat16* wvb = wkb + (size_t)D * D;
    __hip_bfloat16* wob = wvb + (size_t)D * D;
    __hip_bfloat16* w1b = wob + (size_t)D * D;
    __hip_bfloat16* w2b = w1b + (size_t)DFF * D;
    float* after_w = wpool + ((size_t)4 * D * D + 2 * (size_t)DFF * D) / 2;
    float* Mbuf = after_w;
    int* idx    = (int*)(Mbuf + (size_t)B * H * LSEQ);
    int* top    = idx + LU;
    float* vm   = (float*)(top + B * H * U);
    float* vpart  = vm + (size_t)B * H * E;
    float* updbuf = vpart + (size_t)128 * 64;
    float* baseb  = updbuf + (size_t)B * H * U * 64;
    __hip_bfloat16* xbf  = (__hip_bfloat16*)(baseb + (size_t)B * D);   // B*LSEQ*F_IN
    __hip_bfloat16* webf = xbf + (size_t)B * LSEQ * F_IN;              // D*F_IN
    unsigned long long* cand =
        (unsigned long long*)(((uintptr_t)(webf + (size_t)D * F_IN) + 7) & ~(uintptr_t)7);
    float* qkvbias = (float*)(cand + (size_t)B * H * 16 * U);          // 1536 floats

    const int ML = B * LSEQ;  // 8192
    dim3 gD(D / 128, ML / 128);
    dim3 gQKV(3 * D / 128, ML / 128);   // 12 x 64 = 768 blocks
    dim3 gF1(DFF / 128, ML / 128);
    const int CAST_N = 4 * (D * D / 4) + 2 * (DFF * D / 4);  // 786432
    const int CAST_TOT = CAST_N + 384;                       // + packed qkv bias

    // ---- embed as MFMA GEMM + posenc ----
    prep_embed_kernel<<<(B * LSEQ * F_IN / 4 + D * F_IN / 4 + 255) / 256, 256, 0, stream>>>(
        x, We, xbf, webf);
    gemm32<<<gD, 256, 0, stream>>>((const unsigned short*)xbf,
                                   (const unsigned short*)webf, be, aout, ML, D, F_IN);
    posenc_kernel<<<(B * LSEQ * D + 255) / 256, 256, 0, stream>>>(aout, cls, h, h_bf);

    for (int l = 0; l < NL; ++l) {
        cast_weights_kernel<<<(CAST_TOT + 255) / 256, 256, 0, stream>>>(
            Wq + (size_t)l * D * D, Wk + (size_t)l * D * D, Wv + (size_t)l * D * D,
            Wo + (size_t)l * D * D, W1 + (size_t)l * DFF * D, W2 + (size_t)l * D * DFF,
            bq + l * D, bk + l * D, bv + l * D,
            wqb, wkb, wvb, wob, w1b, w2b, qkvbias);

        // fused QKV GEMM: N=1536, 768 blocks (3/CU)
        gemm64<3><<<gQKV, 256, 0, stream>>>((const unsigned short*)h_bf,
                                            (const unsigned short*)wqb, qkvbias,
                                            q, kbf, v_bf, ML, 3 * D, D);

        idx_kernel<<<(HALF_LU + 255) / 256, 256, 0, stream>>>(idx, l);
        mscore_kernel<<<B * LSEQ, 256, 0, stream>>>(q, kbf, idx, Mbuf);
        topk_chunk_kernel<<<B * H * 16, 256, 0, stream>>>(Mbuf, cand);
        topk_merge_kernel<<<B * H, 256, 0, stream>>>(cand, top);
        vmean_part<<<B * H * 8, 256, 0, stream>>>(v_bf, vpart);
        vmean_reduce<<<4, 256, 0, stream>>>(vpart, vm);
        wo_base_kernel<<<B * 128, 256, 0, stream>>>(vm, (const unsigned short*)wob,
                                                    bo + l * D, baseb);
        attn_part<<<dim3(NS, H, B), 256, 0, stream>>>(q, kbf, v_bf, top, Opart, msumb);
        attn_reduce<<<B * H * U, 64, 0, stream>>>(Opart, msumb, updbuf);
        bcast_base<<<(B * LSEQ * D / 4 + 255) / 256, 256, 0, stream>>>(baseb, aout);
        wo_corr_kernel<<<B * H * U, 256, 0, stream>>>(updbuf, vm,
                                                      (const unsigned short*)wob, top, aout);
        add_ln_kernel<<<ML, 64, 0, stream>>>(h, aout, g1 + l * D, b1 + l * D, h_bf);

        gemm64<2><<<gF1, 256, 0, stream>>>((const unsigned short*)h_bf,
                                           (const unsigned short*)w1b, bf1 + l * DFF,
                                           y1_bf, nullptr, nullptr, ML, DFF, D);
        gemm64<0><<<gD, 256, 0, stream>>>((const unsigned short*)y1_bf,
                                          (const unsigned short*)w2b, bf2 + l * D,
                                          aout, nullptr, nullptr, ML, D, DFF);
        add_ln_kernel<<<ML, 64, 0, stream>>>(h, aout, g2 + l * D, b2 + l * D, h_bf);
    }

    final_kernel<<<B, 64, 0, stream>>>(h, Wf, bff, out);
}

// Round 11
// 696.098 us; speedup vs baseline: 4.8196x; 1.0087x over previous
//
#include <hip/hip_runtime.h>
#include <hip/hip_bf16.h>
#include <math.h>
#include <stdint.h>

#define B 2
#define S 4095
#define LSEQ 4096
#define F_IN 32
#define D 512
#define H 8
#define E 64
#define DFF 2048
#define NL 2
#define U 45
#define EPSL 1e-5f
#define LU (LSEQ * U)
#define HALF_LU (LU / 2)
#define NS 32
#define SLICE 128

typedef __attribute__((ext_vector_type(8))) short short8;
typedef __attribute__((ext_vector_type(4))) float f32x4;

#define GLD(gp, lp)                                                            \
    __builtin_amdgcn_global_load_lds(                                          \
        (const __attribute__((address_space(1))) void*)(gp),                   \
        (__attribute__((address_space(3))) void*)(lp), 16, 0, 0)

__device__ __forceinline__ unsigned short bf16_bits(float f) {
    __hip_bfloat16 h = __float2bfloat16(f);
    return *(unsigned short*)&h;
}
__device__ __forceinline__ float bits_to_f32(unsigned short s) {
    union { uint32_t u; float f; } c;
    c.u = ((uint32_t)s) << 16;
    return c.f;
}
// monotone sortable key: desc key order == (value desc, index asc) — JAX top_k ties
__device__ __forceinline__ unsigned long long mkey(float v, int index) {
    uint32_t u = __float_as_uint(v);
    uint32_t mono = (u & 0x80000000u) ? ~u : (u | 0x80000000u);
    return ((unsigned long long)mono << 32) | (uint32_t)(0xFFFFFFFFu - (uint32_t)index);
}

// ---------------- Threefry-2x32 (20 rounds), exactly JAX's algorithm ----------------
__device__ __forceinline__ uint32_t rotl32(uint32_t x, int r) {
    return (x << r) | (x >> (32 - r));
}

__device__ void threefry2x32(uint32_t k0, uint32_t k1, uint32_t c0, uint32_t c1,
                             uint32_t& o0, uint32_t& o1) {
    uint32_t ks2 = k0 ^ k1 ^ 0x1BD11BDAu;
    uint32_t x0 = c0 + k0, x1 = c1 + k1;
    x0 += x1; x1 = rotl32(x1, 13); x1 ^= x0;
    x0 += x1; x1 = rotl32(x1, 15); x1 ^= x0;
    x0 += x1; x1 = rotl32(x1, 26); x1 ^= x0;
    x0 += x1; x1 = rotl32(x1, 6);  x1 ^= x0;
    x0 += k1; x1 += ks2 + 1u;
    x0 += x1; x1 = rotl32(x1, 17); x1 ^= x0;
    x0 += x1; x1 = rotl32(x1, 29); x1 ^= x0;
    x0 += x1; x1 = rotl32(x1, 16); x1 ^= x0;
    x0 += x1; x1 = rotl32(x1, 24); x1 ^= x0;
    x0 += ks2; x1 += k0 + 2u;
    x0 += x1; x1 = rotl32(x1, 13); x1 ^= x0;
    x0 += x1; x1 = rotl32(x1, 15); x1 ^= x0;
    x0 += x1; x1 = rotl32(x1, 26); x1 ^= x0;
    x0 += x1; x1 = rotl32(x1, 6);  x1 ^= x0;
    x0 += k0; x1 += k1 + 3u;
    x0 += x1; x1 = rotl32(x1, 17); x1 ^= x0;
    x0 += x1; x1 = rotl32(x1, 29); x1 ^= x0;
    x0 += x1; x1 = rotl32(x1, 16); x1 ^= x0;
    x0 += x1; x1 = rotl32(x1, 24); x1 ^= x0;
    x0 += k1; x1 += ks2 + 4u;
    x0 += x1; x1 = rotl32(x1, 13); x1 ^= x0;
    x0 += x1; x1 = rotl32(x1, 15); x1 ^= x0;
    x0 += x1; x1 = rotl32(x1, 26); x1 ^= x0;
    x0 += x1; x1 = rotl32(x1, 6);  x1 ^= x0;
    x0 += ks2; x1 += k0 + 5u;
    o0 = x0; o1 = x1;
}

__global__ void idx_kernel(int* __restrict__ idx, int layer) {
    int j = blockIdx.x * blockDim.x + threadIdx.x;
    if (j >= HALF_LU) return;
    uint32_t f0, f1, a0, a1, b0, b1, o0, o1;
    threefry2x32(0u, 42u, 0u, (uint32_t)layer, f0, f1);
    threefry2x32(f0, f1, 0u, 2u, a0, a1);
    threefry2x32(f0, f1, 1u, 3u, b0, b1);
    threefry2x32(a1, b1, (uint32_t)j, (uint32_t)(j + HALF_LU), o0, o1);
    idx[j] = (int)(o0 & 4095u);
    idx[j + HALF_LU] = (int)(o1 & 4095u);
    (void)a0; (void)b0;
}

// ------- prep: xbf[8192x32] (row l=0 zero, else x[b,l-1,:]) + We_bf cast -----------
__global__ void prep_embed_kernel(const float* __restrict__ x, const float* __restrict__ We,
                                  __hip_bfloat16* __restrict__ xbf,
                                  __hip_bfloat16* __restrict__ webf) {
    int u = blockIdx.x * blockDim.x + threadIdx.x;  // 4-element units
    const int NX = B * LSEQ * F_IN / 4;             // 65536
    const int NW = D * F_IN / 4;                    // 4096
    if (u < NX) {
        int e0 = u * 4;
        int i = e0 & 31;
        int l = (e0 >> 5) & (LSEQ - 1);
        int b = e0 >> 17;
        union { unsigned short s[4]; uint2 w; } o;
        if (l == 0) {
            o.s[0] = o.s[1] = o.s[2] = o.s[3] = 0;
        } else {
            float4 v = *(const float4*)(x + ((size_t)b * S + (l - 1)) * F_IN + i);
            o.s[0] = bf16_bits(v.x); o.s[1] = bf16_bits(v.y);
            o.s[2] = bf16_bits(v.z); o.s[3] = bf16_bits(v.w);
        }
        ((uint2*)xbf)[u] = o.w;
    } else if (u < NX + NW) {
        int w = u - NX;
        float4 v = ((const float4*)We)[w];
        union { unsigned short s[4]; uint2 w2; } o;
        o.s[0] = bf16_bits(v.x); o.s[1] = bf16_bits(v.y);
        o.s[2] = bf16_bits(v.z); o.s[3] = bf16_bits(v.w);
        ((uint2*)webf)[w] = o.w2;
    }
}

// ------- posenc: h = (l==0 ? cls : emb) + PE; dual write f32 + bf16 ----------------
__global__ void posenc_kernel(const float* __restrict__ emb, const float* __restrict__ cls,
                              float* __restrict__ h, __hip_bfloat16* __restrict__ hbf) {
    int gid = blockIdx.x * blockDim.x + threadIdx.x;
    if (gid >= B * LSEQ * D) return;
    int d = gid % D;
    int l = (gid / D) % LSEQ;
    float v = (l == 0) ? cls[d] : emb[gid];
    int i = d >> 1;
    float divv = expf((float)(2 * i) * (float)(-9.210340371976184 / 512.0));
    float ang = (float)l * divv;
    v += (d & 1) ? cosf(ang) : sinf(ang);
    h[gid] = v;
    hbf[gid] = __float2bfloat16(v);
}

// ------- fused per-layer weight cast + packed qkv bias -----------------------------
__global__ void cast_weights_kernel(const float* __restrict__ Wq_l,
                                    const float* __restrict__ Wk_l,
                                    const float* __restrict__ Wv_l,
                                    const float* __restrict__ Wo_l,
                                    const float* __restrict__ W1_l,
                                    const float* __restrict__ W2_l,
                                    const float* __restrict__ bq_l,
                                    const float* __restrict__ bk_l,
                                    const float* __restrict__ bv_l,
                                    __hip_bfloat16* __restrict__ wqb,
                                    __hip_bfloat16* __restrict__ wkb,
                                    __hip_bfloat16* __restrict__ wvb,
                                    __hip_bfloat16* __restrict__ wob,
                                    __hip_bfloat16* __restrict__ w1b,
                                    __hip_bfloat16* __restrict__ w2b,
                                    float* __restrict__ qkvbias) {
    const int SDD = D * D / 4;       // 65536
    const int SFD = DFF * D / 4;     // 262144
    const int CAST_N = 4 * SDD + 2 * SFD;
    int u = blockIdx.x * blockDim.x + threadIdx.x;
    if (u >= CAST_N) {
        int j = u - CAST_N;          // 0..383, 4-float units over 1536 bias
        if (j < 384) {
            int seg = (j * 4) >> 9;  // 0:q 1:k 2:v
            int off = (j * 4) & 511;
            const float* src = (seg == 0) ? bq_l : (seg == 1) ? bk_l : bv_l;
            *(float4*)(qkvbias + j * 4) = *(const float4*)(src + off);
        }
        return;
    }
    const float* src;
    __hip_bfloat16* dst;
    int off;
    if (u < SDD) { src = Wq_l; dst = wqb; off = u; }
    else if (u < 2 * SDD) { src = Wk_l; dst = wkb; off = u - SDD; }
    else if (u < 3 * SDD) { src = Wv_l; dst = wvb; off = u - 2 * SDD; }
    else if (u < 4 * SDD) { src = Wo_l; dst = wob; off = u - 3 * SDD; }
    else if (u < 4 * SDD + SFD) { src = W1_l; dst = w1b; off = u - 4 * SDD; }
    else { src = W2_l; dst = w2b; off = u - 4 * SDD - SFD; }
    float4 v = ((const float4*)src)[off];
    union { unsigned short s[4]; uint2 w; } o;
    o.s[0] = bf16_bits(v.x); o.s[1] = bf16_bits(v.y);
    o.s[2] = bf16_bits(v.z); o.s[3] = bf16_bits(v.w);
    ((uint2*)dst)[off] = o.w;
}

// ------- bf16 MFMA GEMM, BK=32 (for K=32 embed) ------------------------------------
__global__ __launch_bounds__(256) void gemm32(const unsigned short* __restrict__ A,
                                              const unsigned short* __restrict__ W,
                                              const float* __restrict__ bias,
                                              float* __restrict__ Cf,
                                              int M, int N, int K) {
    __shared__ unsigned short lds[2 * 128 * 32];
    unsigned short* As = lds;
    unsigned short* Bs = lds + 128 * 32;
    const int tid = threadIdx.x;
    const int m0 = blockIdx.y * 128, n0 = blockIdx.x * 128;
    const int wave = tid >> 6, lane = tid & 63;
    const int wm = (wave >> 1) * 64, wn = (wave & 1) * 64;
    const int quad = lane >> 4, m15 = lane & 15;
    const int srow = tid >> 2, scol = (tid & 3) * 8;
    f32x4 acc[4][4] = {};
    const unsigned short* Ag0 = A + (size_t)(m0 + srow) * K + scol;
    const unsigned short* Ag1 = A + (size_t)(m0 + srow + 64) * K + scol;
    const unsigned short* Wg0 = W + (size_t)(n0 + srow) * K + scol;
    const unsigned short* Wg1 = W + (size_t)(n0 + srow + 64) * K + scol;
    for (int k0 = 0; k0 < K; k0 += 32) {
        __syncthreads();
        GLD(Ag0 + k0, As + tid * 8);
        GLD(Ag1 + k0, As + 2048 + tid * 8);
        GLD(Wg0 + k0, Bs + tid * 8);
        GLD(Wg1 + k0, Bs + 2048 + tid * 8);
        __syncthreads();
        short8 af[4], bfr[4];
#pragma unroll
        for (int mi = 0; mi < 4; ++mi)
            af[mi] = *(const short8*)(As + (wm + mi * 16 + m15) * 32 + quad * 8);
#pragma unroll
        for (int ni = 0; ni < 4; ++ni)
            bfr[ni] = *(const short8*)(Bs + (wn + ni * 16 + m15) * 32 + quad * 8);
#pragma unroll
        for (int mi = 0; mi < 4; ++mi)
#pragma unroll
            for (int ni = 0; ni < 4; ++ni)
                acc[mi][ni] = __builtin_amdgcn_mfma_f32_16x16x32_bf16(
                    af[mi], bfr[ni], acc[mi][ni], 0, 0, 0);
    }
#pragma unroll
    for (int mi = 0; mi < 4; ++mi) {
        int mg = m0 + wm + mi * 16 + quad * 4;
#pragma unroll
        for (int ni = 0; ni < 4; ++ni) {
            int ng = n0 + wn + ni * 16 + m15;
            float bv = bias[ng];
#pragma unroll
            for (int r = 0; r < 4; ++r)
                Cf[(size_t)(mg + r) * N + ng] = acc[mi][ni][r] + bv;
        }
    }
}

// ------- bf16 MFMA GEMM, 128x128 tile, BK=64 ---------------------------------------
// MODE 0: f32 out; 1: bf16 out; 2: relu->bf16; 3: QKV-mixed (seg0 f32 q, seg1/2 bf16)
template <int MODE>
__global__ __launch_bounds__(256) void gemm64(const unsigned short* __restrict__ A,
                                              const unsigned short* __restrict__ W,
                                              const float* __restrict__ bias,
                                              void* __restrict__ C0,
                                              void* __restrict__ C1,
                                              void* __restrict__ C2,
                                              int M, int N, int K) {
    __shared__ unsigned short As[2][128 * 32];
    __shared__ unsigned short Bs[2][128 * 32];
    const int tid = threadIdx.x;
    const int m0 = blockIdx.y * 128, n0 = blockIdx.x * 128;
    const int wave = tid >> 6, lane = tid & 63;
    const int wm = (wave >> 1) * 64, wn = (wave & 1) * 64;
    const int quad = lane >> 4, m15 = lane & 15;
    const int srow = tid >> 2, scol = (tid & 3) * 8;
    f32x4 acc[4][4] = {};
    const unsigned short* Ag0 = A + (size_t)(m0 + srow) * K + scol;
    const unsigned short* Ag1 = A + (size_t)(m0 + srow + 64) * K + scol;
    const unsigned short* Wg0 = W + (size_t)(n0 + srow) * K + scol;
    const unsigned short* Wg1 = W + (size_t)(n0 + srow + 64) * K + scol;
    for (int k0 = 0; k0 < K; k0 += 64) {
        __syncthreads();
        GLD(Ag0 + k0, As[0] + tid * 8);
        GLD(Ag1 + k0, As[0] + 2048 + tid * 8);
        GLD(Ag0 + k0 + 32, As[1] + tid * 8);
        GLD(Ag1 + k0 + 32, As[1] + 2048 + tid * 8);
        GLD(Wg0 + k0, Bs[0] + tid * 8);
        GLD(Wg1 + k0, Bs[0] + 2048 + tid * 8);
        GLD(Wg0 + k0 + 32, Bs[1] + tid * 8);
        GLD(Wg1 + k0 + 32, Bs[1] + 2048 + tid * 8);
        __syncthreads();
#pragma unroll
        for (int ks = 0; ks < 2; ++ks) {
            short8 af[4], bfr[4];
#pragma unroll
            for (int mi = 0; mi < 4; ++mi)
                af[mi] = *(const short8*)(As[ks] + (wm + mi * 16 + m15) * 32 + quad * 8);
#pragma unroll
            for (int ni = 0; ni < 4; ++ni)
                bfr[ni] = *(const short8*)(Bs[ks] + (wn + ni * 16 + m15) * 32 + quad * 8);
#pragma unroll
            for (int mi = 0; mi < 4; ++mi)
#pragma unroll
                for (int ni = 0; ni < 4; ++ni)
                    acc[mi][ni] = __builtin_amdgcn_mfma_f32_16x16x32_bf16(
                        af[mi], bfr[ni], acc[mi][ni], 0, 0, 0);
        }
    }
#pragma unroll
    for (int mi = 0; mi < 4; ++mi) {
        int mg = m0 + wm + mi * 16 + quad * 4;
#pragma unroll
        for (int ni = 0; ni < 4; ++ni) {
            int ng = n0 + wn + ni * 16 + m15;
            float bv = bias[ng];
#pragma unroll
            for (int r = 0; r < 4; ++r) {
                float v = acc[mi][ni][r] + bv;
                if (MODE == 0) {
                    ((float*)C0)[(size_t)(mg + r) * N + ng] = v;
                } else if (MODE == 1) {
                    ((__hip_bfloat16*)C0)[(size_t)(mg + r) * N + ng] = __float2bfloat16(v);
                } else if (MODE == 2) {
                    ((__hip_bfloat16*)C0)[(size_t)(mg + r) * N + ng] =
                        __float2bfloat16(fmaxf(v, 0.f));
                } else {  // QKV mixed: N=1536, segments of 512
                    int seg = ng >> 9;
                    int col = ng & 511;
                    if (seg == 0)
                        ((float*)C0)[(size_t)(mg + r) * D + col] = v;
                    else if (seg == 1)
                        ((__hip_bfloat16*)C1)[(size_t)(mg + r) * D + col] = __float2bfloat16(v);
                    else
                        ((__hip_bfloat16*)C2)[(size_t)(mg + r) * D + col] = __float2bfloat16(v);
                }
            }
        }
    }
}

// ------- bf16 MFMA GEMM, 64x128 tile, BK=64, f32 out — for small-grid GEMMs --------
// wave w computes rows [w*16, w*16+16) x all 128 cols: 1 A-frag x 8 B-frags.
__global__ __launch_bounds__(256) void gemm64_m64(const unsigned short* __restrict__ A,
                                                  const unsigned short* __restrict__ W,
                                                  const float* __restrict__ bias,
                                                  float* __restrict__ Cf,
                                                  int M, int N, int K) {
    __shared__ unsigned short As[2][64 * 32];
    __shared__ unsigned short Bs[2][128 * 32];
    const int tid = threadIdx.x;
    const int m0 = blockIdx.y * 64, n0 = blockIdx.x * 128;
    const int wave = tid >> 6, lane = tid & 63;
    const int quad = lane >> 4, m15 = lane & 15;
    const int srow = tid >> 2, scol = (tid & 3) * 8;
    f32x4 acc[8] = {};
    const unsigned short* Ag0 = A + (size_t)(m0 + srow) * K + scol;
    const unsigned short* Wg0 = W + (size_t)(n0 + srow) * K + scol;
    const unsigned short* Wg1 = W + (size_t)(n0 + srow + 64) * K + scol;
    for (int k0 = 0; k0 < K; k0 += 64) {
        __syncthreads();
        GLD(Ag0 + k0, As[0] + tid * 8);
        GLD(Ag0 + k0 + 32, As[1] + tid * 8);
        GLD(Wg0 + k0, Bs[0] + tid * 8);
        GLD(Wg1 + k0, Bs[0] + 2048 + tid * 8);
        GLD(Wg0 + k0 + 32, Bs[1] + tid * 8);
        GLD(Wg1 + k0 + 32, Bs[1] + 2048 + tid * 8);
        __syncthreads();
#pragma unroll
        for (int ks = 0; ks < 2; ++ks) {
            short8 af = *(const short8*)(As[ks] + (wave * 16 + m15) * 32 + quad * 8);
#pragma unroll
            for (int ni = 0; ni < 8; ++ni) {
                short8 bfr = *(const short8*)(Bs[ks] + (ni * 16 + m15) * 32 + quad * 8);
                acc[ni] = __builtin_amdgcn_mfma_f32_16x16x32_bf16(af, bfr, acc[ni], 0, 0, 0);
            }
        }
    }
    int mg = m0 + wave * 16 + quad * 4;
#pragma unroll
    for (int ni = 0; ni < 8; ++ni) {
        int ng = n0 + ni * 16 + m15;
        float bv = bias[ng];
#pragma unroll
        for (int r = 0; r < 4; ++r)
            Cf[(size_t)(mg + r) * N + ng] = acc[ni][r] + bv;
    }
}

// -------- M-score: block per (b,l); one WAVE per sampled row -----------------------
__global__ __launch_bounds__(256) void mscore_kernel(const float* __restrict__ q,
                                                     const __hip_bfloat16* __restrict__ kbf,
                                                     const int* __restrict__ idx,
                                                     float* __restrict__ Mv) {
    __shared__ float Sbuf[U][8];
    __shared__ int sidx[U];
    int bid = blockIdx.x;
    int b = bid & 1;
    int l = bid >> 1;
    int tid = threadIdx.x;
    int wave = tid >> 6, lane = tid & 63;
    if (tid < U) sidx[tid] = idx[l * U + tid];
    const float* qr = q + ((size_t)(b * LSEQ) + l) * D + lane * 8;
    float4 qa = *(const float4*)qr;
    float4 qb = *(const float4*)(qr + 4);
    __syncthreads();
    const unsigned short* kbase = (const unsigned short*)(kbf + (size_t)(b * LSEQ) * D);
    for (int t = wave; t < U; t += 4) {
        int kr = sidx[t];
        union { uint4 u; unsigned short s[8]; } kv;
        kv.u = *(const uint4*)(kbase + (size_t)kr * D + lane * 8);
        float p = qa.x * bits_to_f32(kv.s[0]) + qa.y * bits_to_f32(kv.s[1]) +
                  qa.z * bits_to_f32(kv.s[2]) + qa.w * bits_to_f32(kv.s[3]) +
                  qb.x * bits_to_f32(kv.s[4]) + qb.y * bits_to_f32(kv.s[5]) +
                  qb.z * bits_to_f32(kv.s[6]) + qb.w * bits_to_f32(kv.s[7]);
        p += __shfl_xor(p, 1);
        p += __shfl_xor(p, 2);
        p += __shfl_xor(p, 4);
        if ((lane & 7) == 0) Sbuf[t][lane >> 3] = p;
    }
    __syncthreads();
    if (tid < 8) {
        float mx = -INFINITY, sm = 0.f;
        for (int t = 0; t < U; ++t) {
            float v = Sbuf[t][tid];
            mx = fmaxf(mx, v);
            sm += v;
        }
        Mv[((size_t)b * H + tid) * LSEQ + l] = mx - sm / (float)LSEQ;
    }
}

// ------- top-k phase A: bitonic sort each 256-chunk desc, emit top-45 keys ---------
__global__ __launch_bounds__(256) void topk_chunk_kernel(const float* __restrict__ Mv,
                                                         unsigned long long* __restrict__ cand) {
    __shared__ unsigned long long sk[256];
    int blk = blockIdx.x;  // B*H*16
    int chunk = blk & 15, bh = blk >> 4;
    int tid = threadIdx.x;
    int gi = chunk * 256 + tid;
    sk[tid] = mkey(Mv[(size_t)bh * LSEQ + gi], gi);
    __syncthreads();
    for (int k = 2; k <= 256; k <<= 1) {
        for (int j = k >> 1; j > 0; j >>= 1) {
            int ixj = tid ^ j;
            if (ixj > tid) {
                unsigned long long a = sk[tid], b = sk[ixj];
                bool desc = ((tid & k) == 0);
                if (desc ? (a < b) : (a > b)) { sk[tid] = b; sk[ixj] = a; }
            }
            __syncthreads();
        }
    }
    if (tid < U) cand[((size_t)bh * 16 + chunk) * U + tid] = sk[tid];
}

// ------- top-k phase B: merge 16x45 candidates via 1024-wide bitonic sort ----------
__global__ __launch_bounds__(256) void topk_merge_kernel(const unsigned long long* __restrict__ cand,
                                                         int* __restrict__ top) {
    __shared__ unsigned long long sk[1024];
    int bh = blockIdx.x;
    int tid = threadIdx.x;
    for (int e = tid; e < 1024; e += 256)
        sk[e] = (e < 16 * U) ? cand[(size_t)bh * 16 * U + e] : 0ull;
    __syncthreads();
    for (int k = 2; k <= 1024; k <<= 1) {
        for (int j = k >> 1; j > 0; j >>= 1) {
            for (int e = tid; e < 1024; e += 256) {
                int ixj = e ^ j;
                if (ixj > e) {
                    unsigned long long a = sk[e], b = sk[ixj];
                    bool desc = ((e & k) == 0);
                    if (desc ? (a < b) : (a > b)) { sk[e] = b; sk[ixj] = a; }
                }
            }
            __syncthreads();
        }
    }
    if (tid < U)
        top[bh * U + tid] = (int)(0xFFFFFFFFu - (uint32_t)(sk[tid] & 0xFFFFFFFFu));
}

// ---------------- v mean: partial (128 blocks) + reduce ----------------
__global__ __launch_bounds__(256) void vmean_part(const __hip_bfloat16* __restrict__ v,
                                                  float* __restrict__ part) {
    int blk = blockIdx.x;  // B*H*8
    int seg = blk & 7, hh = (blk >> 3) & 7, b = blk >> 6;
    int e = threadIdx.x & 63, rg = threadIdx.x >> 6;
    const __hip_bfloat16* vp =
        v + ((size_t)(b * LSEQ) + seg * 512) * D + hh * 64 + e;
    float acc = 0.f;
    for (int r = rg; r < 512; r += 4) acc += __bfloat162float(vp[(size_t)r * D]);
    __shared__ float red[4][64];
    red[rg][e] = acc;
    __syncthreads();
    if (threadIdx.x < 64)
        part[(size_t)blk * 64 + threadIdx.x] =
            red[0][threadIdx.x] + red[1][threadIdx.x] + red[2][threadIdx.x] + red[3][threadIdx.x];
}

__global__ void vmean_reduce(const float* __restrict__ part, float* __restrict__ vm) {
    int gid = blockIdx.x * blockDim.x + threadIdx.x;
    if (gid >= B * H * E) return;
    int e = gid & 63, bh = gid >> 6;
    float acc = 0.f;
#pragma unroll
    for (int s = 0; s < 8; ++s) acc += part[((size_t)bh * 8 + s) * 64 + e];
    vm[gid] = acc / (float)LSEQ;
}

// ------- base[b] = vmeanAll[b] . Wo^T + bo (one wave per output n) -----------------
__global__ __launch_bounds__(256) void wo_base_kernel(const float* __restrict__ vm,
                                                      const unsigned short* __restrict__ wob,
                                                      const float* __restrict__ bo,
                                                      float* __restrict__ base) {
    int b = blockIdx.x >> 7;            // grid B*128
    int n = (blockIdx.x & 127) * 4 + (threadIdx.x >> 6);
    int lane = threadIdx.x & 63;
    const float* vmr = vm + (size_t)b * D + lane * 8;
    float4 va = *(const float4*)vmr;
    float4 vb = *(const float4*)(vmr + 4);
    union { uint4 u; unsigned short s[8]; } w;
    w.u = *(const uint4*)(wob + (size_t)n * D + lane * 8);
    float p = va.x * bits_to_f32(w.s[0]) + va.y * bits_to_f32(w.s[1]) +
              va.z * bits_to_f32(w.s[2]) + va.w * bits_to_f32(w.s[3]) +
              vb.x * bits_to_f32(w.s[4]) + vb.y * bits_to_f32(w.s[5]) +
              vb.z * bits_to_f32(w.s[6]) + vb.w * bits_to_f32(w.s[7]);
    for (int off = 32; off; off >>= 1) p += __shfl_xor(p, off);
    if (lane == 0) base[(size_t)b * D + n] = p + bo[n];
}

// ------- aout[r] = base[b] broadcast (float4) --------------------------------------
__global__ void bcast_base(const float* __restrict__ base, float* __restrict__ aout) {
    int i = blockIdx.x * blockDim.x + threadIdx.x;  // over ML*D/4
    if (i >= B * LSEQ * D / 4) return;
    int b = i >> 19;          // LSEQ*D/4 = 2^19
    int c4 = i & 127;         // D/4 = 128
    ((float4*)aout)[i] = *(const float4*)(base + (size_t)b * D + c4 * 4);
}

// ------- scatter correction: aout[top[bh,t]] += (upd - vmean_h) . Wo_h^T -----------
__global__ __launch_bounds__(256) void wo_corr_kernel(const float* __restrict__ updbuf,
                                                      const float* __restrict__ vm,
                                                      const unsigned short* __restrict__ wob,
                                                      const int* __restrict__ top,
                                                      float* __restrict__ aout) {
    __shared__ float dlt[E];
    int bid = blockIdx.x;  // B*H*U
    int t = bid % U;
    int bh = bid / U;
    int b = bh >> 3, hh = bh & 7;
    int tid = threadIdx.x;
    if (tid < E) dlt[tid] = updbuf[((size_t)bh * U + t) * E + tid] - vm[(size_t)bh * E + tid];
    __syncthreads();
    int r = top[bh * U + t];
    float* arow = aout + (size_t)(b * LSEQ + r) * D;
    for (int n = tid; n < D; n += 256) {
        const unsigned short* wr = wob + (size_t)n * D + hh * E;
        float acc = 0.f;
#pragma unroll
        for (int k2 = 0; k2 < E; ++k2) acc += dlt[k2] * bits_to_f32(wr[k2]);
        atomicAdd(arow + n, acc);
    }
}

// -------- flash-style MFMA attention partial: block = (slice, h, b) ----------------
__global__ __launch_bounds__(256) void attn_part(const float* __restrict__ q,
                                                 const __hip_bfloat16* __restrict__ kbf,
                                                 const __hip_bfloat16* __restrict__ vbf,
                                                 const int* __restrict__ top,
                                                 float* __restrict__ Opart,
                                                 float* __restrict__ msum) {
    __shared__ unsigned short Qs[48 * 72];
    __shared__ unsigned short Ks[SLICE * 72];
    __shared__ unsigned short Vs[SLICE * 68];
    __shared__ unsigned short Ps[48 * 136];
    __shared__ float mred[48][4];
    __shared__ float sred[48][4];
    const int slice = blockIdx.x, hh = blockIdx.y, b = blockIdx.z;
    const int bh = b * H + hh;
    const int tid = threadIdx.x;
    const int s0 = slice * SLICE;
    for (int i = tid; i < 48 * 64; i += 256) {
        int t = i >> 6, e = i & 63;
        float v = 0.f;
        if (t < U) {
            int r = top[bh * U + t];
            v = q[((size_t)(b * LSEQ) + r) * D + hh * E + e];
        }
        Qs[t * 72 + e] = bf16_bits(v);
    }
    {
        const uint4* src = (const uint4*)(kbf + ((size_t)(b * LSEQ) + s0) * D + hh * E);
        for (int i = tid; i < SLICE * 8; i += 256) {
            int r = i >> 3, c = i & 7;
            uint4 d = src[(size_t)r * 64 + c];
            *(uint4*)(Ks + r * 72 + c * 8) = d;
        }
    }
    {
        const uint2* src = (const uint2*)(vbf + ((size_t)(b * LSEQ) + s0) * D + hh * E);
        for (int i = tid; i < SLICE * 16; i += 256) {
            int r = i >> 4, c = i & 15;
            uint2 d = src[(size_t)r * 128 + c];
            *(uint2*)(Vs + r * 68 + c * 4) = d;
        }
    }
    __syncthreads();
    const int wave = tid >> 6, lane = tid & 63;
    const int quad = lane >> 4, m15 = lane & 15;
    const int wc = wave * 32;
    f32x4 acc[3][2] = {};
#pragma unroll
    for (int ks = 0; ks < 2; ++ks) {
        short8 af[3], bfr[2];
#pragma unroll
        for (int mt = 0; mt < 3; ++mt)
            af[mt] = *(const short8*)(Qs + (mt * 16 + m15) * 72 + ks * 32 + quad * 8);
#pragma unroll
        for (int nt = 0; nt < 2; ++nt)
            bfr[nt] = *(const short8*)(Ks + (wc + nt * 16 + m15) * 72 + ks * 32 + quad * 8);
#pragma unroll
        for (int mt = 0; mt < 3; ++mt)
#pragma unroll
            for (int nt = 0; nt < 2; ++nt)
                acc[mt][nt] = __builtin_amdgcn_mfma_f32_16x16x32_bf16(
                    af[mt], bfr[nt], acc[mt][nt], 0, 0, 0);
    }
    float sc[3][2][4];
#pragma unroll
    for (int mt = 0; mt < 3; ++mt)
#pragma unroll
        for (int nt = 0; nt < 2; ++nt)
#pragma unroll
            for (int r = 0; r < 4; ++r) sc[mt][nt][r] = acc[mt][nt][r] * 0.125f;
#pragma unroll
    for (int mt = 0; mt < 3; ++mt)
#pragma unroll
        for (int r = 0; r < 4; ++r) {
            float mv = fmaxf(sc[mt][0][r], sc[mt][1][r]);
            mv = fmaxf(mv, __shfl_xor(mv, 1));
            mv = fmaxf(mv, __shfl_xor(mv, 2));
            mv = fmaxf(mv, __shfl_xor(mv, 4));
            mv = fmaxf(mv, __shfl_xor(mv, 8));
            if (m15 == 0) mred[mt * 16 + quad * 4 + r][wave] = mv;
        }
    __syncthreads();
#pragma unroll
    for (int mt = 0; mt < 3; ++mt)
#pragma unroll
        for (int r = 0; r < 4; ++r) {
            int row = mt * 16 + quad * 4 + r;
            float ms = fmaxf(fmaxf(mred[row][0], mred[row][1]),
                             fmaxf(mred[row][2], mred[row][3]));
            float p0 = __expf(sc[mt][0][r] - ms);
            float p1 = __expf(sc[mt][1][r] - ms);
            float sv = p0 + p1;
            sv += __shfl_xor(sv, 1);
            sv += __shfl_xor(sv, 2);
            sv += __shfl_xor(sv, 4);
            sv += __shfl_xor(sv, 8);
            if (m15 == 0) sred[row][wave] = sv;
            Ps[row * 136 + wc + m15] = bf16_bits(p0);
            Ps[row * 136 + wc + 16 + m15] = bf16_bits(p1);
        }
    __syncthreads();
    if (tid < U) {
        float mm = fmaxf(fmaxf(mred[tid][0], mred[tid][1]),
                         fmaxf(mred[tid][2], mred[tid][3]));
        float ss = sred[tid][0] + sred[tid][1] + sred[tid][2] + sred[tid][3];
        size_t base = (((size_t)bh * NS + slice) * U + tid) * 2;
        msum[base] = mm;
        msum[base + 1] = ss;
    }
    f32x4 apv[3] = {};
#pragma unroll
    for (int ks = 0; ks < 4; ++ks) {
        short8 bv;
#pragma unroll
        for (int j = 0; j < 8; ++j)
            bv[j] = (short)Vs[(ks * 32 + quad * 8 + j) * 68 + wave * 16 + m15];
        short8 af2[3];
#pragma unroll
        for (int mt = 0; mt < 3; ++mt)
            af2[mt] = *(const short8*)(Ps + (mt * 16 + m15) * 136 + ks * 32 + quad * 8);
#pragma unroll
        for (int mt = 0; mt < 3; ++mt)
            apv[mt] = __builtin_amdgcn_mfma_f32_16x16x32_bf16(af2[mt], bv, apv[mt], 0, 0, 0);
    }
    size_t obase = ((size_t)bh * NS + slice) * U;
#pragma unroll
    for (int mt = 0; mt < 3; ++mt)
#pragma unroll
        for (int r = 0; r < 4; ++r) {
            int row = mt * 16 + quad * 4 + r;
            if (row < U)
                Opart[(obase + row) * 64 + wave * 16 + m15] = apv[mt][r];
        }
}

// -------- combine slice partials -> dense upd buffer (f32) -------------------------
__global__ __launch_bounds__(64) void attn_reduce(const float* __restrict__ Opart,
                                                  const float* __restrict__ msum,
                                                  float* __restrict__ updbuf) {
    int t = blockIdx.x % U;
    int bh = blockIdx.x / U;
    int lane = threadIdx.x;
    float m_s = -INFINITY, ss = 0.f;
    if (lane < NS) {
        size_t base = (((size_t)bh * NS + lane) * U + t) * 2;
        m_s = msum[base];
        ss = msum[base + 1];
    }
    float M = m_s;
    for (int off = 32; off; off >>= 1) M = fmaxf(M, __shfl_xor(M, off));
    float e_s = (lane < NS) ? __expf(m_s - M) : 0.f;
    float d = ss * e_s;
    for (int off = 32; off; off >>= 1) d += __shfl_xor(d, off);
    float acc = 0.f;
    for (int s = 0; s < NS; ++s) {
        float w = __shfl(e_s, s);
        acc += w * Opart[(((size_t)bh * NS + s) * U + t) * 64 + lane];
    }
    updbuf[((size_t)bh * U + t) * E + lane] = acc / d;
}

// -------- h = LayerNorm(h + a) * g + b, one wave per row, dual write f32+bf16 -------
__global__ __launch_bounds__(64) void add_ln_kernel(float* __restrict__ h,
                                                    const float* __restrict__ a,
                                                    const float* __restrict__ g,
                                                    const float* __restrict__ bb,
                                                    __hip_bfloat16* __restrict__ hbf) {
    int row = blockIdx.x;
    int lane = threadIdx.x;
    float* hp = h + (size_t)row * D;
    const float* ap = a + (size_t)row * D;
    float x[8];
    float sum = 0.f;
#pragma unroll
    for (int j = 0; j < 8; ++j) {
        x[j] = hp[lane + 64 * j] + ap[lane + 64 * j];
        sum += x[j];
    }
    for (int off = 32; off; off >>= 1) sum += __shfl_xor(sum, off);
    float mu = sum / (float)D;
    float vs = 0.f;
#pragma unroll
    for (int j = 0; j < 8; ++j) {
        float dd = x[j] - mu;
        vs += dd * dd;
    }
    for (int off = 32; off; off >>= 1) vs += __shfl_xor(vs, off);
    float inv = 1.f / sqrtf(vs / (float)D + EPSL);
#pragma unroll
    for (int j = 0; j < 8; ++j) {
        float o = (x[j] - mu) * inv * g[lane + 64 * j] + bb[lane + 64 * j];
        hp[lane + 64 * j] = o;
        hbf[(size_t)row * D + lane + 64 * j] = __float2bfloat16(o);
    }
}

// ---------------- final head ----------------
__global__ void final_kernel(const float* __restrict__ h, const float* __restrict__ Wf,
                             const float* __restrict__ bf, float* __restrict__ out) {
    int b = blockIdx.x;
    int lane = threadIdx.x;
    const float* hp = h + (size_t)b * LSEQ * D;
    float acc = 0.f;
    for (int j = lane; j < D; j += 64) acc += hp[j] * Wf[j];
    for (int off = 32; off; off >>= 1) acc += __shfl_xor(acc, off);
    if (lane == 0) out[b] = acc + bf[0];
}

extern "C" void kernel_launch(void* const* d_in, const int* in_sizes, int n_in,
                              void* d_out, int out_size, void* d_ws, size_t ws_size,
                              hipStream_t stream) {
    (void)in_sizes; (void)n_in; (void)out_size; (void)ws_size;
    const float* x   = (const float*)d_in[0];
    const float* We  = (const float*)d_in[1];
    const float* be  = (const float*)d_in[2];
    const float* cls = (const float*)d_in[3];
    const float* Wq  = (const float*)d_in[4];
    const float* bq  = (const float*)d_in[5];
    const float* Wk  = (const float*)d_in[6];
    const float* bk  = (const float*)d_in[7];
    const float* Wv  = (const float*)d_in[8];
    const float* bv  = (const float*)d_in[9];
    const float* Wo  = (const float*)d_in[10];
    const float* bo  = (const float*)d_in[11];
    const float* g1  = (const float*)d_in[12];
    const float* b1  = (const float*)d_in[13];
    const float* g2  = (const float*)d_in[14];
    const float* b2  = (const float*)d_in[15];
    const float* W1  = (const float*)d_in[16];
    const float* bf1 = (const float*)d_in[17];
    const float* W2  = (const float*)d_in[18];
    const float* bf2 = (const float*)d_in[19];
    const float* Wf  = (const float*)d_in[20];
    const float* bff = (const float*)d_in[21];
    float* out = (float*)d_out;

    float* ws = (float*)d_ws;
    const size_t NT = (size_t)B * LSEQ * D;  // 4,194,304
    float* h    = ws;                         // [0, NT)
    float* aout = ws + NT;                    // [NT, 2NT)
    float* q    = ws + 2 * NT;                // [2NT, 3NT)
    __hip_bfloat16* kbf    = (__hip_bfloat16*)(ws + NT);      // overlays aout
    __hip_bfloat16* y1_bf  = (__hip_bfloat16*)(ws + 2 * NT);  // overlays q post-attn
    __hip_bfloat16* v_bf   = (__hip_bfloat16*)(ws + 4 * NT);
    __hip_bfloat16* h_bf   = (__hip_bfloat16*)(ws + 5 * NT);
    float* Opart = ws + 3 * NT;
    float* msumb = Opart + (size_t)B * H * NS * U * 64;
    float* wpool = ws + 5 * NT + NT / 2;
    __hip_bfloat16* wqb = (__hip_bfloat16*)wpool;   // wq|wk|wv contiguous = packed QKV
    __hip_bfloat16* wkb = wqb + (size_t)D * D;
    __hip_bfloat16* wvb = wkb + (size_t)D * D;
    __hip_bfloat16* wob = wvb + (size_t)D * D;
    __hip_bfloat16* w1b = wob + (size_t)D * D;
    __hip_bfloat16* w2b = w1b + (size_t)DFF * D;
    float* after_w = wpool + ((size_t)4 * D * D + 2 * (size_t)DFF * D) / 2;
    float* Mbuf = after_w;
    int* idx    = (int*)(Mbuf + (size_t)B * H * LSEQ);
    int* top    = idx + LU;
    float* vm   = (float*)(top + B * H * U);
    float* vpart  = vm + (size_t)B * H * E;
    float* updbuf = vpart + (size_t)128 * 64;
    float* baseb  = updbuf + (size_t)B * H * U * 64;
    __hip_bfloat16* xbf  = (__hip_bfloat16*)(baseb + (size_t)B * D);   // B*LSEQ*F_IN
    __hip_bfloat16* webf = xbf + (size_t)B * LSEQ * F_IN;              // D*F_IN
    unsigned long long* cand =
        (unsigned long long*)(((uintptr_t)(webf + (size_t)D * F_IN) + 7) & ~(uintptr_t)7);
    float* qkvbias = (float*)(cand + (size_t)B * H * 16 * U);          // 1536 floats

    const int ML = B * LSEQ;  // 8192
    dim3 gD(D / 128, ML / 128);
    dim3 gQKV(3 * D / 128, ML / 128);   // 12 x 64 = 768 blocks
    dim3 gF1(DFF / 128, ML / 128);
    dim3 gW2(D / 128, ML / 64);         // 4 x 128 = 512 blocks (2/CU)
    const int CAST_N = 4 * (D * D / 4) + 2 * (DFF * D / 4);  // 786432
    const int CAST_TOT = CAST_N + 384;                       // + packed qkv bias

    // ---- embed as MFMA GEMM + posenc ----
    prep_embed_kernel<<<(B * LSEQ * F_IN / 4 + D * F_IN / 4 + 255) / 256, 256, 0, stream>>>(
        x, We, xbf, webf);
    gemm32<<<gD, 256, 0, stream>>>((const unsigned short*)xbf,
                                   (const unsigned short*)webf, be, aout, ML, D, F_IN);
    posenc_kernel<<<(B * LSEQ * D + 255) / 256, 256, 0, stream>>>(aout, cls, h, h_bf);

    for (int l = 0; l < NL; ++l) {
        cast_weights_kernel<<<(CAST_TOT + 255) / 256, 256, 0, stream>>>(
            Wq + (size_t)l * D * D, Wk + (size_t)l * D * D, Wv + (size_t)l * D * D,
            Wo + (size_t)l * D * D, W1 + (size_t)l * DFF * D, W2 + (size_t)l * D * DFF,
            bq + l * D, bk + l * D, bv + l * D,
            wqb, wkb, wvb, wob, w1b, w2b, qkvbias);

        // fused QKV GEMM: N=1536, 768 blocks (3/CU)
        gemm64<3><<<gQKV, 256, 0, stream>>>((const unsigned short*)h_bf,
                                            (const unsigned short*)wqb, qkvbias,
                                            q, kbf, v_bf, ML, 3 * D, D);

        idx_kernel<<<(HALF_LU + 255) / 256, 256, 0, stream>>>(idx, l);
        mscore_kernel<<<B * LSEQ, 256, 0, stream>>>(q, kbf, idx, Mbuf);
        topk_chunk_kernel<<<B * H * 16, 256, 0, stream>>>(Mbuf, cand);
        topk_merge_kernel<<<B * H, 256, 0, stream>>>(cand, top);
        vmean_part<<<B * H * 8, 256, 0, stream>>>(v_bf, vpart);
        vmean_reduce<<<4, 256, 0, stream>>>(vpart, vm);
        wo_base_kernel<<<B * 128, 256, 0, stream>>>(vm, (const unsigned short*)wob,
                                                    bo + l * D, baseb);
        attn_part<<<dim3(NS, H, B), 256, 0, stream>>>(q, kbf, v_bf, top, Opart, msumb);
        attn_reduce<<<B * H * U, 64, 0, stream>>>(Opart, msumb, updbuf);
        bcast_base<<<(B * LSEQ * D / 4 + 255) / 256, 256, 0, stream>>>(baseb, aout);
        wo_corr_kernel<<<B * H * U, 256, 0, stream>>>(updbuf, vm,
                                                      (const unsigned short*)wob, top, aout);
        add_ln_kernel<<<ML, 64, 0, stream>>>(h, aout, g1 + l * D, b1 + l * D, h_bf);

        gemm64<2><<<gF1, 256, 0, stream>>>((const unsigned short*)h_bf,
                                           (const unsigned short*)w1b, bf1 + l * DFF,
                                           y1_bf, nullptr, nullptr, ML, DFF, D);
        gemm64_m64<<<gW2, 256, 0, stream>>>((const unsigned short*)y1_bf,
                                            (const unsigned short*)w2b, bf2 + l * D,
                                            aout, ML, D, DFF);
        add_ln_kernel<<<ML, 64, 0, stream>>>(h, aout, g2 + l * D, b2 + l * D, h_bf);
    }

    final_kernel<<<B, 64, 0, stream>>>(h, Wf, bff, out);
}

// Round 12
// 685.069 us; speedup vs baseline: 4.8972x; 1.0161x over previous
//
#include <hip/hip_runtime.h>
#include <hip/hip_bf16.h>
#include <math.h>
#include <stdint.h>

#define B 2
#define S 4095
#define LSEQ 4096
#define F_IN 32
#define D 512
#define H 8
#define E 64
#define DFF 2048
#define NL 2
#define U 45
#define EPSL 1e-5f
#define LU (LSEQ * U)
#define HALF_LU (LU / 2)
#define NS 32
#define SLICE 128

typedef __attribute__((ext_vector_type(8))) short short8;
typedef __attribute__((ext_vector_type(4))) float f32x4;

#define GLD(gp, lp)                                                            \
    __builtin_amdgcn_global_load_lds(                                          \
        (const __attribute__((address_space(1))) void*)(gp),                   \
        (__attribute__((address_space(3))) void*)(lp), 16, 0, 0)

__device__ __forceinline__ unsigned short bf16_bits(float f) {
    __hip_bfloat16 h = __float2bfloat16(f);
    return *(unsigned short*)&h;
}
__device__ __forceinline__ float bits_to_f32(unsigned short s) {
    union { uint32_t u; float f; } c;
    c.u = ((uint32_t)s) << 16;
    return c.f;
}
// monotone sortable key: desc key order == (value desc, index asc) — JAX top_k ties
__device__ __forceinline__ unsigned long long mkey(float v, int index) {
    uint32_t u = __float_as_uint(v);
    uint32_t mono = (u & 0x80000000u) ? ~u : (u | 0x80000000u);
    return ((unsigned long long)mono << 32) | (uint32_t)(0xFFFFFFFFu - (uint32_t)index);
}

// ---------------- Threefry-2x32 (20 rounds), exactly JAX's algorithm ----------------
__device__ __forceinline__ uint32_t rotl32(uint32_t x, int r) {
    return (x << r) | (x >> (32 - r));
}

__device__ void threefry2x32(uint32_t k0, uint32_t k1, uint32_t c0, uint32_t c1,
                             uint32_t& o0, uint32_t& o1) {
    uint32_t ks2 = k0 ^ k1 ^ 0x1BD11BDAu;
    uint32_t x0 = c0 + k0, x1 = c1 + k1;
    x0 += x1; x1 = rotl32(x1, 13); x1 ^= x0;
    x0 += x1; x1 = rotl32(x1, 15); x1 ^= x0;
    x0 += x1; x1 = rotl32(x1, 26); x1 ^= x0;
    x0 += x1; x1 = rotl32(x1, 6);  x1 ^= x0;
    x0 += k1; x1 += ks2 + 1u;
    x0 += x1; x1 = rotl32(x1, 17); x1 ^= x0;
    x0 += x1; x1 = rotl32(x1, 29); x1 ^= x0;
    x0 += x1; x1 = rotl32(x1, 16); x1 ^= x0;
    x0 += x1; x1 = rotl32(x1, 24); x1 ^= x0;
    x0 += ks2; x1 += k0 + 2u;
    x0 += x1; x1 = rotl32(x1, 13); x1 ^= x0;
    x0 += x1; x1 = rotl32(x1, 15); x1 ^= x0;
    x0 += x1; x1 = rotl32(x1, 26); x1 ^= x0;
    x0 += x1; x1 = rotl32(x1, 6);  x1 ^= x0;
    x0 += k0; x1 += k1 + 3u;
    x0 += x1; x1 = rotl32(x1, 17); x1 ^= x0;
    x0 += x1; x1 = rotl32(x1, 29); x1 ^= x0;
    x0 += x1; x1 = rotl32(x1, 16); x1 ^= x0;
    x0 += x1; x1 = rotl32(x1, 24); x1 ^= x0;
    x0 += k1; x1 += ks2 + 4u;
    x0 += x1; x1 = rotl32(x1, 13); x1 ^= x0;
    x0 += x1; x1 = rotl32(x1, 15); x1 ^= x0;
    x0 += x1; x1 = rotl32(x1, 26); x1 ^= x0;
    x0 += x1; x1 = rotl32(x1, 6);  x1 ^= x0;
    x0 += ks2; x1 += k0 + 5u;
    o0 = x0; o1 = x1;
}

__global__ void idx_kernel(int* __restrict__ idx, int layer) {
    int j = blockIdx.x * blockDim.x + threadIdx.x;
    if (j >= HALF_LU) return;
    uint32_t f0, f1, a0, a1, b0, b1, o0, o1;
    threefry2x32(0u, 42u, 0u, (uint32_t)layer, f0, f1);
    threefry2x32(f0, f1, 0u, 2u, a0, a1);
    threefry2x32(f0, f1, 1u, 3u, b0, b1);
    threefry2x32(a1, b1, (uint32_t)j, (uint32_t)(j + HALF_LU), o0, o1);
    idx[j] = (int)(o0 & 4095u);
    idx[j + HALF_LU] = (int)(o1 & 4095u);
    (void)a0; (void)b0;
}

// ------- prep: xbf[8192x32] (row l=0 zero, else x[b,l-1,:]) + We_bf cast -----------
__global__ void prep_embed_kernel(const float* __restrict__ x, const float* __restrict__ We,
                                  __hip_bfloat16* __restrict__ xbf,
                                  __hip_bfloat16* __restrict__ webf) {
    int u = blockIdx.x * blockDim.x + threadIdx.x;  // 4-element units
    const int NX = B * LSEQ * F_IN / 4;             // 65536
    const int NW = D * F_IN / 4;                    // 4096
    if (u < NX) {
        int e0 = u * 4;
        int i = e0 & 31;
        int l = (e0 >> 5) & (LSEQ - 1);
        int b = e0 >> 17;
        union { unsigned short s[4]; uint2 w; } o;
        if (l == 0) {
            o.s[0] = o.s[1] = o.s[2] = o.s[3] = 0;
        } else {
            float4 v = *(const float4*)(x + ((size_t)b * S + (l - 1)) * F_IN + i);
            o.s[0] = bf16_bits(v.x); o.s[1] = bf16_bits(v.y);
            o.s[2] = bf16_bits(v.z); o.s[3] = bf16_bits(v.w);
        }
        ((uint2*)xbf)[u] = o.w;
    } else if (u < NX + NW) {
        int w = u - NX;
        float4 v = ((const float4*)We)[w];
        union { unsigned short s[4]; uint2 w2; } o;
        o.s[0] = bf16_bits(v.x); o.s[1] = bf16_bits(v.y);
        o.s[2] = bf16_bits(v.z); o.s[3] = bf16_bits(v.w);
        ((uint2*)webf)[w] = o.w2;
    }
}

// ------- posenc: h = (l==0 ? cls : emb) + PE; dual write f32 + bf16 ----------------
__global__ void posenc_kernel(const float* __restrict__ emb, const float* __restrict__ cls,
                              float* __restrict__ h, __hip_bfloat16* __restrict__ hbf) {
    int gid = blockIdx.x * blockDim.x + threadIdx.x;
    if (gid >= B * LSEQ * D) return;
    int d = gid % D;
    int l = (gid / D) % LSEQ;
    float v = (l == 0) ? cls[d] : emb[gid];
    int i = d >> 1;
    float divv = expf((float)(2 * i) * (float)(-9.210340371976184 / 512.0));
    float ang = (float)l * divv;
    v += (d & 1) ? cosf(ang) : sinf(ang);
    h[gid] = v;
    hbf[gid] = __float2bfloat16(v);
}

// ------- fused per-layer weight cast + packed qkv bias -----------------------------
__global__ void cast_weights_kernel(const float* __restrict__ Wq_l,
                                    const float* __restrict__ Wk_l,
                                    const float* __restrict__ Wv_l,
                                    const float* __restrict__ Wo_l,
                                    const float* __restrict__ W1_l,
                                    const float* __restrict__ W2_l,
                                    const float* __restrict__ bq_l,
                                    const float* __restrict__ bk_l,
                                    const float* __restrict__ bv_l,
                                    __hip_bfloat16* __restrict__ wqb,
                                    __hip_bfloat16* __restrict__ wkb,
                                    __hip_bfloat16* __restrict__ wvb,
                                    __hip_bfloat16* __restrict__ wob,
                                    __hip_bfloat16* __restrict__ w1b,
                                    __hip_bfloat16* __restrict__ w2b,
                                    float* __restrict__ qkvbias) {
    const int SDD = D * D / 4;       // 65536
    const int SFD = DFF * D / 4;     // 262144
    const int CAST_N = 4 * SDD + 2 * SFD;
    int u = blockIdx.x * blockDim.x + threadIdx.x;
    if (u >= CAST_N) {
        int j = u - CAST_N;          // 0..383, 4-float units over 1536 bias
        if (j < 384) {
            int seg = (j * 4) >> 9;  // 0:q 1:k 2:v
            int off = (j * 4) & 511;
            const float* src = (seg == 0) ? bq_l : (seg == 1) ? bk_l : bv_l;
            *(float4*)(qkvbias + j * 4) = *(const float4*)(src + off);
        }
        return;
    }
    const float* src;
    __hip_bfloat16* dst;
    int off;
    if (u < SDD) { src = Wq_l; dst = wqb; off = u; }
    else if (u < 2 * SDD) { src = Wk_l; dst = wkb; off = u - SDD; }
    else if (u < 3 * SDD) { src = Wv_l; dst = wvb; off = u - 2 * SDD; }
    else if (u < 4 * SDD) { src = Wo_l; dst = wob; off = u - 3 * SDD; }
    else if (u < 4 * SDD + SFD) { src = W1_l; dst = w1b; off = u - 4 * SDD; }
    else { src = W2_l; dst = w2b; off = u - 4 * SDD - SFD; }
    float4 v = ((const float4*)src)[off];
    union { unsigned short s[4]; uint2 w; } o;
    o.s[0] = bf16_bits(v.x); o.s[1] = bf16_bits(v.y);
    o.s[2] = bf16_bits(v.z); o.s[3] = bf16_bits(v.w);
    ((uint2*)dst)[off] = o.w;
}

// ------- bf16 MFMA GEMM, BK=32 (for K=32 embed) ------------------------------------
__global__ __launch_bounds__(256) void gemm32(const unsigned short* __restrict__ A,
                                              const unsigned short* __restrict__ W,
                                              const float* __restrict__ bias,
                                              float* __restrict__ Cf,
                                              int M, int N, int K) {
    __shared__ unsigned short lds[2 * 128 * 32];
    unsigned short* As = lds;
    unsigned short* Bs = lds + 128 * 32;
    const int tid = threadIdx.x;
    const int m0 = blockIdx.y * 128, n0 = blockIdx.x * 128;
    const int wave = tid >> 6, lane = tid & 63;
    const int wm = (wave >> 1) * 64, wn = (wave & 1) * 64;
    const int quad = lane >> 4, m15 = lane & 15;
    const int srow = tid >> 2, scol = (tid & 3) * 8;
    f32x4 acc[4][4] = {};
    const unsigned short* Ag0 = A + (size_t)(m0 + srow) * K + scol;
    const unsigned short* Ag1 = A + (size_t)(m0 + srow + 64) * K + scol;
    const unsigned short* Wg0 = W + (size_t)(n0 + srow) * K + scol;
    const unsigned short* Wg1 = W + (size_t)(n0 + srow + 64) * K + scol;
    for (int k0 = 0; k0 < K; k0 += 32) {
        __syncthreads();
        GLD(Ag0 + k0, As + tid * 8);
        GLD(Ag1 + k0, As + 2048 + tid * 8);
        GLD(Wg0 + k0, Bs + tid * 8);
        GLD(Wg1 + k0, Bs + 2048 + tid * 8);
        __syncthreads();
        short8 af[4], bfr[4];
#pragma unroll
        for (int mi = 0; mi < 4; ++mi)
            af[mi] = *(const short8*)(As + (wm + mi * 16 + m15) * 32 + quad * 8);
#pragma unroll
        for (int ni = 0; ni < 4; ++ni)
            bfr[ni] = *(const short8*)(Bs + (wn + ni * 16 + m15) * 32 + quad * 8);
#pragma unroll
        for (int mi = 0; mi < 4; ++mi)
#pragma unroll
            for (int ni = 0; ni < 4; ++ni)
                acc[mi][ni] = __builtin_amdgcn_mfma_f32_16x16x32_bf16(
                    af[mi], bfr[ni], acc[mi][ni], 0, 0, 0);
    }
#pragma unroll
    for (int mi = 0; mi < 4; ++mi) {
        int mg = m0 + wm + mi * 16 + quad * 4;
#pragma unroll
        for (int ni = 0; ni < 4; ++ni) {
            int ng = n0 + wn + ni * 16 + m15;
            float bv = bias[ng];
#pragma unroll
            for (int r = 0; r < 4; ++r)
                Cf[(size_t)(mg + r) * N + ng] = acc[mi][ni][r] + bv;
        }
    }
}

// ------- PIPELINED bf16 MFMA GEMM, 128x128 tile, BK=32, double-buffered LDS --------
// Prefetch for iter k+1 issues BEFORE compute of iter k -> load latency overlaps MFMA.
// MODE 0: f32 out; 1: bf16 out; 2: relu->bf16; 3: QKV-mixed (seg0 f32 q, seg1/2 bf16)
template <int MODE>
__global__ __launch_bounds__(256) void gemm_pipe(const unsigned short* __restrict__ A,
                                                 const unsigned short* __restrict__ W,
                                                 const float* __restrict__ bias,
                                                 void* __restrict__ C0,
                                                 void* __restrict__ C1,
                                                 void* __restrict__ C2,
                                                 int M, int N, int K) {
    __shared__ unsigned short As[2][128 * 32];
    __shared__ unsigned short Bs[2][128 * 32];
    const int tid = threadIdx.x;
    const int m0 = blockIdx.y * 128, n0 = blockIdx.x * 128;
    const int wave = tid >> 6, lane = tid & 63;
    const int wm = (wave >> 1) * 64, wn = (wave & 1) * 64;
    const int quad = lane >> 4, m15 = lane & 15;
    const int srow = tid >> 2, scol = (tid & 3) * 8;
    f32x4 acc[4][4] = {};
    const unsigned short* Ag0 = A + (size_t)(m0 + srow) * K + scol;
    const unsigned short* Ag1 = A + (size_t)(m0 + srow + 64) * K + scol;
    const unsigned short* Wg0 = W + (size_t)(n0 + srow) * K + scol;
    const unsigned short* Wg1 = W + (size_t)(n0 + srow + 64) * K + scol;
    // prologue: stage k0=0 into buffer 0
    GLD(Ag0, As[0] + tid * 8);
    GLD(Ag1, As[0] + 2048 + tid * 8);
    GLD(Wg0, Bs[0] + tid * 8);
    GLD(Wg1, Bs[0] + 2048 + tid * 8);
    int cur = 0;
    for (int k0 = 0; k0 < K; k0 += 32) {
        __syncthreads();  // drains loads for buf[cur]
        int kn = k0 + 32;
        if (kn < K) {     // prefetch next chunk into the other buffer BEFORE compute
            GLD(Ag0 + kn, As[cur ^ 1] + tid * 8);
            GLD(Ag1 + kn, As[cur ^ 1] + 2048 + tid * 8);
            GLD(Wg0 + kn, Bs[cur ^ 1] + tid * 8);
            GLD(Wg1 + kn, Bs[cur ^ 1] + 2048 + tid * 8);
        }
        short8 af[4], bfr[4];
#pragma unroll
        for (int mi = 0; mi < 4; ++mi)
            af[mi] = *(const short8*)(As[cur] + (wm + mi * 16 + m15) * 32 + quad * 8);
#pragma unroll
        for (int ni = 0; ni < 4; ++ni)
            bfr[ni] = *(const short8*)(Bs[cur] + (wn + ni * 16 + m15) * 32 + quad * 8);
#pragma unroll
        for (int mi = 0; mi < 4; ++mi)
#pragma unroll
            for (int ni = 0; ni < 4; ++ni)
                acc[mi][ni] = __builtin_amdgcn_mfma_f32_16x16x32_bf16(
                    af[mi], bfr[ni], acc[mi][ni], 0, 0, 0);
        cur ^= 1;
    }
#pragma unroll
    for (int mi = 0; mi < 4; ++mi) {
        int mg = m0 + wm + mi * 16 + quad * 4;
#pragma unroll
        for (int ni = 0; ni < 4; ++ni) {
            int ng = n0 + wn + ni * 16 + m15;
            float bv = bias[ng];
#pragma unroll
            for (int r = 0; r < 4; ++r) {
                float v = acc[mi][ni][r] + bv;
                if (MODE == 0) {
                    ((float*)C0)[(size_t)(mg + r) * N + ng] = v;
                } else if (MODE == 1) {
                    ((__hip_bfloat16*)C0)[(size_t)(mg + r) * N + ng] = __float2bfloat16(v);
                } else if (MODE == 2) {
                    ((__hip_bfloat16*)C0)[(size_t)(mg + r) * N + ng] =
                        __float2bfloat16(fmaxf(v, 0.f));
                } else {  // QKV mixed: N=1536, segments of 512
                    int seg = ng >> 9;
                    int col = ng & 511;
                    if (seg == 0)
                        ((float*)C0)[(size_t)(mg + r) * D + col] = v;
                    else if (seg == 1)
                        ((__hip_bfloat16*)C1)[(size_t)(mg + r) * D + col] = __float2bfloat16(v);
                    else
                        ((__hip_bfloat16*)C2)[(size_t)(mg + r) * D + col] = __float2bfloat16(v);
                }
            }
        }
    }
}

// ------- PIPELINED 64x128 tile, BK=32, dbuf, f32 out — for small-grid W2 -----------
__global__ __launch_bounds__(256) void gemm_pipe_m64(const unsigned short* __restrict__ A,
                                                     const unsigned short* __restrict__ W,
                                                     const float* __restrict__ bias,
                                                     float* __restrict__ Cf,
                                                     int M, int N, int K) {
    __shared__ unsigned short As[2][64 * 32];
    __shared__ unsigned short Bs[2][128 * 32];
    const int tid = threadIdx.x;
    const int m0 = blockIdx.y * 64, n0 = blockIdx.x * 128;
    const int wave = tid >> 6, lane = tid & 63;
    const int quad = lane >> 4, m15 = lane & 15;
    const int srow = tid >> 2, scol = (tid & 3) * 8;
    f32x4 acc[8] = {};
    const unsigned short* Ag0 = A + (size_t)(m0 + srow) * K + scol;
    const unsigned short* Wg0 = W + (size_t)(n0 + srow) * K + scol;
    const unsigned short* Wg1 = W + (size_t)(n0 + srow + 64) * K + scol;
    // prologue
    if (tid < 256) {
        if (tid * 8 < 64 * 32) GLD(Ag0, As[0] + tid * 8);
    }
    GLD(Wg0, Bs[0] + tid * 8);
    GLD(Wg1, Bs[0] + 2048 + tid * 8);
    int cur = 0;
    for (int k0 = 0; k0 < K; k0 += 32) {
        __syncthreads();
        int kn = k0 + 32;
        if (kn < K) {
            if (tid * 8 < 64 * 32) GLD(Ag0 + kn, As[cur ^ 1] + tid * 8);
            GLD(Wg0 + kn, Bs[cur ^ 1] + tid * 8);
            GLD(Wg1 + kn, Bs[cur ^ 1] + 2048 + tid * 8);
        }
        short8 af = *(const short8*)(As[cur] + (wave * 16 + m15) * 32 + quad * 8);
#pragma unroll
        for (int ni = 0; ni < 8; ++ni) {
            short8 bfr = *(const short8*)(Bs[cur] + (ni * 16 + m15) * 32 + quad * 8);
            acc[ni] = __builtin_amdgcn_mfma_f32_16x16x32_bf16(af, bfr, acc[ni], 0, 0, 0);
        }
        cur ^= 1;
    }
    int mg = m0 + wave * 16 + quad * 4;
#pragma unroll
    for (int ni = 0; ni < 8; ++ni) {
        int ng = n0 + ni * 16 + m15;
        float bv = bias[ng];
#pragma unroll
        for (int r = 0; r < 4; ++r)
            Cf[(size_t)(mg + r) * N + ng] = acc[ni][r] + bv;
    }
}

// -------- M-score: block per (b,l); one WAVE per sampled row -----------------------
__global__ __launch_bounds__(256) void mscore_kernel(const float* __restrict__ q,
                                                     const __hip_bfloat16* __restrict__ kbf,
                                                     const int* __restrict__ idx,
                                                     float* __restrict__ Mv) {
    __shared__ float Sbuf[U][8];
    __shared__ int sidx[U];
    int bid = blockIdx.x;
    int b = bid & 1;
    int l = bid >> 1;
    int tid = threadIdx.x;
    int wave = tid >> 6, lane = tid & 63;
    if (tid < U) sidx[tid] = idx[l * U + tid];
    const float* qr = q + ((size_t)(b * LSEQ) + l) * D + lane * 8;
    float4 qa = *(const float4*)qr;
    float4 qb = *(const float4*)(qr + 4);
    __syncthreads();
    const unsigned short* kbase = (const unsigned short*)(kbf + (size_t)(b * LSEQ) * D);
    for (int t = wave; t < U; t += 4) {
        int kr = sidx[t];
        union { uint4 u; unsigned short s[8]; } kv;
        kv.u = *(const uint4*)(kbase + (size_t)kr * D + lane * 8);
        float p = qa.x * bits_to_f32(kv.s[0]) + qa.y * bits_to_f32(kv.s[1]) +
                  qa.z * bits_to_f32(kv.s[2]) + qa.w * bits_to_f32(kv.s[3]) +
                  qb.x * bits_to_f32(kv.s[4]) + qb.y * bits_to_f32(kv.s[5]) +
                  qb.z * bits_to_f32(kv.s[6]) + qb.w * bits_to_f32(kv.s[7]);
        p += __shfl_xor(p, 1);
        p += __shfl_xor(p, 2);
        p += __shfl_xor(p, 4);
        if ((lane & 7) == 0) Sbuf[t][lane >> 3] = p;
    }
    __syncthreads();
    if (tid < 8) {
        float mx = -INFINITY, sm = 0.f;
        for (int t = 0; t < U; ++t) {
            float v = Sbuf[t][tid];
            mx = fmaxf(mx, v);
            sm += v;
        }
        Mv[((size_t)b * H + tid) * LSEQ + l] = mx - sm / (float)LSEQ;
    }
}

// ------- top-k phase A: bitonic sort each 256-chunk desc, emit top-45 keys ---------
__global__ __launch_bounds__(256) void topk_chunk_kernel(const float* __restrict__ Mv,
                                                         unsigned long long* __restrict__ cand) {
    __shared__ unsigned long long sk[256];
    int blk = blockIdx.x;  // B*H*16
    int chunk = blk & 15, bh = blk >> 4;
    int tid = threadIdx.x;
    int gi = chunk * 256 + tid;
    sk[tid] = mkey(Mv[(size_t)bh * LSEQ + gi], gi);
    __syncthreads();
    for (int k = 2; k <= 256; k <<= 1) {
        for (int j = k >> 1; j > 0; j >>= 1) {
            int ixj = tid ^ j;
            if (ixj > tid) {
                unsigned long long a = sk[tid], b = sk[ixj];
                bool desc = ((tid & k) == 0);
                if (desc ? (a < b) : (a > b)) { sk[tid] = b; sk[ixj] = a; }
            }
            __syncthreads();
        }
    }
    if (tid < U) cand[((size_t)bh * 16 + chunk) * U + tid] = sk[tid];
}

// ------- top-k phase B: merge 16x45 candidates via 1024-wide bitonic sort ----------
__global__ __launch_bounds__(256) void topk_merge_kernel(const unsigned long long* __restrict__ cand,
                                                         int* __restrict__ top) {
    __shared__ unsigned long long sk[1024];
    int bh = blockIdx.x;
    int tid = threadIdx.x;
    for (int e = tid; e < 1024; e += 256)
        sk[e] = (e < 16 * U) ? cand[(size_t)bh * 16 * U + e] : 0ull;
    __syncthreads();
    for (int k = 2; k <= 1024; k <<= 1) {
        for (int j = k >> 1; j > 0; j >>= 1) {
            for (int e = tid; e < 1024; e += 256) {
                int ixj = e ^ j;
                if (ixj > e) {
                    unsigned long long a = sk[e], b = sk[ixj];
                    bool desc = ((e & k) == 0);
                    if (desc ? (a < b) : (a > b)) { sk[e] = b; sk[ixj] = a; }
                }
            }
            __syncthreads();
        }
    }
    if (tid < U)
        top[bh * U + tid] = (int)(0xFFFFFFFFu - (uint32_t)(sk[tid] & 0xFFFFFFFFu));
}

// ---------------- v mean: partial (128 blocks) + reduce ----------------
__global__ __launch_bounds__(256) void vmean_part(const __hip_bfloat16* __restrict__ v,
                                                  float* __restrict__ part) {
    int blk = blockIdx.x;  // B*H*8
    int seg = blk & 7, hh = (blk >> 3) & 7, b = blk >> 6;
    int e = threadIdx.x & 63, rg = threadIdx.x >> 6;
    const __hip_bfloat16* vp =
        v + ((size_t)(b * LSEQ) + seg * 512) * D + hh * 64 + e;
    float acc = 0.f;
    for (int r = rg; r < 512; r += 4) acc += __bfloat162float(vp[(size_t)r * D]);
    __shared__ float red[4][64];
    red[rg][e] = acc;
    __syncthreads();
    if (threadIdx.x < 64)
        part[(size_t)blk * 64 + threadIdx.x] =
            red[0][threadIdx.x] + red[1][threadIdx.x] + red[2][threadIdx.x] + red[3][threadIdx.x];
}

__global__ void vmean_reduce(const float* __restrict__ part, float* __restrict__ vm) {
    int gid = blockIdx.x * blockDim.x + threadIdx.x;
    if (gid >= B * H * E) return;
    int e = gid & 63, bh = gid >> 6;
    float acc = 0.f;
#pragma unroll
    for (int s = 0; s < 8; ++s) acc += part[((size_t)bh * 8 + s) * 64 + e];
    vm[gid] = acc / (float)LSEQ;
}

// ------- base[b] = vmeanAll[b] . Wo^T + bo (one wave per output n) -----------------
__global__ __launch_bounds__(256) void wo_base_kernel(const float* __restrict__ vm,
                                                      const unsigned short* __restrict__ wob,
                                                      const float* __restrict__ bo,
                                                      float* __restrict__ base) {
    int b = blockIdx.x >> 7;            // grid B*128
    int n = (blockIdx.x & 127) * 4 + (threadIdx.x >> 6);
    int lane = threadIdx.x & 63;
    const float* vmr = vm + (size_t)b * D + lane * 8;
    float4 va = *(const float4*)vmr;
    float4 vb = *(const float4*)(vmr + 4);
    union { uint4 u; unsigned short s[8]; } w;
    w.u = *(const uint4*)(wob + (size_t)n * D + lane * 8);
    float p = va.x * bits_to_f32(w.s[0]) + va.y * bits_to_f32(w.s[1]) +
              va.z * bits_to_f32(w.s[2]) + va.w * bits_to_f32(w.s[3]) +
              vb.x * bits_to_f32(w.s[4]) + vb.y * bits_to_f32(w.s[5]) +
              vb.z * bits_to_f32(w.s[6]) + vb.w * bits_to_f32(w.s[7]);
    for (int off = 32; off; off >>= 1) p += __shfl_xor(p, off);
    if (lane == 0) base[(size_t)b * D + n] = p + bo[n];
}

// ------- aout[r] = base[b] broadcast (float4) --------------------------------------
__global__ void bcast_base(const float* __restrict__ base, float* __restrict__ aout) {
    int i = blockIdx.x * blockDim.x + threadIdx.x;  // over ML*D/4
    if (i >= B * LSEQ * D / 4) return;
    int b = i >> 19;          // LSEQ*D/4 = 2^19
    int c4 = i & 127;         // D/4 = 128
    ((float4*)aout)[i] = *(const float4*)(base + (size_t)b * D + c4 * 4);
}

// ------- scatter correction: aout[top[bh,t]] += (upd - vmean_h) . Wo_h^T -----------
__global__ __launch_bounds__(256) void wo_corr_kernel(const float* __restrict__ updbuf,
                                                      const float* __restrict__ vm,
                                                      const unsigned short* __restrict__ wob,
                                                      const int* __restrict__ top,
                                                      float* __restrict__ aout) {
    __shared__ float dlt[E];
    int bid = blockIdx.x;  // B*H*U
    int t = bid % U;
    int bh = bid / U;
    int b = bh >> 3, hh = bh & 7;
    int tid = threadIdx.x;
    if (tid < E) dlt[tid] = updbuf[((size_t)bh * U + t) * E + tid] - vm[(size_t)bh * E + tid];
    __syncthreads();
    int r = top[bh * U + t];
    float* arow = aout + (size_t)(b * LSEQ + r) * D;
    for (int n = tid; n < D; n += 256) {
        const unsigned short* wr = wob + (size_t)n * D + hh * E;
        float acc = 0.f;
#pragma unroll
        for (int k2 = 0; k2 < E; ++k2) acc += dlt[k2] * bits_to_f32(wr[k2]);
        atomicAdd(arow + n, acc);
    }
}

// -------- flash-style MFMA attention partial: block = (slice, h, b) ----------------
__global__ __launch_bounds__(256) void attn_part(const float* __restrict__ q,
                                                 const __hip_bfloat16* __restrict__ kbf,
                                                 const __hip_bfloat16* __restrict__ vbf,
                                                 const int* __restrict__ top,
                                                 float* __restrict__ Opart,
                                                 float* __restrict__ msum) {
    __shared__ unsigned short Qs[48 * 72];
    __shared__ unsigned short Ks[SLICE * 72];
    __shared__ unsigned short Vs[SLICE * 68];
    __shared__ unsigned short Ps[48 * 136];
    __shared__ float mred[48][4];
    __shared__ float sred[48][4];
    const int slice = blockIdx.x, hh = blockIdx.y, b = blockIdx.z;
    const int bh = b * H + hh;
    const int tid = threadIdx.x;
    const int s0 = slice * SLICE;
    for (int i = tid; i < 48 * 64; i += 256) {
        int t = i >> 6, e = i & 63;
        float v = 0.f;
        if (t < U) {
            int r = top[bh * U + t];
            v = q[((size_t)(b * LSEQ) + r) * D + hh * E + e];
        }
        Qs[t * 72 + e] = bf16_bits(v);
    }
    {
        const uint4* src = (const uint4*)(kbf + ((size_t)(b * LSEQ) + s0) * D + hh * E);
        for (int i = tid; i < SLICE * 8; i += 256) {
            int r = i >> 3, c = i & 7;
            uint4 d = src[(size_t)r * 64 + c];
            *(uint4*)(Ks + r * 72 + c * 8) = d;
        }
    }
    {
        const uint2* src = (const uint2*)(vbf + ((size_t)(b * LSEQ) + s0) * D + hh * E);
        for (int i = tid; i < SLICE * 16; i += 256) {
            int r = i >> 4, c = i & 15;
            uint2 d = src[(size_t)r * 128 + c];
            *(uint2*)(Vs + r * 68 + c * 4) = d;
        }
    }
    __syncthreads();
    const int wave = tid >> 6, lane = tid & 63;
    const int quad = lane >> 4, m15 = lane & 15;
    const int wc = wave * 32;
    f32x4 acc[3][2] = {};
#pragma unroll
    for (int ks = 0; ks < 2; ++ks) {
        short8 af[3], bfr[2];
#pragma unroll
        for (int mt = 0; mt < 3; ++mt)
            af[mt] = *(const short8*)(Qs + (mt * 16 + m15) * 72 + ks * 32 + quad * 8);
#pragma unroll
        for (int nt = 0; nt < 2; ++nt)
            bfr[nt] = *(const short8*)(Ks + (wc + nt * 16 + m15) * 72 + ks * 32 + quad * 8);
#pragma unroll
        for (int mt = 0; mt < 3; ++mt)
#pragma unroll
            for (int nt = 0; nt < 2; ++nt)
                acc[mt][nt] = __builtin_amdgcn_mfma_f32_16x16x32_bf16(
                    af[mt], bfr[nt], acc[mt][nt], 0, 0, 0);
    }
    float sc[3][2][4];
#pragma unroll
    for (int mt = 0; mt < 3; ++mt)
#pragma unroll
        for (int nt = 0; nt < 2; ++nt)
#pragma unroll
            for (int r = 0; r < 4; ++r) sc[mt][nt][r] = acc[mt][nt][r] * 0.125f;
#pragma unroll
    for (int mt = 0; mt < 3; ++mt)
#pragma unroll
        for (int r = 0; r < 4; ++r) {
            float mv = fmaxf(sc[mt][0][r], sc[mt][1][r]);
            mv = fmaxf(mv, __shfl_xor(mv, 1));
            mv = fmaxf(mv, __shfl_xor(mv, 2));
            mv = fmaxf(mv, __shfl_xor(mv, 4));
            mv = fmaxf(mv, __shfl_xor(mv, 8));
            if (m15 == 0) mred[mt * 16 + quad * 4 + r][wave] = mv;
        }
    __syncthreads();
#pragma unroll
    for (int mt = 0; mt < 3; ++mt)
#pragma unroll
        for (int r = 0; r < 4; ++r) {
            int row = mt * 16 + quad * 4 + r;
            float ms = fmaxf(fmaxf(mred[row][0], mred[row][1]),
                             fmaxf(mred[row][2], mred[row][3]));
            float p0 = __expf(sc[mt][0][r] - ms);
            float p1 = __expf(sc[mt][1][r] - ms);
            float sv = p0 + p1;
            sv += __shfl_xor(sv, 1);
            sv += __shfl_xor(sv, 2);
            sv += __shfl_xor(sv, 4);
            sv += __shfl_xor(sv, 8);
            if (m15 == 0) sred[row][wave] = sv;
            Ps[row * 136 + wc + m15] = bf16_bits(p0);
            Ps[row * 136 + wc + 16 + m15] = bf16_bits(p1);
        }
    __syncthreads();
    if (tid < U) {
        float mm = fmaxf(fmaxf(mred[tid][0], mred[tid][1]),
                         fmaxf(mred[tid][2], mred[tid][3]));
        float ss = sred[tid][0] + sred[tid][1] + sred[tid][2] + sred[tid][3];
        size_t base = (((size_t)bh * NS + slice) * U + tid) * 2;
        msum[base] = mm;
        msum[base + 1] = ss;
    }
    f32x4 apv[3] = {};
#pragma unroll
    for (int ks = 0; ks < 4; ++ks) {
        short8 bv;
#pragma unroll
        for (int j = 0; j < 8; ++j)
            bv[j] = (short)Vs[(ks * 32 + quad * 8 + j) * 68 + wave * 16 + m15];
        short8 af2[3];
#pragma unroll
        for (int mt = 0; mt < 3; ++mt)
            af2[mt] = *(const short8*)(Ps + (mt * 16 + m15) * 136 + ks * 32 + quad * 8);
#pragma unroll
        for (int mt = 0; mt < 3; ++mt)
            apv[mt] = __builtin_amdgcn_mfma_f32_16x16x32_bf16(af2[mt], bv, apv[mt], 0, 0, 0);
    }
    size_t obase = ((size_t)bh * NS + slice) * U;
#pragma unroll
    for (int mt = 0; mt < 3; ++mt)
#pragma unroll
        for (int r = 0; r < 4; ++r) {
            int row = mt * 16 + quad * 4 + r;
            if (row < U)
                Opart[(obase + row) * 64 + wave * 16 + m15] = apv[mt][r];
        }
}

// -------- combine slice partials -> dense upd buffer (f32) -------------------------
__global__ __launch_bounds__(64) void attn_reduce(const float* __restrict__ Opart,
                                                  const float* __restrict__ msum,
                                                  float* __restrict__ updbuf) {
    int t = blockIdx.x % U;
    int bh = blockIdx.x / U;
    int lane = threadIdx.x;
    float m_s = -INFINITY, ss = 0.f;
    if (lane < NS) {
        size_t base = (((size_t)bh * NS + lane) * U + t) * 2;
        m_s = msum[base];
        ss = msum[base + 1];
    }
    float M = m_s;
    for (int off = 32; off; off >>= 1) M = fmaxf(M, __shfl_xor(M, off));
    float e_s = (lane < NS) ? __expf(m_s - M) : 0.f;
    float d = ss * e_s;
    for (int off = 32; off; off >>= 1) d += __shfl_xor(d, off);
    float acc = 0.f;
    for (int s = 0; s < NS; ++s) {
        float w = __shfl(e_s, s);
        acc += w * Opart[(((size_t)bh * NS + s) * U + t) * 64 + lane];
    }
    updbuf[((size_t)bh * U + t) * E + lane] = acc / d;
}

// -------- h = LayerNorm(h + a) * g + b, one wave per row, dual write f32+bf16 -------
__global__ __launch_bounds__(64) void add_ln_kernel(float* __restrict__ h,
                                                    const float* __restrict__ a,
                                                    const float* __restrict__ g,
                                                    const float* __restrict__ bb,
                                                    __hip_bfloat16* __restrict__ hbf) {
    int row = blockIdx.x;
    int lane = threadIdx.x;
    float* hp = h + (size_t)row * D;
    const float* ap = a + (size_t)row * D;
    float x[8];
    float sum = 0.f;
#pragma unroll
    for (int j = 0; j < 8; ++j) {
        x[j] = hp[lane + 64 * j] + ap[lane + 64 * j];
        sum += x[j];
    }
    for (int off = 32; off; off >>= 1) sum += __shfl_xor(sum, off);
    float mu = sum / (float)D;
    float vs = 0.f;
#pragma unroll
    for (int j = 0; j < 8; ++j) {
        float dd = x[j] - mu;
        vs += dd * dd;
    }
    for (int off = 32; off; off >>= 1) vs += __shfl_xor(vs, off);
    float inv = 1.f / sqrtf(vs / (float)D + EPSL);
#pragma unroll
    for (int j = 0; j < 8; ++j) {
        float o = (x[j] - mu) * inv * g[lane + 64 * j] + bb[lane + 64 * j];
        hp[lane + 64 * j] = o;
        hbf[(size_t)row * D + lane + 64 * j] = __float2bfloat16(o);
    }
}

// ---------------- final head ----------------
__global__ void final_kernel(const float* __restrict__ h, const float* __restrict__ Wf,
                             const float* __restrict__ bf, float* __restrict__ out) {
    int b = blockIdx.x;
    int lane = threadIdx.x;
    const float* hp = h + (size_t)b * LSEQ * D;
    float acc = 0.f;
    for (int j = lane; j < D; j += 64) acc += hp[j] * Wf[j];
    for (int off = 32; off; off >>= 1) acc += __shfl_xor(acc, off);
    if (lane == 0) out[b] = acc + bf[0];
}

extern "C" void kernel_launch(void* const* d_in, const int* in_sizes, int n_in,
                              void* d_out, int out_size, void* d_ws, size_t ws_size,
                              hipStream_t stream) {
    (void)in_sizes; (void)n_in; (void)out_size; (void)ws_size;
    const float* x   = (const float*)d_in[0];
    const float* We  = (const float*)d_in[1];
    const float* be  = (const float*)d_in[2];
    const float* cls = (const float*)d_in[3];
    const float* Wq  = (const float*)d_in[4];
    const float* bq  = (const float*)d_in[5];
    const float* Wk  = (const float*)d_in[6];
    const float* bk  = (const float*)d_in[7];
    const float* Wv  = (const float*)d_in[8];
    const float* bv  = (const float*)d_in[9];
    const float* Wo  = (const float*)d_in[10];
    const float* bo  = (const float*)d_in[11];
    const float* g1  = (const float*)d_in[12];
    const float* b1  = (const float*)d_in[13];
    const float* g2  = (const float*)d_in[14];
    const float* b2  = (const float*)d_in[15];
    const float* W1  = (const float*)d_in[16];
    const float* bf1 = (const float*)d_in[17];
    const float* W2  = (const float*)d_in[18];
    const float* bf2 = (const float*)d_in[19];
    const float* Wf  = (const float*)d_in[20];
    const float* bff = (const float*)d_in[21];
    float* out = (float*)d_out;

    float* ws = (float*)d_ws;
    const size_t NT = (size_t)B * LSEQ * D;  // 4,194,304
    float* h    = ws;                         // [0, NT)
    float* aout = ws + NT;                    // [NT, 2NT)
    float* q    = ws + 2 * NT;                // [2NT, 3NT)
    __hip_bfloat16* kbf    = (__hip_bfloat16*)(ws + NT);      // overlays aout
    __hip_bfloat16* y1_bf  = (__hip_bfloat16*)(ws + 2 * NT);  // overlays q post-attn
    __hip_bfloat16* v_bf   = (__hip_bfloat16*)(ws + 4 * NT);
    __hip_bfloat16* h_bf   = (__hip_bfloat16*)(ws + 5 * NT);
    float* Opart = ws + 3 * NT;
    float* msumb = Opart + (size_t)B * H * NS * U * 64;
    float* wpool = ws + 5 * NT + NT / 2;
    __hip_bfloat16* wqb = (__hip_bfloat16*)wpool;   // wq|wk|wv contiguous = packed QKV
    __hip_bfloat16* wkb = wqb + (size_t)D * D;
    __hip_bfloat16* wvb = wkb + (size_t)D * D;
    __hip_bfloat16* wob = wvb + (size_t)D * D;
    __hip_bfloat16* w1b = wob + (size_t)D * D;
    __hip_bfloat16* w2b = w1b + (size_t)DFF * D;
    float* after_w = wpool + ((size_t)4 * D * D + 2 * (size_t)DFF * D) / 2;
    float* Mbuf = after_w;
    int* idx    = (int*)(Mbuf + (size_t)B * H * LSEQ);
    int* top    = idx + LU;
    float* vm   = (float*)(top + B * H * U);
    float* vpart  = vm + (size_t)B * H * E;
    float* updbuf = vpart + (size_t)128 * 64;
    float* baseb  = updbuf + (size_t)B * H * U * 64;
    __hip_bfloat16* xbf  = (__hip_bfloat16*)(baseb + (size_t)B * D);   // B*LSEQ*F_IN
    __hip_bfloat16* webf = xbf + (size_t)B * LSEQ * F_IN;              // D*F_IN
    unsigned long long* cand =
        (unsigned long long*)(((uintptr_t)(webf + (size_t)D * F_IN) + 7) & ~(uintptr_t)7);
    float* qkvbias = (float*)(cand + (size_t)B * H * 16 * U);          // 1536 floats

    const int ML = B * LSEQ;  // 8192
    dim3 gD(D / 128, ML / 128);
    dim3 gQKV(3 * D / 128, ML / 128);   // 12 x 64 = 768 blocks
    dim3 gF1(DFF / 128, ML / 128);
    dim3 gW2(D / 128, ML / 64);         // 4 x 128 = 512 blocks (2/CU)
    const int CAST_N = 4 * (D * D / 4) + 2 * (DFF * D / 4);  // 786432
    const int CAST_TOT = CAST_N + 384;                       // + packed qkv bias

    // ---- embed as MFMA GEMM + posenc ----
    prep_embed_kernel<<<(B * LSEQ * F_IN / 4 + D * F_IN / 4 + 255) / 256, 256, 0, stream>>>(
        x, We, xbf, webf);
    gemm32<<<gD, 256, 0, stream>>>((const unsigned short*)xbf,
                                   (const unsigned short*)webf, be, aout, ML, D, F_IN);
    posenc_kernel<<<(B * LSEQ * D + 255) / 256, 256, 0, stream>>>(aout, cls, h, h_bf);

    for (int l = 0; l < NL; ++l) {
        cast_weights_kernel<<<(CAST_TOT + 255) / 256, 256, 0, stream>>>(
            Wq + (size_t)l * D * D, Wk + (size_t)l * D * D, Wv + (size_t)l * D * D,
            Wo + (size_t)l * D * D, W1 + (size_t)l * DFF * D, W2 + (size_t)l * D * DFF,
            bq + l * D, bk + l * D, bv + l * D,
            wqb, wkb, wvb, wob, w1b, w2b, qkvbias);

        // fused QKV GEMM: N=1536, 768 blocks (3/CU), pipelined
        gemm_pipe<3><<<gQKV, 256, 0, stream>>>((const unsigned short*)h_bf,
                                               (const unsigned short*)wqb, qkvbias,
                                               q, kbf, v_bf, ML, 3 * D, D);

        idx_kernel<<<(HALF_LU + 255) / 256, 256, 0, stream>>>(idx, l);
        mscore_kernel<<<B * LSEQ, 256, 0, stream>>>(q, kbf, idx, Mbuf);
        topk_chunk_kernel<<<B * H * 16, 256, 0, stream>>>(Mbuf, cand);
        topk_merge_kernel<<<B * H, 256, 0, stream>>>(cand, top);
        vmean_part<<<B * H * 8, 256, 0, stream>>>(v_bf, vpart);
        vmean_reduce<<<4, 256, 0, stream>>>(vpart, vm);
        wo_base_kernel<<<B * 128, 256, 0, stream>>>(vm, (const unsigned short*)wob,
                                                    bo + l * D, baseb);
        attn_part<<<dim3(NS, H, B), 256, 0, stream>>>(q, kbf, v_bf, top, Opart, msumb);
        attn_reduce<<<B * H * U, 64, 0, stream>>>(Opart, msumb, updbuf);
        bcast_base<<<(B * LSEQ * D / 4 + 255) / 256, 256, 0, stream>>>(baseb, aout);
        wo_corr_kernel<<<B * H * U, 256, 0, stream>>>(updbuf, vm,
                                                      (const unsigned short*)wob, top, aout);
        add_ln_kernel<<<ML, 64, 0, stream>>>(h, aout, g1 + l * D, b1 + l * D, h_bf);

        gemm_pipe<2><<<gF1, 256, 0, stream>>>((const unsigned short*)h_bf,
                                              (const unsigned short*)w1b, bf1 + l * DFF,
                                              y1_bf, nullptr, nullptr, ML, DFF, D);
        gemm_pipe_m64<<<gW2, 256, 0, stream>>>((const unsigned short*)y1_bf,
                                               (const unsigned short*)w2b, bf2 + l * D,
                                               aout, ML, D, DFF);
        add_ln_kernel<<<ML, 64, 0, stream>>>(h, aout, g2 + l * D, b2 + l * D, h_bf);
    }

    final_kernel<<<B, 64, 0, stream>>>(h, Wf, bff, out);
}

// Round 13
// 664.421 us; speedup vs baseline: 5.0494x; 1.0311x over previous
//
#include <hip/hip_runtime.h>
#include <hip/hip_bf16.h>
#include <math.h>
#include <stdint.h>

#define B 2
#define S 4095
#define LSEQ 4096
#define F_IN 32
#define D 512
#define H 8
#define E 64
#define DFF 2048
#define NL 2
#define U 45
#define EPSL 1e-5f
#define LU (LSEQ * U)
#define HALF_LU (LU / 2)
#define NS 32
#define SLICE 128

typedef __attribute__((ext_vector_type(8))) short short8;
typedef __attribute__((ext_vector_type(4))) float f32x4;

#define GLD(gp, lp)                                                            \
    __builtin_amdgcn_global_load_lds(                                          \
        (const __attribute__((address_space(1))) void*)(gp),                   \
        (__attribute__((address_space(3))) void*)(lp), 16, 0, 0)

__device__ __forceinline__ unsigned short bf16_bits(float f) {
    __hip_bfloat16 h = __float2bfloat16(f);
    return *(unsigned short*)&h;
}
__device__ __forceinline__ float bits_to_f32(unsigned short s) {
    union { uint32_t u; float f; } c;
    c.u = ((uint32_t)s) << 16;
    return c.f;
}
// monotone sortable key: desc key order == (value desc, index asc) — JAX top_k ties
__device__ __forceinline__ unsigned long long mkey(float v, int index) {
    uint32_t u = __float_as_uint(v);
    uint32_t mono = (u & 0x80000000u) ? ~u : (u | 0x80000000u);
    return ((unsigned long long)mono << 32) | (uint32_t)(0xFFFFFFFFu - (uint32_t)index);
}

// ---------------- Threefry-2x32 (20 rounds), exactly JAX's algorithm ----------------
__device__ __forceinline__ uint32_t rotl32(uint32_t x, int r) {
    return (x << r) | (x >> (32 - r));
}

__device__ void threefry2x32(uint32_t k0, uint32_t k1, uint32_t c0, uint32_t c1,
                             uint32_t& o0, uint32_t& o1) {
    uint32_t ks2 = k0 ^ k1 ^ 0x1BD11BDAu;
    uint32_t x0 = c0 + k0, x1 = c1 + k1;
    x0 += x1; x1 = rotl32(x1, 13); x1 ^= x0;
    x0 += x1; x1 = rotl32(x1, 15); x1 ^= x0;
    x0 += x1; x1 = rotl32(x1, 26); x1 ^= x0;
    x0 += x1; x1 = rotl32(x1, 6);  x1 ^= x0;
    x0 += k1; x1 += ks2 + 1u;
    x0 += x1; x1 = rotl32(x1, 17); x1 ^= x0;
    x0 += x1; x1 = rotl32(x1, 29); x1 ^= x0;
    x0 += x1; x1 = rotl32(x1, 16); x1 ^= x0;
    x0 += x1; x1 = rotl32(x1, 24); x1 ^= x0;
    x0 += ks2; x1 += k0 + 2u;
    x0 += x1; x1 = rotl32(x1, 13); x1 ^= x0;
    x0 += x1; x1 = rotl32(x1, 15); x1 ^= x0;
    x0 += x1; x1 = rotl32(x1, 26); x1 ^= x0;
    x0 += x1; x1 = rotl32(x1, 6);  x1 ^= x0;
    x0 += k0; x1 += k1 + 3u;
    x0 += x1; x1 = rotl32(x1, 17); x1 ^= x0;
    x0 += x1; x1 = rotl32(x1, 29); x1 ^= x0;
    x0 += x1; x1 = rotl32(x1, 16); x1 ^= x0;
    x0 += x1; x1 = rotl32(x1, 24); x1 ^= x0;
    x0 += k1; x1 += ks2 + 4u;
    x0 += x1; x1 = rotl32(x1, 13); x1 ^= x0;
    x0 += x1; x1 = rotl32(x1, 15); x1 ^= x0;
    x0 += x1; x1 = rotl32(x1, 26); x1 ^= x0;
    x0 += x1; x1 = rotl32(x1, 6);  x1 ^= x0;
    x0 += ks2; x1 += k0 + 5u;
    o0 = x0; o1 = x1;
}

__global__ void idx_kernel(int* __restrict__ idx, int layer) {
    int j = blockIdx.x * blockDim.x + threadIdx.x;
    if (j >= HALF_LU) return;
    uint32_t f0, f1, a0, a1, b0, b1, o0, o1;
    threefry2x32(0u, 42u, 0u, (uint32_t)layer, f0, f1);
    threefry2x32(f0, f1, 0u, 2u, a0, a1);
    threefry2x32(f0, f1, 1u, 3u, b0, b1);
    threefry2x32(a1, b1, (uint32_t)j, (uint32_t)(j + HALF_LU), o0, o1);
    idx[j] = (int)(o0 & 4095u);
    idx[j + HALF_LU] = (int)(o1 & 4095u);
    (void)a0; (void)b0;
}

// ------- prep: xbf[8192x32] (row l=0 zero, else x[b,l-1,:]) + We_bf cast -----------
__global__ void prep_embed_kernel(const float* __restrict__ x, const float* __restrict__ We,
                                  __hip_bfloat16* __restrict__ xbf,
                                  __hip_bfloat16* __restrict__ webf) {
    int u = blockIdx.x * blockDim.x + threadIdx.x;  // 4-element units
    const int NX = B * LSEQ * F_IN / 4;             // 65536
    const int NW = D * F_IN / 4;                    // 4096
    if (u < NX) {
        int e0 = u * 4;
        int i = e0 & 31;
        int l = (e0 >> 5) & (LSEQ - 1);
        int b = e0 >> 17;
        union { unsigned short s[4]; uint2 w; } o;
        if (l == 0) {
            o.s[0] = o.s[1] = o.s[2] = o.s[3] = 0;
        } else {
            float4 v = *(const float4*)(x + ((size_t)b * S + (l - 1)) * F_IN + i);
            o.s[0] = bf16_bits(v.x); o.s[1] = bf16_bits(v.y);
            o.s[2] = bf16_bits(v.z); o.s[3] = bf16_bits(v.w);
        }
        ((uint2*)xbf)[u] = o.w;
    } else if (u < NX + NW) {
        int w = u - NX;
        float4 v = ((const float4*)We)[w];
        union { unsigned short s[4]; uint2 w2; } o;
        o.s[0] = bf16_bits(v.x); o.s[1] = bf16_bits(v.y);
        o.s[2] = bf16_bits(v.z); o.s[3] = bf16_bits(v.w);
        ((uint2*)webf)[w] = o.w2;
    }
}

// ------- posenc: h = (l==0 ? cls : emb) + PE; dual write f32 + bf16 ----------------
__global__ void posenc_kernel(const float* __restrict__ emb, const float* __restrict__ cls,
                              float* __restrict__ h, __hip_bfloat16* __restrict__ hbf) {
    int gid = blockIdx.x * blockDim.x + threadIdx.x;
    if (gid >= B * LSEQ * D) return;
    int d = gid % D;
    int l = (gid / D) % LSEQ;
    float v = (l == 0) ? cls[d] : emb[gid];
    int i = d >> 1;
    float divv = expf((float)(2 * i) * (float)(-9.210340371976184 / 512.0));
    float ang = (float)l * divv;
    v += (d & 1) ? cosf(ang) : sinf(ang);
    h[gid] = v;
    hbf[gid] = __float2bfloat16(v);
}

// ------- fused per-layer weight cast + packed qkv bias -----------------------------
__global__ void cast_weights_kernel(const float* __restrict__ Wq_l,
                                    const float* __restrict__ Wk_l,
                                    const float* __restrict__ Wv_l,
                                    const float* __restrict__ Wo_l,
                                    const float* __restrict__ W1_l,
                                    const float* __restrict__ W2_l,
                                    const float* __restrict__ bq_l,
                                    const float* __restrict__ bk_l,
                                    const float* __restrict__ bv_l,
                                    __hip_bfloat16* __restrict__ wqb,
                                    __hip_bfloat16* __restrict__ wkb,
                                    __hip_bfloat16* __restrict__ wvb,
                                    __hip_bfloat16* __restrict__ wob,
                                    __hip_bfloat16* __restrict__ w1b,
                                    __hip_bfloat16* __restrict__ w2b,
                                    float* __restrict__ qkvbias) {
    const int SDD = D * D / 4;       // 65536
    const int SFD = DFF * D / 4;     // 262144
    const int CAST_N = 4 * SDD + 2 * SFD;
    int u = blockIdx.x * blockDim.x + threadIdx.x;
    if (u >= CAST_N) {
        int j = u - CAST_N;          // 0..383, 4-float units over 1536 bias
        if (j < 384) {
            int seg = (j * 4) >> 9;  // 0:q 1:k 2:v
            int off = (j * 4) & 511;
            const float* src = (seg == 0) ? bq_l : (seg == 1) ? bk_l : bv_l;
            *(float4*)(qkvbias + j * 4) = *(const float4*)(src + off);
        }
        return;
    }
    const float* src;
    __hip_bfloat16* dst;
    int off;
    if (u < SDD) { src = Wq_l; dst = wqb; off = u; }
    else if (u < 2 * SDD) { src = Wk_l; dst = wkb; off = u - SDD; }
    else if (u < 3 * SDD) { src = Wv_l; dst = wvb; off = u - 2 * SDD; }
    else if (u < 4 * SDD) { src = Wo_l; dst = wob; off = u - 3 * SDD; }
    else if (u < 4 * SDD + SFD) { src = W1_l; dst = w1b; off = u - 4 * SDD; }
    else { src = W2_l; dst = w2b; off = u - 4 * SDD - SFD; }
    float4 v = ((const float4*)src)[off];
    union { unsigned short s[4]; uint2 w; } o;
    o.s[0] = bf16_bits(v.x); o.s[1] = bf16_bits(v.y);
    o.s[2] = bf16_bits(v.z); o.s[3] = bf16_bits(v.w);
    ((uint2*)dst)[off] = o.w;
}

// ------- bf16 MFMA GEMM, BK=32 (for K=32 embed) ------------------------------------
__global__ __launch_bounds__(256) void gemm32(const unsigned short* __restrict__ A,
                                              const unsigned short* __restrict__ W,
                                              const float* __restrict__ bias,
                                              float* __restrict__ Cf,
                                              int M, int N, int K) {
    __shared__ unsigned short lds[2 * 128 * 32];
    unsigned short* As = lds;
    unsigned short* Bs = lds + 128 * 32;
    const int tid = threadIdx.x;
    const int m0 = blockIdx.y * 128, n0 = blockIdx.x * 128;
    const int wave = tid >> 6, lane = tid & 63;
    const int wm = (wave >> 1) * 64, wn = (wave & 1) * 64;
    const int quad = lane >> 4, m15 = lane & 15;
    const int srow = tid >> 2, scol = (tid & 3) * 8;
    f32x4 acc[4][4] = {};
    const unsigned short* Ag0 = A + (size_t)(m0 + srow) * K + scol;
    const unsigned short* Ag1 = A + (size_t)(m0 + srow + 64) * K + scol;
    const unsigned short* Wg0 = W + (size_t)(n0 + srow) * K + scol;
    const unsigned short* Wg1 = W + (size_t)(n0 + srow + 64) * K + scol;
    for (int k0 = 0; k0 < K; k0 += 32) {
        __syncthreads();
        GLD(Ag0 + k0, As + tid * 8);
        GLD(Ag1 + k0, As + 2048 + tid * 8);
        GLD(Wg0 + k0, Bs + tid * 8);
        GLD(Wg1 + k0, Bs + 2048 + tid * 8);
        __syncthreads();
        short8 af[4], bfr[4];
#pragma unroll
        for (int mi = 0; mi < 4; ++mi)
            af[mi] = *(const short8*)(As + (wm + mi * 16 + m15) * 32 + quad * 8);
#pragma unroll
        for (int ni = 0; ni < 4; ++ni)
            bfr[ni] = *(const short8*)(Bs + (wn + ni * 16 + m15) * 32 + quad * 8);
#pragma unroll
        for (int mi = 0; mi < 4; ++mi)
#pragma unroll
            for (int ni = 0; ni < 4; ++ni)
                acc[mi][ni] = __builtin_amdgcn_mfma_f32_16x16x32_bf16(
                    af[mi], bfr[ni], acc[mi][ni], 0, 0, 0);
    }
#pragma unroll
    for (int mi = 0; mi < 4; ++mi) {
        int mg = m0 + wm + mi * 16 + quad * 4;
#pragma unroll
        for (int ni = 0; ni < 4; ++ni) {
            int ng = n0 + wn + ni * 16 + m15;
            float bv = bias[ng];
#pragma unroll
            for (int r = 0; r < 4; ++r)
                Cf[(size_t)(mg + r) * N + ng] = acc[mi][ni][r] + bv;
        }
    }
}

// ------- PIPELINED bf16 MFMA GEMM, 128x128 tile, BK=32, dbuf, XCD-swizzled ---------
// 1D grid; all n-tiles of one m-tile land on the same XCD (round-robin dispatch).
// MODE 0: f32 out; 1: bf16 out; 2: relu->bf16; 3: QKV-mixed (seg0 f32 q, seg1/2 bf16)
template <int MODE>
__global__ __launch_bounds__(256) void gemm_pipe(const unsigned short* __restrict__ A,
                                                 const unsigned short* __restrict__ W,
                                                 const float* __restrict__ bias,
                                                 void* __restrict__ C0,
                                                 void* __restrict__ C1,
                                                 void* __restrict__ C2,
                                                 int M, int N, int K, int NBN) {
    __shared__ unsigned short As[2][128 * 32];
    __shared__ unsigned short Bs[2][128 * 32];
    const int tid = threadIdx.x;
    const int NBM = M >> 7;
    const int bid = blockIdx.x;
    const int xcd = bid & 7, local = bid >> 3;
    const int m_t = xcd * (NBM >> 3) + local / NBN;
    const int n_t = local % NBN;
    const int m0 = m_t * 128, n0 = n_t * 128;
    const int wave = tid >> 6, lane = tid & 63;
    const int wm = (wave >> 1) * 64, wn = (wave & 1) * 64;
    const int quad = lane >> 4, m15 = lane & 15;
    const int srow = tid >> 2, scol = (tid & 3) * 8;
    f32x4 acc[4][4] = {};
    const unsigned short* Ag0 = A + (size_t)(m0 + srow) * K + scol;
    const unsigned short* Ag1 = A + (size_t)(m0 + srow + 64) * K + scol;
    const unsigned short* Wg0 = W + (size_t)(n0 + srow) * K + scol;
    const unsigned short* Wg1 = W + (size_t)(n0 + srow + 64) * K + scol;
    GLD(Ag0, As[0] + tid * 8);
    GLD(Ag1, As[0] + 2048 + tid * 8);
    GLD(Wg0, Bs[0] + tid * 8);
    GLD(Wg1, Bs[0] + 2048 + tid * 8);
    int cur = 0;
    for (int k0 = 0; k0 < K; k0 += 32) {
        __syncthreads();
        int kn = k0 + 32;
        if (kn < K) {
            GLD(Ag0 + kn, As[cur ^ 1] + tid * 8);
            GLD(Ag1 + kn, As[cur ^ 1] + 2048 + tid * 8);
            GLD(Wg0 + kn, Bs[cur ^ 1] + tid * 8);
            GLD(Wg1 + kn, Bs[cur ^ 1] + 2048 + tid * 8);
        }
        short8 af[4], bfr[4];
#pragma unroll
        for (int mi = 0; mi < 4; ++mi)
            af[mi] = *(const short8*)(As[cur] + (wm + mi * 16 + m15) * 32 + quad * 8);
#pragma unroll
        for (int ni = 0; ni < 4; ++ni)
            bfr[ni] = *(const short8*)(Bs[cur] + (wn + ni * 16 + m15) * 32 + quad * 8);
#pragma unroll
        for (int mi = 0; mi < 4; ++mi)
#pragma unroll
            for (int ni = 0; ni < 4; ++ni)
                acc[mi][ni] = __builtin_amdgcn_mfma_f32_16x16x32_bf16(
                    af[mi], bfr[ni], acc[mi][ni], 0, 0, 0);
        cur ^= 1;
    }
#pragma unroll
    for (int mi = 0; mi < 4; ++mi) {
        int mg = m0 + wm + mi * 16 + quad * 4;
#pragma unroll
        for (int ni = 0; ni < 4; ++ni) {
            int ng = n0 + wn + ni * 16 + m15;
            float bv = bias[ng];
#pragma unroll
            for (int r = 0; r < 4; ++r) {
                float v = acc[mi][ni][r] + bv;
                if (MODE == 0) {
                    ((float*)C0)[(size_t)(mg + r) * N + ng] = v;
                } else if (MODE == 1) {
                    ((__hip_bfloat16*)C0)[(size_t)(mg + r) * N + ng] = __float2bfloat16(v);
                } else if (MODE == 2) {
                    ((__hip_bfloat16*)C0)[(size_t)(mg + r) * N + ng] =
                        __float2bfloat16(fmaxf(v, 0.f));
                } else {  // QKV mixed: N=1536, segments of 512
                    int seg = ng >> 9;
                    int col = ng & 511;
                    if (seg == 0)
                        ((float*)C0)[(size_t)(mg + r) * D + col] = v;
                    else if (seg == 1)
                        ((__hip_bfloat16*)C1)[(size_t)(mg + r) * D + col] = __float2bfloat16(v);
                    else
                        ((__hip_bfloat16*)C2)[(size_t)(mg + r) * D + col] = __float2bfloat16(v);
                }
            }
        }
    }
}

// ------- 64x128 tile, BK=64, f32 out, XCD-swizzled (non-pipelined; pipe regressed) -
__global__ __launch_bounds__(256) void gemm64_m64(const unsigned short* __restrict__ A,
                                                  const unsigned short* __restrict__ W,
                                                  const float* __restrict__ bias,
                                                  float* __restrict__ Cf,
                                                  int M, int N, int K, int NBN) {
    __shared__ unsigned short As[2][64 * 32];
    __shared__ unsigned short Bs[2][128 * 32];
    const int tid = threadIdx.x;
    const int NBM = M >> 6;
    const int bid = blockIdx.x;
    const int xcd = bid & 7, local = bid >> 3;
    const int m_t = xcd * (NBM >> 3) + local / NBN;
    const int n_t = local % NBN;
    const int m0 = m_t * 64, n0 = n_t * 128;
    const int wave = tid >> 6, lane = tid & 63;
    const int quad = lane >> 4, m15 = lane & 15;
    const int srow = tid >> 2, scol = (tid & 3) * 8;
    f32x4 acc[8] = {};
    const unsigned short* Ag0 = A + (size_t)(m0 + srow) * K + scol;
    const unsigned short* Wg0 = W + (size_t)(n0 + srow) * K + scol;
    const unsigned short* Wg1 = W + (size_t)(n0 + srow + 64) * K + scol;
    for (int k0 = 0; k0 < K; k0 += 64) {
        __syncthreads();
        if (tid * 8 < 64 * 32) {
            GLD(Ag0 + k0, As[0] + tid * 8);
            GLD(Ag0 + k0 + 32, As[1] + tid * 8);
        }
        GLD(Wg0 + k0, Bs[0] + tid * 8);
        GLD(Wg1 + k0, Bs[0] + 2048 + tid * 8);
        GLD(Wg0 + k0 + 32, Bs[1] + tid * 8);
        GLD(Wg1 + k0 + 32, Bs[1] + 2048 + tid * 8);
        __syncthreads();
#pragma unroll
        for (int ks = 0; ks < 2; ++ks) {
            short8 af = *(const short8*)(As[ks] + (wave * 16 + m15) * 32 + quad * 8);
#pragma unroll
            for (int ni = 0; ni < 8; ++ni) {
                short8 bfr = *(const short8*)(Bs[ks] + (ni * 16 + m15) * 32 + quad * 8);
                acc[ni] = __builtin_amdgcn_mfma_f32_16x16x32_bf16(af, bfr, acc[ni], 0, 0, 0);
            }
        }
    }
    int mg = m0 + wave * 16 + quad * 4;
#pragma unroll
    for (int ni = 0; ni < 8; ++ni) {
        int ng = n0 + ni * 16 + m15;
        float bv = bias[ng];
#pragma unroll
        for (int r = 0; r < 4; ++r)
            Cf[(size_t)(mg + r) * N + ng] = acc[ni][r] + bv;
    }
}

// -------- M-score: block per (b,l); one WAVE per sampled row -----------------------
__global__ __launch_bounds__(256) void mscore_kernel(const float* __restrict__ q,
                                                     const __hip_bfloat16* __restrict__ kbf,
                                                     const int* __restrict__ idx,
                                                     float* __restrict__ Mv) {
    __shared__ float Sbuf[U][8];
    __shared__ int sidx[U];
    int bid = blockIdx.x;
    int b = bid & 1;
    int l = bid >> 1;
    int tid = threadIdx.x;
    int wave = tid >> 6, lane = tid & 63;
    if (tid < U) sidx[tid] = idx[l * U + tid];
    const float* qr = q + ((size_t)(b * LSEQ) + l) * D + lane * 8;
    float4 qa = *(const float4*)qr;
    float4 qb = *(const float4*)(qr + 4);
    __syncthreads();
    const unsigned short* kbase = (const unsigned short*)(kbf + (size_t)(b * LSEQ) * D);
    for (int t = wave; t < U; t += 4) {
        int kr = sidx[t];
        union { uint4 u; unsigned short s[8]; } kv;
        kv.u = *(const uint4*)(kbase + (size_t)kr * D + lane * 8);
        float p = qa.x * bits_to_f32(kv.s[0]) + qa.y * bits_to_f32(kv.s[1]) +
                  qa.z * bits_to_f32(kv.s[2]) + qa.w * bits_to_f32(kv.s[3]) +
                  qb.x * bits_to_f32(kv.s[4]) + qb.y * bits_to_f32(kv.s[5]) +
                  qb.z * bits_to_f32(kv.s[6]) + qb.w * bits_to_f32(kv.s[7]);
        p += __shfl_xor(p, 1);
        p += __shfl_xor(p, 2);
        p += __shfl_xor(p, 4);
        if ((lane & 7) == 0) Sbuf[t][lane >> 3] = p;
    }
    __syncthreads();
    if (tid < 8) {
        float mx = -INFINITY, sm = 0.f;
        for (int t = 0; t < U; ++t) {
            float v = Sbuf[t][tid];
            mx = fmaxf(mx, v);
            sm += v;
        }
        Mv[((size_t)b * H + tid) * LSEQ + l] = mx - sm / (float)LSEQ;
    }
}

// ------- top-k phase A: bitonic sort each 256-chunk desc, emit top-45 keys ---------
__global__ __launch_bounds__(256) void topk_chunk_kernel(const float* __restrict__ Mv,
                                                         unsigned long long* __restrict__ cand) {
    __shared__ unsigned long long sk[256];
    int blk = blockIdx.x;  // B*H*16
    int chunk = blk & 15, bh = blk >> 4;
    int tid = threadIdx.x;
    int gi = chunk * 256 + tid;
    sk[tid] = mkey(Mv[(size_t)bh * LSEQ + gi], gi);
    __syncthreads();
    for (int k = 2; k <= 256; k <<= 1) {
        for (int j = k >> 1; j > 0; j >>= 1) {
            int ixj = tid ^ j;
            if (ixj > tid) {
                unsigned long long a = sk[tid], b = sk[ixj];
                bool desc = ((tid & k) == 0);
                if (desc ? (a < b) : (a > b)) { sk[tid] = b; sk[ixj] = a; }
            }
            __syncthreads();
        }
    }
    if (tid < U) cand[((size_t)bh * 16 + chunk) * U + tid] = sk[tid];
}

// ------- top-k phase B: merge 16x45 candidates via 1024-wide bitonic sort ----------
__global__ __launch_bounds__(256) void topk_merge_kernel(const unsigned long long* __restrict__ cand,
                                                         int* __restrict__ top) {
    __shared__ unsigned long long sk[1024];
    int bh = blockIdx.x;
    int tid = threadIdx.x;
    for (int e = tid; e < 1024; e += 256)
        sk[e] = (e < 16 * U) ? cand[(size_t)bh * 16 * U + e] : 0ull;
    __syncthreads();
    for (int k = 2; k <= 1024; k <<= 1) {
        for (int j = k >> 1; j > 0; j >>= 1) {
            for (int e = tid; e < 1024; e += 256) {
                int ixj = e ^ j;
                if (ixj > e) {
                    unsigned long long a = sk[e], b = sk[ixj];
                    bool desc = ((e & k) == 0);
                    if (desc ? (a < b) : (a > b)) { sk[e] = b; sk[ixj] = a; }
                }
            }
            __syncthreads();
        }
    }
    if (tid < U)
        top[bh * U + tid] = (int)(0xFFFFFFFFu - (uint32_t)(sk[tid] & 0xFFFFFFFFu));
}

// ---------------- v mean: partial (128 blocks) + reduce ----------------
__global__ __launch_bounds__(256) void vmean_part(const __hip_bfloat16* __restrict__ v,
                                                  float* __restrict__ part) {
    int blk = blockIdx.x;  // B*H*8
    int seg = blk & 7, hh = (blk >> 3) & 7, b = blk >> 6;
    int e = threadIdx.x & 63, rg = threadIdx.x >> 6;
    const __hip_bfloat16* vp =
        v + ((size_t)(b * LSEQ) + seg * 512) * D + hh * 64 + e;
    float acc = 0.f;
    for (int r = rg; r < 512; r += 4) acc += __bfloat162float(vp[(size_t)r * D]);
    __shared__ float red[4][64];
    red[rg][e] = acc;
    __syncthreads();
    if (threadIdx.x < 64)
        part[(size_t)blk * 64 + threadIdx.x] =
            red[0][threadIdx.x] + red[1][threadIdx.x] + red[2][threadIdx.x] + red[3][threadIdx.x];
}

__global__ void vmean_reduce(const float* __restrict__ part, float* __restrict__ vm) {
    int gid = blockIdx.x * blockDim.x + threadIdx.x;
    if (gid >= B * H * E) return;
    int e = gid & 63, bh = gid >> 6;
    float acc = 0.f;
#pragma unroll
    for (int s = 0; s < 8; ++s) acc += part[((size_t)bh * 8 + s) * 64 + e];
    vm[gid] = acc / (float)LSEQ;
}

// ------- base[b] = vmeanAll[b] . Wo^T + bo (one wave per output n) -----------------
__global__ __launch_bounds__(256) void wo_base_kernel(const float* __restrict__ vm,
                                                      const unsigned short* __restrict__ wob,
                                                      const float* __restrict__ bo,
                                                      float* __restrict__ base) {
    int b = blockIdx.x >> 7;            // grid B*128
    int n = (blockIdx.x & 127) * 4 + (threadIdx.x >> 6);
    int lane = threadIdx.x & 63;
    const float* vmr = vm + (size_t)b * D + lane * 8;
    float4 va = *(const float4*)vmr;
    float4 vb = *(const float4*)(vmr + 4);
    union { uint4 u; unsigned short s[8]; } w;
    w.u = *(const uint4*)(wob + (size_t)n * D + lane * 8);
    float p = va.x * bits_to_f32(w.s[0]) + va.y * bits_to_f32(w.s[1]) +
              va.z * bits_to_f32(w.s[2]) + va.w * bits_to_f32(w.s[3]) +
              vb.x * bits_to_f32(w.s[4]) + vb.y * bits_to_f32(w.s[5]) +
              vb.z * bits_to_f32(w.s[6]) + vb.w * bits_to_f32(w.s[7]);
    for (int off = 32; off; off >>= 1) p += __shfl_xor(p, off);
    if (lane == 0) base[(size_t)b * D + n] = p + bo[n];
}

// ------- aout[r] = base[b] broadcast (float4) --------------------------------------
__global__ void bcast_base(const float* __restrict__ base, float* __restrict__ aout) {
    int i = blockIdx.x * blockDim.x + threadIdx.x;  // over ML*D/4
    if (i >= B * LSEQ * D / 4) return;
    int b = i >> 19;          // LSEQ*D/4 = 2^19
    int c4 = i & 127;         // D/4 = 128
    ((float4*)aout)[i] = *(const float4*)(base + (size_t)b * D + c4 * 4);
}

// ------- scatter correction: aout[top[bh,t]] += (upd - vmean_h) . Wo_h^T -----------
__global__ __launch_bounds__(256) void wo_corr_kernel(const float* __restrict__ updbuf,
                                                      const float* __restrict__ vm,
                                                      const unsigned short* __restrict__ wob,
                                                      const int* __restrict__ top,
                                                      float* __restrict__ aout) {
    __shared__ float dlt[E];
    int bid = blockIdx.x;  // B*H*U
    int t = bid % U;
    int bh = bid / U;
    int b = bh >> 3, hh = bh & 7;
    int tid = threadIdx.x;
    if (tid < E) dlt[tid] = updbuf[((size_t)bh * U + t) * E + tid] - vm[(size_t)bh * E + tid];
    __syncthreads();
    int r = top[bh * U + t];
    float* arow = aout + (size_t)(b * LSEQ + r) * D;
    for (int n = tid; n < D; n += 256) {
        const unsigned short* wr = wob + (size_t)n * D + hh * E;
        float acc = 0.f;
#pragma unroll
        for (int k2 = 0; k2 < E; ++k2) acc += dlt[k2] * bits_to_f32(wr[k2]);
        atomicAdd(arow + n, acc);
    }
}

// -------- flash-style MFMA attention partial: block = (slice, h, b) ----------------
__global__ __launch_bounds__(256) void attn_part(const float* __restrict__ q,
                                                 const __hip_bfloat16* __restrict__ kbf,
                                                 const __hip_bfloat16* __restrict__ vbf,
                                                 const int* __restrict__ top,
                                                 float* __restrict__ Opart,
                                                 float* __restrict__ msum) {
    __shared__ unsigned short Qs[48 * 72];
    __shared__ unsigned short Ks[SLICE * 72];
    __shared__ unsigned short Vs[SLICE * 68];
    __shared__ unsigned short Ps[48 * 136];
    __shared__ float mred[48][4];
    __shared__ float sred[48][4];
    const int slice = blockIdx.x, hh = blockIdx.y, b = blockIdx.z;
    const int bh = b * H + hh;
    const int tid = threadIdx.x;
    const int s0 = slice * SLICE;
    for (int i = tid; i < 48 * 64; i += 256) {
        int t = i >> 6, e = i & 63;
        float v = 0.f;
        if (t < U) {
            int r = top[bh * U + t];
            v = q[((size_t)(b * LSEQ) + r) * D + hh * E + e];
        }
        Qs[t * 72 + e] = bf16_bits(v);
    }
    {
        const uint4* src = (const uint4*)(kbf + ((size_t)(b * LSEQ) + s0) * D + hh * E);
        for (int i = tid; i < SLICE * 8; i += 256) {
            int r = i >> 3, c = i & 7;
            uint4 d = src[(size_t)r * 64 + c];
            *(uint4*)(Ks + r * 72 + c * 8) = d;
        }
    }
    {
        const uint2* src = (const uint2*)(vbf + ((size_t)(b * LSEQ) + s0) * D + hh * E);
        for (int i = tid; i < SLICE * 16; i += 256) {
            int r = i >> 4, c = i & 15;
            uint2 d = src[(size_t)r * 128 + c];
            *(uint2*)(Vs + r * 68 + c * 4) = d;
        }
    }
    __syncthreads();
    const int wave = tid >> 6, lane = tid & 63;
    const int quad = lane >> 4, m15 = lane & 15;
    const int wc = wave * 32;
    f32x4 acc[3][2] = {};
#pragma unroll
    for (int ks = 0; ks < 2; ++ks) {
        short8 af[3], bfr[2];
#pragma unroll
        for (int mt = 0; mt < 3; ++mt)
            af[mt] = *(const short8*)(Qs + (mt * 16 + m15) * 72 + ks * 32 + quad * 8);
#pragma unroll
        for (int nt = 0; nt < 2; ++nt)
            bfr[nt] = *(const short8*)(Ks + (wc + nt * 16 + m15) * 72 + ks * 32 + quad * 8);
#pragma unroll
        for (int mt = 0; mt < 3; ++mt)
#pragma unroll
            for (int nt = 0; nt < 2; ++nt)
                acc[mt][nt] = __builtin_amdgcn_mfma_f32_16x16x32_bf16(
                    af[mt], bfr[nt], acc[mt][nt], 0, 0, 0);
    }
    float sc[3][2][4];
#pragma unroll
    for (int mt = 0; mt < 3; ++mt)
#pragma unroll
        for (int nt = 0; nt < 2; ++nt)
#pragma unroll
            for (int r = 0; r < 4; ++r) sc[mt][nt][r] = acc[mt][nt][r] * 0.125f;
#pragma unroll
    for (int mt = 0; mt < 3; ++mt)
#pragma unroll
        for (int r = 0; r < 4; ++r) {
            float mv = fmaxf(sc[mt][0][r], sc[mt][1][r]);
            mv = fmaxf(mv, __shfl_xor(mv, 1));
            mv = fmaxf(mv, __shfl_xor(mv, 2));
            mv = fmaxf(mv, __shfl_xor(mv, 4));
            mv = fmaxf(mv, __shfl_xor(mv, 8));
            if (m15 == 0) mred[mt * 16 + quad * 4 + r][wave] = mv;
        }
    __syncthreads();
#pragma unroll
    for (int mt = 0; mt < 3; ++mt)
#pragma unroll
        for (int r = 0; r < 4; ++r) {
            int row = mt * 16 + quad * 4 + r;
            float ms = fmaxf(fmaxf(mred[row][0], mred[row][1]),
                             fmaxf(mred[row][2], mred[row][3]));
            float p0 = __expf(sc[mt][0][r] - ms);
            float p1 = __expf(sc[mt][1][r] - ms);
            float sv = p0 + p1;
            sv += __shfl_xor(sv, 1);
            sv += __shfl_xor(sv, 2);
            sv += __shfl_xor(sv, 4);
            sv += __shfl_xor(sv, 8);
            if (m15 == 0) sred[row][wave] = sv;
            Ps[row * 136 + wc + m15] = bf16_bits(p0);
            Ps[row * 136 + wc + 16 + m15] = bf16_bits(p1);
        }
    __syncthreads();
    if (tid < U) {
        float mm = fmaxf(fmaxf(mred[tid][0], mred[tid][1]),
                         fmaxf(mred[tid][2], mred[tid][3]));
        float ss = sred[tid][0] + sred[tid][1] + sred[tid][2] + sred[tid][3];
        size_t base = (((size_t)bh * NS + slice) * U + tid) * 2;
        msum[base] = mm;
        msum[base + 1] = ss;
    }
    f32x4 apv[3] = {};
#pragma unroll
    for (int ks = 0; ks < 4; ++ks) {
        short8 bv;
#pragma unroll
        for (int j = 0; j < 8; ++j)
            bv[j] = (short)Vs[(ks * 32 + quad * 8 + j) * 68 + wave * 16 + m15];
        short8 af2[3];
#pragma unroll
        for (int mt = 0; mt < 3; ++mt)
            af2[mt] = *(const short8*)(Ps + (mt * 16 + m15) * 136 + ks * 32 + quad * 8);
#pragma unroll
        for (int mt = 0; mt < 3; ++mt)
            apv[mt] = __builtin_amdgcn_mfma_f32_16x16x32_bf16(af2[mt], bv, apv[mt], 0, 0, 0);
    }
    size_t obase = ((size_t)bh * NS + slice) * U;
#pragma unroll
    for (int mt = 0; mt < 3; ++mt)
#pragma unroll
        for (int r = 0; r < 4; ++r) {
            int row = mt * 16 + quad * 4 + r;
            if (row < U)
                Opart[(obase + row) * 64 + wave * 16 + m15] = apv[mt][r];
        }
}

// -------- combine slice partials -> dense upd buffer (f32) -------------------------
__global__ __launch_bounds__(64) void attn_reduce(const float* __restrict__ Opart,
                                                  const float* __restrict__ msum,
                                                  float* __restrict__ updbuf) {
    int t = blockIdx.x % U;
    int bh = blockIdx.x / U;
    int lane = threadIdx.x;
    float m_s = -INFINITY, ss = 0.f;
    if (lane < NS) {
        size_t base = (((size_t)bh * NS + lane) * U + t) * 2;
        m_s = msum[base];
        ss = msum[base + 1];
    }
    float M = m_s;
    for (int off = 32; off; off >>= 1) M = fmaxf(M, __shfl_xor(M, off));
    float e_s = (lane < NS) ? __expf(m_s - M) : 0.f;
    float d = ss * e_s;
    for (int off = 32; off; off >>= 1) d += __shfl_xor(d, off);
    float acc = 0.f;
    for (int s = 0; s < NS; ++s) {
        float w = __shfl(e_s, s);
        acc += w * Opart[(((size_t)bh * NS + s) * U + t) * 64 + lane];
    }
    updbuf[((size_t)bh * U + t) * E + lane] = acc / d;
}

// -------- h = LayerNorm(h + a) * g + b, one wave per row, dual write f32+bf16 -------
__global__ __launch_bounds__(64) void add_ln_kernel(float* __restrict__ h,
                                                    const float* __restrict__ a,
                                                    const float* __restrict__ g,
                                                    const float* __restrict__ bb,
                                                    __hip_bfloat16* __restrict__ hbf) {
    int row = blockIdx.x;
    int lane = threadIdx.x;
    float* hp = h + (size_t)row * D;
    const float* ap = a + (size_t)row * D;
    float x[8];
    float sum = 0.f;
#pragma unroll
    for (int j = 0; j < 8; ++j) {
        x[j] = hp[lane + 64 * j] + ap[lane + 64 * j];
        sum += x[j];
    }
    for (int off = 32; off; off >>= 1) sum += __shfl_xor(sum, off);
    float mu = sum / (float)D;
    float vs = 0.f;
#pragma unroll
    for (int j = 0; j < 8; ++j) {
        float dd = x[j] - mu;
        vs += dd * dd;
    }
    for (int off = 32; off; off >>= 1) vs += __shfl_xor(vs, off);
    float inv = 1.f / sqrtf(vs / (float)D + EPSL);
#pragma unroll
    for (int j = 0; j < 8; ++j) {
        float o = (x[j] - mu) * inv * g[lane + 64 * j] + bb[lane + 64 * j];
        hp[lane + 64 * j] = o;
        hbf[(size_t)row * D + lane + 64 * j] = __float2bfloat16(o);
    }
}

// ---------------- final head ----------------
__global__ void final_kernel(const float* __restrict__ h, const float* __restrict__ Wf,
                             const float* __restrict__ bf, float* __restrict__ out) {
    int b = blockIdx.x;
    int lane = threadIdx.x;
    const float* hp = h + (size_t)b * LSEQ * D;
    float acc = 0.f;
    for (int j = lane; j < D; j += 64) acc += hp[j] * Wf[j];
    for (int off = 32; off; off >>= 1) acc += __shfl_xor(acc, off);
    if (lane == 0) out[b] = acc + bf[0];
}

extern "C" void kernel_launch(void* const* d_in, const int* in_sizes, int n_in,
                              void* d_out, int out_size, void* d_ws, size_t ws_size,
                              hipStream_t stream) {
    (void)in_sizes; (void)n_in; (void)out_size; (void)ws_size;
    const float* x   = (const float*)d_in[0];
    const float* We  = (const float*)d_in[1];
    const float* be  = (const float*)d_in[2];
    const float* cls = (const float*)d_in[3];
    const float* Wq  = (const float*)d_in[4];
    const float* bq  = (const float*)d_in[5];
    const float* Wk  = (const float*)d_in[6];
    const float* bk  = (const float*)d_in[7];
    const float* Wv  = (const float*)d_in[8];
    const float* bv  = (const float*)d_in[9];
    const float* Wo  = (const float*)d_in[10];
    const float* bo  = (const float*)d_in[11];
    const float* g1  = (const float*)d_in[12];
    const float* b1  = (const float*)d_in[13];
    const float* g2  = (const float*)d_in[14];
    const float* b2  = (const float*)d_in[15];
    const float* W1  = (const float*)d_in[16];
    const float* bf1 = (const float*)d_in[17];
    const float* W2  = (const float*)d_in[18];
    const float* bf2 = (const float*)d_in[19];
    const float* Wf  = (const float*)d_in[20];
    const float* bff = (const float*)d_in[21];
    float* out = (float*)d_out;

    float* ws = (float*)d_ws;
    const size_t NT = (size_t)B * LSEQ * D;  // 4,194,304
    float* h    = ws;                         // [0, NT)
    float* aout = ws + NT;                    // [NT, 2NT)
    float* q    = ws + 2 * NT;                // [2NT, 3NT)
    __hip_bfloat16* kbf    = (__hip_bfloat16*)(ws + NT);      // overlays aout
    __hip_bfloat16* y1_bf  = (__hip_bfloat16*)(ws + 2 * NT);  // overlays q post-attn
    __hip_bfloat16* v_bf   = (__hip_bfloat16*)(ws + 4 * NT);
    __hip_bfloat16* h_bf   = (__hip_bfloat16*)(ws + 5 * NT);
    float* Opart = ws + 3 * NT;
    float* msumb = Opart + (size_t)B * H * NS * U * 64;
    float* wpool = ws + 5 * NT + NT / 2;
    __hip_bfloat16* wqb = (__hip_bfloat16*)wpool;   // wq|wk|wv contiguous = packed QKV
    __hip_bfloat16* wkb = wqb + (size_t)D * D;
    __hip_bfloat16* wvb = wkb + (size_t)D * D;
    __hip_bfloat16* wob = wvb + (size_t)D * D;
    __hip_bfloat16* w1b = wob + (size_t)D * D;
    __hip_bfloat16* w2b = w1b + (size_t)DFF * D;
    float* after_w = wpool + ((size_t)4 * D * D + 2 * (size_t)DFF * D) / 2;
    float* Mbuf = after_w;
    int* idx    = (int*)(Mbuf + (size_t)B * H * LSEQ);
    int* top    = idx + LU;
    float* vm   = (float*)(top + B * H * U);
    float* vpart  = vm + (size_t)B * H * E;
    float* updbuf = vpart + (size_t)128 * 64;
    float* baseb  = updbuf + (size_t)B * H * U * 64;
    __hip_bfloat16* xbf  = (__hip_bfloat16*)(baseb + (size_t)B * D);   // B*LSEQ*F_IN
    __hip_bfloat16* webf = xbf + (size_t)B * LSEQ * F_IN;              // D*F_IN
    unsigned long long* cand =
        (unsigned long long*)(((uintptr_t)(webf + (size_t)D * F_IN) + 7) & ~(uintptr_t)7);
    float* qkvbias = (float*)(cand + (size_t)B * H * 16 * U);          // 1536 floats

    const int ML = B * LSEQ;  // 8192
    dim3 gD(D / 128, ML / 128);
    const int CAST_N = 4 * (D * D / 4) + 2 * (DFF * D / 4);  // 786432
    const int CAST_TOT = CAST_N + 384;                       // + packed qkv bias

    // ---- embed as MFMA GEMM + posenc ----
    prep_embed_kernel<<<(B * LSEQ * F_IN / 4 + D * F_IN / 4 + 255) / 256, 256, 0, stream>>>(
        x, We, xbf, webf);
    gemm32<<<gD, 256, 0, stream>>>((const unsigned short*)xbf,
                                   (const unsigned short*)webf, be, aout, ML, D, F_IN);
    posenc_kernel<<<(B * LSEQ * D + 255) / 256, 256, 0, stream>>>(aout, cls, h, h_bf);

    for (int l = 0; l < NL; ++l) {
        cast_weights_kernel<<<(CAST_TOT + 255) / 256, 256, 0, stream>>>(
            Wq + (size_t)l * D * D, Wk + (size_t)l * D * D, Wv + (size_t)l * D * D,
            Wo + (size_t)l * D * D, W1 + (size_t)l * DFF * D, W2 + (size_t)l * D * DFF,
            bq + l * D, bk + l * D, bv + l * D,
            wqb, wkb, wvb, wob, w1b, w2b, qkvbias);

        // fused QKV GEMM: N=1536, 768 blocks, pipelined + XCD-swizzled (NBN=12)
        gemm_pipe<3><<<768, 256, 0, stream>>>((const unsigned short*)h_bf,
                                              (const unsigned short*)wqb, qkvbias,
                                              q, kbf, v_bf, ML, 3 * D, D, 12);

        idx_kernel<<<(HALF_LU + 255) / 256, 256, 0, stream>>>(idx, l);
        mscore_kernel<<<B * LSEQ, 256, 0, stream>>>(q, kbf, idx, Mbuf);
        topk_chunk_kernel<<<B * H * 16, 256, 0, stream>>>(Mbuf, cand);
        topk_merge_kernel<<<B * H, 256, 0, stream>>>(cand, top);
        vmean_part<<<B * H * 8, 256, 0, stream>>>(v_bf, vpart);
        vmean_reduce<<<4, 256, 0, stream>>>(vpart, vm);
        wo_base_kernel<<<B * 128, 256, 0, stream>>>(vm, (const unsigned short*)wob,
                                                    bo + l * D, baseb);
        attn_part<<<dim3(NS, H, B), 256, 0, stream>>>(q, kbf, v_bf, top, Opart, msumb);
        attn_reduce<<<B * H * U, 64, 0, stream>>>(Opart, msumb, updbuf);
        bcast_base<<<(B * LSEQ * D / 4 + 255) / 256, 256, 0, stream>>>(baseb, aout);
        wo_corr_kernel<<<B * H * U, 256, 0, stream>>>(updbuf, vm,
                                                      (const unsigned short*)wob, top, aout);
        add_ln_kernel<<<ML, 64, 0, stream>>>(h, aout, g1 + l * D, b1 + l * D, h_bf);

        // W1: N=2048, 1024 blocks, pipelined + swizzled (NBN=16)
        gemm_pipe<2><<<1024, 256, 0, stream>>>((const unsigned short*)h_bf,
                                               (const unsigned short*)w1b, bf1 + l * DFF,
                                               y1_bf, nullptr, nullptr, ML, DFF, D, 16);
        // W2: 64x128 tile, 512 blocks, non-pipelined + swizzled (NBN=4)
        gemm64_m64<<<512, 256, 0, stream>>>((const unsigned short*)y1_bf,
                                            (const unsigned short*)w2b, bf2 + l * D,
                                            aout, ML, D, DFF, 4);
        add_ln_kernel<<<ML, 64, 0, stream>>>(h, aout, g2 + l * D, b2 + l * D, h_bf);
    }

    final_kernel<<<B, 64, 0, stream>>>(h, Wf, bff, out);
}